// Round 10
// baseline (1420.355 us; speedup 1.0000x reference)
//
#include <hip/hip_runtime.h>
#include <cstdint>

static constexpr int B2 = 2;
static constexpr int C = 512;
static constexpr int N = 4096;
static constexpr long CN = (long)C * N;
static constexpr long NC = (long)N * C;
static constexpr long CC = (long)C * C;
static constexpr long NN = (long)N * N;
static constexpr long NL = (long)N * 1536;   // K-concat row plane
static constexpr float EPSC = 1e-5f;
static constexpr int KSEL = 308;       // N - int(N*0.925)
static constexpr int NS_ITERS = 4;

typedef __attribute__((ext_vector_type(8))) __bf16 bf16x8;
typedef __attribute__((ext_vector_type(4))) float f32x4;

__device__ __forceinline__ float wredSum(float v){
#pragma unroll
  for (int o = 32; o >= 1; o >>= 1) v += __shfl_xor(v, o, 64);
  return v;
}

__device__ __forceinline__ void gld16(const __bf16* g, __bf16* l){
  __builtin_amdgcn_global_load_lds(
      (const __attribute__((address_space(1))) void*)g,
      (__attribute__((address_space(3))) void*)l, 16, 0, 0);
}

__device__ __forceinline__ void splitw(float v, __bf16* ph, __bf16* pl, long o){
  __bf16 h = (__bf16)v;
  ph[o] = h;
  pl[o] = (__bf16)(v - (float)h);
}

// ======================= split/plain bf16 MFMA GEMM, 128x128 tile, BK=32 =======================
// XCD swizzle; ROWP=1 emits per-(block,row) softmax partials.
// OUTMODE: 0 fp32 | 1 bf16 pair | 2 bf16 high | 3 triple [H|L|H] | 4 triple [H|H|L]
template<int PASSES, int TMH, int OUTMODE, int ROWP>
__global__ __launch_bounds__(256) void k_mm(
    const __bf16* __restrict__ Ah, const __bf16* __restrict__ Al,
    const __bf16* __restrict__ Bh, const __bf16* __restrict__ Bl,
    float* __restrict__ Cf, __bf16* __restrict__ Coh, __bf16* __restrict__ Col,
    int Nn, int K, int ldC, long sAz, long sBz, long sCz,
    float alpha, const float* __restrict__ alpha_ptr,
    const float* __restrict__ brow, long sBr,
    const float* __restrict__ bcol, long sBc,
    const float* __restrict__ c0p,
    const float* __restrict__ addsrc, long sAddz,
    float* __restrict__ Pm, float* __restrict__ Ps)
{
  constexpr int NB = (PASSES == 3) ? 4 : 2;
  constexpr int SB = (PASSES == 3) ? 2 : 1;
  __shared__ __align__(16) __bf16 sm[NB][128 * 32];
  __shared__ float pmx[2][128], psx[2][128];
  const int z = blockIdx.z;
  const int nwx = gridDim.x;
  int lin = blockIdx.y * nwx + blockIdx.x;
  const int nwg = nwx * gridDim.y;
  if ((nwg & 7) == 0){
    const int cpx = nwg >> 3;
    lin = (lin & 7) * cpx + (lin >> 3);
  }
  const int i0 = (lin % nwx) * 128;
  const int j0 = (lin / nwx) * 128;
  const int tid = threadIdx.x;
  const int lane = tid & 63;
  const int w = tid >> 6;
  const int wr = (w >> 1) * 64, wc = (w & 1) * 64;
  const int lr = lane & 15;
  const int g = lane >> 4;

  const __bf16* pAh = Ah + (long)z * sAz + (long)i0 * K;
  const __bf16* pBh = Bh + (long)z * sBz + (long)j0 * K;
  const __bf16* pAl = (PASSES == 3) ? (Al + (long)z * sAz + (long)i0 * K) : nullptr;
  const __bf16* pBl = (PASSES == 3) ? (Bl + (long)z * sBz + (long)j0 * K) : nullptr;

  f32x4 acc[4][4] = {};

  for (int kt = 0; kt < K; kt += 32){
#pragma unroll
    for (int p = 0; p < 2; ++p){
      const int t2 = p * 256 + tid;
      const int row = t2 >> 2;
      const int gs = (t2 & 3) ^ ((row >> 1) & 3);
      const long go = (long)row * K + kt + gs * 8;
      gld16(pAh + go, &sm[0][t2 * 8]);
      gld16(pBh + go, &sm[SB][t2 * 8]);
      if constexpr (PASSES == 3){
        gld16(pAl + go, &sm[1][t2 * 8]);
        gld16(pBl + go, &sm[3][t2 * 8]);
      }
    }
    __syncthreads();
    bf16x8 fa[4], fal[4], fb[4], fbl[4];
#pragma unroll
    for (int mi = 0; mi < 4; ++mi){
      const int row = wr + mi * 16 + lr;
      const int off = row * 32 + ((g ^ ((row >> 1) & 3)) * 8);
      fa[mi] = *(const bf16x8*)(&sm[0][off]);
      if constexpr (PASSES == 3) fal[mi] = *(const bf16x8*)(&sm[1][off]);
    }
#pragma unroll
    for (int ni = 0; ni < 4; ++ni){
      const int row = wc + ni * 16 + lr;
      const int off = row * 32 + ((g ^ ((row >> 1) & 3)) * 8);
      fb[ni] = *(const bf16x8*)(&sm[SB][off]);
      if constexpr (PASSES == 3) fbl[ni] = *(const bf16x8*)(&sm[3][off]);
    }
#pragma unroll
    for (int mi = 0; mi < 4; ++mi)
#pragma unroll
      for (int ni = 0; ni < 4; ++ni){
        acc[mi][ni] = __builtin_amdgcn_mfma_f32_16x16x32_bf16(fa[mi], fb[ni], acc[mi][ni], 0, 0, 0);
        if constexpr (PASSES == 3){
          acc[mi][ni] = __builtin_amdgcn_mfma_f32_16x16x32_bf16(fa[mi],  fbl[ni], acc[mi][ni], 0, 0, 0);
          acc[mi][ni] = __builtin_amdgcn_mfma_f32_16x16x32_bf16(fal[mi], fb[ni],  acc[mi][ni], 0, 0, 0);
        }
      }
    __syncthreads();
  }

  float al2 = alpha;
  if (alpha_ptr) al2 *= alpha_ptr[z];
  const float c0v = c0p ? c0p[z] : 0.f;
#pragma unroll
  for (int mi = 0; mi < 4; ++mi){
    float mrow[4] = {-3.4e38f, -3.4e38f, -3.4e38f, -3.4e38f};
    float srow[4] = {0.f, 0.f, 0.f, 0.f};
#pragma unroll
    for (int ni = 0; ni < 4; ++ni){
      const int col = j0 + wc + ni * 16 + lr;
      const float bc = (bcol ? bcol[z * sBc + col] : 0.f) + c0v;
#pragma unroll
      for (int j = 0; j < 4; ++j){
        const int row = i0 + wr + mi * 16 + g * 4 + j;
        float v = acc[mi][ni][j] * al2;
        if (TMH) v = (((row == col) ? 3.f : 0.f) - v) * 0.5f;
        if (brow) v += brow[z * sBr + row];
        v += bc;
        if (addsrc) v += addsrc[(long)z * sAddz + (long)row * Nn + col];
        const long o = (long)z * sCz + (long)row * ldC + col;
        if (OUTMODE == 0){ Cf[o] = v; }
        else if (OUTMODE == 1){ __bf16 h = (__bf16)v; Coh[o] = h; Col[o] = (__bf16)(v - (float)h); }
        else if (OUTMODE == 2){ Coh[o] = (__bf16)v; }
        else if (OUTMODE == 3){ __bf16 h = (__bf16)v; Coh[o] = h; Coh[o + 512] = (__bf16)(v - (float)h); Coh[o + 1024] = h; }
        else { __bf16 h = (__bf16)v; Coh[o] = h; Coh[o + 512] = h; Coh[o + 1024] = (__bf16)(v - (float)h); }
        if constexpr (ROWP){
          if (v > mrow[j]){ srow[j] *= __expf(mrow[j] - v); mrow[j] = v; }
          srow[j] += __expf(v - mrow[j]);
        }
      }
    }
    if constexpr (ROWP){
#pragma unroll
      for (int j = 0; j < 4; ++j){
        float m = mrow[j], s = srow[j];
#pragma unroll
        for (int o = 1; o <= 8; o <<= 1){
          const float mo = __shfl_xor(m, o, 64);
          const float so = __shfl_xor(s, o, 64);
          const float nm = fmaxf(m, mo);
          s = s * __expf(m - nm) + so * __expf(mo - nm);
          m = nm;
        }
        if (lr == 0){
          const int rl = wr + mi * 16 + g * 4 + j;
          pmx[w & 1][rl] = m;
          psx[w & 1][rl] = s;
        }
      }
    }
  }
  if constexpr (ROWP){
    __syncthreads();
    if (tid < 128){
      const float m0 = pmx[0][tid], s0 = psx[0][tid];
      const float m1 = pmx[1][tid], s1 = psx[1][tid];
      const float nm = fmaxf(m0, m1);
      const float s = s0 * __expf(m0 - nm) + s1 * __expf(m1 - nm);
      Pm[(long)(j0 >> 7) * N + i0 + tid] = nm;
      Ps[(long)(j0 >> 7) * N + i0 + tid] = s;
    }
  }
}

// ======================= split-bf16 MFMA GEMM, 64x64 tile, BK=64 (always 3-pass) =======================
template<int TMH, int OUTMODE, int NSYZ>
__global__ __launch_bounds__(256) void k_mm64(
    const __bf16* __restrict__ Ah, const __bf16* __restrict__ Al,
    const __bf16* __restrict__ Bh, const __bf16* __restrict__ Bl,
    const __bf16* __restrict__ tH, const __bf16* __restrict__ tL,
    float* __restrict__ Cf, __bf16* __restrict__ Coh, __bf16* __restrict__ Col,
    int Nn, int K, long sAz, long sBz, long sCz, float alpha)
{
  __shared__ __align__(16) __bf16 sm[4][64 * 64];
  const int z = blockIdx.z;
  const __bf16 *bAh, *bAl, *bBh, *bBl;
  long oC;
  if constexpr (NSYZ){
    if (z < 4){
      bAh = Ah + (long)z * CC; bAl = Al + (long)z * CC;
      bBh = tH + (long)z * CC; bBl = tL + (long)z * CC;
      oC = (long)z * CC;
    } else {
      const int zz = z - 4;
      bAh = tH + (long)zz * CC; bAl = tL + (long)zz * CC;
      bBh = Ah + (long)(4 + zz) * CC; bBl = Al + (long)(4 + zz) * CC;
      oC = (long)(4 + zz) * CC;
    }
  } else {
    bAh = Ah + (long)z * sAz; bAl = Al + (long)z * sAz;
    bBh = Bh + (long)z * sBz; bBl = Bl + (long)z * sBz;
    oC = (long)z * sCz;
  }
  const int i0 = blockIdx.x * 64;
  const int j0 = blockIdx.y * 64;
  const int tid = threadIdx.x;
  const int lane = tid & 63;
  const int w = tid >> 6;
  const int wr = (w >> 1) * 32, wc = (w & 1) * 32;
  const int lr = lane & 15;
  const int g = lane >> 4;

  const __bf16* pAh = bAh + (long)i0 * K;
  const __bf16* pAl = bAl + (long)i0 * K;
  const __bf16* pBh = bBh + (long)j0 * K;
  const __bf16* pBl = bBl + (long)j0 * K;

  f32x4 acc[2][2] = {};

  for (int kt = 0; kt < K; kt += 64){
#pragma unroll
    for (int p = 0; p < 2; ++p){
      const int t2 = p * 256 + tid;
      const int row = t2 >> 3;
      const int gs = (t2 & 7) ^ (row & 7);
      const long go = (long)row * K + kt + gs * 8;
      gld16(pAh + go, &sm[0][t2 * 8]);
      gld16(pAl + go, &sm[1][t2 * 8]);
      gld16(pBh + go, &sm[2][t2 * 8]);
      gld16(pBl + go, &sm[3][t2 * 8]);
    }
    __syncthreads();
#pragma unroll
    for (int ks = 0; ks < 2; ++ks){
      bf16x8 fa[2], fal[2], fb[2], fbl[2];
#pragma unroll
      for (int mi = 0; mi < 2; ++mi){
        const int row = wr + mi * 16 + lr;
        const int off = row * 64 + (((ks * 4 + g) ^ (row & 7)) * 8);
        fa[mi]  = *(const bf16x8*)(&sm[0][off]);
        fal[mi] = *(const bf16x8*)(&sm[1][off]);
      }
#pragma unroll
      for (int ni = 0; ni < 2; ++ni){
        const int row = wc + ni * 16 + lr;
        const int off = row * 64 + (((ks * 4 + g) ^ (row & 7)) * 8);
        fb[ni]  = *(const bf16x8*)(&sm[2][off]);
        fbl[ni] = *(const bf16x8*)(&sm[3][off]);
      }
#pragma unroll
      for (int mi = 0; mi < 2; ++mi)
#pragma unroll
        for (int ni = 0; ni < 2; ++ni){
          acc[mi][ni] = __builtin_amdgcn_mfma_f32_16x16x32_bf16(fa[mi],  fb[ni],  acc[mi][ni], 0, 0, 0);
          acc[mi][ni] = __builtin_amdgcn_mfma_f32_16x16x32_bf16(fa[mi],  fbl[ni], acc[mi][ni], 0, 0, 0);
          acc[mi][ni] = __builtin_amdgcn_mfma_f32_16x16x32_bf16(fal[mi], fb[ni],  acc[mi][ni], 0, 0, 0);
        }
    }
    __syncthreads();
  }

#pragma unroll
  for (int mi = 0; mi < 2; ++mi){
#pragma unroll
    for (int ni = 0; ni < 2; ++ni){
      const int col = j0 + wc + ni * 16 + lr;
#pragma unroll
      for (int j = 0; j < 4; ++j){
        const int row = i0 + wr + mi * 16 + g * 4 + j;
        float v = acc[mi][ni][j] * alpha;
        if (TMH) v = (((row == col) ? 3.f : 0.f) - v) * 0.5f;
        const long o = oC + (long)row * Nn + col;
        if (OUTMODE == 0){ Cf[o] = v; }
        else { __bf16 h = (__bf16)v; Coh[o] = h; Col[o] = (__bf16)(v - (float)h); }
      }
    }
  }
}

// ======================= fused corr+PV (bf16 E) =======================
__global__ __launch_bounds__(256) void k_pv(
    const __bf16* __restrict__ E, const __bf16* __restrict__ Bh,
    const float* __restrict__ rm, const float* __restrict__ rsc,
    const float* __restrict__ mxv, const float* __restrict__ myv,
    __bf16* __restrict__ resH)
{
  __shared__ __align__(16) __bf16 sa[64 * 64];
  __shared__ __align__(16) __bf16 sb[128 * 64];
  const int z = blockIdx.z;
  int lin = blockIdx.y * 64 + blockIdx.x;
  lin = (lin & 7) * 32 + (lin >> 3);
  const int n0 = (lin & 63) * 64;
  const int c0 = (lin >> 6) * 128;
  const int tid = threadIdx.x;
  const int lane = tid & 63;
  const int w = tid >> 6;
  const int wr = (w >> 1) * 32, wc = (w & 1) * 64;
  const int lr = lane & 15, g = lane >> 4;

  const __bf16* pe = E + (long)z * NN + (long)n0 * N;
  const __bf16* pB = Bh + (long)z * CN + (long)c0 * N;

  const int ar = tid >> 2;
  const int slot = tid & 3;
  const float rmv = rm[(long)z * N + n0 + ar];
  const float rsv = rsc[(long)z * N + n0 + ar];
  const float tgt = mxv[n0 + ar];
  const __bf16* per = pe + (long)ar * N;

  f32x4 acc[2][4] = {};

  for (int kt = 0; kt < N; kt += 64){
#pragma unroll
    for (int d = 0; d < 2; ++d){
      const int gd = slot * 2 + d;
      const bf16x8 ev = *(const bf16x8*)(per + kt + gd * 8);
      const float4 m0 = *(const float4*)(myv + kt + gd * 8);
      const float4 m1 = *(const float4*)(myv + kt + gd * 8 + 4);
      bf16x8 pk;
      pk[0] = (__bf16)((m0.x == tgt) ? __expf((float)ev[0] - rmv) * rsv : 0.f);
      pk[1] = (__bf16)((m0.y == tgt) ? __expf((float)ev[1] - rmv) * rsv : 0.f);
      pk[2] = (__bf16)((m0.z == tgt) ? __expf((float)ev[2] - rmv) * rsv : 0.f);
      pk[3] = (__bf16)((m0.w == tgt) ? __expf((float)ev[3] - rmv) * rsv : 0.f);
      pk[4] = (__bf16)((m1.x == tgt) ? __expf((float)ev[4] - rmv) * rsv : 0.f);
      pk[5] = (__bf16)((m1.y == tgt) ? __expf((float)ev[5] - rmv) * rsv : 0.f);
      pk[6] = (__bf16)((m1.z == tgt) ? __expf((float)ev[6] - rmv) * rsv : 0.f);
      pk[7] = (__bf16)((m1.w == tgt) ? __expf((float)ev[7] - rmv) * rsv : 0.f);
      *(bf16x8*)(&sa[ar * 64 + ((gd ^ (ar & 7)) * 8)]) = pk;
    }
#pragma unroll
    for (int p = 0; p < 4; ++p){
      const int t2 = p * 256 + tid;
      const int row = t2 >> 3;
      const int gs = (t2 & 7) ^ (row & 7);
      gld16(pB + (long)row * N + kt + gs * 8, &sb[t2 * 8]);
    }
    __syncthreads();
#pragma unroll
    for (int ks = 0; ks < 2; ++ks){
      bf16x8 fa[2], fb[4];
#pragma unroll
      for (int mi = 0; mi < 2; ++mi){
        const int row = wr + mi * 16 + lr;
        fa[mi] = *(const bf16x8*)(&sa[row * 64 + (((ks * 4 + g) ^ (row & 7)) * 8)]);
      }
#pragma unroll
      for (int ni = 0; ni < 4; ++ni){
        const int row = wc + ni * 16 + lr;
        fb[ni] = *(const bf16x8*)(&sb[row * 64 + (((ks * 4 + g) ^ (row & 7)) * 8)]);
      }
#pragma unroll
      for (int mi = 0; mi < 2; ++mi)
#pragma unroll
        for (int ni = 0; ni < 4; ++ni)
          acc[mi][ni] = __builtin_amdgcn_mfma_f32_16x16x32_bf16(fa[mi], fb[ni], acc[mi][ni], 0, 0, 0);
    }
    __syncthreads();
  }
#pragma unroll
  for (int mi = 0; mi < 2; ++mi)
#pragma unroll
    for (int ni = 0; ni < 4; ++ni){
      const int c = c0 + wc + ni * 16 + lr;
#pragma unroll
      for (int j = 0; j < 4; ++j){
        const int n = n0 + wr + mi * 16 + g * 4 + j;
        resH[(long)z * NC + (long)n * C + c] = (__bf16)acc[mi][ni][j];
      }
    }
}

// ======================= small helpers =======================
__global__ __launch_bounds__(256) void k_wtw(const float* __restrict__ A, const float* __restrict__ B,
                                             float* __restrict__ C2, float alpha){
  __shared__ float sa[16][32], sb[16][32];
  const int i0 = blockIdx.x * 32, j0 = blockIdx.y * 32;
  const int t = threadIdx.x;
  const int ti = t & 15, tj = t >> 4;
  const int li = t & 31, lc = t >> 5;
  float acc[2][2] = {};
  for (int cb = 0; cb < C; cb += 16){
    sa[lc][li]     = A[(long)(cb + lc) * C + i0 + li];
    sa[lc + 8][li] = A[(long)(cb + lc + 8) * C + i0 + li];
    sb[lc][li]     = B[(long)(cb + lc) * C + j0 + li];
    sb[lc + 8][li] = B[(long)(cb + lc + 8) * C + j0 + li];
    __syncthreads();
#pragma unroll
    for (int c = 0; c < 16; ++c){
      const float a0 = sa[c][ti * 2], a1 = sa[c][ti * 2 + 1];
      const float b0 = sb[c][tj * 2], b1 = sb[c][tj * 2 + 1];
      acc[0][0] = fmaf(a0, b0, acc[0][0]); acc[0][1] = fmaf(a0, b1, acc[0][1]);
      acc[1][0] = fmaf(a1, b0, acc[1][0]); acc[1][1] = fmaf(a1, b1, acc[1][1]);
    }
    __syncthreads();
  }
#pragma unroll
  for (int r = 0; r < 2; ++r)
#pragma unroll
    for (int s = 0; s < 2; ++s)
      C2[(long)(i0 + ti * 2 + r) * C + j0 + tj * 2 + s] = acc[r][s] * alpha;
}

__global__ __launch_bounds__(256) void k_wtv(const float* __restrict__ W, const float* __restrict__ b,
                                             float* __restrict__ u){
  __shared__ float sb2[C];
  const int t = threadIdx.x;
  sb2[t] = b[t]; sb2[t + 256] = b[t + 256];
  __syncthreads();
  const int e = blockIdx.x * 256 + t;
  float acc = 0.f;
  for (int c = 0; c < C; ++c) acc = fmaf(W[(long)c * C + e], sb2[c], acc);
  u[e] = acc;
}

__global__ void k_dot2(const float* __restrict__ a1, const float* __restrict__ b1,
                       const float* __restrict__ a2, const float* __restrict__ b2,
                       float* __restrict__ c0m2, float* __restrict__ c0s4){
  const int t = threadIdx.x;
  float s1 = 0.f, s2 = 0.f;
  for (int i = t; i < C; i += 256){ s1 += a1[i] * b1[i]; s2 += a2[i] * b2[i]; }
  __shared__ float sh1[4], sh2[4];
  s1 = wredSum(s1); s2 = wredSum(s2);
  if ((t & 63) == 0){ sh1[t >> 6] = s1; sh2[t >> 6] = s2; }
  __syncthreads();
  if (t == 0){
    float d1 = sh1[0] + sh1[1] + sh1[2] + sh1[3];
    float d2 = sh2[0] + sh2[1] + sh2[2] + sh2[3];
    c0m2[0] = d1; c0m2[1] = d1;
    c0s4[0] = d2; c0s4[1] = d2; c0s4[2] = d2; c0s4[3] = d2;
  }
}

// out[z][n] = sum_d X[z*sz + n*ld + d]*u[d]
__global__ __launch_bounds__(256) void k_pixvec(const __bf16* __restrict__ X, const float* __restrict__ u,
                                                float* __restrict__ out, long sz, int ld){
  const int z = blockIdx.y;
  const int wv = threadIdx.x >> 6, lane = threadIdx.x & 63;
  const int n = blockIdx.x * 4 + wv;
  float acc = 0.f;
  for (int d = lane; d < C; d += 64) acc += (float)X[(long)z * sz + (long)n * ld + d] * u[d];
  acc = wredSum(acc);
  if (lane == 0) out[(long)z * N + n] = acc;
}

// ======================= prep / stats =======================
__global__ __launch_bounds__(256) void k_stats(const float* __restrict__ x, const float* __restrict__ y,
                                               float* __restrict__ meanv, float* __restrict__ invs){
  const int bid = blockIdx.x;
  const int t = bid >> 9, c = bid & 511;
  const float* src = (t < 2 ? x : y) + (long)(t & 1) * CN + (long)c * N;
  const int tid = threadIdx.x;
  float s1 = 0.f, s2 = 0.f;
  for (int i = tid; i < N; i += 256){ float v = src[i]; s1 += v; s2 += v * v; }
  __shared__ float sh1[4], sh2[4];
  s1 = wredSum(s1); s2 = wredSum(s2);
  if ((tid & 63) == 0){ sh1[tid >> 6] = s1; sh2[tid >> 6] = s2; }
  __syncthreads();
  if (tid == 0){
    float m = (sh1[0] + sh1[1] + sh1[2] + sh1[3]) * (1.f / (float)N);
    float ex2 = (sh2[0] + sh2[1] + sh2[2] + sh2[3]) * (1.f / (float)N);
    float var = ex2 - m * m;
    meanv[t * C + c] = m;
    invs[t * C + c] = rsqrtf((var > 0.f ? var : 0.f) + EPSC);
  }
}

__global__ __launch_bounds__(256) void k_prep(const float* __restrict__ src,
                                              const float* __restrict__ meanv, const float* __restrict__ invs, int toff,
                                              __bf16* __restrict__ adH,
                                              __bf16* __restrict__ fcH, __bf16* __restrict__ fcL,
                                              __bf16* __restrict__ ccH, __bf16* __restrict__ ccL,
                                              __bf16* __restrict__ rwH){
  __shared__ float tile[64][65];
  const int z = blockIdx.z;
  const int n0 = blockIdx.x * 64;
  const int c0 = blockIdx.y * 64;
  const int tid = threadIdx.x;
  const int tx = tid & 63, ty = tid >> 6;
  const int tgt = toff + z;
#pragma unroll
  for (int it = 0; it < 16; ++it){
    const int cc = it * 4 + ty;
    const float v = src[(long)z * CN + (long)(c0 + cc) * N + n0 + tx];
    tile[cc][tx] = v;
    const float cen = v - meanv[tgt * C + c0 + cc];
    splitw(cen, ccH, ccL, (long)tgt * CN + (long)(c0 + cc) * N + n0 + tx);
  }
  __syncthreads();
  const float m = meanv[tgt * C + c0 + tx];
  const float r = invs[tgt * C + c0 + tx];
#pragma unroll
  for (int it = 0; it < 16; ++it){
    const int p = it * 4 + ty;
    const float v = tile[tx][p];
    const float cen = v - m;
    const long o = (long)z * NC + (long)(n0 + p) * C + c0 + tx;
    adH[o] = (__bf16)(cen * r);
    splitw(cen, fcH, fcL, (long)tgt * NC + (long)(n0 + p) * C + c0 + tx);
    if (rwH) rwH[o] = (__bf16)v;
  }
}

__global__ __launch_bounds__(256) void k_wcvt_h(const float* __restrict__ s, __bf16* __restrict__ h, int n){
  int i = blockIdx.x * 256 + threadIdx.x;
  if (i < n) h[i] = (__bf16)s[i];
}

// [C][C] fp32 -> [C][1536] bf16 slabs [H|H|L]
__global__ __launch_bounds__(256) void k_wcvt3(const float* __restrict__ s, __bf16* __restrict__ o3){
  const int i = blockIdx.x * 256 + threadIdx.x;
  if (i < (int)CC){
    const int r = i >> 9, c = i & 511;
    const float v = s[i];
    const __bf16 h = (__bf16)v;
    const long base = (long)r * 1536 + c;
    o3[base] = h;
    o3[base + 512] = h;
    o3[base + 1024] = (__bf16)(v - (float)h);
  }
}

// ======================= cov diag / power iteration / NS init =======================
__global__ void k_diag(float* __restrict__ cov){
  const int z = blockIdx.x, t = threadIdx.x;
  for (int i = t; i < C; i += 256) cov[(long)z * CC + (long)i * C + i] += 2.f * EPSC;
}

__global__ __launch_bounds__(256) void k_powit(const float* __restrict__ cov,
                                               float* __restrict__ invt, float* __restrict__ invsqt){
  __shared__ float v[C], red[4];
  const int z = blockIdx.x, t = threadIdx.x;
  const float* A = cov + (long)z * CC;
  const int j0 = t, j1 = t + 256;
  v[j0] = 1.f + 0.0003f * (float)j0;
  v[j1] = 1.f + 0.0003f * (float)j1;
  __syncthreads();
  float lam = 1.f;
  for (int it = 0; it < 4; ++it){
    float w0a = 0.f, w0b = 0.f, w1a = 0.f, w1b = 0.f;
#pragma unroll 8
    for (int c = 0; c < C; c += 2){
      const float vc0 = v[c], vc1 = v[c + 1];
      w0a = fmaf(A[(long)c * C + j0], vc0, w0a);
      w1a = fmaf(A[(long)c * C + j1], vc0, w1a);
      w0b = fmaf(A[(long)(c + 1) * C + j0], vc1, w0b);
      w1b = fmaf(A[(long)(c + 1) * C + j1], vc1, w1b);
    }
    const float w0 = w0a + w0b, w1 = w1a + w1b;
    float s = w0 * w0 + w1 * w1;
    s = wredSum(s);
    if ((t & 63) == 0) red[t >> 6] = s;
    __syncthreads();
    const float nrm = sqrtf(red[0] + red[1] + red[2] + red[3]);
    lam = nrm;
    const float inv = 1.f / nrm;
    v[j0] = w0 * inv;
    v[j1] = w1 * inv;
    __syncthreads();
  }
  if (t == 0){
    const float tt = 1.02f * lam;
    invt[z] = 1.f / tt;
    invsqt[z] = rsqrtf(tt);
  }
}

__global__ __launch_bounds__(256) void k_ns_init(const float* __restrict__ cov, const float* __restrict__ invt,
                                                 __bf16* __restrict__ h, __bf16* __restrict__ l,
                                                 __bf16* __restrict__ cph, __bf16* __restrict__ cpl){
  const int r = blockIdx.x, z = blockIdx.y;
  const long base = (long)z * CC + (long)r * C;
  const float it = invt[z];
  for (int i = threadIdx.x; i < C; i += 256){
    const float v = cov[base + i] * it;
    splitw(v, h, l, base + i);
    splitw(v, cph, cpl, base + i);
    h[4 * CC + base + i] = (__bf16)((i == r) ? 1.f : 0.f);
    l[4 * CC + base + i] = (__bf16)0.f;
  }
}

// ======================= self-path softmax aux =======================
__global__ __launch_bounds__(256) void k_prowmerge(const float* __restrict__ Pm, const float* __restrict__ Ps,
                                                   float* __restrict__ rm, float* __restrict__ rsc){
  const int row = blockIdx.x * 256 + threadIdx.x;
  float m = -3.4e38f, s = 0.f;
#pragma unroll 4
  for (int p = 0; p < 32; ++p){
    const float mp = Pm[(long)p * N + row];
    const float sp = Ps[(long)p * N + row];
    const float nm = fmaxf(m, mp);
    s = s * __expf(m - nm) + sp * __expf(mp - nm);
    m = nm;
  }
  rm[row] = m;
  rsc[row] = 1.f / s;
}

__global__ __launch_bounds__(256) void k_colaccum(const float* __restrict__ E, const float* __restrict__ rowmax,
                                                  const float* __restrict__ rowscale, float* __restrict__ partials){
  const int j = (blockIdx.x * 256 + threadIdx.x) * 4;
  const int r0 = blockIdx.y * 128;
  float4 acc = {0.f, 0.f, 0.f, 0.f};
  for (int r2 = r0; r2 < r0 + 128; ++r2){
    const float4 e = *reinterpret_cast<const float4*>(E + (long)r2 * N + j);
    const float rmv = rowmax[r2], rsv = rowscale[r2];
    acc.x += __expf(e.x - rmv) * rsv;
    acc.y += __expf(e.y - rmv) * rsv;
    acc.z += __expf(e.z - rmv) * rsv;
    acc.w += __expf(e.w - rmv) * rsv;
  }
  *reinterpret_cast<float4*>(partials + (long)blockIdx.y * N + j) = acc;
}

__global__ __launch_bounds__(256) void k_colreduce(const float* __restrict__ partials, float* __restrict__ att){
  const int j = blockIdx.x * 256 + threadIdx.x;
  float s = 0.f;
#pragma unroll 4
  for (int p = 0; p < 32; ++p) s += partials[(long)p * N + j];
  att[j] = s * (1.f / (float)N);
}

// ======================= main-path masked row stats (bf16 E) =======================
__global__ __launch_bounds__(256) void k_rowstats1(
    const __bf16* __restrict__ E, const float* __restrict__ mx, const float* __restrict__ my,
    float* __restrict__ rowmax, float* __restrict__ rowscale)
{
  const int zz = blockIdx.y;
  const int r0 = blockIdx.x * 16;
  const int tid = threadIdx.x;
  const int rr = tid >> 4;
  const int l16 = tid & 15;
  const int row = r0 + rr;
  const __bf16* pe = E + (long)zz * NN + (long)row * N;
  const float target = mx[row];
  float m = -3.4e38f, s = 0.f, sm = 0.f;
  for (int i = l16 * 8; i < N; i += 128){
    const bf16x8 ev = *(const bf16x8*)(pe + i);
    const float4 w0 = *(const float4*)(my + i);
    const float4 w1 = *(const float4*)(my + i + 4);
    float e[8];
#pragma unroll
    for (int k = 0; k < 8; ++k) e[k] = (float)ev[k];
    float mv = fmaxf(fmaxf(fmaxf(e[0], e[1]), fmaxf(e[2], e[3])),
                     fmaxf(fmaxf(e[4], e[5]), fmaxf(e[6], e[7])));
    if (mv > m){ const float sc = __expf(m - mv); s *= sc; sm *= sc; m = mv; }
    float x0 = __expf(e[0] - m), x1 = __expf(e[1] - m), x2 = __expf(e[2] - m), x3 = __expf(e[3] - m);
    float x4 = __expf(e[4] - m), x5 = __expf(e[5] - m), x6 = __expf(e[6] - m), x7 = __expf(e[7] - m);
    s += ((x0 + x1) + (x2 + x3)) + ((x4 + x5) + (x6 + x7));
    if (w0.x == target) sm += x0;
    if (w0.y == target) sm += x1;
    if (w0.z == target) sm += x2;
    if (w0.w == target) sm += x3;
    if (w1.x == target) sm += x4;
    if (w1.y == target) sm += x5;
    if (w1.z == target) sm += x6;
    if (w1.w == target) sm += x7;
  }
#pragma unroll
  for (int o = 8; o >= 1; o >>= 1){
    const float mo = __shfl_xor(m, o, 64);
    const float so = __shfl_xor(s, o, 64);
    const float smo = __shfl_xor(sm, o, 64);
    const float nm = fmaxf(m, mo);
    const float sc0 = __expf(m - nm), sc1 = __expf(mo - nm);
    s = s * sc0 + so * sc1;
    sm = sm * sc0 + smo * sc1;
    m = nm;
  }
  if (l16 == 0){
    float l1 = sm / s;
    if (l1 < 1e-12f) l1 = 1e-12f;
    rowscale[(long)zz * N + row] = 1.f / (s * l1);
    rowmax[(long)zz * N + row] = m;
  }
}

// ======================= mask (radix select) =======================
__global__ __launch_bounds__(256) void k_radix(const float* __restrict__ a, float* __restrict__ thr){
  __shared__ unsigned int vals[N];
  __shared__ float shc[4];
  __shared__ unsigned int p_sh;
  __shared__ int k_sh;
  const float* pa = a + (long)blockIdx.x * N;
  const int tid = threadIdx.x;
  for (int i = tid; i < N; i += 256) vals[i] = __float_as_uint(pa[i]);
  if (tid == 0){ p_sh = 0u; k_sh = KSEL; }
  __syncthreads();
  for (int b = 31; b >= 0; --b){
    const unsigned int bit = 1u << b;
    const unsigned int above = (b == 31) ? 0u : ~((bit << 1) - 1u);
    const unsigned int p = p_sh;
    int cnt = 0;
    for (int i = tid; i < N; i += 256){
      unsigned int v = vals[i];
      if ((v & above) == p && (v & bit)) cnt++;
    }
    float cf = wredSum((float)cnt);
    if ((tid & 63) == 0) shc[tid >> 6] = cf;
    __syncthreads();
    if (tid == 0){
      int c1 = (int)(shc[0] + shc[1] + shc[2] + shc[3] + 0.5f);
      if (k_sh <= c1) p_sh = p | bit;
      else k_sh -= c1;
    }
    __syncthreads();
  }
  if (tid == 0) thr[blockIdx.x] = __uint_as_float(p_sh);
}

__global__ __launch_bounds__(256) void k_mask(const float* __restrict__ ax, const float* __restrict__ ay,
                                              const float* __restrict__ thr, float* __restrict__ mx,
                                              float* __restrict__ my){
  int j = blockIdx.x * 256 + threadIdx.x;
  mx[j] = (ax[j] >= thr[0] && ax[N + j] >= thr[1]) ? 1.f : 0.f;
  my[j] = (ay[j] >= thr[2] && ay[N + j] >= thr[3]) ? 1.f : 0.f;
}

// ======================= host =======================
extern "C" void kernel_launch(void* const* d_in, const int* in_sizes, int n_in,
                              void* d_out, int out_size, void* d_ws, size_t ws_size,
                              hipStream_t stream)
{
  const float* x     = (const float*)d_in[0];
  const float* y     = (const float*)d_in[1];
  const float* f_w   = (const float*)d_in[2];
  const float* f_b   = (const float*)d_in[3];
  const float* g_w   = (const float*)d_in[4];
  const float* g_b   = (const float*)d_in[5];
  const float* saf_w = (const float*)d_in[6];
  const float* saf_b = (const float*)d_in[7];
  const float* sag_w = (const float*)d_in[8];
  const float* sag_b = (const float*)d_in[9];
  const float* h_w   = (const float*)d_in[10];
  const float* h_b   = (const float*)d_in[11];
  const float* ow    = (const float*)d_in[12];
  const float* ob    = (const float*)d_in[13];

  const size_t MBy = 1ull << 20;
  const size_t KBy = 1ull << 10;
  char* base = (char*)d_ws;
  if (ws_size < 206 * MBy) return;
  auto F  = [&](size_t off){ return (float*)(base + off); };
  auto Bp = [&](size_t off){ return (__bf16*)(base + off); };

  // ---- [0,64MB): E0 fp32 (self, per-z) / Ebf bf16 [2] (main). Early residents (all dead pre-step-7):
  float *E0 = F(0);
  __bf16 *Ebf = Bp(0);
  __bf16 *ccH = Bp(0), *ccL = Bp(16*MBy);            // die @cov
  float  *covb = F(32*MBy);                          // dies @ns_init
  __bf16 *zpolH = Bp(36*MBy), *zpolL = Bp(38*MBy);   // die @zca
  __bf16 *covPH = Bp(40*MBy), *covPL = Bp(42*MBy);   // die @polish
  float  *KsTf = F(44*MBy), *K2tf = F(45*MBy);
  __bf16 *Ks3 = Bp(46*MBy);                          // [C][1536] HHL, dies @As (1.5MB)
  __bf16 *K2tH = Bp(47*MBy + 512*KBy);               // dies @A2
  __bf16 *hwH = Bp(48*MBy);                          // dies @hconv (0.5MB)
  __bf16 *tpH = Bp(48*MBy + 512*KBy), *tpL = Bp(50*MBy + 512*KBy);  // die @polish
  // ---- [64,112): xa (dies @A2) then xz3 [4][N][1536] (written @zca)
  __bf16 *xaH = Bp(64*MBy);
  __bf16 *xz3 = Bp(64*MBy);
  // ---- [112,160): ypm (dies @hconv), fc pairs (die @zca), then As3 [4][N][1536] (@6.5); resH tail
  __bf16 *ypmH = Bp(112*MBy);
  __bf16 *fcH = Bp(120*MBy), *fcL = Bp(136*MBy);
  __bf16 *As3 = Bp(112*MBy);
  __bf16 *resH = Bp(152*MBy);                        // [2][N][C] (As3 dead by step 9)
  // ---- [160,176): NS ping-pong pairs
  __bf16 *nsAh = Bp(160*MBy), *nsAl = Bp(164*MBy);
  __bf16 *nsBh = Bp(168*MBy), *nsBl = Bp(172*MBy);
  // ---- [176,206): persistent
  __bf16 *A2H = Bp(176*MBy);
  __bf16 *yaH = Bp(184*MBy);
  __bf16 *hH  = Bp(192*MBy);
  __bf16 *owH = Bp(200*MBy);
  size_t so = 200 * MBy + 512 * KBy;
  auto SF = [&](size_t bytes){ float* p = F(so); so += bytes; return p; };
  float *meanv = SF(8*KBy), *invs = SF(8*KBy);
  float *rm = SF(32*KBy), *rsc = SF(32*KBy);
  float *mxv = SF(16*KBy), *myv = SF(16*KBy);
  float *rvec2 = SF(32*KBy), *cvec2 = SF(32*KBy);
  float *rvS = SF(64*KBy), *cvS = SF(64*KBy);
  float *u1m = SF(2*KBy), *u2m = SF(2*KBy), *u1s = SF(2*KBy), *u2s = SF(2*KBy);
  float *c0m2 = SF(64), *c0s4 = SF(64), *thr = SF(64);
  float *invt = SF(64), *invsqt = SF(64);
  float *partials = F(201*MBy);                      // [32][N]
  float *Pm = F(201*MBy + 512*KBy);                  // [32][N]
  float *Ps = F(202*MBy);                            // [32][N]

  float* outm = (float*)d_out;
  float* attx = outm + B2 * CN;
  float* atty = attx + (long)B2 * N;

  // 1) stats + prep
  k_stats<<<dim3(4 * C), dim3(256), 0, stream>>>(x, y, meanv, invs);
  k_prep<<<dim3(64, 8, 2), dim3(256), 0, stream>>>(x, meanv, invs, 0, xaH, fcH, fcL, ccH, ccL, nullptr);
  k_prep<<<dim3(64, 8, 2), dim3(256), 0, stream>>>(y, meanv, invs, 2, yaH, fcH, fcL, ccH, ccL, ypmH);

  // 2) weight products & conversions
  k_wtw<<<dim3(16, 16), dim3(256), 0, stream>>>(sag_w, saf_w, KsTf, 1.f);
  k_wtw<<<dim3(16, 16), dim3(256), 0, stream>>>(g_w, f_w, K2tf, 1.f);
  {
    const int nb = (int)(CC / 256);
    k_wcvt3<<<nb, 256, 0, stream>>>(KsTf, Ks3);
    k_wcvt_h<<<nb, 256, 0, stream>>>(K2tf, K2tH, (int)CC);
    k_wcvt_h<<<nb, 256, 0, stream>>>(h_w, hwH, (int)CC);
    k_wcvt_h<<<nb, 256, 0, stream>>>(ow, owH, (int)CC);
  }
  k_wtv<<<dim3(2), dim3(256), 0, stream>>>(g_w, f_b, u1m);
  k_wtv<<<dim3(2), dim3(256), 0, stream>>>(f_w, g_b, u2m);
  k_wtv<<<dim3(2), dim3(256), 0, stream>>>(sag_w, saf_b, u1s);
  k_wtv<<<dim3(2), dim3(256), 0, stream>>>(saf_w, sag_b, u2s);
  k_dot2<<<dim3(1), dim3(256), 0, stream>>>(f_b, g_b, saf_b, sag_b, c0m2, c0s4);
  k_pixvec<<<dim3(N / 4, 2), dim3(256), 0, stream>>>(xaH, u2m, rvec2, NC, C);
  k_pixvec<<<dim3(N / 4, 2), dim3(256), 0, stream>>>(yaH, u1m, cvec2, NC, C);

  // 3) cov + 2eps*I + power-iteration lambda_max
  k_mm64<0,0,0><<<dim3(8, 8, 4), dim3(256), 0, stream>>>(
      ccH, ccL, ccH, ccL, nullptr, nullptr, covb, nullptr, nullptr, C, N, CN, CN, CC, 1.f / (float)(N - 1));
  k_diag<<<dim3(4), dim3(256), 0, stream>>>(covb);
  k_powit<<<dim3(4), dim3(256), 0, stream>>>(covb, invt, invsqt);

  // 4) A2 = xa . K2^T, h conv
  k_mm<1,0,2,0><<<dim3(32, 4, 2), dim3(256), 0, stream>>>(xaH, nullptr, K2tH, nullptr, nullptr, A2H, nullptr,
      C, C, C, NC, 0, NC, 1.f, nullptr, nullptr, 0, nullptr, 0, nullptr, nullptr, 0, nullptr, nullptr);
  k_mm<1,0,2,0><<<dim3(4, 32, 2), dim3(256), 0, stream>>>(hwH, nullptr, ypmH, nullptr, nullptr, hH, nullptr,
      N, C, N, 0, NC, CN, 1.f, nullptr, h_b, 0, nullptr, 0, nullptr, nullptr, 0, nullptr, nullptr);

  // 5) Newton-Schulz (4 iters) + split-bf16 polish
  k_ns_init<<<dim3(C, 4), dim3(256), 0, stream>>>(covb, invt, nsAh, nsAl, covPH, covPL);
  __bf16 *cah = nsAh, *cal = nsAl, *cbh = nsBh, *cbl = nsBl;
  for (int it = 0; it < NS_ITERS; ++it){
    k_mm64<1,1,0><<<dim3(8, 8, 4), dim3(256), 0, stream>>>(
        cah + 4*CC, cal + 4*CC, cah, cal, nullptr, nullptr, nullptr, tpH, tpL, C, C, CC, CC, CC, 1.f);
    k_mm64<0,1,1><<<dim3(8, 8, 8), dim3(256), 0, stream>>>(
        cah, cal, nullptr, nullptr, tpH, tpL, nullptr, cbh, cbl, C, C, CC, CC, CC, 1.f);
    __bf16* t;
    t = cah; cah = cbh; cbh = t;
    t = cal; cal = cbl; cbl = t;
  }
  k_mm64<0,1,0><<<dim3(8, 8, 4), dim3(256), 0, stream>>>(
      cah + 4*CC, cal + 4*CC, cah + 4*CC, cal + 4*CC, nullptr, nullptr, nullptr, tpH, tpL, C, C, CC, CC, CC, 1.f);
  k_mm64<1,1,0><<<dim3(8, 8, 4), dim3(256), 0, stream>>>(
      covPH, covPL, tpH, tpL, nullptr, nullptr, nullptr, cbh, cbl, C, C, CC, CC, CC, 1.f);
  k_mm64<0,1,0><<<dim3(8, 8, 4), dim3(256), 0, stream>>>(
      cah + 4*CC, cal + 4*CC, cbh, cbl, nullptr, nullptr, nullptr, zpolH, zpolL, C, C, CC, CC, CC, 1.f);

  // 6) zca apply -> xz3 triple [H|L|H]  (fc dies here)
  k_mm<3,0,3,0><<<dim3(32, 4, 4), dim3(256), 0, stream>>>(fcH, fcL, zpolH, zpolL, nullptr, xz3, nullptr,
      C, C, 1536, NC, CC, NL, 1.f, invsqt, nullptr, 0, nullptr, 0, nullptr, nullptr, 0, nullptr, nullptr);

  // 6.5) self bias vecs + As3 = xz.Ks^T (1-pass K=1536) triple [H|H|L]
  k_pixvec<<<dim3(N / 4, 4), dim3(256), 0, stream>>>(xz3, u2s, rvS, NL, 1536);
  k_pixvec<<<dim3(N / 4, 4), dim3(256), 0, stream>>>(xz3, u1s, cvS, NL, 1536);
  k_mm<1,0,4,0><<<dim3(32, 4, 4), dim3(256), 0, stream>>>(xz3, nullptr, Ks3, nullptr, nullptr, As3, nullptr,
      C, 1536, 1536, NL, 0, NL, 1.f, nullptr, nullptr, 0, nullptr, 0, nullptr, nullptr, 0, nullptr, nullptr);

  // 7) self-attention energies (1-pass K=1536, fp32 E, fused row-stats)
  for (int z = 0; z < 4; ++z){
    k_mm<1,0,0,1><<<dim3(32, 32, 1), dim3(256), 0, stream>>>(As3 + (long)z*NL, nullptr,
        xz3 + (long)z*NL, nullptr, E0, nullptr, nullptr,
        N, 1536, N, 0, 0, 0, 1.f, nullptr, rvS + (long)z*N, 0, cvS + (long)z*N, 0, c0s4, nullptr, 0, Pm, Ps);
    k_prowmerge<<<dim3(16), dim3(256), 0, stream>>>(Pm, Ps, rm, rsc);
    k_colaccum<<<dim3(4, 32), dim3(256), 0, stream>>>(E0, rm, rsc, partials);
    k_colreduce<<<dim3(16), dim3(256), 0, stream>>>(partials, (z < 2 ? attx : atty) + (long)(z & 1) * N);
  }

  // 8) masks
  k_radix<<<dim3(2), dim3(256), 0, stream>>>(attx, thr);
  k_radix<<<dim3(2), dim3(256), 0, stream>>>(atty, thr + 2);
  k_mask<<<dim3(16), dim3(256), 0, stream>>>(attx, atty, thr, mxv, myv);

  // 9) main path: energy -> bf16 E; online masked rowstats; fused corr+PV; out conv
  k_mm<1,0,2,0><<<dim3(32, 32, 2), dim3(256), 0, stream>>>(A2H, nullptr, yaH, nullptr, nullptr, Ebf, nullptr,
      N, C, N, NC, NC, NN, 1.f, nullptr, rvec2, N, cvec2, N, c0m2, nullptr, 0, nullptr, nullptr);
  k_rowstats1<<<dim3(N / 16, 2), dim3(256), 0, stream>>>(Ebf, mxv, myv, rm, rsc);
  k_pv<<<dim3(64, 4, 2), dim3(256), 0, stream>>>(Ebf, hH, rm, rsc, mxv, myv, resH);
  k_mm<1,0,0,0><<<dim3(4, 32, 2), dim3(256), 0, stream>>>(owH, nullptr, resH, nullptr, outm, nullptr, nullptr,
      N, C, N, 0, NC, CN, 1.f, nullptr, ob, 0, nullptr, 0, nullptr, x, CN, nullptr, nullptr);
}

// Round 11
// 1292.919 us; speedup vs baseline: 1.0986x; 1.0986x over previous
//
#include <hip/hip_runtime.h>
#include <cstdint>

static constexpr int B2 = 2;
static constexpr int C = 512;
static constexpr int N = 4096;
static constexpr long CN = (long)C * N;
static constexpr long NC = (long)N * C;
static constexpr long CC = (long)C * C;
static constexpr long NN = (long)N * N;
static constexpr float EPSC = 1e-5f;
static constexpr int KSEL = 308;       // N - int(N*0.925)
static constexpr int NS_ITERS = 4;

typedef __attribute__((ext_vector_type(8))) __bf16 bf16x8;
typedef __attribute__((ext_vector_type(4))) float f32x4;

__device__ __forceinline__ float wredSum(float v){
#pragma unroll
  for (int o = 32; o >= 1; o >>= 1) v += __shfl_xor(v, o, 64);
  return v;
}

__device__ __forceinline__ void gld16(const __bf16* g, __bf16* l){
  __builtin_amdgcn_global_load_lds(
      (const __attribute__((address_space(1))) void*)g,
      (__attribute__((address_space(3))) void*)l, 16, 0, 0);
}

__device__ __forceinline__ void splitw(float v, __bf16* ph, __bf16* pl, long o){
  __bf16 h = (__bf16)v;
  ph[o] = h;
  pl[o] = (__bf16)(v - (float)h);
}

// ======================= split/plain bf16 MFMA GEMM, 128x128 tile, BK=32 =======================
// XCD swizzle. ROWP: 0 none | 1 plain row softmax partials | 2 masked (uses mxp/myp, writes Pq too)
template<int PASSES, int TMH, int OUTMODE, int ROWP>
__global__ __launch_bounds__(256) void k_mm(
    const __bf16* __restrict__ Ah, const __bf16* __restrict__ Al,
    const __bf16* __restrict__ Bh, const __bf16* __restrict__ Bl,
    float* __restrict__ Cf, __bf16* __restrict__ Coh, __bf16* __restrict__ Col,
    int Nn, int K, long sAz, long sBz, long sCz,
    float alpha, const float* __restrict__ alpha_ptr,
    const float* __restrict__ brow, long sBr,
    const float* __restrict__ bcol, long sBc,
    const float* __restrict__ c0p,
    const float* __restrict__ addsrc, long sAddz,
    float* __restrict__ Pm, float* __restrict__ Ps, float* __restrict__ Pq,
    const float* __restrict__ mxp, const float* __restrict__ myp)
{
  constexpr int NB = (PASSES == 3) ? 4 : 2;
  constexpr int SB = (PASSES == 3) ? 2 : 1;
  __shared__ __align__(16) __bf16 sm[NB][128 * 32];
  __shared__ float pmx[2][128], psx[2][128], pqx[2][128];
  const int z = blockIdx.z;
  const int nwx = gridDim.x;
  int lin = blockIdx.y * nwx + blockIdx.x;
  const int nwg = nwx * gridDim.y;
  if ((nwg & 7) == 0){
    const int cpx = nwg >> 3;
    lin = (lin & 7) * cpx + (lin >> 3);
  }
  const int i0 = (lin % nwx) * 128;
  const int j0 = (lin / nwx) * 128;
  const int tid = threadIdx.x;
  const int lane = tid & 63;
  const int w = tid >> 6;
  const int wr = (w >> 1) * 64, wc = (w & 1) * 64;
  const int lr = lane & 15;
  const int g = lane >> 4;

  const __bf16* pAh = Ah + (long)z * sAz + (long)i0 * K;
  const __bf16* pBh = Bh + (long)z * sBz + (long)j0 * K;
  const __bf16* pAl = (PASSES == 3) ? (Al + (long)z * sAz + (long)i0 * K) : nullptr;
  const __bf16* pBl = (PASSES == 3) ? (Bl + (long)z * sBz + (long)j0 * K) : nullptr;

  f32x4 acc[4][4] = {};

  for (int kt = 0; kt < K; kt += 32){
#pragma unroll
    for (int p = 0; p < 2; ++p){
      const int t2 = p * 256 + tid;
      const int row = t2 >> 2;
      const int gs = (t2 & 3) ^ ((row >> 1) & 3);
      const long go = (long)row * K + kt + gs * 8;
      gld16(pAh + go, &sm[0][t2 * 8]);
      gld16(pBh + go, &sm[SB][t2 * 8]);
      if constexpr (PASSES == 3){
        gld16(pAl + go, &sm[1][t2 * 8]);
        gld16(pBl + go, &sm[3][t2 * 8]);
      }
    }
    __syncthreads();
    bf16x8 fa[4], fal[4], fb[4], fbl[4];
#pragma unroll
    for (int mi = 0; mi < 4; ++mi){
      const int row = wr + mi * 16 + lr;
      const int off = row * 32 + ((g ^ ((row >> 1) & 3)) * 8);
      fa[mi] = *(const bf16x8*)(&sm[0][off]);
      if constexpr (PASSES == 3) fal[mi] = *(const bf16x8*)(&sm[1][off]);
    }
#pragma unroll
    for (int ni = 0; ni < 4; ++ni){
      const int row = wc + ni * 16 + lr;
      const int off = row * 32 + ((g ^ ((row >> 1) & 3)) * 8);
      fb[ni] = *(const bf16x8*)(&sm[SB][off]);
      if constexpr (PASSES == 3) fbl[ni] = *(const bf16x8*)(&sm[3][off]);
    }
#pragma unroll
    for (int mi = 0; mi < 4; ++mi)
#pragma unroll
      for (int ni = 0; ni < 4; ++ni){
        acc[mi][ni] = __builtin_amdgcn_mfma_f32_16x16x32_bf16(fa[mi], fb[ni], acc[mi][ni], 0, 0, 0);
        if constexpr (PASSES == 3){
          acc[mi][ni] = __builtin_amdgcn_mfma_f32_16x16x32_bf16(fa[mi],  fbl[ni], acc[mi][ni], 0, 0, 0);
          acc[mi][ni] = __builtin_amdgcn_mfma_f32_16x16x32_bf16(fal[mi], fb[ni],  acc[mi][ni], 0, 0, 0);
        }
      }
    __syncthreads();
  }

  float al2 = alpha;
  if (alpha_ptr) al2 *= alpha_ptr[z];
  const float c0v = c0p ? c0p[z] : 0.f;
#pragma unroll
  for (int mi = 0; mi < 4; ++mi){
    float mrow[4] = {-3.4e38f, -3.4e38f, -3.4e38f, -3.4e38f};
    float srow[4] = {0.f, 0.f, 0.f, 0.f};
    float qrow[4] = {0.f, 0.f, 0.f, 0.f};
#pragma unroll
    for (int ni = 0; ni < 4; ++ni){
      const int col = j0 + wc + ni * 16 + lr;
      const float bc = (bcol ? bcol[z * sBc + col] : 0.f) + c0v;
      const float mycol = (ROWP == 2) ? myp[col] : 0.f;
#pragma unroll
      for (int j = 0; j < 4; ++j){
        const int row = i0 + wr + mi * 16 + g * 4 + j;
        float v = acc[mi][ni][j] * al2;
        if (TMH) v = (((row == col) ? 3.f : 0.f) - v) * 0.5f;
        if (brow) v += brow[z * sBr + row];
        v += bc;
        if (addsrc) v += addsrc[(long)z * sAddz + (long)row * Nn + col];
        const long o = (long)z * sCz + (long)row * Nn + col;
        if (OUTMODE == 0){ Cf[o] = v; }
        else if (OUTMODE == 1){ __bf16 h = (__bf16)v; Coh[o] = h; Col[o] = (__bf16)(v - (float)h); }
        else { __bf16 h = (__bf16)v; Coh[o] = h; if (ROWP == 2) v = (float)h; }
        if constexpr (ROWP >= 1){
          if (v > mrow[j]){
            const float sc = __expf(mrow[j] - v);
            srow[j] *= sc;
            if constexpr (ROWP == 2) qrow[j] *= sc;
            mrow[j] = v;
          }
          const float ev = __expf(v - mrow[j]);
          srow[j] += ev;
          if constexpr (ROWP == 2){
            if (mycol == mxp[row]) qrow[j] += ev;
          }
        }
      }
    }
    if constexpr (ROWP >= 1){
#pragma unroll
      for (int j = 0; j < 4; ++j){
        float m = mrow[j], s = srow[j], q = qrow[j];
#pragma unroll
        for (int o = 1; o <= 8; o <<= 1){
          const float mo = __shfl_xor(m, o, 64);
          const float so = __shfl_xor(s, o, 64);
          float qo = 0.f;
          if constexpr (ROWP == 2) qo = __shfl_xor(q, o, 64);
          const float nm = fmaxf(m, mo);
          const float c0_ = __expf(m - nm), c1_ = __expf(mo - nm);
          s = s * c0_ + so * c1_;
          if constexpr (ROWP == 2) q = q * c0_ + qo * c1_;
          m = nm;
        }
        if (lr == 0){
          const int rl = wr + mi * 16 + g * 4 + j;
          pmx[w & 1][rl] = m;
          psx[w & 1][rl] = s;
          if constexpr (ROWP == 2) pqx[w & 1][rl] = q;
        }
      }
    }
  }
  if constexpr (ROWP >= 1){
    __syncthreads();
    if (tid < 128){
      const float m0 = pmx[0][tid], s0 = psx[0][tid];
      const float m1 = pmx[1][tid], s1 = psx[1][tid];
      const float nm = fmaxf(m0, m1);
      const float c0_ = __expf(m0 - nm), c1_ = __expf(m1 - nm);
      const float s = s0 * c0_ + s1 * c1_;
      const long po = (long)(z * 32 + (j0 >> 7)) * N + i0 + tid;
      Pm[po] = nm;
      Ps[po] = s;
      if constexpr (ROWP == 2){
        Pq[po] = pqx[0][tid] * c0_ + pqx[1][tid] * c1_;
      }
    }
  }
}

// ======================= split-bf16 MFMA GEMM, 64x64 tile, BK=64 (always 3-pass) =======================
template<int TMH, int OUTMODE, int NSYZ>
__global__ __launch_bounds__(256) void k_mm64(
    const __bf16* __restrict__ Ah, const __bf16* __restrict__ Al,
    const __bf16* __restrict__ Bh, const __bf16* __restrict__ Bl,
    const __bf16* __restrict__ tH, const __bf16* __restrict__ tL,
    float* __restrict__ Cf, __bf16* __restrict__ Coh, __bf16* __restrict__ Col,
    int Nn, int K, long sAz, long sBz, long sCz, float alpha)
{
  __shared__ __align__(16) __bf16 sm[4][64 * 64];
  const int z = blockIdx.z;
  const __bf16 *bAh, *bAl, *bBh, *bBl;
  long oC;
  if constexpr (NSYZ){
    if (z < 4){
      bAh = Ah + (long)z * CC; bAl = Al + (long)z * CC;
      bBh = tH + (long)z * CC; bBl = tL + (long)z * CC;
      oC = (long)z * CC;
    } else {
      const int zz = z - 4;
      bAh = tH + (long)zz * CC; bAl = tL + (long)zz * CC;
      bBh = Ah + (long)(4 + zz) * CC; bBl = Al + (long)(4 + zz) * CC;
      oC = (long)(4 + zz) * CC;
    }
  } else {
    bAh = Ah + (long)z * sAz; bAl = Al + (long)z * sAz;
    bBh = Bh + (long)z * sBz; bBl = Bl + (long)z * sBz;
    oC = (long)z * sCz;
  }
  const int i0 = blockIdx.x * 64;
  const int j0 = blockIdx.y * 64;
  const int tid = threadIdx.x;
  const int lane = tid & 63;
  const int w = tid >> 6;
  const int wr = (w >> 1) * 32, wc = (w & 1) * 32;
  const int lr = lane & 15;
  const int g = lane >> 4;

  const __bf16* pAh = bAh + (long)i0 * K;
  const __bf16* pAl = bAl + (long)i0 * K;
  const __bf16* pBh = bBh + (long)j0 * K;
  const __bf16* pBl = bBl + (long)j0 * K;

  f32x4 acc[2][2] = {};

  for (int kt = 0; kt < K; kt += 64){
#pragma unroll
    for (int p = 0; p < 2; ++p){
      const int t2 = p * 256 + tid;
      const int row = t2 >> 3;
      const int gs = (t2 & 7) ^ (row & 7);
      const long go = (long)row * K + kt + gs * 8;
      gld16(pAh + go, &sm[0][t2 * 8]);
      gld16(pAl + go, &sm[1][t2 * 8]);
      gld16(pBh + go, &sm[2][t2 * 8]);
      gld16(pBl + go, &sm[3][t2 * 8]);
    }
    __syncthreads();
#pragma unroll
    for (int ks = 0; ks < 2; ++ks){
      bf16x8 fa[2], fal[2], fb[2], fbl[2];
#pragma unroll
      for (int mi = 0; mi < 2; ++mi){
        const int row = wr + mi * 16 + lr;
        const int off = row * 64 + (((ks * 4 + g) ^ (row & 7)) * 8);
        fa[mi]  = *(const bf16x8*)(&sm[0][off]);
        fal[mi] = *(const bf16x8*)(&sm[1][off]);
      }
#pragma unroll
      for (int ni = 0; ni < 2; ++ni){
        const int row = wc + ni * 16 + lr;
        const int off = row * 64 + (((ks * 4 + g) ^ (row & 7)) * 8);
        fb[ni]  = *(const bf16x8*)(&sm[2][off]);
        fbl[ni] = *(const bf16x8*)(&sm[3][off]);
      }
#pragma unroll
      for (int mi = 0; mi < 2; ++mi)
#pragma unroll
        for (int ni = 0; ni < 2; ++ni){
          acc[mi][ni] = __builtin_amdgcn_mfma_f32_16x16x32_bf16(fa[mi],  fb[ni],  acc[mi][ni], 0, 0, 0);
          acc[mi][ni] = __builtin_amdgcn_mfma_f32_16x16x32_bf16(fa[mi],  fbl[ni], acc[mi][ni], 0, 0, 0);
          acc[mi][ni] = __builtin_amdgcn_mfma_f32_16x16x32_bf16(fal[mi], fb[ni],  acc[mi][ni], 0, 0, 0);
        }
    }
    __syncthreads();
  }

#pragma unroll
  for (int mi = 0; mi < 2; ++mi){
#pragma unroll
    for (int ni = 0; ni < 2; ++ni){
      const int col = j0 + wc + ni * 16 + lr;
#pragma unroll
      for (int j = 0; j < 4; ++j){
        const int row = i0 + wr + mi * 16 + g * 4 + j;
        float v = acc[mi][ni][j] * alpha;
        if (TMH) v = (((row == col) ? 3.f : 0.f) - v) * 0.5f;
        const long o = oC + (long)row * Nn + col;
        if (OUTMODE == 0){ Cf[o] = v; }
        else { __bf16 h = (__bf16)v; Coh[o] = h; Col[o] = (__bf16)(v - (float)h); }
      }
    }
  }
}

// ======================= fused corr+PV (bf16 E) =======================
__global__ __launch_bounds__(256) void k_pv(
    const __bf16* __restrict__ E, const __bf16* __restrict__ Bh,
    const float* __restrict__ rm, const float* __restrict__ rsc,
    const float* __restrict__ mxv, const float* __restrict__ myv,
    __bf16* __restrict__ resH)
{
  __shared__ __align__(16) __bf16 sa[64 * 64];
  __shared__ __align__(16) __bf16 sb[128 * 64];
  const int z = blockIdx.z;
  int lin = blockIdx.y * 64 + blockIdx.x;
  lin = (lin & 7) * 32 + (lin >> 3);
  const int n0 = (lin & 63) * 64;
  const int c0 = (lin >> 6) * 128;
  const int tid = threadIdx.x;
  const int lane = tid & 63;
  const int w = tid >> 6;
  const int wr = (w >> 1) * 32, wc = (w & 1) * 64;
  const int lr = lane & 15, g = lane >> 4;

  const __bf16* pe = E + (long)z * NN + (long)n0 * N;
  const __bf16* pB = Bh + (long)z * CN + (long)c0 * N;

  const int ar = tid >> 2;
  const int slot = tid & 3;
  const float rmv = rm[(long)z * N + n0 + ar];
  const float rsv = rsc[(long)z * N + n0 + ar];
  const float tgt = mxv[n0 + ar];
  const __bf16* per = pe + (long)ar * N;

  f32x4 acc[2][4] = {};

  for (int kt = 0; kt < N; kt += 64){
#pragma unroll
    for (int d = 0; d < 2; ++d){
      const int gd = slot * 2 + d;
      const bf16x8 ev = *(const bf16x8*)(per + kt + gd * 8);
      const float4 m0 = *(const float4*)(myv + kt + gd * 8);
      const float4 m1 = *(const float4*)(myv + kt + gd * 8 + 4);
      bf16x8 pk;
      pk[0] = (__bf16)((m0.x == tgt) ? __expf((float)ev[0] - rmv) * rsv : 0.f);
      pk[1] = (__bf16)((m0.y == tgt) ? __expf((float)ev[1] - rmv) * rsv : 0.f);
      pk[2] = (__bf16)((m0.z == tgt) ? __expf((float)ev[2] - rmv) * rsv : 0.f);
      pk[3] = (__bf16)((m0.w == tgt) ? __expf((float)ev[3] - rmv) * rsv : 0.f);
      pk[4] = (__bf16)((m1.x == tgt) ? __expf((float)ev[4] - rmv) * rsv : 0.f);
      pk[5] = (__bf16)((m1.y == tgt) ? __expf((float)ev[5] - rmv) * rsv : 0.f);
      pk[6] = (__bf16)((m1.z == tgt) ? __expf((float)ev[6] - rmv) * rsv : 0.f);
      pk[7] = (__bf16)((m1.w == tgt) ? __expf((float)ev[7] - rmv) * rsv : 0.f);
      *(bf16x8*)(&sa[ar * 64 + ((gd ^ (ar & 7)) * 8)]) = pk;
    }
#pragma unroll
    for (int p = 0; p < 4; ++p){
      const int t2 = p * 256 + tid;
      const int row = t2 >> 3;
      const int gs = (t2 & 7) ^ (row & 7);
      gld16(pB + (long)row * N + kt + gs * 8, &sb[t2 * 8]);
    }
    __syncthreads();
#pragma unroll
    for (int ks = 0; ks < 2; ++ks){
      bf16x8 fa[2], fb[4];
#pragma unroll
      for (int mi = 0; mi < 2; ++mi){
        const int row = wr + mi * 16 + lr;
        fa[mi] = *(const bf16x8*)(&sa[row * 64 + (((ks * 4 + g) ^ (row & 7)) * 8)]);
      }
#pragma unroll
      for (int ni = 0; ni < 4; ++ni){
        const int row = wc + ni * 16 + lr;
        fb[ni] = *(const bf16x8*)(&sb[row * 64 + (((ks * 4 + g) ^ (row & 7)) * 8)]);
      }
#pragma unroll
      for (int mi = 0; mi < 2; ++mi)
#pragma unroll
        for (int ni = 0; ni < 4; ++ni)
          acc[mi][ni] = __builtin_amdgcn_mfma_f32_16x16x32_bf16(fa[mi], fb[ni], acc[mi][ni], 0, 0, 0);
    }
    __syncthreads();
  }
#pragma unroll
  for (int mi = 0; mi < 2; ++mi)
#pragma unroll
    for (int ni = 0; ni < 4; ++ni){
      const int c = c0 + wc + ni * 16 + lr;
#pragma unroll
      for (int j = 0; j < 4; ++j){
        const int n = n0 + wr + mi * 16 + g * 4 + j;
        resH[(long)z * NC + (long)n * C + c] = (__bf16)acc[mi][ni][j];
      }
    }
}

// ======================= small helpers =======================
__global__ __launch_bounds__(256) void k_wtw(const float* __restrict__ A, const float* __restrict__ B,
                                             float* __restrict__ C2, float alpha){
  __shared__ float sa[16][32], sb[16][32];
  const int i0 = blockIdx.x * 32, j0 = blockIdx.y * 32;
  const int t = threadIdx.x;
  const int ti = t & 15, tj = t >> 4;
  const int li = t & 31, lc = t >> 5;
  float acc[2][2] = {};
  for (int cb = 0; cb < C; cb += 16){
    sa[lc][li]     = A[(long)(cb + lc) * C + i0 + li];
    sa[lc + 8][li] = A[(long)(cb + lc + 8) * C + i0 + li];
    sb[lc][li]     = B[(long)(cb + lc) * C + j0 + li];
    sb[lc + 8][li] = B[(long)(cb + lc + 8) * C + j0 + li];
    __syncthreads();
#pragma unroll
    for (int c = 0; c < 16; ++c){
      const float a0 = sa[c][ti * 2], a1 = sa[c][ti * 2 + 1];
      const float b0 = sb[c][tj * 2], b1 = sb[c][tj * 2 + 1];
      acc[0][0] = fmaf(a0, b0, acc[0][0]); acc[0][1] = fmaf(a0, b1, acc[0][1]);
      acc[1][0] = fmaf(a1, b0, acc[1][0]); acc[1][1] = fmaf(a1, b1, acc[1][1]);
    }
    __syncthreads();
  }
#pragma unroll
  for (int r = 0; r < 2; ++r)
#pragma unroll
    for (int s = 0; s < 2; ++s)
      C2[(long)(i0 + ti * 2 + r) * C + j0 + tj * 2 + s] = acc[r][s] * alpha;
}

__global__ __launch_bounds__(256) void k_wtv(const float* __restrict__ W, const float* __restrict__ b,
                                             float* __restrict__ u){
  __shared__ float sb2[C];
  const int t = threadIdx.x;
  sb2[t] = b[t]; sb2[t + 256] = b[t + 256];
  __syncthreads();
  const int e = blockIdx.x * 256 + t;
  float acc = 0.f;
  for (int c = 0; c < C; ++c) acc = fmaf(W[(long)c * C + e], sb2[c], acc);
  u[e] = acc;
}

__global__ void k_dot2(const float* __restrict__ a1, const float* __restrict__ b1,
                       const float* __restrict__ a2, const float* __restrict__ b2,
                       float* __restrict__ c0m2, float* __restrict__ c0s4){
  const int t = threadIdx.x;
  float s1 = 0.f, s2 = 0.f;
  for (int i = t; i < C; i += 256){ s1 += a1[i] * b1[i]; s2 += a2[i] * b2[i]; }
  __shared__ float sh1[4], sh2[4];
  s1 = wredSum(s1); s2 = wredSum(s2);
  if ((t & 63) == 0){ sh1[t >> 6] = s1; sh2[t >> 6] = s2; }
  __syncthreads();
  if (t == 0){
    float d1 = sh1[0] + sh1[1] + sh1[2] + sh1[3];
    float d2 = sh2[0] + sh2[1] + sh2[2] + sh2[3];
    c0m2[0] = d1; c0m2[1] = d1;
    c0s4[0] = d2; c0s4[1] = d2; c0s4[2] = d2; c0s4[3] = d2;
  }
}

__global__ __launch_bounds__(256) void k_pixvec(const __bf16* __restrict__ X, const float* __restrict__ u,
                                                float* __restrict__ out){
  const int z = blockIdx.y;
  const int wv = threadIdx.x >> 6, lane = threadIdx.x & 63;
  const int n = blockIdx.x * 4 + wv;
  float acc = 0.f;
  for (int d = lane; d < C; d += 64) acc += (float)X[(long)z * NC + (long)n * C + d] * u[d];
  acc = wredSum(acc);
  if (lane == 0) out[(long)z * N + n] = acc;
}

// ======================= prep / stats =======================
__global__ __launch_bounds__(256) void k_stats(const float* __restrict__ x, const float* __restrict__ y,
                                               float* __restrict__ meanv, float* __restrict__ invs){
  const int bid = blockIdx.x;
  const int t = bid >> 9, c = bid & 511;
  const float* src = (t < 2 ? x : y) + (long)(t & 1) * CN + (long)c * N;
  const int tid = threadIdx.x;
  float s1 = 0.f, s2 = 0.f;
  for (int i = tid; i < N; i += 256){ float v = src[i]; s1 += v; s2 += v * v; }
  __shared__ float sh1[4], sh2[4];
  s1 = wredSum(s1); s2 = wredSum(s2);
  if ((tid & 63) == 0){ sh1[tid >> 6] = s1; sh2[tid >> 6] = s2; }
  __syncthreads();
  if (tid == 0){
    float m = (sh1[0] + sh1[1] + sh1[2] + sh1[3]) * (1.f / (float)N);
    float ex2 = (sh2[0] + sh2[1] + sh2[2] + sh2[3]) * (1.f / (float)N);
    float var = ex2 - m * m;
    meanv[t * C + c] = m;
    invs[t * C + c] = rsqrtf((var > 0.f ? var : 0.f) + EPSC);
  }
}

__global__ __launch_bounds__(256) void k_prep(const float* __restrict__ src,
                                              const float* __restrict__ meanv, const float* __restrict__ invs, int toff,
                                              __bf16* __restrict__ adH,
                                              __bf16* __restrict__ fcH, __bf16* __restrict__ fcL,
                                              __bf16* __restrict__ ccH, __bf16* __restrict__ ccL,
                                              __bf16* __restrict__ rwH){
  __shared__ float tile[64][65];
  const int z = blockIdx.z;
  const int n0 = blockIdx.x * 64;
  const int c0 = blockIdx.y * 64;
  const int tid = threadIdx.x;
  const int tx = tid & 63, ty = tid >> 6;
  const int tgt = toff + z;
#pragma unroll
  for (int it = 0; it < 16; ++it){
    const int cc = it * 4 + ty;
    const float v = src[(long)z * CN + (long)(c0 + cc) * N + n0 + tx];
    tile[cc][tx] = v;
    const float cen = v - meanv[tgt * C + c0 + cc];
    splitw(cen, ccH, ccL, (long)tgt * CN + (long)(c0 + cc) * N + n0 + tx);
  }
  __syncthreads();
  const float m = meanv[tgt * C + c0 + tx];
  const float r = invs[tgt * C + c0 + tx];
#pragma unroll
  for (int it = 0; it < 16; ++it){
    const int p = it * 4 + ty;
    const float v = tile[tx][p];
    const float cen = v - m;
    const long o = (long)z * NC + (long)(n0 + p) * C + c0 + tx;
    adH[o] = (__bf16)(cen * r);
    splitw(cen, fcH, fcL, (long)tgt * NC + (long)(n0 + p) * C + c0 + tx);
    if (rwH) rwH[o] = (__bf16)v;
  }
}

__global__ __launch_bounds__(256) void k_wcvt(const float* __restrict__ s, __bf16* __restrict__ h,
                                              __bf16* __restrict__ l, int n){
  int i = blockIdx.x * 256 + threadIdx.x;
  if (i < n) splitw(s[i], h, l, i);
}
__global__ __launch_bounds__(256) void k_wcvt_h(const float* __restrict__ s, __bf16* __restrict__ h, int n){
  int i = blockIdx.x * 256 + threadIdx.x;
  if (i < n) h[i] = (__bf16)s[i];
}

// ======================= cov diag / power iteration / NS init =======================
__global__ void k_diag(float* __restrict__ cov){
  const int z = blockIdx.x, t = threadIdx.x;
  for (int i = t; i < C; i += 256) cov[(long)z * CC + (long)i * C + i] += 2.f * EPSC;
}

__global__ __launch_bounds__(256) void k_powit(const float* __restrict__ cov,
                                               float* __restrict__ invt, float* __restrict__ invsqt){
  __shared__ float v[C], red[4];
  const int z = blockIdx.x, t = threadIdx.x;
  const float* A = cov + (long)z * CC;
  const int j0 = t, j1 = t + 256;
  v[j0] = 1.f + 0.0003f * (float)j0;
  v[j1] = 1.f + 0.0003f * (float)j1;
  __syncthreads();
  float lam = 1.f;
  for (int it = 0; it < 4; ++it){
    float w0a = 0.f, w0b = 0.f, w1a = 0.f, w1b = 0.f;
#pragma unroll 8
    for (int c = 0; c < C; c += 2){
      const float vc0 = v[c], vc1 = v[c + 1];
      w0a = fmaf(A[(long)c * C + j0], vc0, w0a);
      w1a = fmaf(A[(long)c * C + j1], vc0, w1a);
      w0b = fmaf(A[(long)(c + 1) * C + j0], vc1, w0b);
      w1b = fmaf(A[(long)(c + 1) * C + j1], vc1, w1b);
    }
    const float w0 = w0a + w0b, w1 = w1a + w1b;
    float s = w0 * w0 + w1 * w1;
    s = wredSum(s);
    if ((t & 63) == 0) red[t >> 6] = s;
    __syncthreads();
    const float nrm = sqrtf(red[0] + red[1] + red[2] + red[3]);
    lam = nrm;
    const float inv = 1.f / nrm;
    v[j0] = w0 * inv;
    v[j1] = w1 * inv;
    __syncthreads();
  }
  if (t == 0){
    const float tt = 1.02f * lam;
    invt[z] = 1.f / tt;
    invsqt[z] = rsqrtf(tt);
  }
}

__global__ __launch_bounds__(256) void k_ns_init(const float* __restrict__ cov, const float* __restrict__ invt,
                                                 __bf16* __restrict__ h, __bf16* __restrict__ l,
                                                 __bf16* __restrict__ cph, __bf16* __restrict__ cpl){
  const int r = blockIdx.x, z = blockIdx.y;
  const long base = (long)z * CC + (long)r * C;
  const float it = invt[z];
  for (int i = threadIdx.x; i < C; i += 256){
    const float v = cov[base + i] * it;
    splitw(v, h, l, base + i);
    splitw(v, cph, cpl, base + i);
    h[4 * CC + base + i] = (__bf16)((i == r) ? 1.f : 0.f);
    l[4 * CC + base + i] = (__bf16)0.f;
  }
}

// ======================= softmax aux =======================
// self path: merge 32 per-block (m,s) partials per row
__global__ __launch_bounds__(256) void k_prowmerge(const float* __restrict__ Pm, const float* __restrict__ Ps,
                                                   float* __restrict__ rm, float* __restrict__ rsc){
  const int row = blockIdx.x * 256 + threadIdx.x;
  float m = -3.4e38f, s = 0.f;
#pragma unroll 4
  for (int p = 0; p < 32; ++p){
    const float mp = Pm[(long)p * N + row];
    const float sp = Ps[(long)p * N + row];
    const float nm = fmaxf(m, mp);
    s = s * __expf(m - nm) + sp * __expf(mp - nm);
    m = nm;
  }
  rm[row] = m;
  rsc[row] = 1.f / s;
}

// main path: masked merge of (m,s,sm) partials -> rm, rsc = 1/(S*l1)
__global__ __launch_bounds__(256) void k_prowmerge_m(const float* __restrict__ Pm, const float* __restrict__ Ps,
                                                     const float* __restrict__ Pq,
                                                     float* __restrict__ rm, float* __restrict__ rsc){
  const int z = blockIdx.y;
  const int row = blockIdx.x * 256 + threadIdx.x;
  float m = -3.4e38f, s = 0.f, q = 0.f;
#pragma unroll 4
  for (int p = 0; p < 32; ++p){
    const long idx = (long)(z * 32 + p) * N + row;
    const float mp = Pm[idx], sp = Ps[idx], qp = Pq[idx];
    const float nm = fmaxf(m, mp);
    const float c0_ = __expf(m - nm), c1_ = __expf(mp - nm);
    s = s * c0_ + sp * c1_;
    q = q * c0_ + qp * c1_;
    m = nm;
  }
  float l1 = q / s;
  if (l1 < 1e-12f) l1 = 1e-12f;
  rsc[(long)z * N + row] = 1.f / (s * l1);
  rm[(long)z * N + row] = m;
}

// single E read: column partial accumulation, 32 rows per y-block (512 blocks -> 2/CU)
__global__ __launch_bounds__(256) void k_colaccum(const float* __restrict__ E, const float* __restrict__ rowmax,
                                                  const float* __restrict__ rowscale, float* __restrict__ partials){
  const int j = (blockIdx.x * 256 + threadIdx.x) * 4;
  const int r0 = blockIdx.y * 32;
  float4 acc = {0.f, 0.f, 0.f, 0.f};
#pragma unroll 4
  for (int r2 = r0; r2 < r0 + 32; ++r2){
    const float4 e = *reinterpret_cast<const float4*>(E + (long)r2 * N + j);
    const float rmv = rowmax[r2], rsv = rowscale[r2];
    acc.x += __expf(e.x - rmv) * rsv;
    acc.y += __expf(e.y - rmv) * rsv;
    acc.z += __expf(e.z - rmv) * rsv;
    acc.w += __expf(e.w - rmv) * rsv;
  }
  *reinterpret_cast<float4*>(partials + (long)blockIdx.y * N + j) = acc;
}

__global__ __launch_bounds__(256) void k_colreduce(const float* __restrict__ partials, float* __restrict__ att){
  const int j = blockIdx.x * 256 + threadIdx.x;
  float s = 0.f;
#pragma unroll 8
  for (int p = 0; p < 128; ++p) s += partials[(long)p * N + j];
  att[j] = s * (1.f / (float)N);
}

// ======================= mask (radix select) =======================
__global__ __launch_bounds__(256) void k_radix(const float* __restrict__ a, float* __restrict__ thr){
  __shared__ unsigned int vals[N];
  __shared__ float shc[4];
  __shared__ unsigned int p_sh;
  __shared__ int k_sh;
  const float* pa = a + (long)blockIdx.x * N;
  const int tid = threadIdx.x;
  for (int i = tid; i < N; i += 256) vals[i] = __float_as_uint(pa[i]);
  if (tid == 0){ p_sh = 0u; k_sh = KSEL; }
  __syncthreads();
  for (int b = 31; b >= 0; --b){
    const unsigned int bit = 1u << b;
    const unsigned int above = (b == 31) ? 0u : ~((bit << 1) - 1u);
    const unsigned int p = p_sh;
    int cnt = 0;
    for (int i = tid; i < N; i += 256){
      unsigned int v = vals[i];
      if ((v & above) == p && (v & bit)) cnt++;
    }
    float cf = wredSum((float)cnt);
    if ((tid & 63) == 0) shc[tid >> 6] = cf;
    __syncthreads();
    if (tid == 0){
      int c1 = (int)(shc[0] + shc[1] + shc[2] + shc[3] + 0.5f);
      if (k_sh <= c1) p_sh = p | bit;
      else k_sh -= c1;
    }
    __syncthreads();
  }
  if (tid == 0) thr[blockIdx.x] = __uint_as_float(p_sh);
}

__global__ __launch_bounds__(256) void k_mask(const float* __restrict__ ax, const float* __restrict__ ay,
                                              const float* __restrict__ thr, float* __restrict__ mx,
                                              float* __restrict__ my){
  int j = blockIdx.x * 256 + threadIdx.x;
  mx[j] = (ax[j] >= thr[0] && ax[N + j] >= thr[1]) ? 1.f : 0.f;
  my[j] = (ay[j] >= thr[2] && ay[N + j] >= thr[3]) ? 1.f : 0.f;
}

// ======================= host =======================
extern "C" void kernel_launch(void* const* d_in, const int* in_sizes, int n_in,
                              void* d_out, int out_size, void* d_ws, size_t ws_size,
                              hipStream_t stream)
{
  const float* x     = (const float*)d_in[0];
  const float* y     = (const float*)d_in[1];
  const float* f_w   = (const float*)d_in[2];
  const float* f_b   = (const float*)d_in[3];
  const float* g_w   = (const float*)d_in[4];
  const float* g_b   = (const float*)d_in[5];
  const float* saf_w = (const float*)d_in[6];
  const float* saf_b = (const float*)d_in[7];
  const float* sag_w = (const float*)d_in[8];
  const float* sag_b = (const float*)d_in[9];
  const float* h_w   = (const float*)d_in[10];
  const float* h_b   = (const float*)d_in[11];
  const float* ow    = (const float*)d_in[12];
  const float* ob    = (const float*)d_in[13];

  const size_t MBy = 1ull << 20;
  const size_t KBy = 1ull << 10;
  char* base = (char*)d_ws;
  if (ws_size < 206 * MBy) return;
  auto F  = [&](size_t off){ return (float*)(base + off); };
  auto Bp = [&](size_t off){ return (__bf16*)(base + off); };

  float *E0 = F(0);
  __bf16 *Ebf = Bp(0);
  __bf16 *ccH = Bp(0), *ccL = Bp(16*MBy);
  float  *covb = F(32*MBy);
  __bf16 *zpolH = Bp(36*MBy), *zpolL = Bp(38*MBy);
  __bf16 *covPH = Bp(40*MBy), *covPL = Bp(42*MBy);
  float  *KsTf = F(44*MBy), *K2tf = F(45*MBy);
  __bf16 *KsTH = Bp(46*MBy), *KsTL = Bp(46*MBy + 512*KBy);
  __bf16 *K2tH = Bp(47*MBy), *hwH = Bp(47*MBy + 512*KBy);
  __bf16 *tpH = Bp(48*MBy), *tpL = Bp(50*MBy);
  __bf16 *xaH = Bp(64*MBy);
  __bf16 *xzH = Bp(64*MBy), *xzL = Bp(80*MBy);
  __bf16 *ypmH = Bp(96*MBy);
  __bf16 *AsH = Bp(96*MBy), *AsL = Bp(112*MBy);
  __bf16 *fcH = Bp(128*MBy), *fcL = Bp(144*MBy);
  __bf16 *resH = Bp(128*MBy);
  __bf16 *nsAh = Bp(160*MBy), *nsAl = Bp(164*MBy);
  __bf16 *nsBh = Bp(168*MBy), *nsBl = Bp(172*MBy);
  __bf16 *A2H = Bp(176*MBy);
  __bf16 *yaH = Bp(184*MBy);
  __bf16 *hH  = Bp(192*MBy);
  __bf16 *owH = Bp(200*MBy);
  size_t so = 200 * MBy + 512 * KBy;
  auto SF = [&](size_t bytes){ float* p = F(so); so += bytes; return p; };
  float *meanv = SF(8*KBy), *invs = SF(8*KBy);
  float *rm = SF(32*KBy), *rsc = SF(32*KBy);
  float *mxv = SF(16*KBy), *myv = SF(16*KBy);
  float *rvec2 = SF(32*KBy), *cvec2 = SF(32*KBy);
  float *rvS = SF(64*KBy), *cvS = SF(64*KBy);
  float *u1m = SF(2*KBy), *u2m = SF(2*KBy), *u1s = SF(2*KBy), *u2s = SF(2*KBy);
  float *c0m2 = SF(64), *c0s4 = SF(64), *thr = SF(64);
  float *invt = SF(64), *invsqt = SF(64);
  float *partials = F(201*MBy);                      // [128][N] = 2MB  [201,203)
  float *Pm = F(203*MBy);                            // [64][N] = 1MB   [203,204)
  float *Ps = F(204*MBy);                            // [64][N] = 1MB   [204,205)
  float *Pq = F(205*MBy);                            // [64][N] = 1MB   [205,206)

  float* outm = (float*)d_out;
  float* attx = outm + B2 * CN;
  float* atty = attx + (long)B2 * N;

  // 1) stats + prep
  k_stats<<<dim3(4 * C), dim3(256), 0, stream>>>(x, y, meanv, invs);
  k_prep<<<dim3(64, 8, 2), dim3(256), 0, stream>>>(x, meanv, invs, 0, xaH, fcH, fcL, ccH, ccL, nullptr);
  k_prep<<<dim3(64, 8, 2), dim3(256), 0, stream>>>(y, meanv, invs, 2, yaH, fcH, fcL, ccH, ccL, ypmH);

  // 2) weight products & conversions
  k_wtw<<<dim3(16, 16), dim3(256), 0, stream>>>(sag_w, saf_w, KsTf, 1.f);
  k_wtw<<<dim3(16, 16), dim3(256), 0, stream>>>(g_w, f_w, K2tf, 1.f);
  {
    const int nb = (int)(CC / 256);
    k_wcvt<<<nb, 256, 0, stream>>>(KsTf, KsTH, KsTL, (int)CC);
    k_wcvt_h<<<nb, 256, 0, stream>>>(K2tf, K2tH, (int)CC);
    k_wcvt_h<<<nb, 256, 0, stream>>>(h_w, hwH, (int)CC);
    k_wcvt_h<<<nb, 256, 0, stream>>>(ow, owH, (int)CC);
  }
  k_wtv<<<dim3(2), dim3(256), 0, stream>>>(g_w, f_b, u1m);
  k_wtv<<<dim3(2), dim3(256), 0, stream>>>(f_w, g_b, u2m);
  k_wtv<<<dim3(2), dim3(256), 0, stream>>>(sag_w, saf_b, u1s);
  k_wtv<<<dim3(2), dim3(256), 0, stream>>>(saf_w, sag_b, u2s);
  k_dot2<<<dim3(1), dim3(256), 0, stream>>>(f_b, g_b, saf_b, sag_b, c0m2, c0s4);
  k_pixvec<<<dim3(N / 4, 2), dim3(256), 0, stream>>>(xaH, u2m, rvec2);
  k_pixvec<<<dim3(N / 4, 2), dim3(256), 0, stream>>>(yaH, u1m, cvec2);

  // 3) cov + 2eps*I + power-iteration lambda_max
  k_mm64<0,0,0><<<dim3(8, 8, 4), dim3(256), 0, stream>>>(
      ccH, ccL, ccH, ccL, nullptr, nullptr, covb, nullptr, nullptr, C, N, CN, CN, CC, 1.f / (float)(N - 1));
  k_diag<<<dim3(4), dim3(256), 0, stream>>>(covb);
  k_powit<<<dim3(4), dim3(256), 0, stream>>>(covb, invt, invsqt);

  // 4) A2 = xa . K2^T, h conv
  k_mm<1,0,2,0><<<dim3(32, 4, 2), dim3(256), 0, stream>>>(xaH, nullptr, K2tH, nullptr, nullptr, A2H, nullptr,
      C, C, NC, 0, NC, 1.f, nullptr, nullptr, 0, nullptr, 0, nullptr, nullptr, 0,
      nullptr, nullptr, nullptr, nullptr, nullptr);
  k_mm<1,0,2,0><<<dim3(4, 32, 2), dim3(256), 0, stream>>>(hwH, nullptr, ypmH, nullptr, nullptr, hH, nullptr,
      N, C, 0, NC, CN, 1.f, nullptr, h_b, 0, nullptr, 0, nullptr, nullptr, 0,
      nullptr, nullptr, nullptr, nullptr, nullptr);

  // 5) Newton-Schulz (4 iters) + split-bf16 polish
  k_ns_init<<<dim3(C, 4), dim3(256), 0, stream>>>(covb, invt, nsAh, nsAl, covPH, covPL);
  __bf16 *cah = nsAh, *cal = nsAl, *cbh = nsBh, *cbl = nsBl;
  for (int it = 0; it < NS_ITERS; ++it){
    k_mm64<1,1,0><<<dim3(8, 8, 4), dim3(256), 0, stream>>>(
        cah + 4*CC, cal + 4*CC, cah, cal, nullptr, nullptr, nullptr, tpH, tpL, C, C, CC, CC, CC, 1.f);
    k_mm64<0,1,1><<<dim3(8, 8, 8), dim3(256), 0, stream>>>(
        cah, cal, nullptr, nullptr, tpH, tpL, nullptr, cbh, cbl, C, C, CC, CC, CC, 1.f);
    __bf16* t;
    t = cah; cah = cbh; cbh = t;
    t = cal; cal = cbl; cbl = t;
  }
  k_mm64<0,1,0><<<dim3(8, 8, 4), dim3(256), 0, stream>>>(
      cah + 4*CC, cal + 4*CC, cah + 4*CC, cal + 4*CC, nullptr, nullptr, nullptr, tpH, tpL, C, C, CC, CC, CC, 1.f);
  k_mm64<1,1,0><<<dim3(8, 8, 4), dim3(256), 0, stream>>>(
      covPH, covPL, tpH, tpL, nullptr, nullptr, nullptr, cbh, cbl, C, C, CC, CC, CC, 1.f);
  k_mm64<0,1,0><<<dim3(8, 8, 4), dim3(256), 0, stream>>>(
      cah + 4*CC, cal + 4*CC, cbh, cbl, nullptr, nullptr, nullptr, zpolH, zpolL, C, C, CC, CC, CC, 1.f);

  // 6) zca apply: xz = invsqt * fc . Z
  k_mm<3,0,1,0><<<dim3(32, 4, 4), dim3(256), 0, stream>>>(fcH, fcL, zpolH, zpolL, nullptr, xzH, xzL,
      C, C, NC, CC, NC, 1.f, invsqt, nullptr, 0, nullptr, 0, nullptr, nullptr, 0,
      nullptr, nullptr, nullptr, nullptr, nullptr);

  // 6.5) self bias vecs + As = xz . Ks^T
  k_pixvec<<<dim3(N / 4, 4), dim3(256), 0, stream>>>(xzH, u2s, rvS);
  k_pixvec<<<dim3(N / 4, 4), dim3(256), 0, stream>>>(xzH, u1s, cvS);
  k_mm<3,0,1,0><<<dim3(32, 4, 4), dim3(256), 0, stream>>>(xzH, xzL, KsTH, KsTL, nullptr, AsH, AsL,
      C, C, NC, 0, NC, 1.f, nullptr, nullptr, 0, nullptr, 0, nullptr, nullptr, 0,
      nullptr, nullptr, nullptr, nullptr, nullptr);

  // 7) self-attention energies (3-pass, fp32 E, fused row-stats) -> atten
  for (int z = 0; z < 4; ++z){
    k_mm<3,0,0,1><<<dim3(32, 32, 1), dim3(256), 0, stream>>>(AsH + (long)z*NC, AsL + (long)z*NC,
        xzH + (long)z*NC, xzL + (long)z*NC, E0, nullptr, nullptr,
        N, C, 0, 0, 0, 1.f, nullptr, rvS + (long)z*N, 0, cvS + (long)z*N, 0, c0s4, nullptr, 0,
        Pm, Ps, nullptr, nullptr, nullptr);
    k_prowmerge<<<dim3(16), dim3(256), 0, stream>>>(Pm, Ps, rm, rsc);
    k_colaccum<<<dim3(4, 128), dim3(256), 0, stream>>>(E0, rm, rsc, partials);
    k_colreduce<<<dim3(16), dim3(256), 0, stream>>>(partials, (z < 2 ? attx : atty) + (long)(z & 1) * N);
  }

  // 8) masks
  k_radix<<<dim3(2), dim3(256), 0, stream>>>(attx, thr);
  k_radix<<<dim3(2), dim3(256), 0, stream>>>(atty, thr + 2);
  k_mask<<<dim3(16), dim3(256), 0, stream>>>(attx, atty, thr, mxv, myv);

  // 9) main path: energy -> bf16 E with fused masked row-stats; merge; fused corr+PV; out conv
  k_mm<1,0,2,2><<<dim3(32, 32, 2), dim3(256), 0, stream>>>(A2H, nullptr, yaH, nullptr, nullptr, Ebf, nullptr,
      N, C, NC, NC, NN, 1.f, nullptr, rvec2, N, cvec2, N, c0m2, nullptr, 0,
      Pm, Ps, Pq, mxv, myv);
  k_prowmerge_m<<<dim3(16, 2), dim3(256), 0, stream>>>(Pm, Ps, Pq, rm, rsc);
  k_pv<<<dim3(64, 4, 2), dim3(256), 0, stream>>>(Ebf, hH, rm, rsc, mxv, myv, resH);
  k_mm<1,0,0,0><<<dim3(4, 32, 2), dim3(256), 0, stream>>>(owH, nullptr, resH, nullptr, outm, nullptr, nullptr,
      N, C, 0, NC, CN, 1.f, nullptr, ob, 0, nullptr, 0, nullptr, x, CN,
      nullptr, nullptr, nullptr, nullptr, nullptr);
}

// Round 12
// 1253.514 us; speedup vs baseline: 1.1331x; 1.0314x over previous
//
#include <hip/hip_runtime.h>
#include <cstdint>

static constexpr int B2 = 2;
static constexpr int C = 512;
static constexpr int N = 4096;
static constexpr long CN = (long)C * N;
static constexpr long NC = (long)N * C;
static constexpr long CC = (long)C * C;
static constexpr long NN = (long)N * N;
static constexpr float EPSC = 1e-5f;
static constexpr int KSEL = 308;       // N - int(N*0.925)
static constexpr int NS_ITERS = 4;

typedef __attribute__((ext_vector_type(8))) __bf16 bf16x8;
typedef __attribute__((ext_vector_type(4))) float f32x4;

__device__ __forceinline__ float wredSum(float v){
#pragma unroll
  for (int o = 32; o >= 1; o >>= 1) v += __shfl_xor(v, o, 64);
  return v;
}

__device__ __forceinline__ void gld16(const __bf16* g, __bf16* l){
  __builtin_amdgcn_global_load_lds(
      (const __attribute__((address_space(1))) void*)g,
      (__attribute__((address_space(3))) void*)l, 16, 0, 0);
}

__device__ __forceinline__ void splitw(float v, __bf16* ph, __bf16* pl, long o){
  __bf16 h = (__bf16)v;
  ph[o] = h;
  pl[o] = (__bf16)(v - (float)h);
}

// ======================= split/plain bf16 MFMA GEMM, 128x128 tile, BK=32 =======================
// XCD swizzle. ROWP: 0 none | 1 row softmax partials | 2 masked (mxp/myp, writes Pq)
// Two-phase epilogue: pass1 value+max (fmax only), pass2 exp-sums vs final max (no rescale).
template<int PASSES, int TMH, int OUTMODE, int ROWP>
__global__ __launch_bounds__(256) void k_mm(
    const __bf16* __restrict__ Ah, const __bf16* __restrict__ Al,
    const __bf16* __restrict__ Bh, const __bf16* __restrict__ Bl,
    float* __restrict__ Cf, __bf16* __restrict__ Coh, __bf16* __restrict__ Col,
    int Nn, int K, long sAz, long sBz, long sCz,
    float alpha, const float* __restrict__ alpha_ptr,
    const float* __restrict__ brow, long sBr,
    const float* __restrict__ bcol, long sBc,
    const float* __restrict__ c0p,
    const float* __restrict__ addsrc, long sAddz,
    float* __restrict__ Pm, float* __restrict__ Ps, float* __restrict__ Pq,
    const float* __restrict__ mxp, const float* __restrict__ myp)
{
  constexpr int NB = (PASSES == 3) ? 4 : 2;
  constexpr int SB = (PASSES == 3) ? 2 : 1;
  __shared__ __align__(16) __bf16 sm[NB][128 * 32];
  __shared__ float pmx[2][128], psx[2][128], pqx[2][128];
  const int z = blockIdx.z;
  const int nwx = gridDim.x;
  int lin = blockIdx.y * nwx + blockIdx.x;
  const int nwg = nwx * gridDim.y;
  if ((nwg & 7) == 0){
    const int cpx = nwg >> 3;
    lin = (lin & 7) * cpx + (lin >> 3);
  }
  const int i0 = (lin % nwx) * 128;
  const int j0 = (lin / nwx) * 128;
  const int tid = threadIdx.x;
  const int lane = tid & 63;
  const int w = tid >> 6;
  const int wr = (w >> 1) * 64, wc = (w & 1) * 64;
  const int lr = lane & 15;
  const int g = lane >> 4;

  const __bf16* pAh = Ah + (long)z * sAz + (long)i0 * K;
  const __bf16* pBh = Bh + (long)z * sBz + (long)j0 * K;
  const __bf16* pAl = (PASSES == 3) ? (Al + (long)z * sAz + (long)i0 * K) : nullptr;
  const __bf16* pBl = (PASSES == 3) ? (Bl + (long)z * sBz + (long)j0 * K) : nullptr;

  f32x4 acc[4][4] = {};

  for (int kt = 0; kt < K; kt += 32){
#pragma unroll
    for (int p = 0; p < 2; ++p){
      const int t2 = p * 256 + tid;
      const int row = t2 >> 2;
      const int gs = (t2 & 3) ^ ((row >> 1) & 3);
      const long go = (long)row * K + kt + gs * 8;
      gld16(pAh + go, &sm[0][t2 * 8]);
      gld16(pBh + go, &sm[SB][t2 * 8]);
      if constexpr (PASSES == 3){
        gld16(pAl + go, &sm[1][t2 * 8]);
        gld16(pBl + go, &sm[3][t2 * 8]);
      }
    }
    __syncthreads();
    bf16x8 fa[4], fal[4], fb[4], fbl[4];
#pragma unroll
    for (int mi = 0; mi < 4; ++mi){
      const int row = wr + mi * 16 + lr;
      const int off = row * 32 + ((g ^ ((row >> 1) & 3)) * 8);
      fa[mi] = *(const bf16x8*)(&sm[0][off]);
      if constexpr (PASSES == 3) fal[mi] = *(const bf16x8*)(&sm[1][off]);
    }
#pragma unroll
    for (int ni = 0; ni < 4; ++ni){
      const int row = wc + ni * 16 + lr;
      const int off = row * 32 + ((g ^ ((row >> 1) & 3)) * 8);
      fb[ni] = *(const bf16x8*)(&sm[SB][off]);
      if constexpr (PASSES == 3) fbl[ni] = *(const bf16x8*)(&sm[3][off]);
    }
#pragma unroll
    for (int mi = 0; mi < 4; ++mi)
#pragma unroll
      for (int ni = 0; ni < 4; ++ni){
        acc[mi][ni] = __builtin_amdgcn_mfma_f32_16x16x32_bf16(fa[mi], fb[ni], acc[mi][ni], 0, 0, 0);
        if constexpr (PASSES == 3){
          acc[mi][ni] = __builtin_amdgcn_mfma_f32_16x16x32_bf16(fa[mi],  fbl[ni], acc[mi][ni], 0, 0, 0);
          acc[mi][ni] = __builtin_amdgcn_mfma_f32_16x16x32_bf16(fal[mi], fb[ni],  acc[mi][ni], 0, 0, 0);
        }
      }
    __syncthreads();
  }

  float al2 = alpha;
  if (alpha_ptr) al2 *= alpha_ptr[z];
  const float c0v = c0p ? c0p[z] : 0.f;
#pragma unroll
  for (int mi = 0; mi < 4; ++mi){
    float vv[4][4];
    float mrow[4] = {-3.4e38f, -3.4e38f, -3.4e38f, -3.4e38f};
    // pass 1: values + C write + per-thread max (no exp)
#pragma unroll
    for (int ni = 0; ni < 4; ++ni){
      const int col = j0 + wc + ni * 16 + lr;
      const float bc = (bcol ? bcol[z * sBc + col] : 0.f) + c0v;
#pragma unroll
      for (int j = 0; j < 4; ++j){
        const int row = i0 + wr + mi * 16 + g * 4 + j;
        float v = acc[mi][ni][j] * al2;
        if (TMH) v = (((row == col) ? 3.f : 0.f) - v) * 0.5f;
        if (brow) v += brow[z * sBr + row];
        v += bc;
        if (addsrc) v += addsrc[(long)z * sAddz + (long)row * Nn + col];
        const long o = (long)z * sCz + (long)row * Nn + col;
        if (OUTMODE == 0){ Cf[o] = v; }
        else if (OUTMODE == 1){ __bf16 h = (__bf16)v; Coh[o] = h; Col[o] = (__bf16)(v - (float)h); }
        else { __bf16 h = (__bf16)v; Coh[o] = h; if (ROWP == 2) v = (float)h; }
        if constexpr (ROWP >= 1){
          vv[ni][j] = v;
          mrow[j] = fmaxf(mrow[j], v);
        }
      }
    }
    if constexpr (ROWP >= 1){
      // merge max across the 16-lane row group (fmax only)
#pragma unroll
      for (int j = 0; j < 4; ++j)
#pragma unroll
        for (int o = 1; o <= 8; o <<= 1)
          mrow[j] = fmaxf(mrow[j], __shfl_xor(mrow[j], o, 64));
      float tgt[4];
      if constexpr (ROWP == 2){
#pragma unroll
        for (int j = 0; j < 4; ++j)
          tgt[j] = mxp[i0 + wr + mi * 16 + g * 4 + j];
      }
      // pass 2: exp sums vs final max
      float srow[4] = {0.f, 0.f, 0.f, 0.f};
      float qrow[4] = {0.f, 0.f, 0.f, 0.f};
#pragma unroll
      for (int ni = 0; ni < 4; ++ni){
        const float mycol = (ROWP == 2) ? myp[j0 + wc + ni * 16 + lr] : 0.f;
#pragma unroll
        for (int j = 0; j < 4; ++j){
          const float ev = __expf(vv[ni][j] - mrow[j]);
          srow[j] += ev;
          if constexpr (ROWP == 2){
            if (mycol == tgt[j]) qrow[j] += ev;
          }
        }
      }
      // merge sums (plain adds)
#pragma unroll
      for (int j = 0; j < 4; ++j){
#pragma unroll
        for (int o = 1; o <= 8; o <<= 1){
          srow[j] += __shfl_xor(srow[j], o, 64);
          if constexpr (ROWP == 2) qrow[j] += __shfl_xor(qrow[j], o, 64);
        }
        if (lr == 0){
          const int rl = wr + mi * 16 + g * 4 + j;
          pmx[w & 1][rl] = mrow[j];
          psx[w & 1][rl] = srow[j];
          if constexpr (ROWP == 2) pqx[w & 1][rl] = qrow[j];
        }
      }
    }
  }
  if constexpr (ROWP >= 1){
    __syncthreads();
    if (tid < 128){
      const float m0 = pmx[0][tid], s0 = psx[0][tid];
      const float m1 = pmx[1][tid], s1 = psx[1][tid];
      const float nm = fmaxf(m0, m1);
      const float c0_ = __expf(m0 - nm), c1_ = __expf(m1 - nm);
      const float s = s0 * c0_ + s1 * c1_;
      const long po = (long)(z * 32 + (j0 >> 7)) * N + i0 + tid;
      Pm[po] = nm;
      Ps[po] = s;
      if constexpr (ROWP == 2){
        Pq[po] = pqx[0][tid] * c0_ + pqx[1][tid] * c1_;
      }
    }
  }
}

// ======================= split-bf16 MFMA GEMM, 64x64 tile, BK=64 (always 3-pass) =======================
template<int TMH, int OUTMODE, int NSYZ>
__global__ __launch_bounds__(256) void k_mm64(
    const __bf16* __restrict__ Ah, const __bf16* __restrict__ Al,
    const __bf16* __restrict__ Bh, const __bf16* __restrict__ Bl,
    const __bf16* __restrict__ tH, const __bf16* __restrict__ tL,
    float* __restrict__ Cf, __bf16* __restrict__ Coh, __bf16* __restrict__ Col,
    int Nn, int K, long sAz, long sBz, long sCz, float alpha)
{
  __shared__ __align__(16) __bf16 sm[4][64 * 64];
  const int z = blockIdx.z;
  const __bf16 *bAh, *bAl, *bBh, *bBl;
  long oC;
  if constexpr (NSYZ){
    if (z < 4){
      bAh = Ah + (long)z * CC; bAl = Al + (long)z * CC;
      bBh = tH + (long)z * CC; bBl = tL + (long)z * CC;
      oC = (long)z * CC;
    } else {
      const int zz = z - 4;
      bAh = tH + (long)zz * CC; bAl = tL + (long)zz * CC;
      bBh = Ah + (long)(4 + zz) * CC; bBl = Al + (long)(4 + zz) * CC;
      oC = (long)(4 + zz) * CC;
    }
  } else {
    bAh = Ah + (long)z * sAz; bAl = Al + (long)z * sAz;
    bBh = Bh + (long)z * sBz; bBl = Bl + (long)z * sBz;
    oC = (long)z * sCz;
  }
  const int i0 = blockIdx.x * 64;
  const int j0 = blockIdx.y * 64;
  const int tid = threadIdx.x;
  const int lane = tid & 63;
  const int w = tid >> 6;
  const int wr = (w >> 1) * 32, wc = (w & 1) * 32;
  const int lr = lane & 15;
  const int g = lane >> 4;

  const __bf16* pAh = bAh + (long)i0 * K;
  const __bf16* pAl = bAl + (long)i0 * K;
  const __bf16* pBh = bBh + (long)j0 * K;
  const __bf16* pBl = bBl + (long)j0 * K;

  f32x4 acc[2][2] = {};

  for (int kt = 0; kt < K; kt += 64){
#pragma unroll
    for (int p = 0; p < 2; ++p){
      const int t2 = p * 256 + tid;
      const int row = t2 >> 3;
      const int gs = (t2 & 7) ^ (row & 7);
      const long go = (long)row * K + kt + gs * 8;
      gld16(pAh + go, &sm[0][t2 * 8]);
      gld16(pAl + go, &sm[1][t2 * 8]);
      gld16(pBh + go, &sm[2][t2 * 8]);
      gld16(pBl + go, &sm[3][t2 * 8]);
    }
    __syncthreads();
#pragma unroll
    for (int ks = 0; ks < 2; ++ks){
      bf16x8 fa[2], fal[2], fb[2], fbl[2];
#pragma unroll
      for (int mi = 0; mi < 2; ++mi){
        const int row = wr + mi * 16 + lr;
        const int off = row * 64 + (((ks * 4 + g) ^ (row & 7)) * 8);
        fa[mi]  = *(const bf16x8*)(&sm[0][off]);
        fal[mi] = *(const bf16x8*)(&sm[1][off]);
      }
#pragma unroll
      for (int ni = 0; ni < 2; ++ni){
        const int row = wc + ni * 16 + lr;
        const int off = row * 64 + (((ks * 4 + g) ^ (row & 7)) * 8);
        fb[ni]  = *(const bf16x8*)(&sm[2][off]);
        fbl[ni] = *(const bf16x8*)(&sm[3][off]);
      }
#pragma unroll
      for (int mi = 0; mi < 2; ++mi)
#pragma unroll
        for (int ni = 0; ni < 2; ++ni){
          acc[mi][ni] = __builtin_amdgcn_mfma_f32_16x16x32_bf16(fa[mi],  fb[ni],  acc[mi][ni], 0, 0, 0);
          acc[mi][ni] = __builtin_amdgcn_mfma_f32_16x16x32_bf16(fa[mi],  fbl[ni], acc[mi][ni], 0, 0, 0);
          acc[mi][ni] = __builtin_amdgcn_mfma_f32_16x16x32_bf16(fal[mi], fb[ni],  acc[mi][ni], 0, 0, 0);
        }
    }
    __syncthreads();
  }

#pragma unroll
  for (int mi = 0; mi < 2; ++mi){
#pragma unroll
    for (int ni = 0; ni < 2; ++ni){
      const int col = j0 + wc + ni * 16 + lr;
#pragma unroll
      for (int j = 0; j < 4; ++j){
        const int row = i0 + wr + mi * 16 + g * 4 + j;
        float v = acc[mi][ni][j] * alpha;
        if (TMH) v = (((row == col) ? 3.f : 0.f) - v) * 0.5f;
        const long o = oC + (long)row * Nn + col;
        if (OUTMODE == 0){ Cf[o] = v; }
        else { __bf16 h = (__bf16)v; Coh[o] = h; Col[o] = (__bf16)(v - (float)h); }
      }
    }
  }
}

// ======================= fused corr+PV (bf16 E) =======================
__global__ __launch_bounds__(256) void k_pv(
    const __bf16* __restrict__ E, const __bf16* __restrict__ Bh,
    const float* __restrict__ rm, const float* __restrict__ rsc,
    const float* __restrict__ mxv, const float* __restrict__ myv,
    __bf16* __restrict__ resH)
{
  __shared__ __align__(16) __bf16 sa[64 * 64];
  __shared__ __align__(16) __bf16 sb[128 * 64];
  const int z = blockIdx.z;
  int lin = blockIdx.y * 64 + blockIdx.x;
  lin = (lin & 7) * 32 + (lin >> 3);
  const int n0 = (lin & 63) * 64;
  const int c0 = (lin >> 6) * 128;
  const int tid = threadIdx.x;
  const int lane = tid & 63;
  const int w = tid >> 6;
  const int wr = (w >> 1) * 32, wc = (w & 1) * 64;
  const int lr = lane & 15, g = lane >> 4;

  const __bf16* pe = E + (long)z * NN + (long)n0 * N;
  const __bf16* pB = Bh + (long)z * CN + (long)c0 * N;

  const int ar = tid >> 2;
  const int slot = tid & 3;
  const float rmv = rm[(long)z * N + n0 + ar];
  const float rsv = rsc[(long)z * N + n0 + ar];
  const float tgt = mxv[n0 + ar];
  const __bf16* per = pe + (long)ar * N;

  f32x4 acc[2][4] = {};

  for (int kt = 0; kt < N; kt += 64){
#pragma unroll
    for (int d = 0; d < 2; ++d){
      const int gd = slot * 2 + d;
      const bf16x8 ev = *(const bf16x8*)(per + kt + gd * 8);
      const float4 m0 = *(const float4*)(myv + kt + gd * 8);
      const float4 m1 = *(const float4*)(myv + kt + gd * 8 + 4);
      bf16x8 pk;
      pk[0] = (__bf16)((m0.x == tgt) ? __expf((float)ev[0] - rmv) * rsv : 0.f);
      pk[1] = (__bf16)((m0.y == tgt) ? __expf((float)ev[1] - rmv) * rsv : 0.f);
      pk[2] = (__bf16)((m0.z == tgt) ? __expf((float)ev[2] - rmv) * rsv : 0.f);
      pk[3] = (__bf16)((m0.w == tgt) ? __expf((float)ev[3] - rmv) * rsv : 0.f);
      pk[4] = (__bf16)((m1.x == tgt) ? __expf((float)ev[4] - rmv) * rsv : 0.f);
      pk[5] = (__bf16)((m1.y == tgt) ? __expf((float)ev[5] - rmv) * rsv : 0.f);
      pk[6] = (__bf16)((m1.z == tgt) ? __expf((float)ev[6] - rmv) * rsv : 0.f);
      pk[7] = (__bf16)((m1.w == tgt) ? __expf((float)ev[7] - rmv) * rsv : 0.f);
      *(bf16x8*)(&sa[ar * 64 + ((gd ^ (ar & 7)) * 8)]) = pk;
    }
#pragma unroll
    for (int p = 0; p < 4; ++p){
      const int t2 = p * 256 + tid;
      const int row = t2 >> 3;
      const int gs = (t2 & 7) ^ (row & 7);
      gld16(pB + (long)row * N + kt + gs * 8, &sb[t2 * 8]);
    }
    __syncthreads();
#pragma unroll
    for (int ks = 0; ks < 2; ++ks){
      bf16x8 fa[2], fb[4];
#pragma unroll
      for (int mi = 0; mi < 2; ++mi){
        const int row = wr + mi * 16 + lr;
        fa[mi] = *(const bf16x8*)(&sa[row * 64 + (((ks * 4 + g) ^ (row & 7)) * 8)]);
      }
#pragma unroll
      for (int ni = 0; ni < 4; ++ni){
        const int row = wc + ni * 16 + lr;
        fb[ni] = *(const bf16x8*)(&sb[row * 64 + (((ks * 4 + g) ^ (row & 7)) * 8)]);
      }
#pragma unroll
      for (int mi = 0; mi < 2; ++mi)
#pragma unroll
        for (int ni = 0; ni < 4; ++ni)
          acc[mi][ni] = __builtin_amdgcn_mfma_f32_16x16x32_bf16(fa[mi], fb[ni], acc[mi][ni], 0, 0, 0);
    }
    __syncthreads();
  }
#pragma unroll
  for (int mi = 0; mi < 2; ++mi)
#pragma unroll
    for (int ni = 0; ni < 4; ++ni){
      const int c = c0 + wc + ni * 16 + lr;
#pragma unroll
      for (int j = 0; j < 4; ++j){
        const int n = n0 + wr + mi * 16 + g * 4 + j;
        resH[(long)z * NC + (long)n * C + c] = (__bf16)acc[mi][ni][j];
      }
    }
}

// ======================= small helpers =======================
__global__ __launch_bounds__(256) void k_wtw(const float* __restrict__ A, const float* __restrict__ B,
                                             float* __restrict__ C2, float alpha){
  __shared__ float sa[16][32], sb[16][32];
  const int i0 = blockIdx.x * 32, j0 = blockIdx.y * 32;
  const int t = threadIdx.x;
  const int ti = t & 15, tj = t >> 4;
  const int li = t & 31, lc = t >> 5;
  float acc[2][2] = {};
  for (int cb = 0; cb < C; cb += 16){
    sa[lc][li]     = A[(long)(cb + lc) * C + i0 + li];
    sa[lc + 8][li] = A[(long)(cb + lc + 8) * C + i0 + li];
    sb[lc][li]     = B[(long)(cb + lc) * C + j0 + li];
    sb[lc + 8][li] = B[(long)(cb + lc + 8) * C + j0 + li];
    __syncthreads();
#pragma unroll
    for (int c = 0; c < 16; ++c){
      const float a0 = sa[c][ti * 2], a1 = sa[c][ti * 2 + 1];
      const float b0 = sb[c][tj * 2], b1 = sb[c][tj * 2 + 1];
      acc[0][0] = fmaf(a0, b0, acc[0][0]); acc[0][1] = fmaf(a0, b1, acc[0][1]);
      acc[1][0] = fmaf(a1, b0, acc[1][0]); acc[1][1] = fmaf(a1, b1, acc[1][1]);
    }
    __syncthreads();
  }
#pragma unroll
  for (int r = 0; r < 2; ++r)
#pragma unroll
    for (int s = 0; s < 2; ++s)
      C2[(long)(i0 + ti * 2 + r) * C + j0 + tj * 2 + s] = acc[r][s] * alpha;
}

__global__ __launch_bounds__(256) void k_wtv(const float* __restrict__ W, const float* __restrict__ b,
                                             float* __restrict__ u){
  __shared__ float sb2[C];
  const int t = threadIdx.x;
  sb2[t] = b[t]; sb2[t + 256] = b[t + 256];
  __syncthreads();
  const int e = blockIdx.x * 256 + t;
  float acc = 0.f;
  for (int c = 0; c < C; ++c) acc = fmaf(W[(long)c * C + e], sb2[c], acc);
  u[e] = acc;
}

__global__ void k_dot2(const float* __restrict__ a1, const float* __restrict__ b1,
                       const float* __restrict__ a2, const float* __restrict__ b2,
                       float* __restrict__ c0m2, float* __restrict__ c0s4){
  const int t = threadIdx.x;
  float s1 = 0.f, s2 = 0.f;
  for (int i = t; i < C; i += 256){ s1 += a1[i] * b1[i]; s2 += a2[i] * b2[i]; }
  __shared__ float sh1[4], sh2[4];
  s1 = wredSum(s1); s2 = wredSum(s2);
  if ((t & 63) == 0){ sh1[t >> 6] = s1; sh2[t >> 6] = s2; }
  __syncthreads();
  if (t == 0){
    float d1 = sh1[0] + sh1[1] + sh1[2] + sh1[3];
    float d2 = sh2[0] + sh2[1] + sh2[2] + sh2[3];
    c0m2[0] = d1; c0m2[1] = d1;
    c0s4[0] = d2; c0s4[1] = d2; c0s4[2] = d2; c0s4[3] = d2;
  }
}

__global__ __launch_bounds__(256) void k_pixvec(const __bf16* __restrict__ X, const float* __restrict__ u,
                                                float* __restrict__ out){
  const int z = blockIdx.y;
  const int wv = threadIdx.x >> 6, lane = threadIdx.x & 63;
  const int n = blockIdx.x * 4 + wv;
  float acc = 0.f;
  for (int d = lane; d < C; d += 64) acc += (float)X[(long)z * NC + (long)n * C + d] * u[d];
  acc = wredSum(acc);
  if (lane == 0) out[(long)z * N + n] = acc;
}

// ======================= prep / stats =======================
__global__ __launch_bounds__(256) void k_stats(const float* __restrict__ x, const float* __restrict__ y,
                                               float* __restrict__ meanv, float* __restrict__ invs){
  const int bid = blockIdx.x;
  const int t = bid >> 9, c = bid & 511;
  const float* src = (t < 2 ? x : y) + (long)(t & 1) * CN + (long)c * N;
  const int tid = threadIdx.x;
  float s1 = 0.f, s2 = 0.f;
  for (int i = tid; i < N; i += 256){ float v = src[i]; s1 += v; s2 += v * v; }
  __shared__ float sh1[4], sh2[4];
  s1 = wredSum(s1); s2 = wredSum(s2);
  if ((tid & 63) == 0){ sh1[tid >> 6] = s1; sh2[tid >> 6] = s2; }
  __syncthreads();
  if (tid == 0){
    float m = (sh1[0] + sh1[1] + sh1[2] + sh1[3]) * (1.f / (float)N);
    float ex2 = (sh2[0] + sh2[1] + sh2[2] + sh2[3]) * (1.f / (float)N);
    float var = ex2 - m * m;
    meanv[t * C + c] = m;
    invs[t * C + c] = rsqrtf((var > 0.f ? var : 0.f) + EPSC);
  }
}

__global__ __launch_bounds__(256) void k_prep(const float* __restrict__ src,
                                              const float* __restrict__ meanv, const float* __restrict__ invs, int toff,
                                              __bf16* __restrict__ adH,
                                              __bf16* __restrict__ fcH, __bf16* __restrict__ fcL,
                                              __bf16* __restrict__ ccH, __bf16* __restrict__ ccL,
                                              __bf16* __restrict__ rwH){
  __shared__ float tile[64][65];
  const int z = blockIdx.z;
  const int n0 = blockIdx.x * 64;
  const int c0 = blockIdx.y * 64;
  const int tid = threadIdx.x;
  const int tx = tid & 63, ty = tid >> 6;
  const int tgt = toff + z;
#pragma unroll
  for (int it = 0; it < 16; ++it){
    const int cc = it * 4 + ty;
    const float v = src[(long)z * CN + (long)(c0 + cc) * N + n0 + tx];
    tile[cc][tx] = v;
    const float cen = v - meanv[tgt * C + c0 + cc];
    splitw(cen, ccH, ccL, (long)tgt * CN + (long)(c0 + cc) * N + n0 + tx);
  }
  __syncthreads();
  const float m = meanv[tgt * C + c0 + tx];
  const float r = invs[tgt * C + c0 + tx];
#pragma unroll
  for (int it = 0; it < 16; ++it){
    const int p = it * 4 + ty;
    const float v = tile[tx][p];
    const float cen = v - m;
    const long o = (long)z * NC + (long)(n0 + p) * C + c0 + tx;
    adH[o] = (__bf16)(cen * r);
    splitw(cen, fcH, fcL, (long)tgt * NC + (long)(n0 + p) * C + c0 + tx);
    if (rwH) rwH[o] = (__bf16)v;
  }
}

__global__ __launch_bounds__(256) void k_wcvt(const float* __restrict__ s, __bf16* __restrict__ h,
                                              __bf16* __restrict__ l, int n){
  int i = blockIdx.x * 256 + threadIdx.x;
  if (i < n) splitw(s[i], h, l, i);
}
__global__ __launch_bounds__(256) void k_wcvt_h(const float* __restrict__ s, __bf16* __restrict__ h, int n){
  int i = blockIdx.x * 256 + threadIdx.x;
  if (i < n) h[i] = (__bf16)s[i];
}

// ======================= cov diag / power iteration / NS init =======================
__global__ void k_diag(float* __restrict__ cov){
  const int z = blockIdx.x, t = threadIdx.x;
  for (int i = t; i < C; i += 256) cov[(long)z * CC + (long)i * C + i] += 2.f * EPSC;
}

__global__ __launch_bounds__(256) void k_powit(const float* __restrict__ cov,
                                               float* __restrict__ invt, float* __restrict__ invsqt){
  __shared__ float v[C], red[4];
  const int z = blockIdx.x, t = threadIdx.x;
  const float* A = cov + (long)z * CC;
  const int j0 = t, j1 = t + 256;
  v[j0] = 1.f + 0.0003f * (float)j0;
  v[j1] = 1.f + 0.0003f * (float)j1;
  __syncthreads();
  float lam = 1.f;
  for (int it = 0; it < 4; ++it){
    float w0a = 0.f, w0b = 0.f, w1a = 0.f, w1b = 0.f;
#pragma unroll 8
    for (int c = 0; c < C; c += 2){
      const float vc0 = v[c], vc1 = v[c + 1];
      w0a = fmaf(A[(long)c * C + j0], vc0, w0a);
      w1a = fmaf(A[(long)c * C + j1], vc0, w1a);
      w0b = fmaf(A[(long)(c + 1) * C + j0], vc1, w0b);
      w1b = fmaf(A[(long)(c + 1) * C + j1], vc1, w1b);
    }
    const float w0 = w0a + w0b, w1 = w1a + w1b;
    float s = w0 * w0 + w1 * w1;
    s = wredSum(s);
    if ((t & 63) == 0) red[t >> 6] = s;
    __syncthreads();
    const float nrm = sqrtf(red[0] + red[1] + red[2] + red[3]);
    lam = nrm;
    const float inv = 1.f / nrm;
    v[j0] = w0 * inv;
    v[j1] = w1 * inv;
    __syncthreads();
  }
  if (t == 0){
    const float tt = 1.02f * lam;
    invt[z] = 1.f / tt;
    invsqt[z] = rsqrtf(tt);
  }
}

__global__ __launch_bounds__(256) void k_ns_init(const float* __restrict__ cov, const float* __restrict__ invt,
                                                 __bf16* __restrict__ h, __bf16* __restrict__ l,
                                                 __bf16* __restrict__ cph, __bf16* __restrict__ cpl){
  const int r = blockIdx.x, z = blockIdx.y;
  const long base = (long)z * CC + (long)r * C;
  const float it = invt[z];
  for (int i = threadIdx.x; i < C; i += 256){
    const float v = cov[base + i] * it;
    splitw(v, h, l, base + i);
    splitw(v, cph, cpl, base + i);
    h[4 * CC + base + i] = (__bf16)((i == r) ? 1.f : 0.f);
    l[4 * CC + base + i] = (__bf16)0.f;
  }
}

// ======================= softmax aux =======================
__global__ __launch_bounds__(256) void k_prowmerge(const float* __restrict__ Pm, const float* __restrict__ Ps,
                                                   float* __restrict__ rm, float* __restrict__ rsc){
  const int row = blockIdx.x * 256 + threadIdx.x;
  float m = -3.4e38f, s = 0.f;
#pragma unroll 4
  for (int p = 0; p < 32; ++p){
    const float mp = Pm[(long)p * N + row];
    const float sp = Ps[(long)p * N + row];
    const float nm = fmaxf(m, mp);
    s = s * __expf(m - nm) + sp * __expf(mp - nm);
    m = nm;
  }
  rm[row] = m;
  rsc[row] = 1.f / s;
}

__global__ __launch_bounds__(256) void k_prowmerge_m(const float* __restrict__ Pm, const float* __restrict__ Ps,
                                                     const float* __restrict__ Pq,
                                                     float* __restrict__ rm, float* __restrict__ rsc){
  const int z = blockIdx.y;
  const int row = blockIdx.x * 256 + threadIdx.x;
  float m = -3.4e38f, s = 0.f, q = 0.f;
#pragma unroll 4
  for (int p = 0; p < 32; ++p){
    const long idx = (long)(z * 32 + p) * N + row;
    const float mp = Pm[idx], sp = Ps[idx], qp = Pq[idx];
    const float nm = fmaxf(m, mp);
    const float c0_ = __expf(m - nm), c1_ = __expf(mp - nm);
    s = s * c0_ + sp * c1_;
    q = q * c0_ + qp * c1_;
    m = nm;
  }
  float l1 = q / s;
  if (l1 < 1e-12f) l1 = 1e-12f;
  rsc[(long)z * N + row] = 1.f / (s * l1);
  rm[(long)z * N + row] = m;
}

__global__ __launch_bounds__(256) void k_colaccum(const float* __restrict__ E, const float* __restrict__ rowmax,
                                                  const float* __restrict__ rowscale, float* __restrict__ partials){
  const int j = (blockIdx.x * 256 + threadIdx.x) * 4;
  const int r0 = blockIdx.y * 32;
  float4 acc = {0.f, 0.f, 0.f, 0.f};
#pragma unroll 4
  for (int r2 = r0; r2 < r0 + 32; ++r2){
    const float4 e = *reinterpret_cast<const float4*>(E + (long)r2 * N + j);
    const float rmv = rowmax[r2], rsv = rowscale[r2];
    acc.x += __expf(e.x - rmv) * rsv;
    acc.y += __expf(e.y - rmv) * rsv;
    acc.z += __expf(e.z - rmv) * rsv;
    acc.w += __expf(e.w - rmv) * rsv;
  }
  *reinterpret_cast<float4*>(partials + (long)blockIdx.y * N + j) = acc;
}

__global__ __launch_bounds__(256) void k_colreduce(const float* __restrict__ partials, float* __restrict__ att){
  const int j = blockIdx.x * 256 + threadIdx.x;
  float s = 0.f;
#pragma unroll 8
  for (int p = 0; p < 128; ++p) s += partials[(long)p * N + j];
  att[j] = s * (1.f / (float)N);
}

// ======================= mask (radix select) =======================
__global__ __launch_bounds__(256) void k_radix(const float* __restrict__ a, float* __restrict__ thr){
  __shared__ unsigned int vals[N];
  __shared__ float shc[4];
  __shared__ unsigned int p_sh;
  __shared__ int k_sh;
  const float* pa = a + (long)blockIdx.x * N;
  const int tid = threadIdx.x;
  for (int i = tid; i < N; i += 256) vals[i] = __float_as_uint(pa[i]);
  if (tid == 0){ p_sh = 0u; k_sh = KSEL; }
  __syncthreads();
  for (int b = 31; b >= 0; --b){
    const unsigned int bit = 1u << b;
    const unsigned int above = (b == 31) ? 0u : ~((bit << 1) - 1u);
    const unsigned int p = p_sh;
    int cnt = 0;
    for (int i = tid; i < N; i += 256){
      unsigned int v = vals[i];
      if ((v & above) == p && (v & bit)) cnt++;
    }
    float cf = wredSum((float)cnt);
    if ((tid & 63) == 0) shc[tid >> 6] = cf;
    __syncthreads();
    if (tid == 0){
      int c1 = (int)(shc[0] + shc[1] + shc[2] + shc[3] + 0.5f);
      if (k_sh <= c1) p_sh = p | bit;
      else k_sh -= c1;
    }
    __syncthreads();
  }
  if (tid == 0) thr[blockIdx.x] = __uint_as_float(p_sh);
}

__global__ __launch_bounds__(256) void k_mask(const float* __restrict__ ax, const float* __restrict__ ay,
                                              const float* __restrict__ thr, float* __restrict__ mx,
                                              float* __restrict__ my){
  int j = blockIdx.x * 256 + threadIdx.x;
  mx[j] = (ax[j] >= thr[0] && ax[N + j] >= thr[1]) ? 1.f : 0.f;
  my[j] = (ay[j] >= thr[2] && ay[N + j] >= thr[3]) ? 1.f : 0.f;
}

// ======================= host =======================
extern "C" void kernel_launch(void* const* d_in, const int* in_sizes, int n_in,
                              void* d_out, int out_size, void* d_ws, size_t ws_size,
                              hipStream_t stream)
{
  const float* x     = (const float*)d_in[0];
  const float* y     = (const float*)d_in[1];
  const float* f_w   = (const float*)d_in[2];
  const float* f_b   = (const float*)d_in[3];
  const float* g_w   = (const float*)d_in[4];
  const float* g_b   = (const float*)d_in[5];
  const float* saf_w = (const float*)d_in[6];
  const float* saf_b = (const float*)d_in[7];
  const float* sag_w = (const float*)d_in[8];
  const float* sag_b = (const float*)d_in[9];
  const float* h_w   = (const float*)d_in[10];
  const float* h_b   = (const float*)d_in[11];
  const float* ow    = (const float*)d_in[12];
  const float* ob    = (const float*)d_in[13];

  const size_t MBy = 1ull << 20;
  const size_t KBy = 1ull << 10;
  char* base = (char*)d_ws;
  if (ws_size < 206 * MBy) return;
  auto F  = [&](size_t off){ return (float*)(base + off); };
  auto Bp = [&](size_t off){ return (__bf16*)(base + off); };

  float *E0 = F(0);
  __bf16 *Ebf = Bp(0);
  __bf16 *ccH = Bp(0), *ccL = Bp(16*MBy);
  float  *covb = F(32*MBy);
  __bf16 *zpolH = Bp(36*MBy), *zpolL = Bp(38*MBy);
  __bf16 *covPH = Bp(40*MBy), *covPL = Bp(42*MBy);
  float  *KsTf = F(44*MBy), *K2tf = F(45*MBy);
  __bf16 *KsTH = Bp(46*MBy), *KsTL = Bp(46*MBy + 512*KBy);
  __bf16 *K2tH = Bp(47*MBy), *hwH = Bp(47*MBy + 512*KBy);
  __bf16 *tpH = Bp(48*MBy), *tpL = Bp(50*MBy);
  __bf16 *xaH = Bp(64*MBy);
  __bf16 *xzH = Bp(64*MBy), *xzL = Bp(80*MBy);
  __bf16 *ypmH = Bp(96*MBy);
  __bf16 *AsH = Bp(96*MBy), *AsL = Bp(112*MBy);
  __bf16 *fcH = Bp(128*MBy), *fcL = Bp(144*MBy);
  __bf16 *resH = Bp(128*MBy);
  __bf16 *nsAh = Bp(160*MBy), *nsAl = Bp(164*MBy);
  __bf16 *nsBh = Bp(168*MBy), *nsBl = Bp(172*MBy);
  __bf16 *A2H = Bp(176*MBy);
  __bf16 *yaH = Bp(184*MBy);
  __bf16 *hH  = Bp(192*MBy);
  __bf16 *owH = Bp(200*MBy);
  size_t so = 200 * MBy + 512 * KBy;
  auto SF = [&](size_t bytes){ float* p = F(so); so += bytes; return p; };
  float *meanv = SF(8*KBy), *invs = SF(8*KBy);
  float *rm = SF(32*KBy), *rsc = SF(32*KBy);
  float *mxv = SF(16*KBy), *myv = SF(16*KBy);
  float *rvec2 = SF(32*KBy), *cvec2 = SF(32*KBy);
  float *rvS = SF(64*KBy), *cvS = SF(64*KBy);
  float *u1m = SF(2*KBy), *u2m = SF(2*KBy), *u1s = SF(2*KBy), *u2s = SF(2*KBy);
  float *c0m2 = SF(64), *c0s4 = SF(64), *thr = SF(64);
  float *invt = SF(64), *invsqt = SF(64);
  float *partials = F(201*MBy);                      // [128][N] = 2MB  [201,203)
  float *Pm = F(203*MBy);                            // [64][N] = 1MB   [203,204)
  float *Ps = F(204*MBy);                            // [64][N] = 1MB   [204,205)
  float *Pq = F(205*MBy);                            // [64][N] = 1MB   [205,206)

  float* outm = (float*)d_out;
  float* attx = outm + B2 * CN;
  float* atty = attx + (long)B2 * N;

  // 1) stats + prep
  k_stats<<<dim3(4 * C), dim3(256), 0, stream>>>(x, y, meanv, invs);
  k_prep<<<dim3(64, 8, 2), dim3(256), 0, stream>>>(x, meanv, invs, 0, xaH, fcH, fcL, ccH, ccL, nullptr);
  k_prep<<<dim3(64, 8, 2), dim3(256), 0, stream>>>(y, meanv, invs, 2, yaH, fcH, fcL, ccH, ccL, ypmH);

  // 2) weight products & conversions
  k_wtw<<<dim3(16, 16), dim3(256), 0, stream>>>(sag_w, saf_w, KsTf, 1.f);
  k_wtw<<<dim3(16, 16), dim3(256), 0, stream>>>(g_w, f_w, K2tf, 1.f);
  {
    const int nb = (int)(CC / 256);
    k_wcvt<<<nb, 256, 0, stream>>>(KsTf, KsTH, KsTL, (int)CC);
    k_wcvt_h<<<nb, 256, 0, stream>>>(K2tf, K2tH, (int)CC);
    k_wcvt_h<<<nb, 256, 0, stream>>>(h_w, hwH, (int)CC);
    k_wcvt_h<<<nb, 256, 0, stream>>>(ow, owH, (int)CC);
  }
  k_wtv<<<dim3(2), dim3(256), 0, stream>>>(g_w, f_b, u1m);
  k_wtv<<<dim3(2), dim3(256), 0, stream>>>(f_w, g_b, u2m);
  k_wtv<<<dim3(2), dim3(256), 0, stream>>>(sag_w, saf_b, u1s);
  k_wtv<<<dim3(2), dim3(256), 0, stream>>>(saf_w, sag_b, u2s);
  k_dot2<<<dim3(1), dim3(256), 0, stream>>>(f_b, g_b, saf_b, sag_b, c0m2, c0s4);
  k_pixvec<<<dim3(N / 4, 2), dim3(256), 0, stream>>>(xaH, u2m, rvec2);
  k_pixvec<<<dim3(N / 4, 2), dim3(256), 0, stream>>>(yaH, u1m, cvec2);

  // 3) cov + 2eps*I + power-iteration lambda_max
  k_mm64<0,0,0><<<dim3(8, 8, 4), dim3(256), 0, stream>>>(
      ccH, ccL, ccH, ccL, nullptr, nullptr, covb, nullptr, nullptr, C, N, CN, CN, CC, 1.f / (float)(N - 1));
  k_diag<<<dim3(4), dim3(256), 0, stream>>>(covb);
  k_powit<<<dim3(4), dim3(256), 0, stream>>>(covb, invt, invsqt);

  // 4) A2 = xa . K2^T, h conv
  k_mm<1,0,2,0><<<dim3(32, 4, 2), dim3(256), 0, stream>>>(xaH, nullptr, K2tH, nullptr, nullptr, A2H, nullptr,
      C, C, NC, 0, NC, 1.f, nullptr, nullptr, 0, nullptr, 0, nullptr, nullptr, 0,
      nullptr, nullptr, nullptr, nullptr, nullptr);
  k_mm<1,0,2,0><<<dim3(4, 32, 2), dim3(256), 0, stream>>>(hwH, nullptr, ypmH, nullptr, nullptr, hH, nullptr,
      N, C, 0, NC, CN, 1.f, nullptr, h_b, 0, nullptr, 0, nullptr, nullptr, 0,
      nullptr, nullptr, nullptr, nullptr, nullptr);

  // 5) Newton-Schulz (4 iters) + split-bf16 polish
  k_ns_init<<<dim3(C, 4), dim3(256), 0, stream>>>(covb, invt, nsAh, nsAl, covPH, covPL);
  __bf16 *cah = nsAh, *cal = nsAl, *cbh = nsBh, *cbl = nsBl;
  for (int it = 0; it < NS_ITERS; ++it){
    k_mm64<1,1,0><<<dim3(8, 8, 4), dim3(256), 0, stream>>>(
        cah + 4*CC, cal + 4*CC, cah, cal, nullptr, nullptr, nullptr, tpH, tpL, C, C, CC, CC, CC, 1.f);
    k_mm64<0,1,1><<<dim3(8, 8, 8), dim3(256), 0, stream>>>(
        cah, cal, nullptr, nullptr, tpH, tpL, nullptr, cbh, cbl, C, C, CC, CC, CC, 1.f);
    __bf16* t;
    t = cah; cah = cbh; cbh = t;
    t = cal; cal = cbl; cbl = t;
  }
  k_mm64<0,1,0><<<dim3(8, 8, 4), dim3(256), 0, stream>>>(
      cah + 4*CC, cal + 4*CC, cah + 4*CC, cal + 4*CC, nullptr, nullptr, nullptr, tpH, tpL, C, C, CC, CC, CC, 1.f);
  k_mm64<1,1,0><<<dim3(8, 8, 4), dim3(256), 0, stream>>>(
      covPH, covPL, tpH, tpL, nullptr, nullptr, nullptr, cbh, cbl, C, C, CC, CC, CC, 1.f);
  k_mm64<0,1,0><<<dim3(8, 8, 4), dim3(256), 0, stream>>>(
      cah + 4*CC, cal + 4*CC, cbh, cbl, nullptr, nullptr, nullptr, zpolH, zpolL, C, C, CC, CC, CC, 1.f);

  // 6) zca apply: xz = invsqt * fc . Z
  k_mm<3,0,1,0><<<dim3(32, 4, 4), dim3(256), 0, stream>>>(fcH, fcL, zpolH, zpolL, nullptr, xzH, xzL,
      C, C, NC, CC, NC, 1.f, invsqt, nullptr, 0, nullptr, 0, nullptr, nullptr, 0,
      nullptr, nullptr, nullptr, nullptr, nullptr);

  // 6.5) self bias vecs + As = xz . Ks^T
  k_pixvec<<<dim3(N / 4, 4), dim3(256), 0, stream>>>(xzH, u2s, rvS);
  k_pixvec<<<dim3(N / 4, 4), dim3(256), 0, stream>>>(xzH, u1s, cvS);
  k_mm<3,0,1,0><<<dim3(32, 4, 4), dim3(256), 0, stream>>>(xzH, xzL, KsTH, KsTL, nullptr, AsH, AsL,
      C, C, NC, 0, NC, 1.f, nullptr, nullptr, 0, nullptr, 0, nullptr, nullptr, 0,
      nullptr, nullptr, nullptr, nullptr, nullptr);

  // 7) self-attention energies (3-pass, fp32 E, two-phase fused row-stats) -> atten
  for (int z = 0; z < 4; ++z){
    k_mm<3,0,0,1><<<dim3(32, 32, 1), dim3(256), 0, stream>>>(AsH + (long)z*NC, AsL + (long)z*NC,
        xzH + (long)z*NC, xzL + (long)z*NC, E0, nullptr, nullptr,
        N, C, 0, 0, 0, 1.f, nullptr, rvS + (long)z*N, 0, cvS + (long)z*N, 0, c0s4, nullptr, 0,
        Pm, Ps, nullptr, nullptr, nullptr);
    k_prowmerge<<<dim3(16), dim3(256), 0, stream>>>(Pm, Ps, rm, rsc);
    k_colaccum<<<dim3(4, 128), dim3(256), 0, stream>>>(E0, rm, rsc, partials);
    k_colreduce<<<dim3(16), dim3(256), 0, stream>>>(partials, (z < 2 ? attx : atty) + (long)(z & 1) * N);
  }

  // 8) masks
  k_radix<<<dim3(2), dim3(256), 0, stream>>>(attx, thr);
  k_radix<<<dim3(2), dim3(256), 0, stream>>>(atty, thr + 2);
  k_mask<<<dim3(16), dim3(256), 0, stream>>>(attx, atty, thr, mxv, myv);

  // 9) main path: energy -> bf16 E with two-phase fused masked row-stats; merge; PV; out conv
  k_mm<1,0,2,2><<<dim3(32, 32, 2), dim3(256), 0, stream>>>(A2H, nullptr, yaH, nullptr, nullptr, Ebf, nullptr,
      N, C, NC, NC, NN, 1.f, nullptr, rvec2, N, cvec2, N, c0m2, nullptr, 0,
      Pm, Ps, Pq, mxv, myv);
  k_prowmerge_m<<<dim3(16, 2), dim3(256), 0, stream>>>(Pm, Ps, Pq, rm, rsc);
  k_pv<<<dim3(64, 4, 2), dim3(256), 0, stream>>>(Ebf, hH, rm, rsc, mxv, myv, resH);
  k_mm<1,0,0,0><<<dim3(4, 32, 2), dim3(256), 0, stream>>>(owH, nullptr, resH, nullptr, outm, nullptr, nullptr,
      N, C, 0, NC, CN, 1.f, nullptr, ob, 0, nullptr, 0, nullptr, x, CN,
      nullptr, nullptr, nullptr, nullptr, nullptr);
}

// Round 13
// 1242.105 us; speedup vs baseline: 1.1435x; 1.0092x over previous
//
#include <hip/hip_runtime.h>
#include <cstdint>

static constexpr int B2 = 2;
static constexpr int C = 512;
static constexpr int N = 4096;
static constexpr long CN = (long)C * N;
static constexpr long NC = (long)N * C;
static constexpr long CC = (long)C * C;
static constexpr long NN = (long)N * N;
static constexpr float EPSC = 1e-5f;
static constexpr int KSEL = 308;       // N - int(N*0.925)
static constexpr int NS_ITERS = 4;

typedef __attribute__((ext_vector_type(8))) __bf16 bf16x8;
typedef __attribute__((ext_vector_type(4))) float f32x4;

__device__ __forceinline__ float wredSum(float v){
#pragma unroll
  for (int o = 32; o >= 1; o >>= 1) v += __shfl_xor(v, o, 64);
  return v;
}

__device__ __forceinline__ void gld16(const __bf16* g, __bf16* l){
  __builtin_amdgcn_global_load_lds(
      (const __attribute__((address_space(1))) void*)g,
      (__attribute__((address_space(3))) void*)l, 16, 0, 0);
}

__device__ __forceinline__ void splitw(float v, __bf16* ph, __bf16* pl, long o){
  __bf16 h = (__bf16)v;
  ph[o] = h;
  pl[o] = (__bf16)(v - (float)h);
}

// ======================= split/plain bf16 MFMA GEMM, 128x128 tile, BK=32 =======================
// XCD swizzle. ROWP: 0 none | 1 row softmax partials | 2 masked (mxp/myp, writes Pq)
// Two-phase epilogue: pass1 value+max (fmax only), pass2 exp-sums vs final max.
template<int PASSES, int TMH, int OUTMODE, int ROWP>
__global__ __launch_bounds__(256) void k_mm(
    const __bf16* __restrict__ Ah, const __bf16* __restrict__ Al,
    const __bf16* __restrict__ Bh, const __bf16* __restrict__ Bl,
    float* __restrict__ Cf, __bf16* __restrict__ Coh, __bf16* __restrict__ Col,
    int Nn, int K, long sAz, long sBz, long sCz,
    float alpha, const float* __restrict__ alpha_ptr,
    const float* __restrict__ brow, long sBr,
    const float* __restrict__ bcol, long sBc,
    const float* __restrict__ c0p,
    const float* __restrict__ addsrc, long sAddz,
    float* __restrict__ Pm, float* __restrict__ Ps, float* __restrict__ Pq,
    const float* __restrict__ mxp, const float* __restrict__ myp)
{
  constexpr int NB = (PASSES == 3) ? 4 : 2;
  constexpr int SB = (PASSES == 3) ? 2 : 1;
  __shared__ __align__(16) __bf16 sm[NB][128 * 32];
  __shared__ float pmx[2][128], psx[2][128], pqx[2][128];
  const int z = blockIdx.z;
  const int nwx = gridDim.x;
  int lin = blockIdx.y * nwx + blockIdx.x;
  const int nwg = nwx * gridDim.y;
  if ((nwg & 7) == 0){
    const int cpx = nwg >> 3;
    lin = (lin & 7) * cpx + (lin >> 3);
  }
  const int i0 = (lin % nwx) * 128;
  const int j0 = (lin / nwx) * 128;
  const int tid = threadIdx.x;
  const int lane = tid & 63;
  const int w = tid >> 6;
  const int wr = (w >> 1) * 64, wc = (w & 1) * 64;
  const int lr = lane & 15;
  const int g = lane >> 4;

  const __bf16* pAh = Ah + (long)z * sAz + (long)i0 * K;
  const __bf16* pBh = Bh + (long)z * sBz + (long)j0 * K;
  const __bf16* pAl = (PASSES == 3) ? (Al + (long)z * sAz + (long)i0 * K) : nullptr;
  const __bf16* pBl = (PASSES == 3) ? (Bl + (long)z * sBz + (long)j0 * K) : nullptr;

  f32x4 acc[4][4] = {};

  for (int kt = 0; kt < K; kt += 32){
#pragma unroll
    for (int p = 0; p < 2; ++p){
      const int t2 = p * 256 + tid;
      const int row = t2 >> 2;
      const int gs = (t2 & 3) ^ ((row >> 1) & 3);
      const long go = (long)row * K + kt + gs * 8;
      gld16(pAh + go, &sm[0][t2 * 8]);
      gld16(pBh + go, &sm[SB][t2 * 8]);
      if constexpr (PASSES == 3){
        gld16(pAl + go, &sm[1][t2 * 8]);
        gld16(pBl + go, &sm[3][t2 * 8]);
      }
    }
    __syncthreads();
    bf16x8 fa[4], fal[4], fb[4], fbl[4];
#pragma unroll
    for (int mi = 0; mi < 4; ++mi){
      const int row = wr + mi * 16 + lr;
      const int off = row * 32 + ((g ^ ((row >> 1) & 3)) * 8);
      fa[mi] = *(const bf16x8*)(&sm[0][off]);
      if constexpr (PASSES == 3) fal[mi] = *(const bf16x8*)(&sm[1][off]);
    }
#pragma unroll
    for (int ni = 0; ni < 4; ++ni){
      const int row = wc + ni * 16 + lr;
      const int off = row * 32 + ((g ^ ((row >> 1) & 3)) * 8);
      fb[ni] = *(const bf16x8*)(&sm[SB][off]);
      if constexpr (PASSES == 3) fbl[ni] = *(const bf16x8*)(&sm[3][off]);
    }
#pragma unroll
    for (int mi = 0; mi < 4; ++mi)
#pragma unroll
      for (int ni = 0; ni < 4; ++ni){
        acc[mi][ni] = __builtin_amdgcn_mfma_f32_16x16x32_bf16(fa[mi], fb[ni], acc[mi][ni], 0, 0, 0);
        if constexpr (PASSES == 3){
          acc[mi][ni] = __builtin_amdgcn_mfma_f32_16x16x32_bf16(fa[mi],  fbl[ni], acc[mi][ni], 0, 0, 0);
          acc[mi][ni] = __builtin_amdgcn_mfma_f32_16x16x32_bf16(fal[mi], fb[ni],  acc[mi][ni], 0, 0, 0);
        }
      }
    __syncthreads();
  }

  float al2 = alpha;
  if (alpha_ptr) al2 *= alpha_ptr[z];
  const float c0v = c0p ? c0p[z] : 0.f;
#pragma unroll
  for (int mi = 0; mi < 4; ++mi){
    float vv[4][4];
    float mrow[4] = {-3.4e38f, -3.4e38f, -3.4e38f, -3.4e38f};
#pragma unroll
    for (int ni = 0; ni < 4; ++ni){
      const int col = j0 + wc + ni * 16 + lr;
      const float bc = (bcol ? bcol[z * sBc + col] : 0.f) + c0v;
#pragma unroll
      for (int j = 0; j < 4; ++j){
        const int row = i0 + wr + mi * 16 + g * 4 + j;
        float v = acc[mi][ni][j] * al2;
        if (TMH) v = (((row == col) ? 3.f : 0.f) - v) * 0.5f;
        if (brow) v += brow[z * sBr + row];
        v += bc;
        if (addsrc) v += addsrc[(long)z * sAddz + (long)row * Nn + col];
        const long o = (long)z * sCz + (long)row * Nn + col;
        if (OUTMODE == 0){ Cf[o] = v; }
        else if (OUTMODE == 1){ __bf16 h = (__bf16)v; Coh[o] = h; Col[o] = (__bf16)(v - (float)h); }
        else { __bf16 h = (__bf16)v; Coh[o] = h; if (ROWP == 2) v = (float)h; }
        if constexpr (ROWP >= 1){
          vv[ni][j] = v;
          mrow[j] = fmaxf(mrow[j], v);
        }
      }
    }
    if constexpr (ROWP >= 1){
#pragma unroll
      for (int j = 0; j < 4; ++j)
#pragma unroll
        for (int o = 1; o <= 8; o <<= 1)
          mrow[j] = fmaxf(mrow[j], __shfl_xor(mrow[j], o, 64));
      float tgt[4];
      if constexpr (ROWP == 2){
#pragma unroll
        for (int j = 0; j < 4; ++j)
          tgt[j] = mxp[i0 + wr + mi * 16 + g * 4 + j];
      }
      float srow[4] = {0.f, 0.f, 0.f, 0.f};
      float qrow[4] = {0.f, 0.f, 0.f, 0.f};
#pragma unroll
      for (int ni = 0; ni < 4; ++ni){
        const float mycol = (ROWP == 2) ? myp[j0 + wc + ni * 16 + lr] : 0.f;
#pragma unroll
        for (int j = 0; j < 4; ++j){
          const float ev = __expf(vv[ni][j] - mrow[j]);
          srow[j] += ev;
          if constexpr (ROWP == 2){
            if (mycol == tgt[j]) qrow[j] += ev;
          }
        }
      }
#pragma unroll
      for (int j = 0; j < 4; ++j){
#pragma unroll
        for (int o = 1; o <= 8; o <<= 1){
          srow[j] += __shfl_xor(srow[j], o, 64);
          if constexpr (ROWP == 2) qrow[j] += __shfl_xor(qrow[j], o, 64);
        }
        if (lr == 0){
          const int rl = wr + mi * 16 + g * 4 + j;
          pmx[w & 1][rl] = mrow[j];
          psx[w & 1][rl] = srow[j];
          if constexpr (ROWP == 2) pqx[w & 1][rl] = qrow[j];
        }
      }
    }
  }
  if constexpr (ROWP >= 1){
    __syncthreads();
    if (tid < 128){
      const float m0 = pmx[0][tid], s0 = psx[0][tid];
      const float m1 = pmx[1][tid], s1 = psx[1][tid];
      const float nm = fmaxf(m0, m1);
      const float c0_ = __expf(m0 - nm), c1_ = __expf(m1 - nm);
      const float s = s0 * c0_ + s1 * c1_;
      const long po = (long)(z * 32 + (j0 >> 7)) * N + i0 + tid;
      Pm[po] = nm;
      Ps[po] = s;
      if constexpr (ROWP == 2){
        Pq[po] = pqx[0][tid] * c0_ + pqx[1][tid] * c1_;
      }
    }
  }
}

// ======================= split-bf16 MFMA GEMM, 64x64 tile, BK=64 (always 3-pass) =======================
// NSYZ: 0 plain | 1 z<4: Y=Yz*T^T, z>=4: Z'=T*Z^T | 2 (z in [0,4)): Z'=T*Z^T only
template<int TMH, int OUTMODE, int NSYZ>
__global__ __launch_bounds__(256) void k_mm64(
    const __bf16* __restrict__ Ah, const __bf16* __restrict__ Al,
    const __bf16* __restrict__ Bh, const __bf16* __restrict__ Bl,
    const __bf16* __restrict__ tH, const __bf16* __restrict__ tL,
    float* __restrict__ Cf, __bf16* __restrict__ Coh, __bf16* __restrict__ Col,
    int Nn, int K, long sAz, long sBz, long sCz, float alpha)
{
  __shared__ __align__(16) __bf16 sm[4][64 * 64];
  const int z = blockIdx.z;
  const __bf16 *bAh, *bAl, *bBh, *bBl;
  long oC;
  if constexpr (NSYZ == 1){
    if (z < 4){
      bAh = Ah + (long)z * CC; bAl = Al + (long)z * CC;
      bBh = tH + (long)z * CC; bBl = tL + (long)z * CC;
      oC = (long)z * CC;
    } else {
      const int zz = z - 4;
      bAh = tH + (long)zz * CC; bAl = tL + (long)zz * CC;
      bBh = Ah + (long)(4 + zz) * CC; bBl = Al + (long)(4 + zz) * CC;
      oC = (long)(4 + zz) * CC;
    }
  } else if constexpr (NSYZ == 2){
    bAh = tH + (long)z * CC; bAl = tL + (long)z * CC;
    bBh = Ah + (long)(4 + z) * CC; bBl = Al + (long)(4 + z) * CC;
    oC = (long)(4 + z) * CC;
  } else {
    bAh = Ah + (long)z * sAz; bAl = Al + (long)z * sAz;
    bBh = Bh + (long)z * sBz; bBl = Bl + (long)z * sBz;
    oC = (long)z * sCz;
  }
  const int i0 = blockIdx.x * 64;
  const int j0 = blockIdx.y * 64;
  const int tid = threadIdx.x;
  const int lane = tid & 63;
  const int w = tid >> 6;
  const int wr = (w >> 1) * 32, wc = (w & 1) * 32;
  const int lr = lane & 15;
  const int g = lane >> 4;

  const __bf16* pAh = bAh + (long)i0 * K;
  const __bf16* pAl = bAl + (long)i0 * K;
  const __bf16* pBh = bBh + (long)j0 * K;
  const __bf16* pBl = bBl + (long)j0 * K;

  f32x4 acc[2][2] = {};

  for (int kt = 0; kt < K; kt += 64){
#pragma unroll
    for (int p = 0; p < 2; ++p){
      const int t2 = p * 256 + tid;
      const int row = t2 >> 3;
      const int gs = (t2 & 7) ^ (row & 7);
      const long go = (long)row * K + kt + gs * 8;
      gld16(pAh + go, &sm[0][t2 * 8]);
      gld16(pAl + go, &sm[1][t2 * 8]);
      gld16(pBh + go, &sm[2][t2 * 8]);
      gld16(pBl + go, &sm[3][t2 * 8]);
    }
    __syncthreads();
#pragma unroll
    for (int ks = 0; ks < 2; ++ks){
      bf16x8 fa[2], fal[2], fb[2], fbl[2];
#pragma unroll
      for (int mi = 0; mi < 2; ++mi){
        const int row = wr + mi * 16 + lr;
        const int off = row * 64 + (((ks * 4 + g) ^ (row & 7)) * 8);
        fa[mi]  = *(const bf16x8*)(&sm[0][off]);
        fal[mi] = *(const bf16x8*)(&sm[1][off]);
      }
#pragma unroll
      for (int ni = 0; ni < 2; ++ni){
        const int row = wc + ni * 16 + lr;
        const int off = row * 64 + (((ks * 4 + g) ^ (row & 7)) * 8);
        fb[ni]  = *(const bf16x8*)(&sm[2][off]);
        fbl[ni] = *(const bf16x8*)(&sm[3][off]);
      }
#pragma unroll
      for (int mi = 0; mi < 2; ++mi)
#pragma unroll
        for (int ni = 0; ni < 2; ++ni){
          acc[mi][ni] = __builtin_amdgcn_mfma_f32_16x16x32_bf16(fa[mi],  fb[ni],  acc[mi][ni], 0, 0, 0);
          acc[mi][ni] = __builtin_amdgcn_mfma_f32_16x16x32_bf16(fa[mi],  fbl[ni], acc[mi][ni], 0, 0, 0);
          acc[mi][ni] = __builtin_amdgcn_mfma_f32_16x16x32_bf16(fal[mi], fb[ni],  acc[mi][ni], 0, 0, 0);
        }
    }
    __syncthreads();
  }

#pragma unroll
  for (int mi = 0; mi < 2; ++mi){
#pragma unroll
    for (int ni = 0; ni < 2; ++ni){
      const int col = j0 + wc + ni * 16 + lr;
#pragma unroll
      for (int j = 0; j < 4; ++j){
        const int row = i0 + wr + mi * 16 + g * 4 + j;
        float v = acc[mi][ni][j] * alpha;
        if (TMH) v = (((row == col) ? 3.f : 0.f) - v) * 0.5f;
        const long o = oC + (long)row * Nn + col;
        if (OUTMODE == 0){ Cf[o] = v; }
        else { __bf16 h = (__bf16)v; Coh[o] = h; Col[o] = (__bf16)(v - (float)h); }
      }
    }
  }
}

// ======================= fused corr+PV (bf16 E), K-step 128 =======================
__global__ __launch_bounds__(256) void k_pv(
    const __bf16* __restrict__ E, const __bf16* __restrict__ Bh,
    const float* __restrict__ rm, const float* __restrict__ rsc,
    const float* __restrict__ mxv, const float* __restrict__ myv,
    __bf16* __restrict__ resH)
{
  __shared__ __align__(16) __bf16 sa[64 * 128];    // 16 KB
  __shared__ __align__(16) __bf16 sb[128 * 128];   // 32 KB
  const int z = blockIdx.z;
  int lin = blockIdx.y * 64 + blockIdx.x;
  lin = (lin & 7) * 32 + (lin >> 3);
  const int n0 = (lin & 63) * 64;
  const int c0 = (lin >> 6) * 128;
  const int tid = threadIdx.x;
  const int lane = tid & 63;
  const int w = tid >> 6;
  const int wr = (w >> 1) * 32, wc = (w & 1) * 64;
  const int lr = lane & 15, g = lane >> 4;

  const __bf16* pe = E + (long)z * NN + (long)n0 * N;
  const __bf16* pB = Bh + (long)z * CN + (long)c0 * N;

  const int ar = tid >> 2;          // row 0..63
  const int slot = tid & 3;         // covers granules slot*4 .. slot*4+3 (of 16)
  const float rmv = rm[(long)z * N + n0 + ar];
  const float rsv = rsc[(long)z * N + n0 + ar];
  const float tgt = mxv[n0 + ar];
  const __bf16* per = pe + (long)ar * N;

  f32x4 acc[2][4] = {};

  for (int kt = 0; kt < N; kt += 128){
#pragma unroll
    for (int d = 0; d < 4; ++d){
      const int gd = slot * 4 + d;
      const bf16x8 ev = *(const bf16x8*)(per + kt + gd * 8);
      const float4 m0 = *(const float4*)(myv + kt + gd * 8);
      const float4 m1 = *(const float4*)(myv + kt + gd * 8 + 4);
      bf16x8 pk;
      pk[0] = (__bf16)((m0.x == tgt) ? __expf((float)ev[0] - rmv) * rsv : 0.f);
      pk[1] = (__bf16)((m0.y == tgt) ? __expf((float)ev[1] - rmv) * rsv : 0.f);
      pk[2] = (__bf16)((m0.z == tgt) ? __expf((float)ev[2] - rmv) * rsv : 0.f);
      pk[3] = (__bf16)((m0.w == tgt) ? __expf((float)ev[3] - rmv) * rsv : 0.f);
      pk[4] = (__bf16)((m1.x == tgt) ? __expf((float)ev[4] - rmv) * rsv : 0.f);
      pk[5] = (__bf16)((m1.y == tgt) ? __expf((float)ev[5] - rmv) * rsv : 0.f);
      pk[6] = (__bf16)((m1.z == tgt) ? __expf((float)ev[6] - rmv) * rsv : 0.f);
      pk[7] = (__bf16)((m1.w == tgt) ? __expf((float)ev[7] - rmv) * rsv : 0.f);
      *(bf16x8*)(&sa[ar * 128 + ((gd ^ (ar & 15)) * 8)]) = pk;
    }
#pragma unroll
    for (int p = 0; p < 8; ++p){
      const int t2 = p * 256 + tid;
      const int row = t2 >> 4;
      const int gs = (t2 & 15) ^ (row & 15);
      gld16(pB + (long)row * N + kt + gs * 8, &sb[t2 * 8]);
    }
    __syncthreads();
#pragma unroll
    for (int ks = 0; ks < 4; ++ks){
      bf16x8 fa[2], fb[4];
#pragma unroll
      for (int mi = 0; mi < 2; ++mi){
        const int row = wr + mi * 16 + lr;
        fa[mi] = *(const bf16x8*)(&sa[row * 128 + (((ks * 4 + g) ^ (row & 15)) * 8)]);
      }
#pragma unroll
      for (int ni = 0; ni < 4; ++ni){
        const int row = wc + ni * 16 + lr;
        fb[ni] = *(const bf16x8*)(&sb[row * 128 + (((ks * 4 + g) ^ (row & 15)) * 8)]);
      }
#pragma unroll
      for (int mi = 0; mi < 2; ++mi)
#pragma unroll
        for (int ni = 0; ni < 4; ++ni)
          acc[mi][ni] = __builtin_amdgcn_mfma_f32_16x16x32_bf16(fa[mi], fb[ni], acc[mi][ni], 0, 0, 0);
    }
    __syncthreads();
  }
#pragma unroll
  for (int mi = 0; mi < 2; ++mi)
#pragma unroll
    for (int ni = 0; ni < 4; ++ni){
      const int c = c0 + wc + ni * 16 + lr;
#pragma unroll
      for (int j = 0; j < 4; ++j){
        const int n = n0 + wr + mi * 16 + g * 4 + j;
        resH[(long)z * NC + (long)n * C + c] = (__bf16)acc[mi][ni][j];
      }
    }
}

// ======================= small helpers =======================
__global__ __launch_bounds__(256) void k_wtw(const float* __restrict__ A, const float* __restrict__ B,
                                             float* __restrict__ C2, float alpha){
  __shared__ float sa[16][32], sb[16][32];
  const int i0 = blockIdx.x * 32, j0 = blockIdx.y * 32;
  const int t = threadIdx.x;
  const int ti = t & 15, tj = t >> 4;
  const int li = t & 31, lc = t >> 5;
  float acc[2][2] = {};
  for (int cb = 0; cb < C; cb += 16){
    sa[lc][li]     = A[(long)(cb + lc) * C + i0 + li];
    sa[lc + 8][li] = A[(long)(cb + lc + 8) * C + i0 + li];
    sb[lc][li]     = B[(long)(cb + lc) * C + j0 + li];
    sb[lc + 8][li] = B[(long)(cb + lc + 8) * C + j0 + li];
    __syncthreads();
#pragma unroll
    for (int c = 0; c < 16; ++c){
      const float a0 = sa[c][ti * 2], a1 = sa[c][ti * 2 + 1];
      const float b0 = sb[c][tj * 2], b1 = sb[c][tj * 2 + 1];
      acc[0][0] = fmaf(a0, b0, acc[0][0]); acc[0][1] = fmaf(a0, b1, acc[0][1]);
      acc[1][0] = fmaf(a1, b0, acc[1][0]); acc[1][1] = fmaf(a1, b1, acc[1][1]);
    }
    __syncthreads();
  }
#pragma unroll
  for (int r = 0; r < 2; ++r)
#pragma unroll
    for (int s = 0; s < 2; ++s)
      C2[(long)(i0 + ti * 2 + r) * C + j0 + tj * 2 + s] = acc[r][s] * alpha;
}

__global__ __launch_bounds__(256) void k_wtv(const float* __restrict__ W, const float* __restrict__ b,
                                             float* __restrict__ u){
  __shared__ float sb2[C];
  const int t = threadIdx.x;
  sb2[t] = b[t]; sb2[t + 256] = b[t + 256];
  __syncthreads();
  const int e = blockIdx.x * 256 + t;
  float acc = 0.f;
  for (int c = 0; c < C; ++c) acc = fmaf(W[(long)c * C + e], sb2[c], acc);
  u[e] = acc;
}

__global__ void k_dot2(const float* __restrict__ a1, const float* __restrict__ b1,
                       const float* __restrict__ a2, const float* __restrict__ b2,
                       float* __restrict__ c0m2, float* __restrict__ c0s4){
  const int t = threadIdx.x;
  float s1 = 0.f, s2 = 0.f;
  for (int i = t; i < C; i += 256){ s1 += a1[i] * b1[i]; s2 += a2[i] * b2[i]; }
  __shared__ float sh1[4], sh2[4];
  s1 = wredSum(s1); s2 = wredSum(s2);
  if ((t & 63) == 0){ sh1[t >> 6] = s1; sh2[t >> 6] = s2; }
  __syncthreads();
  if (t == 0){
    float d1 = sh1[0] + sh1[1] + sh1[2] + sh1[3];
    float d2 = sh2[0] + sh2[1] + sh2[2] + sh2[3];
    c0m2[0] = d1; c0m2[1] = d1;
    c0s4[0] = d2; c0s4[1] = d2; c0s4[2] = d2; c0s4[3] = d2;
  }
}

__global__ __launch_bounds__(256) void k_pixvec(const __bf16* __restrict__ X, const float* __restrict__ u,
                                                float* __restrict__ out){
  const int z = blockIdx.y;
  const int wv = threadIdx.x >> 6, lane = threadIdx.x & 63;
  const int n = blockIdx.x * 4 + wv;
  float acc = 0.f;
  for (int d = lane; d < C; d += 64) acc += (float)X[(long)z * NC + (long)n * C + d] * u[d];
  acc = wredSum(acc);
  if (lane == 0) out[(long)z * N + n] = acc;
}

// two dot products in one pass over X
__global__ __launch_bounds__(256) void k_pixvec2(const __bf16* __restrict__ X,
                                                 const float* __restrict__ u1, const float* __restrict__ u2,
                                                 float* __restrict__ out1, float* __restrict__ out2){
  const int z = blockIdx.y;
  const int wv = threadIdx.x >> 6, lane = threadIdx.x & 63;
  const int n = blockIdx.x * 4 + wv;
  float a1 = 0.f, a2 = 0.f;
  for (int d = lane; d < C; d += 64){
    const float xv = (float)X[(long)z * NC + (long)n * C + d];
    a1 = fmaf(xv, u1[d], a1);
    a2 = fmaf(xv, u2[d], a2);
  }
  a1 = wredSum(a1);
  a2 = wredSum(a2);
  if (lane == 0){ out1[(long)z * N + n] = a1; out2[(long)z * N + n] = a2; }
}

// ======================= prep / stats =======================
__global__ __launch_bounds__(256) void k_stats(const float* __restrict__ x, const float* __restrict__ y,
                                               float* __restrict__ meanv, float* __restrict__ invs){
  const int bid = blockIdx.x;
  const int t = bid >> 9, c = bid & 511;
  const float* src = (t < 2 ? x : y) + (long)(t & 1) * CN + (long)c * N;
  const int tid = threadIdx.x;
  float s1 = 0.f, s2 = 0.f;
  for (int i = tid; i < N; i += 256){ float v = src[i]; s1 += v; s2 += v * v; }
  __shared__ float sh1[4], sh2[4];
  s1 = wredSum(s1); s2 = wredSum(s2);
  if ((tid & 63) == 0){ sh1[tid >> 6] = s1; sh2[tid >> 6] = s2; }
  __syncthreads();
  if (tid == 0){
    float m = (sh1[0] + sh1[1] + sh1[2] + sh1[3]) * (1.f / (float)N);
    float ex2 = (sh2[0] + sh2[1] + sh2[2] + sh2[3]) * (1.f / (float)N);
    float var = ex2 - m * m;
    meanv[t * C + c] = m;
    invs[t * C + c] = rsqrtf((var > 0.f ? var : 0.f) + EPSC);
  }
}

__global__ __launch_bounds__(256) void k_prep(const float* __restrict__ src,
                                              const float* __restrict__ meanv, const float* __restrict__ invs, int toff,
                                              __bf16* __restrict__ adH,
                                              __bf16* __restrict__ fcH, __bf16* __restrict__ fcL,
                                              __bf16* __restrict__ ccH, __bf16* __restrict__ ccL,
                                              __bf16* __restrict__ rwH){
  __shared__ float tile[64][65];
  const int z = blockIdx.z;
  const int n0 = blockIdx.x * 64;
  const int c0 = blockIdx.y * 64;
  const int tid = threadIdx.x;
  const int tx = tid & 63, ty = tid >> 6;
  const int tgt = toff + z;
#pragma unroll
  for (int it = 0; it < 16; ++it){
    const int cc = it * 4 + ty;
    const float v = src[(long)z * CN + (long)(c0 + cc) * N + n0 + tx];
    tile[cc][tx] = v;
    const float cen = v - meanv[tgt * C + c0 + cc];
    splitw(cen, ccH, ccL, (long)tgt * CN + (long)(c0 + cc) * N + n0 + tx);
  }
  __syncthreads();
  const float m = meanv[tgt * C + c0 + tx];
  const float r = invs[tgt * C + c0 + tx];
#pragma unroll
  for (int it = 0; it < 16; ++it){
    const int p = it * 4 + ty;
    const float v = tile[tx][p];
    const float cen = v - m;
    const long o = (long)z * NC + (long)(n0 + p) * C + c0 + tx;
    adH[o] = (__bf16)(cen * r);
    splitw(cen, fcH, fcL, (long)tgt * NC + (long)(n0 + p) * C + c0 + tx);
    if (rwH) rwH[o] = (__bf16)v;
  }
}

__global__ __launch_bounds__(256) void k_wcvt(const float* __restrict__ s, __bf16* __restrict__ h,
                                              __bf16* __restrict__ l, int n){
  int i = blockIdx.x * 256 + threadIdx.x;
  if (i < n) splitw(s[i], h, l, i);
}
__global__ __launch_bounds__(256) void k_wcvt_h(const float* __restrict__ s, __bf16* __restrict__ h, int n){
  int i = blockIdx.x * 256 + threadIdx.x;
  if (i < n) h[i] = (__bf16)s[i];
}

// ======================= power iteration / NS init (2eps*I folded in) =======================
__global__ __launch_bounds__(256) void k_powit(const float* __restrict__ cov,
                                               float* __restrict__ invt, float* __restrict__ invsqt){
  __shared__ float v[C], red[4];
  const int z = blockIdx.x, t = threadIdx.x;
  const float* A = cov + (long)z * CC;
  const int j0 = t, j1 = t + 256;
  v[j0] = 1.f + 0.0003f * (float)j0;
  v[j1] = 1.f + 0.0003f * (float)j1;
  __syncthreads();
  float lam = 1.f;
  for (int it = 0; it < 4; ++it){
    float w0a = 0.f, w0b = 0.f, w1a = 0.f, w1b = 0.f;
#pragma unroll 8
    for (int c = 0; c < C; c += 2){
      const float vc0 = v[c], vc1 = v[c + 1];
      w0a = fmaf(A[(long)c * C + j0], vc0, w0a);
      w1a = fmaf(A[(long)c * C + j1], vc0, w1a);
      w0b = fmaf(A[(long)(c + 1) * C + j0], vc1, w0b);
      w1b = fmaf(A[(long)(c + 1) * C + j1], vc1, w1b);
    }
    const float w0 = w0a + w0b + 2.f * EPSC * v[j0];
    const float w1 = w1a + w1b + 2.f * EPSC * v[j1];
    float s = w0 * w0 + w1 * w1;
    s = wredSum(s);
    if ((t & 63) == 0) red[t >> 6] = s;
    __syncthreads();
    const float nrm = sqrtf(red[0] + red[1] + red[2] + red[3]);
    lam = nrm;
    const float inv = 1.f / nrm;
    v[j0] = w0 * inv;
    v[j1] = w1 * inv;
    __syncthreads();
  }
  if (t == 0){
    const float tt = 1.02f * lam;
    invt[z] = 1.f / tt;
    invsqt[z] = rsqrtf(tt);
  }
}

__global__ __launch_bounds__(256) void k_ns_init(const float* __restrict__ cov, const float* __restrict__ invt,
                                                 __bf16* __restrict__ h, __bf16* __restrict__ l,
                                                 __bf16* __restrict__ cph, __bf16* __restrict__ cpl){
  const int r = blockIdx.x, z = blockIdx.y;
  const long base = (long)z * CC + (long)r * C;
  const float it = invt[z];
  for (int i = threadIdx.x; i < C; i += 256){
    const float cv = cov[base + i] + ((i == r) ? 2.f * EPSC : 0.f);
    const float v = cv * it;
    splitw(v, h, l, base + i);
    splitw(v, cph, cpl, base + i);
    h[4 * CC + base + i] = (__bf16)((i == r) ? 1.f : 0.f);
    l[4 * CC + base + i] = (__bf16)0.f;
  }
}

// ======================= softmax aux =======================
__global__ __launch_bounds__(256) void k_prowmerge(const float* __restrict__ Pm, const float* __restrict__ Ps,
                                                   float* __restrict__ rm, float* __restrict__ rsc){
  const int row = blockIdx.x * 256 + threadIdx.x;
  float m = -3.4e38f, s = 0.f;
#pragma unroll 4
  for (int p = 0; p < 32; ++p){
    const float mp = Pm[(long)p * N + row];
    const float sp = Ps[(long)p * N + row];
    const float nm = fmaxf(m, mp);
    s = s * __expf(m - nm) + sp * __expf(mp - nm);
    m = nm;
  }
  rm[row] = m;
  rsc[row] = 1.f / s;
}

__global__ __launch_bounds__(256) void k_prowmerge_m(const float* __restrict__ Pm, const float* __restrict__ Ps,
                                                     const float* __restrict__ Pq,
                                                     float* __restrict__ rm, float* __restrict__ rsc){
  const int z = blockIdx.y;
  const int row = blockIdx.x * 256 + threadIdx.x;
  float m = -3.4e38f, s = 0.f, q = 0.f;
#pragma unroll 4
  for (int p = 0; p < 32; ++p){
    const long idx = (long)(z * 32 + p) * N + row;
    const float mp = Pm[idx], sp = Ps[idx], qp = Pq[idx];
    const float nm = fmaxf(m, mp);
    const float c0_ = __expf(m - nm), c1_ = __expf(mp - nm);
    s = s * c0_ + sp * c1_;
    q = q * c0_ + qp * c1_;
    m = nm;
  }
  float l1 = q / s;
  if (l1 < 1e-12f) l1 = 1e-12f;
  rsc[(long)z * N + row] = 1.f / (s * l1);
  rm[(long)z * N + row] = m;
}

__global__ __launch_bounds__(256) void k_colaccum(const float* __restrict__ E, const float* __restrict__ rowmax,
                                                  const float* __restrict__ rowscale, float* __restrict__ partials){
  const int j = (blockIdx.x * 256 + threadIdx.x) * 4;
  const int r0 = blockIdx.y * 32;
  float4 acc = {0.f, 0.f, 0.f, 0.f};
#pragma unroll 4
  for (int r2 = r0; r2 < r0 + 32; ++r2){
    const float4 e = *reinterpret_cast<const float4*>(E + (long)r2 * N + j);
    const float rmv = rowmax[r2], rsv = rowscale[r2];
    acc.x += __expf(e.x - rmv) * rsv;
    acc.y += __expf(e.y - rmv) * rsv;
    acc.z += __expf(e.z - rmv) * rsv;
    acc.w += __expf(e.w - rmv) * rsv;
  }
  *reinterpret_cast<float4*>(partials + (long)blockIdx.y * N + j) = acc;
}

__global__ __launch_bounds__(256) void k_colreduce(const float* __restrict__ partials, float* __restrict__ att){
  const int j = blockIdx.x * 256 + threadIdx.x;
  float s = 0.f;
#pragma unroll 8
  for (int p = 0; p < 128; ++p) s += partials[(long)p * N + j];
  att[j] = s * (1.f / (float)N);
}

// ======================= mask (radix select), all 4 selections in one launch =======================
__global__ __launch_bounds__(256) void k_radix(const float* __restrict__ a, float* __restrict__ thr){
  __shared__ unsigned int vals[N];
  __shared__ float shc[4];
  __shared__ unsigned int p_sh;
  __shared__ int k_sh;
  const float* pa = a + (long)blockIdx.x * N;
  const int tid = threadIdx.x;
  for (int i = tid; i < N; i += 256) vals[i] = __float_as_uint(pa[i]);
  if (tid == 0){ p_sh = 0u; k_sh = KSEL; }
  __syncthreads();
  for (int b = 31; b >= 0; --b){
    const unsigned int bit = 1u << b;
    const unsigned int above = (b == 31) ? 0u : ~((bit << 1) - 1u);
    const unsigned int p = p_sh;
    int cnt = 0;
    for (int i = tid; i < N; i += 256){
      unsigned int v = vals[i];
      if ((v & above) == p && (v & bit)) cnt++;
    }
    float cf = wredSum((float)cnt);
    if ((tid & 63) == 0) shc[tid >> 6] = cf;
    __syncthreads();
    if (tid == 0){
      int c1 = (int)(shc[0] + shc[1] + shc[2] + shc[3] + 0.5f);
      if (k_sh <= c1) p_sh = p | bit;
      else k_sh -= c1;
    }
    __syncthreads();
  }
  if (tid == 0) thr[blockIdx.x] = __uint_as_float(p_sh);
}

__global__ __launch_bounds__(256) void k_mask(const float* __restrict__ ax, const float* __restrict__ ay,
                                              const float* __restrict__ thr, float* __restrict__ mx,
                                              float* __restrict__ my){
  int j = blockIdx.x * 256 + threadIdx.x;
  mx[j] = (ax[j] >= thr[0] && ax[N + j] >= thr[1]) ? 1.f : 0.f;
  my[j] = (ay[j] >= thr[2] && ay[N + j] >= thr[3]) ? 1.f : 0.f;
}

// ======================= host =======================
extern "C" void kernel_launch(void* const* d_in, const int* in_sizes, int n_in,
                              void* d_out, int out_size, void* d_ws, size_t ws_size,
                              hipStream_t stream)
{
  const float* x     = (const float*)d_in[0];
  const float* y     = (const float*)d_in[1];
  const float* f_w   = (const float*)d_in[2];
  const float* f_b   = (const float*)d_in[3];
  const float* g_w   = (const float*)d_in[4];
  const float* g_b   = (const float*)d_in[5];
  const float* saf_w = (const float*)d_in[6];
  const float* saf_b = (const float*)d_in[7];
  const float* sag_w = (const float*)d_in[8];
  const float* sag_b = (const float*)d_in[9];
  const float* h_w   = (const float*)d_in[10];
  const float* h_b   = (const float*)d_in[11];
  const float* ow    = (const float*)d_in[12];
  const float* ob    = (const float*)d_in[13];

  const size_t MBy = 1ull << 20;
  const size_t KBy = 1ull << 10;
  char* base = (char*)d_ws;
  if (ws_size < 206 * MBy) return;
  auto F  = [&](size_t off){ return (float*)(base + off); };
  auto Bp = [&](size_t off){ return (__bf16*)(base + off); };

  float *E0 = F(0);
  __bf16 *Ebf = Bp(0);
  __bf16 *ccH = Bp(0), *ccL = Bp(16*MBy);
  float  *covb = F(32*MBy);
  __bf16 *zpolH = Bp(36*MBy), *zpolL = Bp(38*MBy);
  __bf16 *covPH = Bp(40*MBy), *covPL = Bp(42*MBy);
  float  *KsTf = F(44*MBy), *K2tf = F(45*MBy);
  __bf16 *KsTH = Bp(46*MBy), *KsTL = Bp(46*MBy + 512*KBy);
  __bf16 *K2tH = Bp(47*MBy), *hwH = Bp(47*MBy + 512*KBy);
  __bf16 *tpH = Bp(48*MBy), *tpL = Bp(50*MBy);
  __bf16 *xaH = Bp(64*MBy);
  __bf16 *xzH = Bp(64*MBy), *xzL = Bp(80*MBy);
  __bf16 *ypmH = Bp(96*MBy);
  __bf16 *AsH = Bp(96*MBy), *AsL = Bp(112*MBy);
  __bf16 *fcH = Bp(128*MBy), *fcL = Bp(144*MBy);
  __bf16 *resH = Bp(128*MBy);
  __bf16 *nsAh = Bp(160*MBy), *nsAl = Bp(164*MBy);
  __bf16 *nsBh = Bp(168*MBy), *nsBl = Bp(172*MBy);
  __bf16 *A2H = Bp(176*MBy);
  __bf16 *yaH = Bp(184*MBy);
  __bf16 *hH  = Bp(192*MBy);
  __bf16 *owH = Bp(200*MBy);
  size_t so = 200 * MBy + 512 * KBy;
  auto SF = [&](size_t bytes){ float* p = F(so); so += bytes; return p; };
  float *meanv = SF(8*KBy), *invs = SF(8*KBy);
  float *rm = SF(32*KBy), *rsc = SF(32*KBy);
  float *mxv = SF(16*KBy), *myv = SF(16*KBy);
  float *rvec2 = SF(32*KBy), *cvec2 = SF(32*KBy);
  float *rvS = SF(64*KBy), *cvS = SF(64*KBy);
  float *u1m = SF(2*KBy), *u2m = SF(2*KBy), *u1s = SF(2*KBy), *u2s = SF(2*KBy);
  float *c0m2 = SF(64), *c0s4 = SF(64), *thr = SF(64);
  float *invt = SF(64), *invsqt = SF(64);
  float *partials = F(201*MBy);                      // [128][N]
  float *Pm = F(203*MBy);                            // [64][N]
  float *Ps = F(204*MBy);                            // [64][N]
  float *Pq = F(205*MBy);                            // [64][N]

  float* outm = (float*)d_out;
  float* attx = outm + B2 * CN;                      // attx[2][N] then atty[2][N], contiguous
  float* atty = attx + (long)B2 * N;

  // 1) stats + prep
  k_stats<<<dim3(4 * C), dim3(256), 0, stream>>>(x, y, meanv, invs);
  k_prep<<<dim3(64, 8, 2), dim3(256), 0, stream>>>(x, meanv, invs, 0, xaH, fcH, fcL, ccH, ccL, nullptr);
  k_prep<<<dim3(64, 8, 2), dim3(256), 0, stream>>>(y, meanv, invs, 2, yaH, fcH, fcL, ccH, ccL, ypmH);

  // 2) weight products & conversions
  k_wtw<<<dim3(16, 16), dim3(256), 0, stream>>>(sag_w, saf_w, KsTf, 1.f);
  k_wtw<<<dim3(16, 16), dim3(256), 0, stream>>>(g_w, f_w, K2tf, 1.f);
  {
    const int nb = (int)(CC / 256);
    k_wcvt<<<nb, 256, 0, stream>>>(KsTf, KsTH, KsTL, (int)CC);
    k_wcvt_h<<<nb, 256, 0, stream>>>(K2tf, K2tH, (int)CC);
    k_wcvt_h<<<nb, 256, 0, stream>>>(h_w, hwH, (int)CC);
    k_wcvt_h<<<nb, 256, 0, stream>>>(ow, owH, (int)CC);
  }
  k_wtv<<<dim3(2), dim3(256), 0, stream>>>(g_w, f_b, u1m);
  k_wtv<<<dim3(2), dim3(256), 0, stream>>>(f_w, g_b, u2m);
  k_wtv<<<dim3(2), dim3(256), 0, stream>>>(sag_w, saf_b, u1s);
  k_wtv<<<dim3(2), dim3(256), 0, stream>>>(saf_w, sag_b, u2s);
  k_dot2<<<dim3(1), dim3(256), 0, stream>>>(f_b, g_b, saf_b, sag_b, c0m2, c0s4);
  k_pixvec<<<dim3(N / 4, 2), dim3(256), 0, stream>>>(xaH, u2m, rvec2);
  k_pixvec<<<dim3(N / 4, 2), dim3(256), 0, stream>>>(yaH, u1m, cvec2);

  // 3) cov (2eps*I folded downstream) + power-iteration lambda_max
  k_mm64<0,0,0><<<dim3(8, 8, 4), dim3(256), 0, stream>>>(
      ccH, ccL, ccH, ccL, nullptr, nullptr, covb, nullptr, nullptr, C, N, CN, CN, CC, 1.f / (float)(N - 1));
  k_powit<<<dim3(4), dim3(256), 0, stream>>>(covb, invt, invsqt);

  // 4) A2 = xa . K2^T, h conv
  k_mm<1,0,2,0><<<dim3(32, 4, 2), dim3(256), 0, stream>>>(xaH, nullptr, K2tH, nullptr, nullptr, A2H, nullptr,
      C, C, NC, 0, NC, 1.f, nullptr, nullptr, 0, nullptr, 0, nullptr, nullptr, 0,
      nullptr, nullptr, nullptr, nullptr, nullptr);
  k_mm<1,0,2,0><<<dim3(4, 32, 2), dim3(256), 0, stream>>>(hwH, nullptr, ypmH, nullptr, nullptr, hH, nullptr,
      N, C, 0, NC, CN, 1.f, nullptr, h_b, 0, nullptr, 0, nullptr, nullptr, 0,
      nullptr, nullptr, nullptr, nullptr, nullptr);

  // 5) Newton-Schulz (4 iters; last iter Z-only) + split-bf16 polish
  k_ns_init<<<dim3(C, 4), dim3(256), 0, stream>>>(covb, invt, nsAh, nsAl, covPH, covPL);
  __bf16 *cah = nsAh, *cal = nsAl, *cbh = nsBh, *cbl = nsBl;
  for (int it = 0; it < NS_ITERS; ++it){
    k_mm64<1,1,0><<<dim3(8, 8, 4), dim3(256), 0, stream>>>(
        cah + 4*CC, cal + 4*CC, cah, cal, nullptr, nullptr, nullptr, tpH, tpL, C, C, CC, CC, CC, 1.f);
    if (it < NS_ITERS - 1){
      k_mm64<0,1,1><<<dim3(8, 8, 8), dim3(256), 0, stream>>>(
          cah, cal, nullptr, nullptr, tpH, tpL, nullptr, cbh, cbl, C, C, CC, CC, CC, 1.f);
    } else {
      k_mm64<0,1,2><<<dim3(8, 8, 4), dim3(256), 0, stream>>>(
          cah, cal, nullptr, nullptr, tpH, tpL, nullptr, cbh, cbl, C, C, CC, CC, CC, 1.f);
    }
    __bf16* t;
    t = cah; cah = cbh; cbh = t;
    t = cal; cal = cbl; cbl = t;
  }
  k_mm64<0,1,0><<<dim3(8, 8, 4), dim3(256), 0, stream>>>(
      cah + 4*CC, cal + 4*CC, cah + 4*CC, cal + 4*CC, nullptr, nullptr, nullptr, tpH, tpL, C, C, CC, CC, CC, 1.f);
  k_mm64<1,1,0><<<dim3(8, 8, 4), dim3(256), 0, stream>>>(
      covPH, covPL, tpH, tpL, nullptr, nullptr, nullptr, cbh, cbl, C, C, CC, CC, CC, 1.f);
  k_mm64<0,1,0><<<dim3(8, 8, 4), dim3(256), 0, stream>>>(
      cah + 4*CC, cal + 4*CC, cbh, cbl, nullptr, nullptr, nullptr, zpolH, zpolL, C, C, CC, CC, CC, 1.f);

  // 6) zca apply: xz = invsqt * fc . Z
  k_mm<3,0,1,0><<<dim3(32, 4, 4), dim3(256), 0, stream>>>(fcH, fcL, zpolH, zpolL, nullptr, xzH, xzL,
      C, C, NC, CC, NC, 1.f, invsqt, nullptr, 0, nullptr, 0, nullptr, nullptr, 0,
      nullptr, nullptr, nullptr, nullptr, nullptr);

  // 6.5) self bias vecs (one pass) + As = xz . Ks^T
  k_pixvec2<<<dim3(N / 4, 4), dim3(256), 0, stream>>>(xzH, u2s, u1s, rvS, cvS);
  k_mm<3,0,1,0><<<dim3(32, 4, 4), dim3(256), 0, stream>>>(xzH, xzL, KsTH, KsTL, nullptr, AsH, AsL,
      C, C, NC, 0, NC, 1.f, nullptr, nullptr, 0, nullptr, 0, nullptr, nullptr, 0,
      nullptr, nullptr, nullptr, nullptr, nullptr);

  // 7) self-attention energies (3-pass, fp32 E, fused row-stats) -> atten
  for (int z = 0; z < 4; ++z){
    k_mm<3,0,0,1><<<dim3(32, 32, 1), dim3(256), 0, stream>>>(AsH + (long)z*NC, AsL + (long)z*NC,
        xzH + (long)z*NC, xzL + (long)z*NC, E0, nullptr, nullptr,
        N, C, 0, 0, 0, 1.f, nullptr, rvS + (long)z*N, 0, cvS + (long)z*N, 0, c0s4, nullptr, 0,
        Pm, Ps, nullptr, nullptr, nullptr);
    k_prowmerge<<<dim3(16), dim3(256), 0, stream>>>(Pm, Ps, rm, rsc);
    k_colaccum<<<dim3(4, 128), dim3(256), 0, stream>>>(E0, rm, rsc, partials);
    k_colreduce<<<dim3(16), dim3(256), 0, stream>>>(partials, (z < 2 ? attx : atty) + (long)(z & 1) * N);
  }

  // 8) masks (single radix launch over the 4 contiguous atten arrays)
  k_radix<<<dim3(4), dim3(256), 0, stream>>>(attx, thr);
  k_mask<<<dim3(16), dim3(256), 0, stream>>>(attx, atty, thr, mxv, myv);

  // 9) main path: energy -> bf16 E with fused masked row-stats; merge; PV; out conv
  k_mm<1,0,2,2><<<dim3(32, 32, 2), dim3(256), 0, stream>>>(A2H, nullptr, yaH, nullptr, nullptr, Ebf, nullptr,
      N, C, NC, NC, NN, 1.f, nullptr, rvec2, N, cvec2, N, c0m2, nullptr, 0,
      Pm, Ps, Pq, mxv, myv);
  k_prowmerge_m<<<dim3(16, 2), dim3(256), 0, stream>>>(Pm, Ps, Pq, rm, rsc);
  k_pv<<<dim3(64, 4, 2), dim3(256), 0, stream>>>(Ebf, hH, rm, rsc, mxv, myv, resH);
  k_mm<1,0,0,0><<<dim3(4, 32, 2), dim3(256), 0, stream>>>(owH, nullptr, resH, nullptr, outm, nullptr, nullptr,
      N, C, 0, NC, CN, 1.f, nullptr, ob, 0, nullptr, 0, nullptr, x, CN,
      nullptr, nullptr, nullptr, nullptr, nullptr);
}

// Round 14
// 1220.989 us; speedup vs baseline: 1.1633x; 1.0173x over previous
//
#include <hip/hip_runtime.h>
#include <cstdint>

static constexpr int B2 = 2;
static constexpr int C = 512;
static constexpr int N = 4096;
static constexpr long CN = (long)C * N;
static constexpr long NC = (long)N * C;
static constexpr long CC = (long)C * C;
static constexpr long NN = (long)N * N;
static constexpr float EPSC = 1e-5f;
static constexpr int KSEL = 308;       // N - int(N*0.925)
static constexpr int NS_ITERS = 4;

typedef __attribute__((ext_vector_type(8))) __bf16 bf16x8;
typedef __attribute__((ext_vector_type(4))) float f32x4;

__device__ __forceinline__ float wredSum(float v){
#pragma unroll
  for (int o = 32; o >= 1; o >>= 1) v += __shfl_xor(v, o, 64);
  return v;
}

__device__ __forceinline__ void gld16(const __bf16* g, __bf16* l){
  __builtin_amdgcn_global_load_lds(
      (const __attribute__((address_space(1))) void*)g,
      (__attribute__((address_space(3))) void*)l, 16, 0, 0);
}

__device__ __forceinline__ void splitw(float v, __bf16* ph, __bf16* pl, long o){
  __bf16 h = (__bf16)v;
  ph[o] = h;
  pl[o] = (__bf16)(v - (float)h);
}

// ======================= split/plain bf16 MFMA GEMM, 128x128 tile, BK=32 =======================
// XCD swizzle. ROWP: 0 none | 1 row softmax partials | 2 masked (mxp/myp, writes Pq)
// Two-phase epilogue: pass1 value+max (fmax only), pass2 exp-sums vs final max.
template<int PASSES, int TMH, int OUTMODE, int ROWP>
__global__ __launch_bounds__(256) void k_mm(
    const __bf16* __restrict__ Ah, const __bf16* __restrict__ Al,
    const __bf16* __restrict__ Bh, const __bf16* __restrict__ Bl,
    float* __restrict__ Cf, __bf16* __restrict__ Coh, __bf16* __restrict__ Col,
    int Nn, int K, long sAz, long sBz, long sCz,
    float alpha, const float* __restrict__ alpha_ptr,
    const float* __restrict__ brow, long sBr,
    const float* __restrict__ bcol, long sBc,
    const float* __restrict__ c0p,
    const float* __restrict__ addsrc, long sAddz,
    float* __restrict__ Pm, float* __restrict__ Ps, float* __restrict__ Pq,
    const float* __restrict__ mxp, const float* __restrict__ myp)
{
  constexpr int NB = (PASSES == 3) ? 4 : 2;
  constexpr int SB = (PASSES == 3) ? 2 : 1;
  __shared__ __align__(16) __bf16 sm[NB][128 * 32];
  __shared__ float pmx[2][128], psx[2][128], pqx[2][128];
  const int z = blockIdx.z;
  const int nwx = gridDim.x;
  int lin = blockIdx.y * nwx + blockIdx.x;
  const int nwg = nwx * gridDim.y;
  if ((nwg & 7) == 0){
    const int cpx = nwg >> 3;
    lin = (lin & 7) * cpx + (lin >> 3);
  }
  const int i0 = (lin % nwx) * 128;
  const int j0 = (lin / nwx) * 128;
  const int tid = threadIdx.x;
  const int lane = tid & 63;
  const int w = tid >> 6;
  const int wr = (w >> 1) * 64, wc = (w & 1) * 64;
  const int lr = lane & 15;
  const int g = lane >> 4;

  const __bf16* pAh = Ah + (long)z * sAz + (long)i0 * K;
  const __bf16* pBh = Bh + (long)z * sBz + (long)j0 * K;
  const __bf16* pAl = (PASSES == 3) ? (Al + (long)z * sAz + (long)i0 * K) : nullptr;
  const __bf16* pBl = (PASSES == 3) ? (Bl + (long)z * sBz + (long)j0 * K) : nullptr;

  f32x4 acc[4][4] = {};

  for (int kt = 0; kt < K; kt += 32){
#pragma unroll
    for (int p = 0; p < 2; ++p){
      const int t2 = p * 256 + tid;
      const int row = t2 >> 2;
      const int gs = (t2 & 3) ^ ((row >> 1) & 3);
      const long go = (long)row * K + kt + gs * 8;
      gld16(pAh + go, &sm[0][t2 * 8]);
      gld16(pBh + go, &sm[SB][t2 * 8]);
      if constexpr (PASSES == 3){
        gld16(pAl + go, &sm[1][t2 * 8]);
        gld16(pBl + go, &sm[3][t2 * 8]);
      }
    }
    __syncthreads();
    bf16x8 fa[4], fal[4], fb[4], fbl[4];
#pragma unroll
    for (int mi = 0; mi < 4; ++mi){
      const int row = wr + mi * 16 + lr;
      const int off = row * 32 + ((g ^ ((row >> 1) & 3)) * 8);
      fa[mi] = *(const bf16x8*)(&sm[0][off]);
      if constexpr (PASSES == 3) fal[mi] = *(const bf16x8*)(&sm[1][off]);
    }
#pragma unroll
    for (int ni = 0; ni < 4; ++ni){
      const int row = wc + ni * 16 + lr;
      const int off = row * 32 + ((g ^ ((row >> 1) & 3)) * 8);
      fb[ni] = *(const bf16x8*)(&sm[SB][off]);
      if constexpr (PASSES == 3) fbl[ni] = *(const bf16x8*)(&sm[3][off]);
    }
#pragma unroll
    for (int mi = 0; mi < 4; ++mi)
#pragma unroll
      for (int ni = 0; ni < 4; ++ni){
        acc[mi][ni] = __builtin_amdgcn_mfma_f32_16x16x32_bf16(fa[mi], fb[ni], acc[mi][ni], 0, 0, 0);
        if constexpr (PASSES == 3){
          acc[mi][ni] = __builtin_amdgcn_mfma_f32_16x16x32_bf16(fa[mi],  fbl[ni], acc[mi][ni], 0, 0, 0);
          acc[mi][ni] = __builtin_amdgcn_mfma_f32_16x16x32_bf16(fal[mi], fb[ni],  acc[mi][ni], 0, 0, 0);
        }
      }
    __syncthreads();
  }

  float al2 = alpha;
  if (alpha_ptr) al2 *= alpha_ptr[z];
  const float c0v = c0p ? c0p[z] : 0.f;
#pragma unroll
  for (int mi = 0; mi < 4; ++mi){
    float vv[4][4];
    float mrow[4] = {-3.4e38f, -3.4e38f, -3.4e38f, -3.4e38f};
#pragma unroll
    for (int ni = 0; ni < 4; ++ni){
      const int col = j0 + wc + ni * 16 + lr;
      const float bc = (bcol ? bcol[z * sBc + col] : 0.f) + c0v;
#pragma unroll
      for (int j = 0; j < 4; ++j){
        const int row = i0 + wr + mi * 16 + g * 4 + j;
        float v = acc[mi][ni][j] * al2;
        if (TMH) v = (((row == col) ? 3.f : 0.f) - v) * 0.5f;
        if (brow) v += brow[z * sBr + row];
        v += bc;
        if (addsrc) v += addsrc[(long)z * sAddz + (long)row * Nn + col];
        const long o = (long)z * sCz + (long)row * Nn + col;
        if (OUTMODE == 0){ Cf[o] = v; }
        else if (OUTMODE == 1){ __bf16 h = (__bf16)v; Coh[o] = h; Col[o] = (__bf16)(v - (float)h); }
        else { __bf16 h = (__bf16)v; Coh[o] = h; if (ROWP == 2) v = (float)h; }
        if constexpr (ROWP >= 1){
          vv[ni][j] = v;
          mrow[j] = fmaxf(mrow[j], v);
        }
      }
    }
    if constexpr (ROWP >= 1){
#pragma unroll
      for (int j = 0; j < 4; ++j)
#pragma unroll
        for (int o = 1; o <= 8; o <<= 1)
          mrow[j] = fmaxf(mrow[j], __shfl_xor(mrow[j], o, 64));
      float tgt[4];
      if constexpr (ROWP == 2){
#pragma unroll
        for (int j = 0; j < 4; ++j)
          tgt[j] = mxp[i0 + wr + mi * 16 + g * 4 + j];
      }
      float srow[4] = {0.f, 0.f, 0.f, 0.f};
      float qrow[4] = {0.f, 0.f, 0.f, 0.f};
#pragma unroll
      for (int ni = 0; ni < 4; ++ni){
        const float mycol = (ROWP == 2) ? myp[j0 + wc + ni * 16 + lr] : 0.f;
#pragma unroll
        for (int j = 0; j < 4; ++j){
          const float ev = __expf(vv[ni][j] - mrow[j]);
          srow[j] += ev;
          if constexpr (ROWP == 2){
            if (mycol == tgt[j]) qrow[j] += ev;
          }
        }
      }
#pragma unroll
      for (int j = 0; j < 4; ++j){
#pragma unroll
        for (int o = 1; o <= 8; o <<= 1){
          srow[j] += __shfl_xor(srow[j], o, 64);
          if constexpr (ROWP == 2) qrow[j] += __shfl_xor(qrow[j], o, 64);
        }
        if (lr == 0){
          const int rl = wr + mi * 16 + g * 4 + j;
          pmx[w & 1][rl] = mrow[j];
          psx[w & 1][rl] = srow[j];
          if constexpr (ROWP == 2) pqx[w & 1][rl] = qrow[j];
        }
      }
    }
  }
  if constexpr (ROWP >= 1){
    __syncthreads();
    if (tid < 128){
      const float m0 = pmx[0][tid], s0 = psx[0][tid];
      const float m1 = pmx[1][tid], s1 = psx[1][tid];
      const float nm = fmaxf(m0, m1);
      const float c0_ = __expf(m0 - nm), c1_ = __expf(m1 - nm);
      const float s = s0 * c0_ + s1 * c1_;
      const long po = (long)(z * 32 + (j0 >> 7)) * N + i0 + tid;
      Pm[po] = nm;
      Ps[po] = s;
      if constexpr (ROWP == 2){
        Pq[po] = pqx[0][tid] * c0_ + pqx[1][tid] * c1_;
      }
    }
  }
}

// ======================= split-bf16 MFMA GEMM, 64x64 tile, BK=64 (always 3-pass) =======================
// NSYZ: 0 plain | 1 z<4: Y=Yz*T^T, z>=4: Z'=T*Z^T | 2 (z in [0,4)): Z'=T*Z^T only
template<int TMH, int OUTMODE, int NSYZ>
__global__ __launch_bounds__(256) void k_mm64(
    const __bf16* __restrict__ Ah, const __bf16* __restrict__ Al,
    const __bf16* __restrict__ Bh, const __bf16* __restrict__ Bl,
    const __bf16* __restrict__ tH, const __bf16* __restrict__ tL,
    float* __restrict__ Cf, __bf16* __restrict__ Coh, __bf16* __restrict__ Col,
    int Nn, int K, long sAz, long sBz, long sCz, float alpha)
{
  __shared__ __align__(16) __bf16 sm[4][64 * 64];
  const int z = blockIdx.z;
  const __bf16 *bAh, *bAl, *bBh, *bBl;
  long oC;
  if constexpr (NSYZ == 1){
    if (z < 4){
      bAh = Ah + (long)z * CC; bAl = Al + (long)z * CC;
      bBh = tH + (long)z * CC; bBl = tL + (long)z * CC;
      oC = (long)z * CC;
    } else {
      const int zz = z - 4;
      bAh = tH + (long)zz * CC; bAl = tL + (long)zz * CC;
      bBh = Ah + (long)(4 + zz) * CC; bBl = Al + (long)(4 + zz) * CC;
      oC = (long)(4 + zz) * CC;
    }
  } else if constexpr (NSYZ == 2){
    bAh = tH + (long)z * CC; bAl = tL + (long)z * CC;
    bBh = Ah + (long)(4 + z) * CC; bBl = Al + (long)(4 + z) * CC;
    oC = (long)(4 + z) * CC;
  } else {
    bAh = Ah + (long)z * sAz; bAl = Al + (long)z * sAz;
    bBh = Bh + (long)z * sBz; bBl = Bl + (long)z * sBz;
    oC = (long)z * sCz;
  }
  const int i0 = blockIdx.x * 64;
  const int j0 = blockIdx.y * 64;
  const int tid = threadIdx.x;
  const int lane = tid & 63;
  const int w = tid >> 6;
  const int wr = (w >> 1) * 32, wc = (w & 1) * 32;
  const int lr = lane & 15;
  const int g = lane >> 4;

  const __bf16* pAh = bAh + (long)i0 * K;
  const __bf16* pAl = bAl + (long)i0 * K;
  const __bf16* pBh = bBh + (long)j0 * K;
  const __bf16* pBl = bBl + (long)j0 * K;

  f32x4 acc[2][2] = {};

  for (int kt = 0; kt < K; kt += 64){
#pragma unroll
    for (int p = 0; p < 2; ++p){
      const int t2 = p * 256 + tid;
      const int row = t2 >> 3;
      const int gs = (t2 & 7) ^ (row & 7);
      const long go = (long)row * K + kt + gs * 8;
      gld16(pAh + go, &sm[0][t2 * 8]);
      gld16(pAl + go, &sm[1][t2 * 8]);
      gld16(pBh + go, &sm[2][t2 * 8]);
      gld16(pBl + go, &sm[3][t2 * 8]);
    }
    __syncthreads();
#pragma unroll
    for (int ks = 0; ks < 2; ++ks){
      bf16x8 fa[2], fal[2], fb[2], fbl[2];
#pragma unroll
      for (int mi = 0; mi < 2; ++mi){
        const int row = wr + mi * 16 + lr;
        const int off = row * 64 + (((ks * 4 + g) ^ (row & 7)) * 8);
        fa[mi]  = *(const bf16x8*)(&sm[0][off]);
        fal[mi] = *(const bf16x8*)(&sm[1][off]);
      }
#pragma unroll
      for (int ni = 0; ni < 2; ++ni){
        const int row = wc + ni * 16 + lr;
        const int off = row * 64 + (((ks * 4 + g) ^ (row & 7)) * 8);
        fb[ni]  = *(const bf16x8*)(&sm[2][off]);
        fbl[ni] = *(const bf16x8*)(&sm[3][off]);
      }
#pragma unroll
      for (int mi = 0; mi < 2; ++mi)
#pragma unroll
        for (int ni = 0; ni < 2; ++ni){
          acc[mi][ni] = __builtin_amdgcn_mfma_f32_16x16x32_bf16(fa[mi],  fb[ni],  acc[mi][ni], 0, 0, 0);
          acc[mi][ni] = __builtin_amdgcn_mfma_f32_16x16x32_bf16(fa[mi],  fbl[ni], acc[mi][ni], 0, 0, 0);
          acc[mi][ni] = __builtin_amdgcn_mfma_f32_16x16x32_bf16(fal[mi], fb[ni],  acc[mi][ni], 0, 0, 0);
        }
    }
    __syncthreads();
  }

#pragma unroll
  for (int mi = 0; mi < 2; ++mi){
#pragma unroll
    for (int ni = 0; ni < 2; ++ni){
      const int col = j0 + wc + ni * 16 + lr;
#pragma unroll
      for (int j = 0; j < 4; ++j){
        const int row = i0 + wr + mi * 16 + g * 4 + j;
        float v = acc[mi][ni][j] * alpha;
        if (TMH) v = (((row == col) ? 3.f : 0.f) - v) * 0.5f;
        const long o = oC + (long)row * Nn + col;
        if (OUTMODE == 0){ Cf[o] = v; }
        else { __bf16 h = (__bf16)v; Coh[o] = h; Col[o] = (__bf16)(v - (float)h); }
      }
    }
  }
}

// ======================= fused corr+PV (bf16 E), K-step 64 (round-12 proven, 0-conflict) =======================
__global__ __launch_bounds__(256) void k_pv(
    const __bf16* __restrict__ E, const __bf16* __restrict__ Bh,
    const float* __restrict__ rm, const float* __restrict__ rsc,
    const float* __restrict__ mxv, const float* __restrict__ myv,
    __bf16* __restrict__ resH)
{
  __shared__ __align__(16) __bf16 sa[64 * 64];
  __shared__ __align__(16) __bf16 sb[128 * 64];
  const int z = blockIdx.z;
  int lin = blockIdx.y * 64 + blockIdx.x;
  lin = (lin & 7) * 32 + (lin >> 3);
  const int n0 = (lin & 63) * 64;
  const int c0 = (lin >> 6) * 128;
  const int tid = threadIdx.x;
  const int lane = tid & 63;
  const int w = tid >> 6;
  const int wr = (w >> 1) * 32, wc = (w & 1) * 64;
  const int lr = lane & 15, g = lane >> 4;

  const __bf16* pe = E + (long)z * NN + (long)n0 * N;
  const __bf16* pB = Bh + (long)z * CN + (long)c0 * N;

  const int ar = tid >> 2;
  const int slot = tid & 3;
  const float rmv = rm[(long)z * N + n0 + ar];
  const float rsv = rsc[(long)z * N + n0 + ar];
  const float tgt = mxv[n0 + ar];
  const __bf16* per = pe + (long)ar * N;

  f32x4 acc[2][4] = {};

  for (int kt = 0; kt < N; kt += 64){
#pragma unroll
    for (int d = 0; d < 2; ++d){
      const int gd = slot * 2 + d;
      const bf16x8 ev = *(const bf16x8*)(per + kt + gd * 8);
      const float4 m0 = *(const float4*)(myv + kt + gd * 8);
      const float4 m1 = *(const float4*)(myv + kt + gd * 8 + 4);
      bf16x8 pk;
      pk[0] = (__bf16)((m0.x == tgt) ? __expf((float)ev[0] - rmv) * rsv : 0.f);
      pk[1] = (__bf16)((m0.y == tgt) ? __expf((float)ev[1] - rmv) * rsv : 0.f);
      pk[2] = (__bf16)((m0.z == tgt) ? __expf((float)ev[2] - rmv) * rsv : 0.f);
      pk[3] = (__bf16)((m0.w == tgt) ? __expf((float)ev[3] - rmv) * rsv : 0.f);
      pk[4] = (__bf16)((m1.x == tgt) ? __expf((float)ev[4] - rmv) * rsv : 0.f);
      pk[5] = (__bf16)((m1.y == tgt) ? __expf((float)ev[5] - rmv) * rsv : 0.f);
      pk[6] = (__bf16)((m1.z == tgt) ? __expf((float)ev[6] - rmv) * rsv : 0.f);
      pk[7] = (__bf16)((m1.w == tgt) ? __expf((float)ev[7] - rmv) * rsv : 0.f);
      *(bf16x8*)(&sa[ar * 64 + ((gd ^ (ar & 7)) * 8)]) = pk;
    }
#pragma unroll
    for (int p = 0; p < 4; ++p){
      const int t2 = p * 256 + tid;
      const int row = t2 >> 3;
      const int gs = (t2 & 7) ^ (row & 7);
      gld16(pB + (long)row * N + kt + gs * 8, &sb[t2 * 8]);
    }
    __syncthreads();
#pragma unroll
    for (int ks = 0; ks < 2; ++ks){
      bf16x8 fa[2], fb[4];
#pragma unroll
      for (int mi = 0; mi < 2; ++mi){
        const int row = wr + mi * 16 + lr;
        fa[mi] = *(const bf16x8*)(&sa[row * 64 + (((ks * 4 + g) ^ (row & 7)) * 8)]);
      }
#pragma unroll
      for (int ni = 0; ni < 4; ++ni){
        const int row = wc + ni * 16 + lr;
        fb[ni] = *(const bf16x8*)(&sb[row * 64 + (((ks * 4 + g) ^ (row & 7)) * 8)]);
      }
#pragma unroll
      for (int mi = 0; mi < 2; ++mi)
#pragma unroll
        for (int ni = 0; ni < 4; ++ni)
          acc[mi][ni] = __builtin_amdgcn_mfma_f32_16x16x32_bf16(fa[mi], fb[ni], acc[mi][ni], 0, 0, 0);
    }
    __syncthreads();
  }
#pragma unroll
  for (int mi = 0; mi < 2; ++mi)
#pragma unroll
    for (int ni = 0; ni < 4; ++ni){
      const int c = c0 + wc + ni * 16 + lr;
#pragma unroll
      for (int j = 0; j < 4; ++j){
        const int n = n0 + wr + mi * 16 + g * 4 + j;
        resH[(long)z * NC + (long)n * C + c] = (__bf16)acc[mi][ni][j];
      }
    }
}

// ======================= small helpers =======================
__global__ __launch_bounds__(256) void k_wtw(const float* __restrict__ A, const float* __restrict__ B,
                                             float* __restrict__ C2, float alpha){
  __shared__ float sa[16][32], sb[16][32];
  const int i0 = blockIdx.x * 32, j0 = blockIdx.y * 32;
  const int t = threadIdx.x;
  const int ti = t & 15, tj = t >> 4;
  const int li = t & 31, lc = t >> 5;
  float acc[2][2] = {};
  for (int cb = 0; cb < C; cb += 16){
    sa[lc][li]     = A[(long)(cb + lc) * C + i0 + li];
    sa[lc + 8][li] = A[(long)(cb + lc + 8) * C + i0 + li];
    sb[lc][li]     = B[(long)(cb + lc) * C + j0 + li];
    sb[lc + 8][li] = B[(long)(cb + lc + 8) * C + j0 + li];
    __syncthreads();
#pragma unroll
    for (int c = 0; c < 16; ++c){
      const float a0 = sa[c][ti * 2], a1 = sa[c][ti * 2 + 1];
      const float b0 = sb[c][tj * 2], b1 = sb[c][tj * 2 + 1];
      acc[0][0] = fmaf(a0, b0, acc[0][0]); acc[0][1] = fmaf(a0, b1, acc[0][1]);
      acc[1][0] = fmaf(a1, b0, acc[1][0]); acc[1][1] = fmaf(a1, b1, acc[1][1]);
    }
    __syncthreads();
  }
#pragma unroll
  for (int r = 0; r < 2; ++r)
#pragma unroll
    for (int s = 0; s < 2; ++s)
      C2[(long)(i0 + ti * 2 + r) * C + j0 + tj * 2 + s] = acc[r][s] * alpha;
}

__global__ __launch_bounds__(256) void k_wtv(const float* __restrict__ W, const float* __restrict__ b,
                                             float* __restrict__ u){
  __shared__ float sb2[C];
  const int t = threadIdx.x;
  sb2[t] = b[t]; sb2[t + 256] = b[t + 256];
  __syncthreads();
  const int e = blockIdx.x * 256 + t;
  float acc = 0.f;
  for (int c = 0; c < C; ++c) acc = fmaf(W[(long)c * C + e], sb2[c], acc);
  u[e] = acc;
}

__global__ void k_dot2(const float* __restrict__ a1, const float* __restrict__ b1,
                       const float* __restrict__ a2, const float* __restrict__ b2,
                       float* __restrict__ c0m2, float* __restrict__ c0s4){
  const int t = threadIdx.x;
  float s1 = 0.f, s2 = 0.f;
  for (int i = t; i < C; i += 256){ s1 += a1[i] * b1[i]; s2 += a2[i] * b2[i]; }
  __shared__ float sh1[4], sh2[4];
  s1 = wredSum(s1); s2 = wredSum(s2);
  if ((t & 63) == 0){ sh1[t >> 6] = s1; sh2[t >> 6] = s2; }
  __syncthreads();
  if (t == 0){
    float d1 = sh1[0] + sh1[1] + sh1[2] + sh1[3];
    float d2 = sh2[0] + sh2[1] + sh2[2] + sh2[3];
    c0m2[0] = d1; c0m2[1] = d1;
    c0s4[0] = d2; c0s4[1] = d2; c0s4[2] = d2; c0s4[3] = d2;
  }
}

__global__ __launch_bounds__(256) void k_pixvec(const __bf16* __restrict__ X, const float* __restrict__ u,
                                                float* __restrict__ out){
  const int z = blockIdx.y;
  const int wv = threadIdx.x >> 6, lane = threadIdx.x & 63;
  const int n = blockIdx.x * 4 + wv;
  float acc = 0.f;
  for (int d = lane; d < C; d += 64) acc += (float)X[(long)z * NC + (long)n * C + d] * u[d];
  acc = wredSum(acc);
  if (lane == 0) out[(long)z * N + n] = acc;
}

__global__ __launch_bounds__(256) void k_pixvec2(const __bf16* __restrict__ X,
                                                 const float* __restrict__ u1, const float* __restrict__ u2,
                                                 float* __restrict__ out1, float* __restrict__ out2){
  const int z = blockIdx.y;
  const int wv = threadIdx.x >> 6, lane = threadIdx.x & 63;
  const int n = blockIdx.x * 4 + wv;
  float a1 = 0.f, a2 = 0.f;
  for (int d = lane; d < C; d += 64){
    const float xv = (float)X[(long)z * NC + (long)n * C + d];
    a1 = fmaf(xv, u1[d], a1);
    a2 = fmaf(xv, u2[d], a2);
  }
  a1 = wredSum(a1);
  a2 = wredSum(a2);
  if (lane == 0){ out1[(long)z * N + n] = a1; out2[(long)z * N + n] = a2; }
}

// ======================= prep / stats =======================
__global__ __launch_bounds__(256) void k_stats(const float* __restrict__ x, const float* __restrict__ y,
                                               float* __restrict__ meanv, float* __restrict__ invs){
  const int bid = blockIdx.x;
  const int t = bid >> 9, c = bid & 511;
  const float* src = (t < 2 ? x : y) + (long)(t & 1) * CN + (long)c * N;
  const int tid = threadIdx.x;
  float s1 = 0.f, s2 = 0.f;
  for (int i = tid; i < N; i += 256){ float v = src[i]; s1 += v; s2 += v * v; }
  __shared__ float sh1[4], sh2[4];
  s1 = wredSum(s1); s2 = wredSum(s2);
  if ((tid & 63) == 0){ sh1[tid >> 6] = s1; sh2[tid >> 6] = s2; }
  __syncthreads();
  if (tid == 0){
    float m = (sh1[0] + sh1[1] + sh1[2] + sh1[3]) * (1.f / (float)N);
    float ex2 = (sh2[0] + sh2[1] + sh2[2] + sh2[3]) * (1.f / (float)N);
    float var = ex2 - m * m;
    meanv[t * C + c] = m;
    invs[t * C + c] = rsqrtf((var > 0.f ? var : 0.f) + EPSC);
  }
}

__global__ __launch_bounds__(256) void k_prep(const float* __restrict__ src,
                                              const float* __restrict__ meanv, const float* __restrict__ invs, int toff,
                                              __bf16* __restrict__ adH,
                                              __bf16* __restrict__ fcH, __bf16* __restrict__ fcL,
                                              __bf16* __restrict__ ccH, __bf16* __restrict__ ccL,
                                              __bf16* __restrict__ rwH){
  __shared__ float tile[64][65];
  const int z = blockIdx.z;
  const int n0 = blockIdx.x * 64;
  const int c0 = blockIdx.y * 64;
  const int tid = threadIdx.x;
  const int tx = tid & 63, ty = tid >> 6;
  const int tgt = toff + z;
#pragma unroll
  for (int it = 0; it < 16; ++it){
    const int cc = it * 4 + ty;
    const float v = src[(long)z * CN + (long)(c0 + cc) * N + n0 + tx];
    tile[cc][tx] = v;
    const float cen = v - meanv[tgt * C + c0 + cc];
    splitw(cen, ccH, ccL, (long)tgt * CN + (long)(c0 + cc) * N + n0 + tx);
  }
  __syncthreads();
  const float m = meanv[tgt * C + c0 + tx];
  const float r = invs[tgt * C + c0 + tx];
#pragma unroll
  for (int it = 0; it < 16; ++it){
    const int p = it * 4 + ty;
    const float v = tile[tx][p];
    const float cen = v - m;
    const long o = (long)z * NC + (long)(n0 + p) * C + c0 + tx;
    adH[o] = (__bf16)(cen * r);
    splitw(cen, fcH, fcL, (long)tgt * NC + (long)(n0 + p) * C + c0 + tx);
    if (rwH) rwH[o] = (__bf16)v;
  }
}

__global__ __launch_bounds__(256) void k_wcvt(const float* __restrict__ s, __bf16* __restrict__ h,
                                              __bf16* __restrict__ l, int n){
  int i = blockIdx.x * 256 + threadIdx.x;
  if (i < n) splitw(s[i], h, l, i);
}
__global__ __launch_bounds__(256) void k_wcvt_h(const float* __restrict__ s, __bf16* __restrict__ h, int n){
  int i = blockIdx.x * 256 + threadIdx.x;
  if (i < n) h[i] = (__bf16)s[i];
}

// ======================= power iteration / NS init (2eps*I folded in) =======================
__global__ __launch_bounds__(256) void k_powit(const float* __restrict__ cov,
                                               float* __restrict__ invt, float* __restrict__ invsqt){
  __shared__ float v[C], red[4];
  const int z = blockIdx.x, t = threadIdx.x;
  const float* A = cov + (long)z * CC;
  const int j0 = t, j1 = t + 256;
  v[j0] = 1.f + 0.0003f * (float)j0;
  v[j1] = 1.f + 0.0003f * (float)j1;
  __syncthreads();
  float lam = 1.f;
  for (int it = 0; it < 4; ++it){
    float w0a = 0.f, w0b = 0.f, w1a = 0.f, w1b = 0.f;
#pragma unroll 8
    for (int c = 0; c < C; c += 2){
      const float vc0 = v[c], vc1 = v[c + 1];
      w0a = fmaf(A[(long)c * C + j0], vc0, w0a);
      w1a = fmaf(A[(long)c * C + j1], vc0, w1a);
      w0b = fmaf(A[(long)(c + 1) * C + j0], vc1, w0b);
      w1b = fmaf(A[(long)(c + 1) * C + j1], vc1, w1b);
    }
    const float w0 = w0a + w0b + 2.f * EPSC * v[j0];
    const float w1 = w1a + w1b + 2.f * EPSC * v[j1];
    float s = w0 * w0 + w1 * w1;
    s = wredSum(s);
    if ((t & 63) == 0) red[t >> 6] = s;
    __syncthreads();
    const float nrm = sqrtf(red[0] + red[1] + red[2] + red[3]);
    lam = nrm;
    const float inv = 1.f / nrm;
    v[j0] = w0 * inv;
    v[j1] = w1 * inv;
    __syncthreads();
  }
  if (t == 0){
    const float tt = 1.02f * lam;
    invt[z] = 1.f / tt;
    invsqt[z] = rsqrtf(tt);
  }
}

__global__ __launch_bounds__(256) void k_ns_init(const float* __restrict__ cov, const float* __restrict__ invt,
                                                 __bf16* __restrict__ h, __bf16* __restrict__ l,
                                                 __bf16* __restrict__ cph, __bf16* __restrict__ cpl){
  const int r = blockIdx.x, z = blockIdx.y;
  const long base = (long)z * CC + (long)r * C;
  const float it = invt[z];
  for (int i = threadIdx.x; i < C; i += 256){
    const float cv = cov[base + i] + ((i == r) ? 2.f * EPSC : 0.f);
    const float v = cv * it;
    splitw(v, h, l, base + i);
    splitw(v, cph, cpl, base + i);
    h[4 * CC + base + i] = (__bf16)((i == r) ? 1.f : 0.f);
    l[4 * CC + base + i] = (__bf16)0.f;
  }
}

// ======================= softmax aux =======================
__global__ __launch_bounds__(256) void k_prowmerge(const float* __restrict__ Pm, const float* __restrict__ Ps,
                                                   float* __restrict__ rm, float* __restrict__ rsc){
  const int row = blockIdx.x * 256 + threadIdx.x;
  float m = -3.4e38f, s = 0.f;
#pragma unroll 4
  for (int p = 0; p < 32; ++p){
    const float mp = Pm[(long)p * N + row];
    const float sp = Ps[(long)p * N + row];
    const float nm = fmaxf(m, mp);
    s = s * __expf(m - nm) + sp * __expf(mp - nm);
    m = nm;
  }
  rm[row] = m;
  rsc[row] = 1.f / s;
}

__global__ __launch_bounds__(256) void k_prowmerge_m(const float* __restrict__ Pm, const float* __restrict__ Ps,
                                                     const float* __restrict__ Pq,
                                                     float* __restrict__ rm, float* __restrict__ rsc){
  const int z = blockIdx.y;
  const int row = blockIdx.x * 256 + threadIdx.x;
  float m = -3.4e38f, s = 0.f, q = 0.f;
#pragma unroll 4
  for (int p = 0; p < 32; ++p){
    const long idx = (long)(z * 32 + p) * N + row;
    const float mp = Pm[idx], sp = Ps[idx], qp = Pq[idx];
    const float nm = fmaxf(m, mp);
    const float c0_ = __expf(m - nm), c1_ = __expf(mp - nm);
    s = s * c0_ + sp * c1_;
    q = q * c0_ + qp * c1_;
    m = nm;
  }
  float l1 = q / s;
  if (l1 < 1e-12f) l1 = 1e-12f;
  rsc[(long)z * N + row] = 1.f / (s * l1);
  rm[(long)z * N + row] = m;
}

__global__ __launch_bounds__(256) void k_colaccum(const float* __restrict__ E, const float* __restrict__ rowmax,
                                                  const float* __restrict__ rowscale, float* __restrict__ partials){
  const int j = (blockIdx.x * 256 + threadIdx.x) * 4;
  const int r0 = blockIdx.y * 32;
  float4 acc = {0.f, 0.f, 0.f, 0.f};
#pragma unroll 4
  for (int r2 = r0; r2 < r0 + 32; ++r2){
    const float4 e = *reinterpret_cast<const float4*>(E + (long)r2 * N + j);
    const float rmv = rowmax[r2], rsv = rowscale[r2];
    acc.x += __expf(e.x - rmv) * rsv;
    acc.y += __expf(e.y - rmv) * rsv;
    acc.z += __expf(e.z - rmv) * rsv;
    acc.w += __expf(e.w - rmv) * rsv;
  }
  *reinterpret_cast<float4*>(partials + (long)blockIdx.y * N + j) = acc;
}

__global__ __launch_bounds__(256) void k_colreduce(const float* __restrict__ partials, float* __restrict__ att){
  const int j = blockIdx.x * 256 + threadIdx.x;
  float s = 0.f;
#pragma unroll 8
  for (int p = 0; p < 128; ++p) s += partials[(long)p * N + j];
  att[j] = s * (1.f / (float)N);
}

// ======================= mask (radix select), all 4 selections in one launch =======================
__global__ __launch_bounds__(256) void k_radix(const float* __restrict__ a, float* __restrict__ thr){
  __shared__ unsigned int vals[N];
  __shared__ float shc[4];
  __shared__ unsigned int p_sh;
  __shared__ int k_sh;
  const float* pa = a + (long)blockIdx.x * N;
  const int tid = threadIdx.x;
  for (int i = tid; i < N; i += 256) vals[i] = __float_as_uint(pa[i]);
  if (tid == 0){ p_sh = 0u; k_sh = KSEL; }
  __syncthreads();
  for (int b = 31; b >= 0; --b){
    const unsigned int bit = 1u << b;
    const unsigned int above = (b == 31) ? 0u : ~((bit << 1) - 1u);
    const unsigned int p = p_sh;
    int cnt = 0;
    for (int i = tid; i < N; i += 256){
      unsigned int v = vals[i];
      if ((v & above) == p && (v & bit)) cnt++;
    }
    float cf = wredSum((float)cnt);
    if ((tid & 63) == 0) shc[tid >> 6] = cf;
    __syncthreads();
    if (tid == 0){
      int c1 = (int)(shc[0] + shc[1] + shc[2] + shc[3] + 0.5f);
      if (k_sh <= c1) p_sh = p | bit;
      else k_sh -= c1;
    }
    __syncthreads();
  }
  if (tid == 0) thr[blockIdx.x] = __uint_as_float(p_sh);
}

__global__ __launch_bounds__(256) void k_mask(const float* __restrict__ ax, const float* __restrict__ ay,
                                              const float* __restrict__ thr, float* __restrict__ mx,
                                              float* __restrict__ my){
  int j = blockIdx.x * 256 + threadIdx.x;
  mx[j] = (ax[j] >= thr[0] && ax[N + j] >= thr[1]) ? 1.f : 0.f;
  my[j] = (ay[j] >= thr[2] && ay[N + j] >= thr[3]) ? 1.f : 0.f;
}

// ======================= host =======================
extern "C" void kernel_launch(void* const* d_in, const int* in_sizes, int n_in,
                              void* d_out, int out_size, void* d_ws, size_t ws_size,
                              hipStream_t stream)
{
  const float* x     = (const float*)d_in[0];
  const float* y     = (const float*)d_in[1];
  const float* f_w   = (const float*)d_in[2];
  const float* f_b   = (const float*)d_in[3];
  const float* g_w   = (const float*)d_in[4];
  const float* g_b   = (const float*)d_in[5];
  const float* saf_w = (const float*)d_in[6];
  const float* saf_b = (const float*)d_in[7];
  const float* sag_w = (const float*)d_in[8];
  const float* sag_b = (const float*)d_in[9];
  const float* h_w   = (const float*)d_in[10];
  const float* h_b   = (const float*)d_in[11];
  const float* ow    = (const float*)d_in[12];
  const float* ob    = (const float*)d_in[13];

  const size_t MBy = 1ull << 20;
  const size_t KBy = 1ull << 10;
  char* base = (char*)d_ws;
  if (ws_size < 206 * MBy) return;
  auto F  = [&](size_t off){ return (float*)(base + off); };
  auto Bp = [&](size_t off){ return (__bf16*)(base + off); };

  float *E0 = F(0);
  __bf16 *Ebf = Bp(0);
  __bf16 *ccH = Bp(0), *ccL = Bp(16*MBy);
  float  *covb = F(32*MBy);
  __bf16 *zpolH = Bp(36*MBy), *zpolL = Bp(38*MBy);
  __bf16 *covPH = Bp(40*MBy), *covPL = Bp(42*MBy);
  float  *KsTf = F(44*MBy), *K2tf = F(45*MBy);
  __bf16 *KsTH = Bp(46*MBy), *KsTL = Bp(46*MBy + 512*KBy);
  __bf16 *K2tH = Bp(47*MBy), *hwH = Bp(47*MBy + 512*KBy);
  __bf16 *tpH = Bp(48*MBy), *tpL = Bp(50*MBy);
  __bf16 *xaH = Bp(64*MBy);
  __bf16 *xzH = Bp(64*MBy), *xzL = Bp(80*MBy);
  __bf16 *ypmH = Bp(96*MBy);
  __bf16 *AsH = Bp(96*MBy), *AsL = Bp(112*MBy);
  __bf16 *fcH = Bp(128*MBy), *fcL = Bp(144*MBy);
  __bf16 *resH = Bp(128*MBy);
  __bf16 *nsAh = Bp(160*MBy), *nsAl = Bp(164*MBy);
  __bf16 *nsBh = Bp(168*MBy), *nsBl = Bp(172*MBy);
  __bf16 *A2H = Bp(176*MBy);
  __bf16 *yaH = Bp(184*MBy);
  __bf16 *hH  = Bp(192*MBy);
  __bf16 *owH = Bp(200*MBy);
  size_t so = 200 * MBy + 512 * KBy;
  auto SF = [&](size_t bytes){ float* p = F(so); so += bytes; return p; };
  float *meanv = SF(8*KBy), *invs = SF(8*KBy);
  float *rm = SF(32*KBy), *rsc = SF(32*KBy);
  float *mxv = SF(16*KBy), *myv = SF(16*KBy);
  float *rvec2 = SF(32*KBy), *cvec2 = SF(32*KBy);
  float *rvS = SF(64*KBy), *cvS = SF(64*KBy);
  float *u1m = SF(2*KBy), *u2m = SF(2*KBy), *u1s = SF(2*KBy), *u2s = SF(2*KBy);
  float *c0m2 = SF(64), *c0s4 = SF(64), *thr = SF(64);
  float *invt = SF(64), *invsqt = SF(64);
  float *partials = F(201*MBy);                      // [128][N]
  float *Pm = F(203*MBy);                            // [64][N]
  float *Ps = F(204*MBy);                            // [64][N]
  float *Pq = F(205*MBy);                            // [64][N]

  float* outm = (float*)d_out;
  float* attx = outm + B2 * CN;                      // attx[2][N] then atty[2][N], contiguous
  float* atty = attx + (long)B2 * N;

  // 1) stats + prep
  k_stats<<<dim3(4 * C), dim3(256), 0, stream>>>(x, y, meanv, invs);
  k_prep<<<dim3(64, 8, 2), dim3(256), 0, stream>>>(x, meanv, invs, 0, xaH, fcH, fcL, ccH, ccL, nullptr);
  k_prep<<<dim3(64, 8, 2), dim3(256), 0, stream>>>(y, meanv, invs, 2, yaH, fcH, fcL, ccH, ccL, ypmH);

  // 2) weight products & conversions
  k_wtw<<<dim3(16, 16), dim3(256), 0, stream>>>(sag_w, saf_w, KsTf, 1.f);
  k_wtw<<<dim3(16, 16), dim3(256), 0, stream>>>(g_w, f_w, K2tf, 1.f);
  {
    const int nb = (int)(CC / 256);
    k_wcvt<<<nb, 256, 0, stream>>>(KsTf, KsTH, KsTL, (int)CC);
    k_wcvt_h<<<nb, 256, 0, stream>>>(K2tf, K2tH, (int)CC);
    k_wcvt_h<<<nb, 256, 0, stream>>>(h_w, hwH, (int)CC);
    k_wcvt_h<<<nb, 256, 0, stream>>>(ow, owH, (int)CC);
  }
  k_wtv<<<dim3(2), dim3(256), 0, stream>>>(g_w, f_b, u1m);
  k_wtv<<<dim3(2), dim3(256), 0, stream>>>(f_w, g_b, u2m);
  k_wtv<<<dim3(2), dim3(256), 0, stream>>>(sag_w, saf_b, u1s);
  k_wtv<<<dim3(2), dim3(256), 0, stream>>>(saf_w, sag_b, u2s);
  k_dot2<<<dim3(1), dim3(256), 0, stream>>>(f_b, g_b, saf_b, sag_b, c0m2, c0s4);
  k_pixvec<<<dim3(N / 4, 2), dim3(256), 0, stream>>>(xaH, u2m, rvec2);
  k_pixvec<<<dim3(N / 4, 2), dim3(256), 0, stream>>>(yaH, u1m, cvec2);

  // 3) cov (2eps*I folded downstream) + power-iteration lambda_max
  k_mm64<0,0,0><<<dim3(8, 8, 4), dim3(256), 0, stream>>>(
      ccH, ccL, ccH, ccL, nullptr, nullptr, covb, nullptr, nullptr, C, N, CN, CN, CC, 1.f / (float)(N - 1));
  k_powit<<<dim3(4), dim3(256), 0, stream>>>(covb, invt, invsqt);

  // 4) A2 = xa . K2^T, h conv
  k_mm<1,0,2,0><<<dim3(32, 4, 2), dim3(256), 0, stream>>>(xaH, nullptr, K2tH, nullptr, nullptr, A2H, nullptr,
      C, C, NC, 0, NC, 1.f, nullptr, nullptr, 0, nullptr, 0, nullptr, nullptr, 0,
      nullptr, nullptr, nullptr, nullptr, nullptr);
  k_mm<1,0,2,0><<<dim3(4, 32, 2), dim3(256), 0, stream>>>(hwH, nullptr, ypmH, nullptr, nullptr, hH, nullptr,
      N, C, 0, NC, CN, 1.f, nullptr, h_b, 0, nullptr, 0, nullptr, nullptr, 0,
      nullptr, nullptr, nullptr, nullptr, nullptr);

  // 5) Newton-Schulz (4 iters; last iter Z-only) + split-bf16 polish
  k_ns_init<<<dim3(C, 4), dim3(256), 0, stream>>>(covb, invt, nsAh, nsAl, covPH, covPL);
  __bf16 *cah = nsAh, *cal = nsAl, *cbh = nsBh, *cbl = nsBl;
  for (int it = 0; it < NS_ITERS; ++it){
    k_mm64<1,1,0><<<dim3(8, 8, 4), dim3(256), 0, stream>>>(
        cah + 4*CC, cal + 4*CC, cah, cal, nullptr, nullptr, nullptr, tpH, tpL, C, C, CC, CC, CC, 1.f);
    if (it < NS_ITERS - 1){
      k_mm64<0,1,1><<<dim3(8, 8, 8), dim3(256), 0, stream>>>(
          cah, cal, nullptr, nullptr, tpH, tpL, nullptr, cbh, cbl, C, C, CC, CC, CC, 1.f);
    } else {
      k_mm64<0,1,2><<<dim3(8, 8, 4), dim3(256), 0, stream>>>(
          cah, cal, nullptr, nullptr, tpH, tpL, nullptr, cbh, cbl, C, C, CC, CC, CC, 1.f);
    }
    __bf16* t;
    t = cah; cah = cbh; cbh = t;
    t = cal; cal = cbl; cbl = t;
  }
  k_mm64<0,1,0><<<dim3(8, 8, 4), dim3(256), 0, stream>>>(
      cah + 4*CC, cal + 4*CC, cah + 4*CC, cal + 4*CC, nullptr, nullptr, nullptr, tpH, tpL, C, C, CC, CC, CC, 1.f);
  k_mm64<1,1,0><<<dim3(8, 8, 4), dim3(256), 0, stream>>>(
      covPH, covPL, tpH, tpL, nullptr, nullptr, nullptr, cbh, cbl, C, C, CC, CC, CC, 1.f);
  k_mm64<0,1,0><<<dim3(8, 8, 4), dim3(256), 0, stream>>>(
      cah + 4*CC, cal + 4*CC, cbh, cbl, nullptr, nullptr, nullptr, zpolH, zpolL, C, C, CC, CC, CC, 1.f);

  // 6) zca apply: xz = invsqt * fc . Z
  k_mm<3,0,1,0><<<dim3(32, 4, 4), dim3(256), 0, stream>>>(fcH, fcL, zpolH, zpolL, nullptr, xzH, xzL,
      C, C, NC, CC, NC, 1.f, invsqt, nullptr, 0, nullptr, 0, nullptr, nullptr, 0,
      nullptr, nullptr, nullptr, nullptr, nullptr);

  // 6.5) self bias vecs (one pass) + As = xz . Ks^T
  k_pixvec2<<<dim3(N / 4, 4), dim3(256), 0, stream>>>(xzH, u2s, u1s, rvS, cvS);
  k_mm<3,0,1,0><<<dim3(32, 4, 4), dim3(256), 0, stream>>>(xzH, xzL, KsTH, KsTL, nullptr, AsH, AsL,
      C, C, NC, 0, NC, 1.f, nullptr, nullptr, 0, nullptr, 0, nullptr, nullptr, 0,
      nullptr, nullptr, nullptr, nullptr, nullptr);

  // 7) self-attention energies (3-pass, fp32 E, fused row-stats) -> atten
  for (int z = 0; z < 4; ++z){
    k_mm<3,0,0,1><<<dim3(32, 32, 1), dim3(256), 0, stream>>>(AsH + (long)z*NC, AsL + (long)z*NC,
        xzH + (long)z*NC, xzL + (long)z*NC, E0, nullptr, nullptr,
        N, C, 0, 0, 0, 1.f, nullptr, rvS + (long)z*N, 0, cvS + (long)z*N, 0, c0s4, nullptr, 0,
        Pm, Ps, nullptr, nullptr, nullptr);
    k_prowmerge<<<dim3(16), dim3(256), 0, stream>>>(Pm, Ps, rm, rsc);
    k_colaccum<<<dim3(4, 128), dim3(256), 0, stream>>>(E0, rm, rsc, partials);
    k_colreduce<<<dim3(16), dim3(256), 0, stream>>>(partials, (z < 2 ? attx : atty) + (long)(z & 1) * N);
  }

  // 8) masks (single radix launch over the 4 contiguous atten arrays)
  k_radix<<<dim3(4), dim3(256), 0, stream>>>(attx, thr);
  k_mask<<<dim3(16), dim3(256), 0, stream>>>(attx, atty, thr, mxv, myv);

  // 9) main path: energy -> bf16 E with fused masked row-stats; merge; PV; out conv
  k_mm<1,0,2,2><<<dim3(32, 32, 2), dim3(256), 0, stream>>>(A2H, nullptr, yaH, nullptr, nullptr, Ebf, nullptr,
      N, C, NC, NC, NN, 1.f, nullptr, rvec2, N, cvec2, N, c0m2, nullptr, 0,
      Pm, Ps, Pq, mxv, myv);
  k_prowmerge_m<<<dim3(16, 2), dim3(256), 0, stream>>>(Pm, Ps, Pq, rm, rsc);
  k_pv<<<dim3(64, 4, 2), dim3(256), 0, stream>>>(Ebf, hH, rm, rsc, mxv, myv, resH);
  k_mm<1,0,0,0><<<dim3(4, 32, 2), dim3(256), 0, stream>>>(owH, nullptr, resH, nullptr, outm, nullptr, nullptr,
      N, C, 0, NC, CN, 1.f, nullptr, ob, 0, nullptr, 0, nullptr, x, CN,
      nullptr, nullptr, nullptr, nullptr, nullptr);
}

// Round 15
// 1147.760 us; speedup vs baseline: 1.2375x; 1.0638x over previous
//
#include <hip/hip_runtime.h>
#include <cstdint>

static constexpr int B2 = 2;
static constexpr int C = 512;
static constexpr int N = 4096;
static constexpr long CN = (long)C * N;
static constexpr long NC = (long)N * C;
static constexpr long CC = (long)C * C;
static constexpr long NN = (long)N * N;
static constexpr float EPSC = 1e-5f;
static constexpr int KSEL = 308;       // N - int(N*0.925)
static constexpr int NS_ITERS = 4;

typedef __attribute__((ext_vector_type(8))) __bf16 bf16x8;
typedef __attribute__((ext_vector_type(4))) float f32x4;

__device__ __forceinline__ float wredSum(float v){
#pragma unroll
  for (int o = 32; o >= 1; o >>= 1) v += __shfl_xor(v, o, 64);
  return v;
}

__device__ __forceinline__ void gld16(const __bf16* g, __bf16* l){
  __builtin_amdgcn_global_load_lds(
      (const __attribute__((address_space(1))) void*)g,
      (__attribute__((address_space(3))) void*)l, 16, 0, 0);
}

__device__ __forceinline__ void splitw(float v, __bf16* ph, __bf16* pl, long o){
  __bf16 h = (__bf16)v;
  ph[o] = h;
  pl[o] = (__bf16)(v - (float)h);
}

// ======================= split/plain bf16 MFMA GEMM, 128x128 tile, BK=32 =======================
// XCD swizzle. ROWP: 0 none | 1 row softmax partials | 2 masked (mxp/myp, writes Pq)
template<int PASSES, int TMH, int OUTMODE, int ROWP>
__global__ __launch_bounds__(256) void k_mm(
    const __bf16* __restrict__ Ah, const __bf16* __restrict__ Al,
    const __bf16* __restrict__ Bh, const __bf16* __restrict__ Bl,
    float* __restrict__ Cf, __bf16* __restrict__ Coh, __bf16* __restrict__ Col,
    int Nn, int K, long sAz, long sBz, long sCz,
    float alpha, const float* __restrict__ alpha_ptr,
    const float* __restrict__ brow, long sBr,
    const float* __restrict__ bcol, long sBc,
    const float* __restrict__ c0p,
    const float* __restrict__ addsrc, long sAddz,
    float* __restrict__ Pm, float* __restrict__ Ps, float* __restrict__ Pq,
    const float* __restrict__ mxp, const float* __restrict__ myp)
{
  constexpr int NB = (PASSES == 3) ? 4 : 2;
  constexpr int SB = (PASSES == 3) ? 2 : 1;
  __shared__ __align__(16) __bf16 sm[NB][128 * 32];
  __shared__ float pmx[2][128], psx[2][128], pqx[2][128];
  const int z = blockIdx.z;
  const int nwx = gridDim.x;
  int lin = blockIdx.y * nwx + blockIdx.x;
  const int nwg = nwx * gridDim.y;
  if ((nwg & 7) == 0){
    const int cpx = nwg >> 3;
    lin = (lin & 7) * cpx + (lin >> 3);
  }
  const int i0 = (lin % nwx) * 128;
  const int j0 = (lin / nwx) * 128;
  const int tid = threadIdx.x;
  const int lane = tid & 63;
  const int w = tid >> 6;
  const int wr = (w >> 1) * 64, wc = (w & 1) * 64;
  const int lr = lane & 15;
  const int g = lane >> 4;

  const __bf16* pAh = Ah + (long)z * sAz + (long)i0 * K;
  const __bf16* pBh = Bh + (long)z * sBz + (long)j0 * K;
  const __bf16* pAl = (PASSES == 3) ? (Al + (long)z * sAz + (long)i0 * K) : nullptr;
  const __bf16* pBl = (PASSES == 3) ? (Bl + (long)z * sBz + (long)j0 * K) : nullptr;

  f32x4 acc[4][4] = {};

  for (int kt = 0; kt < K; kt += 32){
#pragma unroll
    for (int p = 0; p < 2; ++p){
      const int t2 = p * 256 + tid;
      const int row = t2 >> 2;
      const int gs = (t2 & 3) ^ ((row >> 1) & 3);
      const long go = (long)row * K + kt + gs * 8;
      gld16(pAh + go, &sm[0][t2 * 8]);
      gld16(pBh + go, &sm[SB][t2 * 8]);
      if constexpr (PASSES == 3){
        gld16(pAl + go, &sm[1][t2 * 8]);
        gld16(pBl + go, &sm[3][t2 * 8]);
      }
    }
    __syncthreads();
    bf16x8 fa[4], fal[4], fb[4], fbl[4];
#pragma unroll
    for (int mi = 0; mi < 4; ++mi){
      const int row = wr + mi * 16 + lr;
      const int off = row * 32 + ((g ^ ((row >> 1) & 3)) * 8);
      fa[mi] = *(const bf16x8*)(&sm[0][off]);
      if constexpr (PASSES == 3) fal[mi] = *(const bf16x8*)(&sm[1][off]);
    }
#pragma unroll
    for (int ni = 0; ni < 4; ++ni){
      const int row = wc + ni * 16 + lr;
      const int off = row * 32 + ((g ^ ((row >> 1) & 3)) * 8);
      fb[ni] = *(const bf16x8*)(&sm[SB][off]);
      if constexpr (PASSES == 3) fbl[ni] = *(const bf16x8*)(&sm[3][off]);
    }
#pragma unroll
    for (int mi = 0; mi < 4; ++mi)
#pragma unroll
      for (int ni = 0; ni < 4; ++ni){
        acc[mi][ni] = __builtin_amdgcn_mfma_f32_16x16x32_bf16(fa[mi], fb[ni], acc[mi][ni], 0, 0, 0);
        if constexpr (PASSES == 3){
          acc[mi][ni] = __builtin_amdgcn_mfma_f32_16x16x32_bf16(fa[mi],  fbl[ni], acc[mi][ni], 0, 0, 0);
          acc[mi][ni] = __builtin_amdgcn_mfma_f32_16x16x32_bf16(fal[mi], fb[ni],  acc[mi][ni], 0, 0, 0);
        }
      }
    __syncthreads();
  }

  float al2 = alpha;
  if (alpha_ptr) al2 *= alpha_ptr[z];
  const float c0v = c0p ? c0p[z] : 0.f;
#pragma unroll
  for (int mi = 0; mi < 4; ++mi){
    float vv[4][4];
    float mrow[4] = {-3.4e38f, -3.4e38f, -3.4e38f, -3.4e38f};
#pragma unroll
    for (int ni = 0; ni < 4; ++ni){
      const int col = j0 + wc + ni * 16 + lr;
      const float bc = (bcol ? bcol[z * sBc + col] : 0.f) + c0v;
#pragma unroll
      for (int j = 0; j < 4; ++j){
        const int row = i0 + wr + mi * 16 + g * 4 + j;
        float v = acc[mi][ni][j] * al2;
        if (TMH) v = (((row == col) ? 3.f : 0.f) - v) * 0.5f;
        if (brow) v += brow[z * sBr + row];
        v += bc;
        if (addsrc) v += addsrc[(long)z * sAddz + (long)row * Nn + col];
        const long o = (long)z * sCz + (long)row * Nn + col;
        if (OUTMODE == 0){ Cf[o] = v; }
        else if (OUTMODE == 1){ __bf16 h = (__bf16)v; Coh[o] = h; Col[o] = (__bf16)(v - (float)h); }
        else { __bf16 h = (__bf16)v; Coh[o] = h; if (ROWP == 2) v = (float)h; }
        if constexpr (ROWP >= 1){
          vv[ni][j] = v;
          mrow[j] = fmaxf(mrow[j], v);
        }
      }
    }
    if constexpr (ROWP >= 1){
#pragma unroll
      for (int j = 0; j < 4; ++j)
#pragma unroll
        for (int o = 1; o <= 8; o <<= 1)
          mrow[j] = fmaxf(mrow[j], __shfl_xor(mrow[j], o, 64));
      float tgt[4];
      if constexpr (ROWP == 2){
#pragma unroll
        for (int j = 0; j < 4; ++j)
          tgt[j] = mxp[i0 + wr + mi * 16 + g * 4 + j];
      }
      float srow[4] = {0.f, 0.f, 0.f, 0.f};
      float qrow[4] = {0.f, 0.f, 0.f, 0.f};
#pragma unroll
      for (int ni = 0; ni < 4; ++ni){
        const float mycol = (ROWP == 2) ? myp[j0 + wc + ni * 16 + lr] : 0.f;
#pragma unroll
        for (int j = 0; j < 4; ++j){
          const float ev = __expf(vv[ni][j] - mrow[j]);
          srow[j] += ev;
          if constexpr (ROWP == 2){
            if (mycol == tgt[j]) qrow[j] += ev;
          }
        }
      }
#pragma unroll
      for (int j = 0; j < 4; ++j){
#pragma unroll
        for (int o = 1; o <= 8; o <<= 1){
          srow[j] += __shfl_xor(srow[j], o, 64);
          if constexpr (ROWP == 2) qrow[j] += __shfl_xor(qrow[j], o, 64);
        }
        if (lr == 0){
          const int rl = wr + mi * 16 + g * 4 + j;
          pmx[w & 1][rl] = mrow[j];
          psx[w & 1][rl] = srow[j];
          if constexpr (ROWP == 2) pqx[w & 1][rl] = qrow[j];
        }
      }
    }
  }
  if constexpr (ROWP >= 1){
    __syncthreads();
    if (tid < 128){
      const float m0 = pmx[0][tid], s0 = psx[0][tid];
      const float m1 = pmx[1][tid], s1 = psx[1][tid];
      const float nm = fmaxf(m0, m1);
      const float c0_ = __expf(m0 - nm), c1_ = __expf(m1 - nm);
      const float s = s0 * c0_ + s1 * c1_;
      const long po = (long)(z * 32 + (j0 >> 7)) * N + i0 + tid;
      Pm[po] = nm;
      Ps[po] = s;
      if constexpr (ROWP == 2){
        Pq[po] = pqx[0][tid] * c0_ + pqx[1][tid] * c1_;
      }
    }
  }
}

// ======================= split-bf16 MFMA GEMM, 64x64 tile, BK=64 (always 3-pass) =======================
template<int TMH, int OUTMODE, int NSYZ>
__global__ __launch_bounds__(256) void k_mm64(
    const __bf16* __restrict__ Ah, const __bf16* __restrict__ Al,
    const __bf16* __restrict__ Bh, const __bf16* __restrict__ Bl,
    const __bf16* __restrict__ tH, const __bf16* __restrict__ tL,
    float* __restrict__ Cf, __bf16* __restrict__ Coh, __bf16* __restrict__ Col,
    int Nn, int K, long sAz, long sBz, long sCz, float alpha)
{
  __shared__ __align__(16) __bf16 sm[4][64 * 64];
  const int z = blockIdx.z;
  const __bf16 *bAh, *bAl, *bBh, *bBl;
  long oC;
  if constexpr (NSYZ == 1){
    if (z < 4){
      bAh = Ah + (long)z * CC; bAl = Al + (long)z * CC;
      bBh = tH + (long)z * CC; bBl = tL + (long)z * CC;
      oC = (long)z * CC;
    } else {
      const int zz = z - 4;
      bAh = tH + (long)zz * CC; bAl = tL + (long)zz * CC;
      bBh = Ah + (long)(4 + zz) * CC; bBl = Al + (long)(4 + zz) * CC;
      oC = (long)(4 + zz) * CC;
    }
  } else if constexpr (NSYZ == 2){
    bAh = tH + (long)z * CC; bAl = tL + (long)z * CC;
    bBh = Ah + (long)(4 + z) * CC; bBl = Al + (long)(4 + z) * CC;
    oC = (long)(4 + z) * CC;
  } else {
    bAh = Ah + (long)z * sAz; bAl = Al + (long)z * sAz;
    bBh = Bh + (long)z * sBz; bBl = Bl + (long)z * sBz;
    oC = (long)z * sCz;
  }
  const int i0 = blockIdx.x * 64;
  const int j0 = blockIdx.y * 64;
  const int tid = threadIdx.x;
  const int lane = tid & 63;
  const int w = tid >> 6;
  const int wr = (w >> 1) * 32, wc = (w & 1) * 32;
  const int lr = lane & 15;
  const int g = lane >> 4;

  const __bf16* pAh = bAh + (long)i0 * K;
  const __bf16* pAl = bAl + (long)i0 * K;
  const __bf16* pBh = bBh + (long)j0 * K;
  const __bf16* pBl = bBl + (long)j0 * K;

  f32x4 acc[2][2] = {};

  for (int kt = 0; kt < K; kt += 64){
#pragma unroll
    for (int p = 0; p < 2; ++p){
      const int t2 = p * 256 + tid;
      const int row = t2 >> 3;
      const int gs = (t2 & 7) ^ (row & 7);
      const long go = (long)row * K + kt + gs * 8;
      gld16(pAh + go, &sm[0][t2 * 8]);
      gld16(pAl + go, &sm[1][t2 * 8]);
      gld16(pBh + go, &sm[2][t2 * 8]);
      gld16(pBl + go, &sm[3][t2 * 8]);
    }
    __syncthreads();
#pragma unroll
    for (int ks = 0; ks < 2; ++ks){
      bf16x8 fa[2], fal[2], fb[2], fbl[2];
#pragma unroll
      for (int mi = 0; mi < 2; ++mi){
        const int row = wr + mi * 16 + lr;
        const int off = row * 64 + (((ks * 4 + g) ^ (row & 7)) * 8);
        fa[mi]  = *(const bf16x8*)(&sm[0][off]);
        fal[mi] = *(const bf16x8*)(&sm[1][off]);
      }
#pragma unroll
      for (int ni = 0; ni < 2; ++ni){
        const int row = wc + ni * 16 + lr;
        const int off = row * 64 + (((ks * 4 + g) ^ (row & 7)) * 8);
        fb[ni]  = *(const bf16x8*)(&sm[2][off]);
        fbl[ni] = *(const bf16x8*)(&sm[3][off]);
      }
#pragma unroll
      for (int mi = 0; mi < 2; ++mi)
#pragma unroll
        for (int ni = 0; ni < 2; ++ni){
          acc[mi][ni] = __builtin_amdgcn_mfma_f32_16x16x32_bf16(fa[mi],  fb[ni],  acc[mi][ni], 0, 0, 0);
          acc[mi][ni] = __builtin_amdgcn_mfma_f32_16x16x32_bf16(fa[mi],  fbl[ni], acc[mi][ni], 0, 0, 0);
          acc[mi][ni] = __builtin_amdgcn_mfma_f32_16x16x32_bf16(fal[mi], fb[ni],  acc[mi][ni], 0, 0, 0);
        }
    }
    __syncthreads();
  }

#pragma unroll
  for (int mi = 0; mi < 2; ++mi){
#pragma unroll
    for (int ni = 0; ni < 2; ++ni){
      const int col = j0 + wc + ni * 16 + lr;
#pragma unroll
      for (int j = 0; j < 4; ++j){
        const int row = i0 + wr + mi * 16 + g * 4 + j;
        float v = acc[mi][ni][j] * alpha;
        if (TMH) v = (((row == col) ? 3.f : 0.f) - v) * 0.5f;
        const long o = oC + (long)row * Nn + col;
        if (OUTMODE == 0){ Cf[o] = v; }
        else { __bf16 h = (__bf16)v; Coh[o] = h; Col[o] = (__bf16)(v - (float)h); }
      }
    }
  }
}

// ======================= fused corr+PV (bf16 E), K-step 64, row-stat merge fused =======================
__global__ __launch_bounds__(256) void k_pv(
    const __bf16* __restrict__ E, const __bf16* __restrict__ Bh,
    const float* __restrict__ Pm, const float* __restrict__ Ps, const float* __restrict__ Pq,
    const float* __restrict__ mxv, const float* __restrict__ myv,
    __bf16* __restrict__ resH)
{
  __shared__ __align__(16) __bf16 sa[64 * 64];
  __shared__ __align__(16) __bf16 sb[128 * 64];
  __shared__ float srm[64], srs[64];
  const int z = blockIdx.z;
  int lin = blockIdx.y * 64 + blockIdx.x;
  lin = (lin & 7) * 32 + (lin >> 3);
  const int n0 = (lin & 63) * 64;
  const int c0 = (lin >> 6) * 128;
  const int tid = threadIdx.x;
  const int lane = tid & 63;
  const int w = tid >> 6;
  const int wr = (w >> 1) * 32, wc = (w & 1) * 64;
  const int lr = lane & 15, g = lane >> 4;

  // phase A: merge masked row stats for rows n0..n0+63 (4 lanes per row)
  {
    const int row = n0 + (tid >> 2);
    const int pp = tid & 3;
    float m = -3.4e38f, s = 0.f, q = 0.f;
#pragma unroll
    for (int p = pp * 8; p < pp * 8 + 8; ++p){
      const long idx = (long)(z * 32 + p) * N + row;
      const float mp = Pm[idx], sp = Ps[idx], qp = Pq[idx];
      const float nm = fmaxf(m, mp);
      const float c0_ = __expf(m - nm), c1_ = __expf(mp - nm);
      s = s * c0_ + sp * c1_;
      q = q * c0_ + qp * c1_;
      m = nm;
    }
#pragma unroll
    for (int o = 1; o <= 2; o <<= 1){
      const float mo = __shfl_xor(m, o, 64);
      const float so = __shfl_xor(s, o, 64);
      const float qo = __shfl_xor(q, o, 64);
      const float nm = fmaxf(m, mo);
      const float c0_ = __expf(m - nm), c1_ = __expf(mo - nm);
      s = s * c0_ + so * c1_;
      q = q * c0_ + qo * c1_;
      m = nm;
    }
    if (pp == 0){
      float l1 = q / s;
      if (l1 < 1e-12f) l1 = 1e-12f;
      srm[tid >> 2] = m;
      srs[tid >> 2] = 1.f / (s * l1);
    }
  }
  __syncthreads();

  const __bf16* pe = E + (long)z * NN + (long)n0 * N;
  const __bf16* pB = Bh + (long)z * CN + (long)c0 * N;

  const int ar = tid >> 2;
  const int slot = tid & 3;
  const float rmv = srm[ar];
  const float rsv = srs[ar];
  const float tgt = mxv[n0 + ar];
  const __bf16* per = pe + (long)ar * N;

  f32x4 acc[2][4] = {};

  for (int kt = 0; kt < N; kt += 64){
#pragma unroll
    for (int d = 0; d < 2; ++d){
      const int gd = slot * 2 + d;
      const bf16x8 ev = *(const bf16x8*)(per + kt + gd * 8);
      const float4 m0 = *(const float4*)(myv + kt + gd * 8);
      const float4 m1 = *(const float4*)(myv + kt + gd * 8 + 4);
      bf16x8 pk;
      pk[0] = (__bf16)((m0.x == tgt) ? __expf((float)ev[0] - rmv) * rsv : 0.f);
      pk[1] = (__bf16)((m0.y == tgt) ? __expf((float)ev[1] - rmv) * rsv : 0.f);
      pk[2] = (__bf16)((m0.z == tgt) ? __expf((float)ev[2] - rmv) * rsv : 0.f);
      pk[3] = (__bf16)((m0.w == tgt) ? __expf((float)ev[3] - rmv) * rsv : 0.f);
      pk[4] = (__bf16)((m1.x == tgt) ? __expf((float)ev[4] - rmv) * rsv : 0.f);
      pk[5] = (__bf16)((m1.y == tgt) ? __expf((float)ev[5] - rmv) * rsv : 0.f);
      pk[6] = (__bf16)((m1.z == tgt) ? __expf((float)ev[6] - rmv) * rsv : 0.f);
      pk[7] = (__bf16)((m1.w == tgt) ? __expf((float)ev[7] - rmv) * rsv : 0.f);
      *(bf16x8*)(&sa[ar * 64 + ((gd ^ (ar & 7)) * 8)]) = pk;
    }
#pragma unroll
    for (int p = 0; p < 4; ++p){
      const int t2 = p * 256 + tid;
      const int row = t2 >> 3;
      const int gs = (t2 & 7) ^ (row & 7);
      gld16(pB + (long)row * N + kt + gs * 8, &sb[t2 * 8]);
    }
    __syncthreads();
#pragma unroll
    for (int ks = 0; ks < 2; ++ks){
      bf16x8 fa[2], fb[4];
#pragma unroll
      for (int mi = 0; mi < 2; ++mi){
        const int row = wr + mi * 16 + lr;
        fa[mi] = *(const bf16x8*)(&sa[row * 64 + (((ks * 4 + g) ^ (row & 7)) * 8)]);
      }
#pragma unroll
      for (int ni = 0; ni < 4; ++ni){
        const int row = wc + ni * 16 + lr;
        fb[ni] = *(const bf16x8*)(&sb[row * 64 + (((ks * 4 + g) ^ (row & 7)) * 8)]);
      }
#pragma unroll
      for (int mi = 0; mi < 2; ++mi)
#pragma unroll
        for (int ni = 0; ni < 4; ++ni)
          acc[mi][ni] = __builtin_amdgcn_mfma_f32_16x16x32_bf16(fa[mi], fb[ni], acc[mi][ni], 0, 0, 0);
    }
    __syncthreads();
  }
#pragma unroll
  for (int mi = 0; mi < 2; ++mi)
#pragma unroll
    for (int ni = 0; ni < 4; ++ni){
      const int c = c0 + wc + ni * 16 + lr;
#pragma unroll
      for (int j = 0; j < 4; ++j){
        const int n = n0 + wr + mi * 16 + g * 4 + j;
        resH[(long)z * NC + (long)n * C + c] = (__bf16)acc[mi][ni][j];
      }
    }
}

// ======================= small helpers =======================
__global__ __launch_bounds__(256) void k_wtw(const float* __restrict__ A, const float* __restrict__ B,
                                             float* __restrict__ C2, float alpha){
  __shared__ float sa[16][32], sb[16][32];
  const int i0 = blockIdx.x * 32, j0 = blockIdx.y * 32;
  const int t = threadIdx.x;
  const int ti = t & 15, tj = t >> 4;
  const int li = t & 31, lc = t >> 5;
  float acc[2][2] = {};
  for (int cb = 0; cb < C; cb += 16){
    sa[lc][li]     = A[(long)(cb + lc) * C + i0 + li];
    sa[lc + 8][li] = A[(long)(cb + lc + 8) * C + i0 + li];
    sb[lc][li]     = B[(long)(cb + lc) * C + j0 + li];
    sb[lc + 8][li] = B[(long)(cb + lc + 8) * C + j0 + li];
    __syncthreads();
#pragma unroll
    for (int c = 0; c < 16; ++c){
      const float a0 = sa[c][ti * 2], a1 = sa[c][ti * 2 + 1];
      const float b0 = sb[c][tj * 2], b1 = sb[c][tj * 2 + 1];
      acc[0][0] = fmaf(a0, b0, acc[0][0]); acc[0][1] = fmaf(a0, b1, acc[0][1]);
      acc[1][0] = fmaf(a1, b0, acc[1][0]); acc[1][1] = fmaf(a1, b1, acc[1][1]);
    }
    __syncthreads();
  }
#pragma unroll
  for (int r = 0; r < 2; ++r)
#pragma unroll
    for (int s = 0; s < 2; ++s)
      C2[(long)(i0 + ti * 2 + r) * C + j0 + tj * 2 + s] = acc[r][s] * alpha;
}

// 4 W^T b products in one launch: grid (2,4)
__global__ __launch_bounds__(256) void k_wtv4(
    const float* __restrict__ g_w, const float* __restrict__ f_b,
    const float* __restrict__ f_w, const float* __restrict__ g_b,
    const float* __restrict__ sag_w, const float* __restrict__ saf_b,
    const float* __restrict__ saf_w, const float* __restrict__ sag_b,
    float* __restrict__ u1m, float* __restrict__ u2m,
    float* __restrict__ u1s, float* __restrict__ u2s)
{
  const int zz = blockIdx.y;
  const float* W; const float* b; float* u;
  if (zz == 0){ W = g_w; b = f_b; u = u1m; }
  else if (zz == 1){ W = f_w; b = g_b; u = u2m; }
  else if (zz == 2){ W = sag_w; b = saf_b; u = u1s; }
  else { W = saf_w; b = sag_b; u = u2s; }
  __shared__ float sb2[C];
  const int t = threadIdx.x;
  sb2[t] = b[t]; sb2[t + 256] = b[t + 256];
  __syncthreads();
  const int e = blockIdx.x * 256 + t;
  float acc = 0.f;
  for (int c = 0; c < C; ++c) acc = fmaf(W[(long)c * C + e], sb2[c], acc);
  u[e] = acc;
}

__global__ void k_dot2(const float* __restrict__ a1, const float* __restrict__ b1,
                       const float* __restrict__ a2, const float* __restrict__ b2,
                       float* __restrict__ c0m2, float* __restrict__ c0s4){
  const int t = threadIdx.x;
  float s1 = 0.f, s2 = 0.f;
  for (int i = t; i < C; i += 256){ s1 += a1[i] * b1[i]; s2 += a2[i] * b2[i]; }
  __shared__ float sh1[4], sh2[4];
  s1 = wredSum(s1); s2 = wredSum(s2);
  if ((t & 63) == 0){ sh1[t >> 6] = s1; sh2[t >> 6] = s2; }
  __syncthreads();
  if (t == 0){
    float d1 = sh1[0] + sh1[1] + sh1[2] + sh1[3];
    float d2 = sh2[0] + sh2[1] + sh2[2] + sh2[3];
    c0m2[0] = d1; c0m2[1] = d1;
    c0s4[0] = d2; c0s4[1] = d2; c0s4[2] = d2; c0s4[3] = d2;
  }
}

// main-path bias vecs: grid (N/4, 4): z<2 -> xa.u2m -> rvec2 ; z>=2 -> ya.u1m -> cvec2
__global__ __launch_bounds__(256) void k_pixvecm(const __bf16* __restrict__ xa, const __bf16* __restrict__ ya,
                                                 const float* __restrict__ u2m_, const float* __restrict__ u1m_,
                                                 float* __restrict__ rvec2, float* __restrict__ cvec2){
  const int zz = blockIdx.y;
  const __bf16* X = (zz < 2) ? xa + (long)zz * NC : ya + (long)(zz - 2) * NC;
  const float* u = (zz < 2) ? u2m_ : u1m_;
  float* out = (zz < 2) ? rvec2 + (long)zz * N : cvec2 + (long)(zz - 2) * N;
  const int wv = threadIdx.x >> 6, lane = threadIdx.x & 63;
  const int n = blockIdx.x * 4 + wv;
  float acc = 0.f;
  for (int d = lane; d < C; d += 64) acc += (float)X[(long)n * C + d] * u[d];
  acc = wredSum(acc);
  if (lane == 0) out[n] = acc;
}

__global__ __launch_bounds__(256) void k_pixvec2(const __bf16* __restrict__ X,
                                                 const float* __restrict__ u1, const float* __restrict__ u2,
                                                 float* __restrict__ out1, float* __restrict__ out2){
  const int z = blockIdx.y;
  const int wv = threadIdx.x >> 6, lane = threadIdx.x & 63;
  const int n = blockIdx.x * 4 + wv;
  float a1 = 0.f, a2 = 0.f;
  for (int d = lane; d < C; d += 64){
    const float xv = (float)X[(long)z * NC + (long)n * C + d];
    a1 = fmaf(xv, u1[d], a1);
    a2 = fmaf(xv, u2[d], a2);
  }
  a1 = wredSum(a1);
  a2 = wredSum(a2);
  if (lane == 0){ out1[(long)z * N + n] = a1; out2[(long)z * N + n] = a2; }
}

// ======================= prep / stats =======================
__global__ __launch_bounds__(256) void k_stats(const float* __restrict__ x, const float* __restrict__ y,
                                               float* __restrict__ meanv, float* __restrict__ invs){
  const int bid = blockIdx.x;
  const int t = bid >> 9, c = bid & 511;
  const float* src = (t < 2 ? x : y) + (long)(t & 1) * CN + (long)c * N;
  const int tid = threadIdx.x;
  float s1 = 0.f, s2 = 0.f;
  for (int i = tid; i < N; i += 256){ float v = src[i]; s1 += v; s2 += v * v; }
  __shared__ float sh1[4], sh2[4];
  s1 = wredSum(s1); s2 = wredSum(s2);
  if ((tid & 63) == 0){ sh1[tid >> 6] = s1; sh2[tid >> 6] = s2; }
  __syncthreads();
  if (tid == 0){
    float m = (sh1[0] + sh1[1] + sh1[2] + sh1[3]) * (1.f / (float)N);
    float ex2 = (sh2[0] + sh2[1] + sh2[2] + sh2[3]) * (1.f / (float)N);
    float var = ex2 - m * m;
    meanv[t * C + c] = m;
    invs[t * C + c] = rsqrtf((var > 0.f ? var : 0.f) + EPSC);
  }
}

__global__ __launch_bounds__(256) void k_prep(const float* __restrict__ src,
                                              const float* __restrict__ meanv, const float* __restrict__ invs, int toff,
                                              __bf16* __restrict__ adH,
                                              __bf16* __restrict__ fcH, __bf16* __restrict__ fcL,
                                              __bf16* __restrict__ ccH, __bf16* __restrict__ ccL,
                                              __bf16* __restrict__ rwH){
  __shared__ float tile[64][65];
  const int z = blockIdx.z;
  const int n0 = blockIdx.x * 64;
  const int c0 = blockIdx.y * 64;
  const int tid = threadIdx.x;
  const int tx = tid & 63, ty = tid >> 6;
  const int tgt = toff + z;
#pragma unroll
  for (int it = 0; it < 16; ++it){
    const int cc = it * 4 + ty;
    const float v = src[(long)z * CN + (long)(c0 + cc) * N + n0 + tx];
    tile[cc][tx] = v;
    const float cen = v - meanv[tgt * C + c0 + cc];
    splitw(cen, ccH, ccL, (long)tgt * CN + (long)(c0 + cc) * N + n0 + tx);
  }
  __syncthreads();
  const float m = meanv[tgt * C + c0 + tx];
  const float r = invs[tgt * C + c0 + tx];
#pragma unroll
  for (int it = 0; it < 16; ++it){
    const int p = it * 4 + ty;
    const float v = tile[tx][p];
    const float cen = v - m;
    const long o = (long)z * NC + (long)(n0 + p) * C + c0 + tx;
    adH[o] = (__bf16)(cen * r);
    splitw(cen, fcH, fcL, (long)tgt * NC + (long)(n0 + p) * C + c0 + tx);
    if (rwH) rwH[o] = (__bf16)v;
  }
}

// all weight conversions in one launch: z=0 KsT pair; z=1 K2t high; z=2 h high; z=3 ow high
__global__ __launch_bounds__(256) void k_wcvtall(const float* __restrict__ KsTf, const float* __restrict__ K2tf,
                                                 const float* __restrict__ h_w, const float* __restrict__ ow,
                                                 __bf16* __restrict__ KsTH, __bf16* __restrict__ KsTL,
                                                 __bf16* __restrict__ K2tH, __bf16* __restrict__ hwH,
                                                 __bf16* __restrict__ owH){
  const int zz = blockIdx.y;
  const int i = blockIdx.x * 256 + threadIdx.x;
  if (zz == 0){ splitw(KsTf[i], KsTH, KsTL, i); }
  else if (zz == 1){ K2tH[i] = (__bf16)K2tf[i]; }
  else if (zz == 2){ hwH[i] = (__bf16)h_w[i]; }
  else { owH[i] = (__bf16)ow[i]; }
}

// ======================= power iteration / NS init (2eps*I folded in) =======================
__global__ __launch_bounds__(256) void k_powit(const float* __restrict__ cov,
                                               float* __restrict__ invt, float* __restrict__ invsqt){
  __shared__ float v[C], red[4];
  const int z = blockIdx.x, t = threadIdx.x;
  const float* A = cov + (long)z * CC;
  const int j0 = t, j1 = t + 256;
  v[j0] = 1.f + 0.0003f * (float)j0;
  v[j1] = 1.f + 0.0003f * (float)j1;
  __syncthreads();
  float lam = 1.f;
  for (int it = 0; it < 4; ++it){
    float w0a = 0.f, w0b = 0.f, w1a = 0.f, w1b = 0.f;
#pragma unroll 8
    for (int c = 0; c < C; c += 2){
      const float vc0 = v[c], vc1 = v[c + 1];
      w0a = fmaf(A[(long)c * C + j0], vc0, w0a);
      w1a = fmaf(A[(long)c * C + j1], vc0, w1a);
      w0b = fmaf(A[(long)(c + 1) * C + j0], vc1, w0b);
      w1b = fmaf(A[(long)(c + 1) * C + j1], vc1, w1b);
    }
    const float w0 = w0a + w0b + 2.f * EPSC * v[j0];
    const float w1 = w1a + w1b + 2.f * EPSC * v[j1];
    float s = w0 * w0 + w1 * w1;
    s = wredSum(s);
    if ((t & 63) == 0) red[t >> 6] = s;
    __syncthreads();
    const float nrm = sqrtf(red[0] + red[1] + red[2] + red[3]);
    lam = nrm;
    const float inv = 1.f / nrm;
    v[j0] = w0 * inv;
    v[j1] = w1 * inv;
    __syncthreads();
  }
  if (t == 0){
    const float tt = 1.02f * lam;
    invt[z] = 1.f / tt;
    invsqt[z] = rsqrtf(tt);
  }
}

__global__ __launch_bounds__(256) void k_ns_init(const float* __restrict__ cov, const float* __restrict__ invt,
                                                 __bf16* __restrict__ h, __bf16* __restrict__ l,
                                                 __bf16* __restrict__ cph, __bf16* __restrict__ cpl){
  const int r = blockIdx.x, z = blockIdx.y;
  const long base = (long)z * CC + (long)r * C;
  const float it = invt[z];
  for (int i = threadIdx.x; i < C; i += 256){
    const float cv = cov[base + i] + ((i == r) ? 2.f * EPSC : 0.f);
    const float v = cv * it;
    splitw(v, h, l, base + i);
    splitw(v, cph, cpl, base + i);
    h[4 * CC + base + i] = (__bf16)((i == r) ? 1.f : 0.f);
    l[4 * CC + base + i] = (__bf16)0.f;
  }
}

// ======================= self-path col accumulation, row-stat merge fused =======================
__global__ __launch_bounds__(256) void k_colaccum(const float* __restrict__ E,
                                                  const float* __restrict__ Pm, const float* __restrict__ Ps,
                                                  float* __restrict__ partials){
  __shared__ float srm[32], srs[32];
  const int rb = blockIdx.y;
  const int r0 = rb * 32;
  const int tid = threadIdx.x;
  // phase A: merge row stats for rows r0..r0+31 (8 lanes per row)
  {
    const int row = r0 + (tid >> 3);
    const int pp = tid & 7;
    float m = -3.4e38f, s = 0.f;
#pragma unroll
    for (int p = pp * 4; p < pp * 4 + 4; ++p){
      const float mp = Pm[(long)p * N + row];
      const float sp = Ps[(long)p * N + row];
      const float nm = fmaxf(m, mp);
      s = s * __expf(m - nm) + sp * __expf(mp - nm);
      m = nm;
    }
#pragma unroll
    for (int o = 1; o <= 4; o <<= 1){
      const float mo = __shfl_xor(m, o, 64);
      const float so = __shfl_xor(s, o, 64);
      const float nm = fmaxf(m, mo);
      s = s * __expf(m - nm) + so * __expf(mo - nm);
      m = nm;
    }
    if (pp == 0){ srm[tid >> 3] = m; srs[tid >> 3] = 1.f / s; }
  }
  __syncthreads();
  const int j = (blockIdx.x * 256 + tid) * 4;
  float4 acc = {0.f, 0.f, 0.f, 0.f};
#pragma unroll 4
  for (int r2 = 0; r2 < 32; ++r2){
    const float4 e = *reinterpret_cast<const float4*>(E + (long)(r0 + r2) * N + j);
    const float rmv = srm[r2], rsv = srs[r2];
    acc.x += __expf(e.x - rmv) * rsv;
    acc.y += __expf(e.y - rmv) * rsv;
    acc.z += __expf(e.z - rmv) * rsv;
    acc.w += __expf(e.w - rmv) * rsv;
  }
  *reinterpret_cast<float4*>(partials + (long)rb * N + j) = acc;
}

__global__ __launch_bounds__(256) void k_colreduce(const float* __restrict__ partials, float* __restrict__ att){
  const int j = blockIdx.x * 256 + threadIdx.x;
  float s = 0.f;
#pragma unroll 8
  for (int p = 0; p < 128; ++p) s += partials[(long)p * N + j];
  att[j] = s * (1.f / (float)N);
}

// ======================= mask (radix select), all 4 selections in one launch =======================
__global__ __launch_bounds__(256) void k_radix(const float* __restrict__ a, float* __restrict__ thr){
  __shared__ unsigned int vals[N];
  __shared__ float shc[4];
  __shared__ unsigned int p_sh;
  __shared__ int k_sh;
  const float* pa = a + (long)blockIdx.x * N;
  const int tid = threadIdx.x;
  for (int i = tid; i < N; i += 256) vals[i] = __float_as_uint(pa[i]);
  if (tid == 0){ p_sh = 0u; k_sh = KSEL; }
  __syncthreads();
  for (int b = 31; b >= 0; --b){
    const unsigned int bit = 1u << b;
    const unsigned int above = (b == 31) ? 0u : ~((bit << 1) - 1u);
    const unsigned int p = p_sh;
    int cnt = 0;
    for (int i = tid; i < N; i += 256){
      unsigned int v = vals[i];
      if ((v & above) == p && (v & bit)) cnt++;
    }
    float cf = wredSum((float)cnt);
    if ((tid & 63) == 0) shc[tid >> 6] = cf;
    __syncthreads();
    if (tid == 0){
      int c1 = (int)(shc[0] + shc[1] + shc[2] + shc[3] + 0.5f);
      if (k_sh <= c1) p_sh = p | bit;
      else k_sh -= c1;
    }
    __syncthreads();
  }
  if (tid == 0) thr[blockIdx.x] = __uint_as_float(p_sh);
}

__global__ __launch_bounds__(256) void k_mask(const float* __restrict__ ax, const float* __restrict__ ay,
                                              const float* __restrict__ thr, float* __restrict__ mx,
                                              float* __restrict__ my){
  int j = blockIdx.x * 256 + threadIdx.x;
  mx[j] = (ax[j] >= thr[0] && ax[N + j] >= thr[1]) ? 1.f : 0.f;
  my[j] = (ay[j] >= thr[2] && ay[N + j] >= thr[3]) ? 1.f : 0.f;
}

// ======================= host =======================
extern "C" void kernel_launch(void* const* d_in, const int* in_sizes, int n_in,
                              void* d_out, int out_size, void* d_ws, size_t ws_size,
                              hipStream_t stream)
{
  const float* x     = (const float*)d_in[0];
  const float* y     = (const float*)d_in[1];
  const float* f_w   = (const float*)d_in[2];
  const float* f_b   = (const float*)d_in[3];
  const float* g_w   = (const float*)d_in[4];
  const float* g_b   = (const float*)d_in[5];
  const float* saf_w = (const float*)d_in[6];
  const float* saf_b = (const float*)d_in[7];
  const float* sag_w = (const float*)d_in[8];
  const float* sag_b = (const float*)d_in[9];
  const float* h_w   = (const float*)d_in[10];
  const float* h_b   = (const float*)d_in[11];
  const float* ow    = (const float*)d_in[12];
  const float* ob    = (const float*)d_in[13];

  const size_t MBy = 1ull << 20;
  const size_t KBy = 1ull << 10;
  char* base = (char*)d_ws;
  if (ws_size < 206 * MBy) return;
  auto F  = [&](size_t off){ return (float*)(base + off); };
  auto Bp = [&](size_t off){ return (__bf16*)(base + off); };

  float *E0 = F(0);
  __bf16 *Ebf = Bp(0);
  __bf16 *ccH = Bp(0), *ccL = Bp(16*MBy);
  float  *covb = F(32*MBy);
  __bf16 *zpolH = Bp(36*MBy), *zpolL = Bp(38*MBy);
  __bf16 *covPH = Bp(40*MBy), *covPL = Bp(42*MBy);
  float  *KsTf = F(44*MBy), *K2tf = F(45*MBy);
  __bf16 *KsTH = Bp(46*MBy), *KsTL = Bp(46*MBy + 512*KBy);
  __bf16 *K2tH = Bp(47*MBy), *hwH = Bp(47*MBy + 512*KBy);
  __bf16 *tpH = Bp(48*MBy), *tpL = Bp(50*MBy);
  __bf16 *xaH = Bp(64*MBy);
  __bf16 *xzH = Bp(64*MBy), *xzL = Bp(80*MBy);
  __bf16 *ypmH = Bp(96*MBy);
  __bf16 *AsH = Bp(96*MBy), *AsL = Bp(112*MBy);
  __bf16 *fcH = Bp(128*MBy), *fcL = Bp(144*MBy);
  __bf16 *resH = Bp(128*MBy);
  __bf16 *nsAh = Bp(160*MBy), *nsAl = Bp(164*MBy);
  __bf16 *nsBh = Bp(168*MBy), *nsBl = Bp(172*MBy);
  __bf16 *A2H = Bp(176*MBy);
  __bf16 *yaH = Bp(184*MBy);
  __bf16 *hH  = Bp(192*MBy);
  __bf16 *owH = Bp(200*MBy);
  size_t so = 200 * MBy + 512 * KBy;
  auto SF = [&](size_t bytes){ float* p = F(so); so += bytes; return p; };
  float *meanv = SF(8*KBy), *invs = SF(8*KBy);
  float *rm = SF(32*KBy), *rsc = SF(32*KBy);
  float *mxv = SF(16*KBy), *myv = SF(16*KBy);
  float *rvec2 = SF(32*KBy), *cvec2 = SF(32*KBy);
  float *rvS = SF(64*KBy), *cvS = SF(64*KBy);
  float *u1m = SF(2*KBy), *u2m = SF(2*KBy), *u1s = SF(2*KBy), *u2s = SF(2*KBy);
  float *c0m2 = SF(64), *c0s4 = SF(64), *thr = SF(64);
  float *invt = SF(64), *invsqt = SF(64);
  float *partials = F(201*MBy);                      // [128][N]
  float *Pm = F(203*MBy);                            // [64][N]
  float *Ps = F(204*MBy);                            // [64][N]
  float *Pq = F(205*MBy);                            // [64][N]
  (void)rm; (void)rsc;

  float* outm = (float*)d_out;
  float* attx = outm + B2 * CN;
  float* atty = attx + (long)B2 * N;

  // 1) stats + prep
  k_stats<<<dim3(4 * C), dim3(256), 0, stream>>>(x, y, meanv, invs);
  k_prep<<<dim3(64, 8, 2), dim3(256), 0, stream>>>(x, meanv, invs, 0, xaH, fcH, fcL, ccH, ccL, nullptr);
  k_prep<<<dim3(64, 8, 2), dim3(256), 0, stream>>>(y, meanv, invs, 2, yaH, fcH, fcL, ccH, ccL, ypmH);

  // 2) weight products & conversions (merged launches)
  k_wtw<<<dim3(16, 16), dim3(256), 0, stream>>>(sag_w, saf_w, KsTf, 1.f);
  k_wtw<<<dim3(16, 16), dim3(256), 0, stream>>>(g_w, f_w, K2tf, 1.f);
  k_wcvtall<<<dim3((int)(CC / 256), 4), dim3(256), 0, stream>>>(KsTf, K2tf, h_w, ow,
      KsTH, KsTL, K2tH, hwH, owH);
  k_wtv4<<<dim3(2, 4), dim3(256), 0, stream>>>(g_w, f_b, f_w, g_b, sag_w, saf_b, saf_w, sag_b,
      u1m, u2m, u1s, u2s);
  k_dot2<<<dim3(1), dim3(256), 0, stream>>>(f_b, g_b, saf_b, sag_b, c0m2, c0s4);
  k_pixvecm<<<dim3(N / 4, 4), dim3(256), 0, stream>>>(xaH, yaH, u2m, u1m, rvec2, cvec2);

  // 3) cov (2eps*I folded downstream) + power-iteration lambda_max
  k_mm64<0,0,0><<<dim3(8, 8, 4), dim3(256), 0, stream>>>(
      ccH, ccL, ccH, ccL, nullptr, nullptr, covb, nullptr, nullptr, C, N, CN, CN, CC, 1.f / (float)(N - 1));
  k_powit<<<dim3(4), dim3(256), 0, stream>>>(covb, invt, invsqt);

  // 4) A2 = xa . K2^T, h conv
  k_mm<1,0,2,0><<<dim3(32, 4, 2), dim3(256), 0, stream>>>(xaH, nullptr, K2tH, nullptr, nullptr, A2H, nullptr,
      C, C, NC, 0, NC, 1.f, nullptr, nullptr, 0, nullptr, 0, nullptr, nullptr, 0,
      nullptr, nullptr, nullptr, nullptr, nullptr);
  k_mm<1,0,2,0><<<dim3(4, 32, 2), dim3(256), 0, stream>>>(hwH, nullptr, ypmH, nullptr, nullptr, hH, nullptr,
      N, C, 0, NC, CN, 1.f, nullptr, h_b, 0, nullptr, 0, nullptr, nullptr, 0,
      nullptr, nullptr, nullptr, nullptr, nullptr);

  // 5) Newton-Schulz (4 iters; last iter Z-only) + split-bf16 polish
  k_ns_init<<<dim3(C, 4), dim3(256), 0, stream>>>(covb, invt, nsAh, nsAl, covPH, covPL);
  __bf16 *cah = nsAh, *cal = nsAl, *cbh = nsBh, *cbl = nsBl;
  for (int it = 0; it < NS_ITERS; ++it){
    k_mm64<1,1,0><<<dim3(8, 8, 4), dim3(256), 0, stream>>>(
        cah + 4*CC, cal + 4*CC, cah, cal, nullptr, nullptr, nullptr, tpH, tpL, C, C, CC, CC, CC, 1.f);
    if (it < NS_ITERS - 1){
      k_mm64<0,1,1><<<dim3(8, 8, 8), dim3(256), 0, stream>>>(
          cah, cal, nullptr, nullptr, tpH, tpL, nullptr, cbh, cbl, C, C, CC, CC, CC, 1.f);
    } else {
      k_mm64<0,1,2><<<dim3(8, 8, 4), dim3(256), 0, stream>>>(
          cah, cal, nullptr, nullptr, tpH, tpL, nullptr, cbh, cbl, C, C, CC, CC, CC, 1.f);
    }
    __bf16* t;
    t = cah; cah = cbh; cbh = t;
    t = cal; cal = cbl; cbl = t;
  }
  k_mm64<0,1,0><<<dim3(8, 8, 4), dim3(256), 0, stream>>>(
      cah + 4*CC, cal + 4*CC, cah + 4*CC, cal + 4*CC, nullptr, nullptr, nullptr, tpH, tpL, C, C, CC, CC, CC, 1.f);
  k_mm64<1,1,0><<<dim3(8, 8, 4), dim3(256), 0, stream>>>(
      covPH, covPL, tpH, tpL, nullptr, nullptr, nullptr, cbh, cbl, C, C, CC, CC, CC, 1.f);
  k_mm64<0,1,0><<<dim3(8, 8, 4), dim3(256), 0, stream>>>(
      cah + 4*CC, cal + 4*CC, cbh, cbl, nullptr, nullptr, nullptr, zpolH, zpolL, C, C, CC, CC, CC, 1.f);

  // 6) zca apply: xz = invsqt * fc . Z
  k_mm<3,0,1,0><<<dim3(32, 4, 4), dim3(256), 0, stream>>>(fcH, fcL, zpolH, zpolL, nullptr, xzH, xzL,
      C, C, NC, CC, NC, 1.f, invsqt, nullptr, 0, nullptr, 0, nullptr, nullptr, 0,
      nullptr, nullptr, nullptr, nullptr, nullptr);

  // 6.5) self bias vecs (one pass) + As = xz . Ks^T
  k_pixvec2<<<dim3(N / 4, 4), dim3(256), 0, stream>>>(xzH, u2s, u1s, rvS, cvS);
  k_mm<3,0,1,0><<<dim3(32, 4, 4), dim3(256), 0, stream>>>(xzH, xzL, KsTH, KsTL, nullptr, AsH, AsL,
      C, C, NC, 0, NC, 1.f, nullptr, nullptr, 0, nullptr, 0, nullptr, nullptr, 0,
      nullptr, nullptr, nullptr, nullptr, nullptr);

  // 7) self-attention energies (3-pass, fp32 E, fused row-stats; colaccum merges stats in-kernel)
  for (int z = 0; z < 4; ++z){
    k_mm<3,0,0,1><<<dim3(32, 32, 1), dim3(256), 0, stream>>>(AsH + (long)z*NC, AsL + (long)z*NC,
        xzH + (long)z*NC, xzL + (long)z*NC, E0, nullptr, nullptr,
        N, C, 0, 0, 0, 1.f, nullptr, rvS + (long)z*N, 0, cvS + (long)z*N, 0, c0s4, nullptr, 0,
        Pm, Ps, nullptr, nullptr, nullptr);
    k_colaccum<<<dim3(4, 128), dim3(256), 0, stream>>>(E0, Pm, Ps, partials);
    k_colreduce<<<dim3(16), dim3(256), 0, stream>>>(partials, (z < 2 ? attx : atty) + (long)(z & 1) * N);
  }

  // 8) masks (single radix launch over the 4 contiguous atten arrays)
  k_radix<<<dim3(4), dim3(256), 0, stream>>>(attx, thr);
  k_mask<<<dim3(16), dim3(256), 0, stream>>>(attx, atty, thr, mxv, myv);

  // 9) main path: energy -> bf16 E with fused masked row-stats; PV (merges stats in-kernel); out conv
  k_mm<1,0,2,2><<<dim3(32, 32, 2), dim3(256), 0, stream>>>(A2H, nullptr, yaH, nullptr, nullptr, Ebf, nullptr,
      N, C, NC, NC, NN, 1.f, nullptr, rvec2, N, cvec2, N, c0m2, nullptr, 0,
      Pm, Ps, Pq, mxv, myv);
  k_pv<<<dim3(64, 4, 2), dim3(256), 0, stream>>>(Ebf, hH, Pm, Ps, Pq, mxv, myv, resH);
  k_mm<1,0,0,0><<<dim3(4, 32, 2), dim3(256), 0, stream>>>(owH, nullptr, resH, nullptr, outm, nullptr, nullptr,
      N, C, 0, NC, CN, 1.f, nullptr, ob, 0, nullptr, 0, nullptr, x, CN,
      nullptr, nullptr, nullptr, nullptr, nullptr);
}

// Round 16
// 1147.514 us; speedup vs baseline: 1.2378x; 1.0002x over previous
//
#include <hip/hip_runtime.h>
#include <cstdint>

static constexpr int B2 = 2;
static constexpr int C = 512;
static constexpr int N = 4096;
static constexpr long CN = (long)C * N;
static constexpr long NC = (long)N * C;
static constexpr long CC = (long)C * C;
static constexpr long NN = (long)N * N;
static constexpr float EPSC = 1e-5f;
static constexpr int KSEL = 308;       // N - int(N*0.925)
static constexpr int NS_ITERS = 4;

typedef __attribute__((ext_vector_type(8))) __bf16 bf16x8;
typedef __attribute__((ext_vector_type(8))) _Float16 f16x8;
typedef __attribute__((ext_vector_type(4))) float f32x4;

__device__ __forceinline__ float wredSum(float v){
#pragma unroll
  for (int o = 32; o >= 1; o >>= 1) v += __shfl_xor(v, o, 64);
  return v;
}

__device__ __forceinline__ void gld16(const __bf16* g, __bf16* l){
  __builtin_amdgcn_global_load_lds(
      (const __attribute__((address_space(1))) void*)g,
      (__attribute__((address_space(3))) void*)l, 16, 0, 0);
}

__device__ __forceinline__ void splitw(float v, __bf16* ph, __bf16* pl, long o){
  __bf16 h = (__bf16)v;
  ph[o] = h;
  pl[o] = (__bf16)(v - (float)h);
}

// ======================= split/plain bf16 MFMA GEMM, 128x128 tile, BK=32 =======================
// XCD swizzle. ROWP: 0 none | 1 row softmax partials | 2 masked (mxp/myp, writes Pq)
// OUTMODE: 0 fp32 | 1 bf16 pair | 2 bf16 high | 4 fp16 (Coh reinterpreted)
template<int PASSES, int TMH, int OUTMODE, int ROWP>
__global__ __launch_bounds__(256) void k_mm(
    const __bf16* __restrict__ Ah, const __bf16* __restrict__ Al,
    const __bf16* __restrict__ Bh, const __bf16* __restrict__ Bl,
    float* __restrict__ Cf, __bf16* __restrict__ Coh, __bf16* __restrict__ Col,
    int Nn, int K, long sAz, long sBz, long sCz,
    float alpha, const float* __restrict__ alpha_ptr,
    const float* __restrict__ brow, long sBr,
    const float* __restrict__ bcol, long sBc,
    const float* __restrict__ c0p,
    const float* __restrict__ addsrc, long sAddz,
    float* __restrict__ Pm, float* __restrict__ Ps, float* __restrict__ Pq,
    const float* __restrict__ mxp, const float* __restrict__ myp)
{
  constexpr int NB = (PASSES == 3) ? 4 : 2;
  constexpr int SB = (PASSES == 3) ? 2 : 1;
  __shared__ __align__(16) __bf16 sm[NB][128 * 32];
  __shared__ float pmx[2][128], psx[2][128], pqx[2][128];
  const int z = blockIdx.z;
  const int nwx = gridDim.x;
  int lin = blockIdx.y * nwx + blockIdx.x;
  const int nwg = nwx * gridDim.y;
  if ((nwg & 7) == 0){
    const int cpx = nwg >> 3;
    lin = (lin & 7) * cpx + (lin >> 3);
  }
  const int i0 = (lin % nwx) * 128;
  const int j0 = (lin / nwx) * 128;
  const int tid = threadIdx.x;
  const int lane = tid & 63;
  const int w = tid >> 6;
  const int wr = (w >> 1) * 64, wc = (w & 1) * 64;
  const int lr = lane & 15;
  const int g = lane >> 4;

  const __bf16* pAh = Ah + (long)z * sAz + (long)i0 * K;
  const __bf16* pBh = Bh + (long)z * sBz + (long)j0 * K;
  const __bf16* pAl = (PASSES == 3) ? (Al + (long)z * sAz + (long)i0 * K) : nullptr;
  const __bf16* pBl = (PASSES == 3) ? (Bl + (long)z * sBz + (long)j0 * K) : nullptr;

  f32x4 acc[4][4] = {};

  for (int kt = 0; kt < K; kt += 32){
#pragma unroll
    for (int p = 0; p < 2; ++p){
      const int t2 = p * 256 + tid;
      const int row = t2 >> 2;
      const int gs = (t2 & 3) ^ ((row >> 1) & 3);
      const long go = (long)row * K + kt + gs * 8;
      gld16(pAh + go, &sm[0][t2 * 8]);
      gld16(pBh + go, &sm[SB][t2 * 8]);
      if constexpr (PASSES == 3){
        gld16(pAl + go, &sm[1][t2 * 8]);
        gld16(pBl + go, &sm[3][t2 * 8]);
      }
    }
    __syncthreads();
    bf16x8 fa[4], fal[4], fb[4], fbl[4];
#pragma unroll
    for (int mi = 0; mi < 4; ++mi){
      const int row = wr + mi * 16 + lr;
      const int off = row * 32 + ((g ^ ((row >> 1) & 3)) * 8);
      fa[mi] = *(const bf16x8*)(&sm[0][off]);
      if constexpr (PASSES == 3) fal[mi] = *(const bf16x8*)(&sm[1][off]);
    }
#pragma unroll
    for (int ni = 0; ni < 4; ++ni){
      const int row = wc + ni * 16 + lr;
      const int off = row * 32 + ((g ^ ((row >> 1) & 3)) * 8);
      fb[ni] = *(const bf16x8*)(&sm[SB][off]);
      if constexpr (PASSES == 3) fbl[ni] = *(const bf16x8*)(&sm[3][off]);
    }
#pragma unroll
    for (int mi = 0; mi < 4; ++mi)
#pragma unroll
      for (int ni = 0; ni < 4; ++ni){
        acc[mi][ni] = __builtin_amdgcn_mfma_f32_16x16x32_bf16(fa[mi], fb[ni], acc[mi][ni], 0, 0, 0);
        if constexpr (PASSES == 3){
          acc[mi][ni] = __builtin_amdgcn_mfma_f32_16x16x32_bf16(fa[mi],  fbl[ni], acc[mi][ni], 0, 0, 0);
          acc[mi][ni] = __builtin_amdgcn_mfma_f32_16x16x32_bf16(fal[mi], fb[ni],  acc[mi][ni], 0, 0, 0);
        }
      }
    __syncthreads();
  }

  float al2 = alpha;
  if (alpha_ptr) al2 *= alpha_ptr[z];
  const float c0v = c0p ? c0p[z] : 0.f;
#pragma unroll
  for (int mi = 0; mi < 4; ++mi){
    float vv[4][4];
    float mrow[4] = {-3.4e38f, -3.4e38f, -3.4e38f, -3.4e38f};
#pragma unroll
    for (int ni = 0; ni < 4; ++ni){
      const int col = j0 + wc + ni * 16 + lr;
      const float bc = (bcol ? bcol[z * sBc + col] : 0.f) + c0v;
#pragma unroll
      for (int j = 0; j < 4; ++j){
        const int row = i0 + wr + mi * 16 + g * 4 + j;
        float v = acc[mi][ni][j] * al2;
        if (TMH) v = (((row == col) ? 3.f : 0.f) - v) * 0.5f;
        if (brow) v += brow[z * sBr + row];
        v += bc;
        if (addsrc) v += addsrc[(long)z * sAddz + (long)row * Nn + col];
        const long o = (long)z * sCz + (long)row * Nn + col;
        if (OUTMODE == 0){ Cf[o] = v; }
        else if (OUTMODE == 1){ __bf16 h = (__bf16)v; Coh[o] = h; Col[o] = (__bf16)(v - (float)h); }
        else if (OUTMODE == 2){ __bf16 h = (__bf16)v; Coh[o] = h; if (ROWP == 2) v = (float)h; }
        else { _Float16 hf = (_Float16)v; ((_Float16*)Coh)[o] = hf; if (ROWP >= 1) v = (float)hf; }
        if constexpr (ROWP >= 1){
          vv[ni][j] = v;
          mrow[j] = fmaxf(mrow[j], v);
        }
      }
    }
    if constexpr (ROWP >= 1){
#pragma unroll
      for (int j = 0; j < 4; ++j)
#pragma unroll
        for (int o = 1; o <= 8; o <<= 1)
          mrow[j] = fmaxf(mrow[j], __shfl_xor(mrow[j], o, 64));
      float tgt[4];
      if constexpr (ROWP == 2){
#pragma unroll
        for (int j = 0; j < 4; ++j)
          tgt[j] = mxp[i0 + wr + mi * 16 + g * 4 + j];
      }
      float srow[4] = {0.f, 0.f, 0.f, 0.f};
      float qrow[4] = {0.f, 0.f, 0.f, 0.f};
#pragma unroll
      for (int ni = 0; ni < 4; ++ni){
        const float mycol = (ROWP == 2) ? myp[j0 + wc + ni * 16 + lr] : 0.f;
#pragma unroll
        for (int j = 0; j < 4; ++j){
          const float ev = __expf(vv[ni][j] - mrow[j]);
          srow[j] += ev;
          if constexpr (ROWP == 2){
            if (mycol == tgt[j]) qrow[j] += ev;
          }
        }
      }
#pragma unroll
      for (int j = 0; j < 4; ++j){
#pragma unroll
        for (int o = 1; o <= 8; o <<= 1){
          srow[j] += __shfl_xor(srow[j], o, 64);
          if constexpr (ROWP == 2) qrow[j] += __shfl_xor(qrow[j], o, 64);
        }
        if (lr == 0){
          const int rl = wr + mi * 16 + g * 4 + j;
          pmx[w & 1][rl] = mrow[j];
          psx[w & 1][rl] = srow[j];
          if constexpr (ROWP == 2) pqx[w & 1][rl] = qrow[j];
        }
      }
    }
  }
  if constexpr (ROWP >= 1){
    __syncthreads();
    if (tid < 128){
      const float m0 = pmx[0][tid], s0 = psx[0][tid];
      const float m1 = pmx[1][tid], s1 = psx[1][tid];
      const float nm = fmaxf(m0, m1);
      const float c0_ = __expf(m0 - nm), c1_ = __expf(m1 - nm);
      const float s = s0 * c0_ + s1 * c1_;
      const long po = (long)(z * 32 + (j0 >> 7)) * N + i0 + tid;
      Pm[po] = nm;
      Ps[po] = s;
      if constexpr (ROWP == 2){
        Pq[po] = pqx[0][tid] * c0_ + pqx[1][tid] * c1_;
      }
    }
  }
}

// ======================= split-bf16 MFMA GEMM, 64x64 tile, BK=64 (always 3-pass) =======================
template<int TMH, int OUTMODE, int NSYZ>
__global__ __launch_bounds__(256) void k_mm64(
    const __bf16* __restrict__ Ah, const __bf16* __restrict__ Al,
    const __bf16* __restrict__ Bh, const __bf16* __restrict__ Bl,
    const __bf16* __restrict__ tH, const __bf16* __restrict__ tL,
    float* __restrict__ Cf, __bf16* __restrict__ Coh, __bf16* __restrict__ Col,
    int Nn, int K, long sAz, long sBz, long sCz, float alpha)
{
  __shared__ __align__(16) __bf16 sm[4][64 * 64];
  const int z = blockIdx.z;
  const __bf16 *bAh, *bAl, *bBh, *bBl;
  long oC;
  if constexpr (NSYZ == 1){
    if (z < 4){
      bAh = Ah + (long)z * CC; bAl = Al + (long)z * CC;
      bBh = tH + (long)z * CC; bBl = tL + (long)z * CC;
      oC = (long)z * CC;
    } else {
      const int zz = z - 4;
      bAh = tH + (long)zz * CC; bAl = tL + (long)zz * CC;
      bBh = Ah + (long)(4 + zz) * CC; bBl = Al + (long)(4 + zz) * CC;
      oC = (long)(4 + zz) * CC;
    }
  } else if constexpr (NSYZ == 2){
    bAh = tH + (long)z * CC; bAl = tL + (long)z * CC;
    bBh = Ah + (long)(4 + z) * CC; bBl = Al + (long)(4 + z) * CC;
    oC = (long)(4 + z) * CC;
  } else {
    bAh = Ah + (long)z * sAz; bAl = Al + (long)z * sAz;
    bBh = Bh + (long)z * sBz; bBl = Bl + (long)z * sBz;
    oC = (long)z * sCz;
  }
  const int i0 = blockIdx.x * 64;
  const int j0 = blockIdx.y * 64;
  const int tid = threadIdx.x;
  const int lane = tid & 63;
  const int w = tid >> 6;
  const int wr = (w >> 1) * 32, wc = (w & 1) * 32;
  const int lr = lane & 15;
  const int g = lane >> 4;

  const __bf16* pAh = bAh + (long)i0 * K;
  const __bf16* pAl = bAl + (long)i0 * K;
  const __bf16* pBh = bBh + (long)j0 * K;
  const __bf16* pBl = bBl + (long)j0 * K;

  f32x4 acc[2][2] = {};

  for (int kt = 0; kt < K; kt += 64){
#pragma unroll
    for (int p = 0; p < 2; ++p){
      const int t2 = p * 256 + tid;
      const int row = t2 >> 3;
      const int gs = (t2 & 7) ^ (row & 7);
      const long go = (long)row * K + kt + gs * 8;
      gld16(pAh + go, &sm[0][t2 * 8]);
      gld16(pAl + go, &sm[1][t2 * 8]);
      gld16(pBh + go, &sm[2][t2 * 8]);
      gld16(pBl + go, &sm[3][t2 * 8]);
    }
    __syncthreads();
#pragma unroll
    for (int ks = 0; ks < 2; ++ks){
      bf16x8 fa[2], fal[2], fb[2], fbl[2];
#pragma unroll
      for (int mi = 0; mi < 2; ++mi){
        const int row = wr + mi * 16 + lr;
        const int off = row * 64 + (((ks * 4 + g) ^ (row & 7)) * 8);
        fa[mi]  = *(const bf16x8*)(&sm[0][off]);
        fal[mi] = *(const bf16x8*)(&sm[1][off]);
      }
#pragma unroll
      for (int ni = 0; ni < 2; ++ni){
        const int row = wc + ni * 16 + lr;
        const int off = row * 64 + (((ks * 4 + g) ^ (row & 7)) * 8);
        fb[ni]  = *(const bf16x8*)(&sm[2][off]);
        fbl[ni] = *(const bf16x8*)(&sm[3][off]);
      }
#pragma unroll
      for (int mi = 0; mi < 2; ++mi)
#pragma unroll
        for (int ni = 0; ni < 2; ++ni){
          acc[mi][ni] = __builtin_amdgcn_mfma_f32_16x16x32_bf16(fa[mi],  fb[ni],  acc[mi][ni], 0, 0, 0);
          acc[mi][ni] = __builtin_amdgcn_mfma_f32_16x16x32_bf16(fa[mi],  fbl[ni], acc[mi][ni], 0, 0, 0);
          acc[mi][ni] = __builtin_amdgcn_mfma_f32_16x16x32_bf16(fal[mi], fb[ni],  acc[mi][ni], 0, 0, 0);
        }
    }
    __syncthreads();
  }

#pragma unroll
  for (int mi = 0; mi < 2; ++mi){
#pragma unroll
    for (int ni = 0; ni < 2; ++ni){
      const int col = j0 + wc + ni * 16 + lr;
#pragma unroll
      for (int j = 0; j < 4; ++j){
        const int row = i0 + wr + mi * 16 + g * 4 + j;
        float v = acc[mi][ni][j] * alpha;
        if (TMH) v = (((row == col) ? 3.f : 0.f) - v) * 0.5f;
        const long o = oC + (long)row * Nn + col;
        if (OUTMODE == 0){ Cf[o] = v; }
        else { __bf16 h = (__bf16)v; Coh[o] = h; Col[o] = (__bf16)(v - (float)h); }
      }
    }
  }
}

// ======================= fused corr+PV (bf16 E), K-step 64, row-stat merge fused =======================
__global__ __launch_bounds__(256) void k_pv(
    const __bf16* __restrict__ E, const __bf16* __restrict__ Bh,
    const float* __restrict__ Pm, const float* __restrict__ Ps, const float* __restrict__ Pq,
    const float* __restrict__ mxv, const float* __restrict__ myv,
    __bf16* __restrict__ resH)
{
  __shared__ __align__(16) __bf16 sa[64 * 64];
  __shared__ __align__(16) __bf16 sb[128 * 64];
  __shared__ float srm[64], srs[64];
  const int z = blockIdx.z;
  int lin = blockIdx.y * 64 + blockIdx.x;
  lin = (lin & 7) * 32 + (lin >> 3);
  const int n0 = (lin & 63) * 64;
  const int c0 = (lin >> 6) * 128;
  const int tid = threadIdx.x;
  const int lane = tid & 63;
  const int w = tid >> 6;
  const int wr = (w >> 1) * 32, wc = (w & 1) * 64;
  const int lr = lane & 15, g = lane >> 4;

  {
    const int row = n0 + (tid >> 2);
    const int pp = tid & 3;
    float m = -3.4e38f, s = 0.f, q = 0.f;
#pragma unroll
    for (int p = pp * 8; p < pp * 8 + 8; ++p){
      const long idx = (long)(z * 32 + p) * N + row;
      const float mp = Pm[idx], sp = Ps[idx], qp = Pq[idx];
      const float nm = fmaxf(m, mp);
      const float c0_ = __expf(m - nm), c1_ = __expf(mp - nm);
      s = s * c0_ + sp * c1_;
      q = q * c0_ + qp * c1_;
      m = nm;
    }
#pragma unroll
    for (int o = 1; o <= 2; o <<= 1){
      const float mo = __shfl_xor(m, o, 64);
      const float so = __shfl_xor(s, o, 64);
      const float qo = __shfl_xor(q, o, 64);
      const float nm = fmaxf(m, mo);
      const float c0_ = __expf(m - nm), c1_ = __expf(mo - nm);
      s = s * c0_ + so * c1_;
      q = q * c0_ + qo * c1_;
      m = nm;
    }
    if (pp == 0){
      float l1 = q / s;
      if (l1 < 1e-12f) l1 = 1e-12f;
      srm[tid >> 2] = m;
      srs[tid >> 2] = 1.f / (s * l1);
    }
  }
  __syncthreads();

  const __bf16* pe = E + (long)z * NN + (long)n0 * N;
  const __bf16* pB = Bh + (long)z * CN + (long)c0 * N;

  const int ar = tid >> 2;
  const int slot = tid & 3;
  const float rmv = srm[ar];
  const float rsv = srs[ar];
  const float tgt = mxv[n0 + ar];
  const __bf16* per = pe + (long)ar * N;

  f32x4 acc[2][4] = {};

  for (int kt = 0; kt < N; kt += 64){
#pragma unroll
    for (int d = 0; d < 2; ++d){
      const int gd = slot * 2 + d;
      const bf16x8 ev = *(const bf16x8*)(per + kt + gd * 8);
      const float4 m0 = *(const float4*)(myv + kt + gd * 8);
      const float4 m1 = *(const float4*)(myv + kt + gd * 8 + 4);
      bf16x8 pk;
      pk[0] = (__bf16)((m0.x == tgt) ? __expf((float)ev[0] - rmv) * rsv : 0.f);
      pk[1] = (__bf16)((m0.y == tgt) ? __expf((float)ev[1] - rmv) * rsv : 0.f);
      pk[2] = (__bf16)((m0.z == tgt) ? __expf((float)ev[2] - rmv) * rsv : 0.f);
      pk[3] = (__bf16)((m0.w == tgt) ? __expf((float)ev[3] - rmv) * rsv : 0.f);
      pk[4] = (__bf16)((m1.x == tgt) ? __expf((float)ev[4] - rmv) * rsv : 0.f);
      pk[5] = (__bf16)((m1.y == tgt) ? __expf((float)ev[5] - rmv) * rsv : 0.f);
      pk[6] = (__bf16)((m1.z == tgt) ? __expf((float)ev[6] - rmv) * rsv : 0.f);
      pk[7] = (__bf16)((m1.w == tgt) ? __expf((float)ev[7] - rmv) * rsv : 0.f);
      *(bf16x8*)(&sa[ar * 64 + ((gd ^ (ar & 7)) * 8)]) = pk;
    }
#pragma unroll
    for (int p = 0; p < 4; ++p){
      const int t2 = p * 256 + tid;
      const int row = t2 >> 3;
      const int gs = (t2 & 7) ^ (row & 7);
      gld16(pB + (long)row * N + kt + gs * 8, &sb[t2 * 8]);
    }
    __syncthreads();
#pragma unroll
    for (int ks = 0; ks < 2; ++ks){
      bf16x8 fa[2], fb[4];
#pragma unroll
      for (int mi = 0; mi < 2; ++mi){
        const int row = wr + mi * 16 + lr;
        fa[mi] = *(const bf16x8*)(&sa[row * 64 + (((ks * 4 + g) ^ (row & 7)) * 8)]);
      }
#pragma unroll
      for (int ni = 0; ni < 4; ++ni){
        const int row = wc + ni * 16 + lr;
        fb[ni] = *(const bf16x8*)(&sb[row * 64 + (((ks * 4 + g) ^ (row & 7)) * 8)]);
      }
#pragma unroll
      for (int mi = 0; mi < 2; ++mi)
#pragma unroll
        for (int ni = 0; ni < 4; ++ni)
          acc[mi][ni] = __builtin_amdgcn_mfma_f32_16x16x32_bf16(fa[mi], fb[ni], acc[mi][ni], 0, 0, 0);
    }
    __syncthreads();
  }
#pragma unroll
  for (int mi = 0; mi < 2; ++mi)
#pragma unroll
    for (int ni = 0; ni < 4; ++ni){
      const int c = c0 + wc + ni * 16 + lr;
#pragma unroll
      for (int j = 0; j < 4; ++j){
        const int n = n0 + wr + mi * 16 + g * 4 + j;
        resH[(long)z * NC + (long)n * C + c] = (__bf16)acc[mi][ni][j];
      }
    }
}

// ======================= small helpers =======================
__global__ __launch_bounds__(256) void k_wtw(const float* __restrict__ A, const float* __restrict__ B,
                                             float* __restrict__ C2, float alpha){
  __shared__ float sa[16][32], sb[16][32];
  const int i0 = blockIdx.x * 32, j0 = blockIdx.y * 32;
  const int t = threadIdx.x;
  const int ti = t & 15, tj = t >> 4;
  const int li = t & 31, lc = t >> 5;
  float acc[2][2] = {};
  for (int cb = 0; cb < C; cb += 16){
    sa[lc][li]     = A[(long)(cb + lc) * C + i0 + li];
    sa[lc + 8][li] = A[(long)(cb + lc + 8) * C + i0 + li];
    sb[lc][li]     = B[(long)(cb + lc) * C + j0 + li];
    sb[lc + 8][li] = B[(long)(cb + lc + 8) * C + j0 + li];
    __syncthreads();
#pragma unroll
    for (int c = 0; c < 16; ++c){
      const float a0 = sa[c][ti * 2], a1 = sa[c][ti * 2 + 1];
      const float b0 = sb[c][tj * 2], b1 = sb[c][tj * 2 + 1];
      acc[0][0] = fmaf(a0, b0, acc[0][0]); acc[0][1] = fmaf(a0, b1, acc[0][1]);
      acc[1][0] = fmaf(a1, b0, acc[1][0]); acc[1][1] = fmaf(a1, b1, acc[1][1]);
    }
    __syncthreads();
  }
#pragma unroll
  for (int r = 0; r < 2; ++r)
#pragma unroll
    for (int s = 0; s < 2; ++s)
      C2[(long)(i0 + ti * 2 + r) * C + j0 + tj * 2 + s] = acc[r][s] * alpha;
}

__global__ __launch_bounds__(256) void k_wtv4(
    const float* __restrict__ g_w, const float* __restrict__ f_b,
    const float* __restrict__ f_w, const float* __restrict__ g_b,
    const float* __restrict__ sag_w, const float* __restrict__ saf_b,
    const float* __restrict__ saf_w, const float* __restrict__ sag_b,
    float* __restrict__ u1m, float* __restrict__ u2m,
    float* __restrict__ u1s, float* __restrict__ u2s)
{
  const int zz = blockIdx.y;
  const float* W; const float* b; float* u;
  if (zz == 0){ W = g_w; b = f_b; u = u1m; }
  else if (zz == 1){ W = f_w; b = g_b; u = u2m; }
  else if (zz == 2){ W = sag_w; b = saf_b; u = u1s; }
  else { W = saf_w; b = sag_b; u = u2s; }
  __shared__ float sb2[C];
  const int t = threadIdx.x;
  sb2[t] = b[t]; sb2[t + 256] = b[t + 256];
  __syncthreads();
  const int e = blockIdx.x * 256 + t;
  float acc = 0.f;
  for (int c = 0; c < C; ++c) acc = fmaf(W[(long)c * C + e], sb2[c], acc);
  u[e] = acc;
}

__global__ void k_dot2(const float* __restrict__ a1, const float* __restrict__ b1,
                       const float* __restrict__ a2, const float* __restrict__ b2,
                       float* __restrict__ c0m2, float* __restrict__ c0s4){
  const int t = threadIdx.x;
  float s1 = 0.f, s2 = 0.f;
  for (int i = t; i < C; i += 256){ s1 += a1[i] * b1[i]; s2 += a2[i] * b2[i]; }
  __shared__ float sh1[4], sh2[4];
  s1 = wredSum(s1); s2 = wredSum(s2);
  if ((t & 63) == 0){ sh1[t >> 6] = s1; sh2[t >> 6] = s2; }
  __syncthreads();
  if (t == 0){
    float d1 = sh1[0] + sh1[1] + sh1[2] + sh1[3];
    float d2 = sh2[0] + sh2[1] + sh2[2] + sh2[3];
    c0m2[0] = d1; c0m2[1] = d1;
    c0s4[0] = d2; c0s4[1] = d2; c0s4[2] = d2; c0s4[3] = d2;
  }
}

__global__ __launch_bounds__(256) void k_pixvecm(const __bf16* __restrict__ xa, const __bf16* __restrict__ ya,
                                                 const float* __restrict__ u2m_, const float* __restrict__ u1m_,
                                                 float* __restrict__ rvec2, float* __restrict__ cvec2){
  const int zz = blockIdx.y;
  const __bf16* X = (zz < 2) ? xa + (long)zz * NC : ya + (long)(zz - 2) * NC;
  const float* u = (zz < 2) ? u2m_ : u1m_;
  float* out = (zz < 2) ? rvec2 + (long)zz * N : cvec2 + (long)(zz - 2) * N;
  const int wv = threadIdx.x >> 6, lane = threadIdx.x & 63;
  const int n = blockIdx.x * 4 + wv;
  float acc = 0.f;
  for (int d = lane; d < C; d += 64) acc += (float)X[(long)n * C + d] * u[d];
  acc = wredSum(acc);
  if (lane == 0) out[n] = acc;
}

__global__ __launch_bounds__(256) void k_pixvec2(const __bf16* __restrict__ X,
                                                 const float* __restrict__ u1, const float* __restrict__ u2,
                                                 float* __restrict__ out1, float* __restrict__ out2){
  const int z = blockIdx.y;
  const int wv = threadIdx.x >> 6, lane = threadIdx.x & 63;
  const int n = blockIdx.x * 4 + wv;
  float a1 = 0.f, a2 = 0.f;
  for (int d = lane; d < C; d += 64){
    const float xv = (float)X[(long)z * NC + (long)n * C + d];
    a1 = fmaf(xv, u1[d], a1);
    a2 = fmaf(xv, u2[d], a2);
  }
  a1 = wredSum(a1);
  a2 = wredSum(a2);
  if (lane == 0){ out1[(long)z * N + n] = a1; out2[(long)z * N + n] = a2; }
}

// ======================= prep / stats =======================
__global__ __launch_bounds__(256) void k_stats(const float* __restrict__ x, const float* __restrict__ y,
                                               float* __restrict__ meanv, float* __restrict__ invs){
  const int bid = blockIdx.x;
  const int t = bid >> 9, c = bid & 511;
  const float* src = (t < 2 ? x : y) + (long)(t & 1) * CN + (long)c * N;
  const int tid = threadIdx.x;
  float s1 = 0.f, s2 = 0.f;
  for (int i = tid; i < N; i += 256){ float v = src[i]; s1 += v; s2 += v * v; }
  __shared__ float sh1[4], sh2[4];
  s1 = wredSum(s1); s2 = wredSum(s2);
  if ((tid & 63) == 0){ sh1[tid >> 6] = s1; sh2[tid >> 6] = s2; }
  __syncthreads();
  if (tid == 0){
    float m = (sh1[0] + sh1[1] + sh1[2] + sh1[3]) * (1.f / (float)N);
    float ex2 = (sh2[0] + sh2[1] + sh2[2] + sh2[3]) * (1.f / (float)N);
    float var = ex2 - m * m;
    meanv[t * C + c] = m;
    invs[t * C + c] = rsqrtf((var > 0.f ? var : 0.f) + EPSC);
  }
}

__global__ __launch_bounds__(256) void k_prep(const float* __restrict__ src,
                                              const float* __restrict__ meanv, const float* __restrict__ invs, int toff,
                                              __bf16* __restrict__ adH,
                                              __bf16* __restrict__ fcH, __bf16* __restrict__ fcL,
                                              __bf16* __restrict__ ccH, __bf16* __restrict__ ccL,
                                              __bf16* __restrict__ rwH){
  __shared__ float tile[64][65];
  const int z = blockIdx.z;
  const int n0 = blockIdx.x * 64;
  const int c0 = blockIdx.y * 64;
  const int tid = threadIdx.x;
  const int tx = tid & 63, ty = tid >> 6;
  const int tgt = toff + z;
#pragma unroll
  for (int it = 0; it < 16; ++it){
    const int cc = it * 4 + ty;
    const float v = src[(long)z * CN + (long)(c0 + cc) * N + n0 + tx];
    tile[cc][tx] = v;
    const float cen = v - meanv[tgt * C + c0 + cc];
    splitw(cen, ccH, ccL, (long)tgt * CN + (long)(c0 + cc) * N + n0 + tx);
  }
  __syncthreads();
  const float m = meanv[tgt * C + c0 + tx];
  const float r = invs[tgt * C + c0 + tx];
#pragma unroll
  for (int it = 0; it < 16; ++it){
    const int p = it * 4 + ty;
    const float v = tile[tx][p];
    const float cen = v - m;
    const long o = (long)z * NC + (long)(n0 + p) * C + c0 + tx;
    adH[o] = (__bf16)(cen * r);
    splitw(cen, fcH, fcL, (long)tgt * NC + (long)(n0 + p) * C + c0 + tx);
    if (rwH) rwH[o] = (__bf16)v;
  }
}

__global__ __launch_bounds__(256) void k_wcvtall(const float* __restrict__ KsTf, const float* __restrict__ K2tf,
                                                 const float* __restrict__ h_w, const float* __restrict__ ow,
                                                 __bf16* __restrict__ KsTH, __bf16* __restrict__ KsTL,
                                                 __bf16* __restrict__ K2tH, __bf16* __restrict__ hwH,
                                                 __bf16* __restrict__ owH){
  const int zz = blockIdx.y;
  const int i = blockIdx.x * 256 + threadIdx.x;
  if (zz == 0){ splitw(KsTf[i], KsTH, KsTL, i); }
  else if (zz == 1){ K2tH[i] = (__bf16)K2tf[i]; }
  else if (zz == 2){ hwH[i] = (__bf16)h_w[i]; }
  else { owH[i] = (__bf16)ow[i]; }
}

// ======================= power iteration / NS init (2eps*I folded in) =======================
__global__ __launch_bounds__(256) void k_powit(const float* __restrict__ cov,
                                               float* __restrict__ invt, float* __restrict__ invsqt){
  __shared__ float v[C], red[4];
  const int z = blockIdx.x, t = threadIdx.x;
  const float* A = cov + (long)z * CC;
  const int j0 = t, j1 = t + 256;
  v[j0] = 1.f + 0.0003f * (float)j0;
  v[j1] = 1.f + 0.0003f * (float)j1;
  __syncthreads();
  float lam = 1.f;
  for (int it = 0; it < 4; ++it){
    float w0a = 0.f, w0b = 0.f, w1a = 0.f, w1b = 0.f;
#pragma unroll 8
    for (int c = 0; c < C; c += 2){
      const float vc0 = v[c], vc1 = v[c + 1];
      w0a = fmaf(A[(long)c * C + j0], vc0, w0a);
      w1a = fmaf(A[(long)c * C + j1], vc0, w1a);
      w0b = fmaf(A[(long)(c + 1) * C + j0], vc1, w0b);
      w1b = fmaf(A[(long)(c + 1) * C + j1], vc1, w1b);
    }
    const float w0 = w0a + w0b + 2.f * EPSC * v[j0];
    const float w1 = w1a + w1b + 2.f * EPSC * v[j1];
    float s = w0 * w0 + w1 * w1;
    s = wredSum(s);
    if ((t & 63) == 0) red[t >> 6] = s;
    __syncthreads();
    const float nrm = sqrtf(red[0] + red[1] + red[2] + red[3]);
    lam = nrm;
    const float inv = 1.f / nrm;
    v[j0] = w0 * inv;
    v[j1] = w1 * inv;
    __syncthreads();
  }
  if (t == 0){
    const float tt = 1.02f * lam;
    invt[z] = 1.f / tt;
    invsqt[z] = rsqrtf(tt);
  }
}

__global__ __launch_bounds__(256) void k_ns_init(const float* __restrict__ cov, const float* __restrict__ invt,
                                                 __bf16* __restrict__ h, __bf16* __restrict__ l,
                                                 __bf16* __restrict__ cph, __bf16* __restrict__ cpl){
  const int r = blockIdx.x, z = blockIdx.y;
  const long base = (long)z * CC + (long)r * C;
  const float it = invt[z];
  for (int i = threadIdx.x; i < C; i += 256){
    const float cv = cov[base + i] + ((i == r) ? 2.f * EPSC : 0.f);
    const float v = cv * it;
    splitw(v, h, l, base + i);
    splitw(v, cph, cpl, base + i);
    h[4 * CC + base + i] = (__bf16)((i == r) ? 1.f : 0.f);
    l[4 * CC + base + i] = (__bf16)0.f;
  }
}

// ======================= self-path col accumulation (fp16 E), row-stat merge fused =======================
__global__ __launch_bounds__(256) void k_colaccum(const _Float16* __restrict__ E,
                                                  const float* __restrict__ Pm, const float* __restrict__ Ps,
                                                  float* __restrict__ partials){
  __shared__ float srm[32], srs[32];
  const int rb = blockIdx.y;
  const int r0 = rb * 32;
  const int tid = threadIdx.x;
  {
    const int row = r0 + (tid >> 3);
    const int pp = tid & 7;
    float m = -3.4e38f, s = 0.f;
#pragma unroll
    for (int p = pp * 4; p < pp * 4 + 4; ++p){
      const float mp = Pm[(long)p * N + row];
      const float sp = Ps[(long)p * N + row];
      const float nm = fmaxf(m, mp);
      s = s * __expf(m - nm) + sp * __expf(mp - nm);
      m = nm;
    }
#pragma unroll
    for (int o = 1; o <= 4; o <<= 1){
      const float mo = __shfl_xor(m, o, 64);
      const float so = __shfl_xor(s, o, 64);
      const float nm = fmaxf(m, mo);
      s = s * __expf(m - nm) + so * __expf(mo - nm);
      m = nm;
    }
    if (pp == 0){ srm[tid >> 3] = m; srs[tid >> 3] = 1.f / s; }
  }
  __syncthreads();
  const int j = (blockIdx.x * 256 + tid) * 8;
  float a[8] = {0.f, 0.f, 0.f, 0.f, 0.f, 0.f, 0.f, 0.f};
#pragma unroll 4
  for (int r2 = 0; r2 < 32; ++r2){
    const f16x8 e = *reinterpret_cast<const f16x8*>(E + (long)(r0 + r2) * N + j);
    const float rmv = srm[r2], rsv = srs[r2];
#pragma unroll
    for (int k = 0; k < 8; ++k)
      a[k] += __expf((float)e[k] - rmv) * rsv;
  }
  float4 o0 = {a[0], a[1], a[2], a[3]};
  float4 o1 = {a[4], a[5], a[6], a[7]};
  *reinterpret_cast<float4*>(partials + (long)rb * N + j) = o0;
  *reinterpret_cast<float4*>(partials + (long)rb * N + j + 4) = o1;
}

__global__ __launch_bounds__(256) void k_colreduce(const float* __restrict__ partials, float* __restrict__ att){
  const int j = blockIdx.x * 256 + threadIdx.x;
  float s = 0.f;
#pragma unroll 8
  for (int p = 0; p < 128; ++p) s += partials[(long)p * N + j];
  att[j] = s * (1.f / (float)N);
}

// ======================= mask (radix select), all 4 selections in one launch =======================
__global__ __launch_bounds__(256) void k_radix(const float* __restrict__ a, float* __restrict__ thr){
  __shared__ unsigned int vals[N];
  __shared__ float shc[4];
  __shared__ unsigned int p_sh;
  __shared__ int k_sh;
  const float* pa = a + (long)blockIdx.x * N;
  const int tid = threadIdx.x;
  for (int i = tid; i < N; i += 256) vals[i] = __float_as_uint(pa[i]);
  if (tid == 0){ p_sh = 0u; k_sh = KSEL; }
  __syncthreads();
  for (int b = 31; b >= 0; --b){
    const unsigned int bit = 1u << b;
    const unsigned int above = (b == 31) ? 0u : ~((bit << 1) - 1u);
    const unsigned int p = p_sh;
    int cnt = 0;
    for (int i = tid; i < N; i += 256){
      unsigned int v = vals[i];
      if ((v & above) == p && (v & bit)) cnt++;
    }
    float cf = wredSum((float)cnt);
    if ((tid & 63) == 0) shc[tid >> 6] = cf;
    __syncthreads();
    if (tid == 0){
      int c1 = (int)(shc[0] + shc[1] + shc[2] + shc[3] + 0.5f);
      if (k_sh <= c1) p_sh = p | bit;
      else k_sh -= c1;
    }
    __syncthreads();
  }
  if (tid == 0) thr[blockIdx.x] = __uint_as_float(p_sh);
}

__global__ __launch_bounds__(256) void k_mask(const float* __restrict__ ax, const float* __restrict__ ay,
                                              const float* __restrict__ thr, float* __restrict__ mx,
                                              float* __restrict__ my){
  int j = blockIdx.x * 256 + threadIdx.x;
  mx[j] = (ax[j] >= thr[0] && ax[N + j] >= thr[1]) ? 1.f : 0.f;
  my[j] = (ay[j] >= thr[2] && ay[N + j] >= thr[3]) ? 1.f : 0.f;
}

// ======================= host =======================
extern "C" void kernel_launch(void* const* d_in, const int* in_sizes, int n_in,
                              void* d_out, int out_size, void* d_ws, size_t ws_size,
                              hipStream_t stream)
{
  const float* x     = (const float*)d_in[0];
  const float* y     = (const float*)d_in[1];
  const float* f_w   = (const float*)d_in[2];
  const float* f_b   = (const float*)d_in[3];
  const float* g_w   = (const float*)d_in[4];
  const float* g_b   = (const float*)d_in[5];
  const float* saf_w = (const float*)d_in[6];
  const float* saf_b = (const float*)d_in[7];
  const float* sag_w = (const float*)d_in[8];
  const float* sag_b = (const float*)d_in[9];
  const float* h_w   = (const float*)d_in[10];
  const float* h_b   = (const float*)d_in[11];
  const float* ow    = (const float*)d_in[12];
  const float* ob    = (const float*)d_in[13];

  const size_t MBy = 1ull << 20;
  const size_t KBy = 1ull << 10;
  char* base = (char*)d_ws;
  if (ws_size < 206 * MBy) return;
  auto F  = [&](size_t off){ return (float*)(base + off); };
  auto Bp = [&](size_t off){ return (__bf16*)(base + off); };

  __bf16 *Ebf = Bp(0);                               // main: [2][N][N] bf16 ; self: [N][N] fp16 via cast
  _Float16 *E16 = (_Float16*)base;
  __bf16 *ccH = Bp(0), *ccL = Bp(16*MBy);
  float  *covb = F(32*MBy);
  __bf16 *zpolH = Bp(36*MBy), *zpolL = Bp(38*MBy);
  __bf16 *covPH = Bp(40*MBy), *covPL = Bp(42*MBy);
  float  *KsTf = F(44*MBy), *K2tf = F(45*MBy);
  __bf16 *KsTH = Bp(46*MBy), *KsTL = Bp(46*MBy + 512*KBy);
  __bf16 *K2tH = Bp(47*MBy), *hwH = Bp(47*MBy + 512*KBy);
  __bf16 *tpH = Bp(48*MBy), *tpL = Bp(50*MBy);
  __bf16 *xaH = Bp(64*MBy);
  __bf16 *xzH = Bp(64*MBy), *xzL = Bp(80*MBy);
  __bf16 *ypmH = Bp(96*MBy);
  __bf16 *AsH = Bp(96*MBy), *AsL = Bp(112*MBy);
  __bf16 *fcH = Bp(128*MBy), *fcL = Bp(144*MBy);
  __bf16 *resH = Bp(128*MBy);
  __bf16 *nsAh = Bp(160*MBy), *nsAl = Bp(164*MBy);
  __bf16 *nsBh = Bp(168*MBy), *nsBl = Bp(172*MBy);
  __bf16 *A2H = Bp(176*MBy);
  __bf16 *yaH = Bp(184*MBy);
  __bf16 *hH  = Bp(192*MBy);
  __bf16 *owH = Bp(200*MBy);
  size_t so = 200 * MBy + 512 * KBy;
  auto SF = [&](size_t bytes){ float* p = F(so); so += bytes; return p; };
  float *meanv = SF(8*KBy), *invs = SF(8*KBy);
  float *mxv = SF(16*KBy), *myv = SF(16*KBy);
  float *rvec2 = SF(32*KBy), *cvec2 = SF(32*KBy);
  float *rvS = SF(64*KBy), *cvS = SF(64*KBy);
  float *u1m = SF(2*KBy), *u2m = SF(2*KBy), *u1s = SF(2*KBy), *u2s = SF(2*KBy);
  float *c0m2 = SF(64), *c0s4 = SF(64), *thr = SF(64);
  float *invt = SF(64), *invsqt = SF(64);
  float *partials = F(201*MBy);                      // [128][N]
  float *Pm = F(203*MBy);                            // [64][N]
  float *Ps = F(204*MBy);                            // [64][N]
  float *Pq = F(205*MBy);                            // [64][N]

  float* outm = (float*)d_out;
  float* attx = outm + B2 * CN;
  float* atty = attx + (long)B2 * N;

  // 1) stats + prep
  k_stats<<<dim3(4 * C), dim3(256), 0, stream>>>(x, y, meanv, invs);
  k_prep<<<dim3(64, 8, 2), dim3(256), 0, stream>>>(x, meanv, invs, 0, xaH, fcH, fcL, ccH, ccL, nullptr);
  k_prep<<<dim3(64, 8, 2), dim3(256), 0, stream>>>(y, meanv, invs, 2, yaH, fcH, fcL, ccH, ccL, ypmH);

  // 2) weight products & conversions (merged launches)
  k_wtw<<<dim3(16, 16), dim3(256), 0, stream>>>(sag_w, saf_w, KsTf, 1.f);
  k_wtw<<<dim3(16, 16), dim3(256), 0, stream>>>(g_w, f_w, K2tf, 1.f);
  k_wcvtall<<<dim3((int)(CC / 256), 4), dim3(256), 0, stream>>>(KsTf, K2tf, h_w, ow,
      KsTH, KsTL, K2tH, hwH, owH);
  k_wtv4<<<dim3(2, 4), dim3(256), 0, stream>>>(g_w, f_b, f_w, g_b, sag_w, saf_b, saf_w, sag_b,
      u1m, u2m, u1s, u2s);
  k_dot2<<<dim3(1), dim3(256), 0, stream>>>(f_b, g_b, saf_b, sag_b, c0m2, c0s4);
  k_pixvecm<<<dim3(N / 4, 4), dim3(256), 0, stream>>>(xaH, yaH, u2m, u1m, rvec2, cvec2);

  // 3) cov (2eps*I folded downstream) + power-iteration lambda_max
  k_mm64<0,0,0><<<dim3(8, 8, 4), dim3(256), 0, stream>>>(
      ccH, ccL, ccH, ccL, nullptr, nullptr, covb, nullptr, nullptr, C, N, CN, CN, CC, 1.f / (float)(N - 1));
  k_powit<<<dim3(4), dim3(256), 0, stream>>>(covb, invt, invsqt);

  // 4) A2 = xa . K2^T, h conv
  k_mm<1,0,2,0><<<dim3(32, 4, 2), dim3(256), 0, stream>>>(xaH, nullptr, K2tH, nullptr, nullptr, A2H, nullptr,
      C, C, NC, 0, NC, 1.f, nullptr, nullptr, 0, nullptr, 0, nullptr, nullptr, 0,
      nullptr, nullptr, nullptr, nullptr, nullptr);
  k_mm<1,0,2,0><<<dim3(4, 32, 2), dim3(256), 0, stream>>>(hwH, nullptr, ypmH, nullptr, nullptr, hH, nullptr,
      N, C, 0, NC, CN, 1.f, nullptr, h_b, 0, nullptr, 0, nullptr, nullptr, 0,
      nullptr, nullptr, nullptr, nullptr, nullptr);

  // 5) Newton-Schulz (4 iters; last iter Z-only) + split-bf16 polish
  k_ns_init<<<dim3(C, 4), dim3(256), 0, stream>>>(covb, invt, nsAh, nsAl, covPH, covPL);
  __bf16 *cah = nsAh, *cal = nsAl, *cbh = nsBh, *cbl = nsBl;
  for (int it = 0; it < NS_ITERS; ++it){
    k_mm64<1,1,0><<<dim3(8, 8, 4), dim3(256), 0, stream>>>(
        cah + 4*CC, cal + 4*CC, cah, cal, nullptr, nullptr, nullptr, tpH, tpL, C, C, CC, CC, CC, 1.f);
    if (it < NS_ITERS - 1){
      k_mm64<0,1,1><<<dim3(8, 8, 8), dim3(256), 0, stream>>>(
          cah, cal, nullptr, nullptr, tpH, tpL, nullptr, cbh, cbl, C, C, CC, CC, CC, 1.f);
    } else {
      k_mm64<0,1,2><<<dim3(8, 8, 4), dim3(256), 0, stream>>>(
          cah, cal, nullptr, nullptr, tpH, tpL, nullptr, cbh, cbl, C, C, CC, CC, CC, 1.f);
    }
    __bf16* t;
    t = cah; cah = cbh; cbh = t;
    t = cal; cal = cbl; cbl = t;
  }
  k_mm64<0,1,0><<<dim3(8, 8, 4), dim3(256), 0, stream>>>(
      cah + 4*CC, cal + 4*CC, cah + 4*CC, cal + 4*CC, nullptr, nullptr, nullptr, tpH, tpL, C, C, CC, CC, CC, 1.f);
  k_mm64<1,1,0><<<dim3(8, 8, 4), dim3(256), 0, stream>>>(
      covPH, covPL, tpH, tpL, nullptr, nullptr, nullptr, cbh, cbl, C, C, CC, CC, CC, 1.f);
  k_mm64<0,1,0><<<dim3(8, 8, 4), dim3(256), 0, stream>>>(
      cah + 4*CC, cal + 4*CC, cbh, cbl, nullptr, nullptr, nullptr, zpolH, zpolL, C, C, CC, CC, CC, 1.f);

  // 6) zca apply: xz = invsqt * fc . Z
  k_mm<3,0,1,0><<<dim3(32, 4, 4), dim3(256), 0, stream>>>(fcH, fcL, zpolH, zpolL, nullptr, xzH, xzL,
      C, C, NC, CC, NC, 1.f, invsqt, nullptr, 0, nullptr, 0, nullptr, nullptr, 0,
      nullptr, nullptr, nullptr, nullptr, nullptr);

  // 6.5) self bias vecs (one pass) + As = xz . Ks^T
  k_pixvec2<<<dim3(N / 4, 4), dim3(256), 0, stream>>>(xzH, u2s, u1s, rvS, cvS);
  k_mm<3,0,1,0><<<dim3(32, 4, 4), dim3(256), 0, stream>>>(xzH, xzL, KsTH, KsTL, nullptr, AsH, AsL,
      C, C, NC, 0, NC, 1.f, nullptr, nullptr, 0, nullptr, 0, nullptr, nullptr, 0,
      nullptr, nullptr, nullptr, nullptr, nullptr);

  // 7) self-attention energies (3-pass, fp16 E storage, fused row-stats on dequantized values)
  for (int z = 0; z < 4; ++z){
    k_mm<3,0,4,1><<<dim3(32, 32, 1), dim3(256), 0, stream>>>(AsH + (long)z*NC, AsL + (long)z*NC,
        xzH + (long)z*NC, xzL + (long)z*NC, nullptr, Ebf, nullptr,
        N, C, 0, 0, 0, 1.f, nullptr, rvS + (long)z*N, 0, cvS + (long)z*N, 0, c0s4, nullptr, 0,
        Pm, Ps, nullptr, nullptr, nullptr);
    k_colaccum<<<dim3(2, 128), dim3(256), 0, stream>>>(E16, Pm, Ps, partials);
    k_colreduce<<<dim3(16), dim3(256), 0, stream>>>(partials, (z < 2 ? attx : atty) + (long)(z & 1) * N);
  }

  // 8) masks (single radix launch over the 4 contiguous atten arrays)
  k_radix<<<dim3(4), dim3(256), 0, stream>>>(attx, thr);
  k_mask<<<dim3(16), dim3(256), 0, stream>>>(attx, atty, thr, mxv, myv);

  // 9) main path: energy -> bf16 E with fused masked row-stats; PV (merges stats in-kernel); out conv
  k_mm<1,0,2,2><<<dim3(32, 32, 2), dim3(256), 0, stream>>>(A2H, nullptr, yaH, nullptr, nullptr, Ebf, nullptr,
      N, C, NC, NC, NN, 1.f, nullptr, rvec2, N, cvec2, N, c0m2, nullptr, 0,
      Pm, Ps, Pq, mxv, myv);
  k_pv<<<dim3(64, 4, 2), dim3(256), 0, stream>>>(Ebf, hH, Pm, Ps, Pq, mxv, myv, resH);
  k_mm<1,0,0,0><<<dim3(4, 32, 2), dim3(256), 0, stream>>>(owH, nullptr, resH, nullptr, outm, nullptr, nullptr,
      N, C, 0, NC, CN, 1.f, nullptr, ob, 0, nullptr, 0, nullptr, x, CN,
      nullptr, nullptr, nullptr, nullptr, nullptr);
}

// Round 17
// 1078.452 us; speedup vs baseline: 1.3170x; 1.0640x over previous
//
#include <hip/hip_runtime.h>
#include <cstdint>

static constexpr int B2 = 2;
static constexpr int C = 512;
static constexpr int N = 4096;
static constexpr long CN = (long)C * N;
static constexpr long NC = (long)N * C;
static constexpr long CC = (long)C * C;
static constexpr long NN = (long)N * N;
static constexpr float EPSC = 1e-5f;
static constexpr int KSEL = 308;       // N - int(N*0.925)
static constexpr int NS_ITERS = 4;

typedef __attribute__((ext_vector_type(8))) __bf16 bf16x8;
typedef __attribute__((ext_vector_type(8))) _Float16 f16x8;
typedef __attribute__((ext_vector_type(4))) float f32x4;

__device__ __forceinline__ float wredSum(float v){
#pragma unroll
  for (int o = 32; o >= 1; o >>= 1) v += __shfl_xor(v, o, 64);
  return v;
}

__device__ __forceinline__ void gld16(const __bf16* g, __bf16* l){
  __builtin_amdgcn_global_load_lds(
      (const __attribute__((address_space(1))) void*)g,
      (__attribute__((address_space(3))) void*)l, 16, 0, 0);
}

__device__ __forceinline__ void splitw(float v, __bf16* ph, __bf16* pl, long o){
  __bf16 h = (__bf16)v;
  ph[o] = h;
  pl[o] = (__bf16)(v - (float)h);
}

// ======================= split/plain bf16 MFMA GEMM, 128x128 tile, BK=32 =======================
// XCD swizzle. ROWP: 0 none | 1 row softmax partials | 2 masked (mxp/myp, writes Pq)
// OUTMODE: 0 fp32 | 1 bf16 pair | 2 bf16 high | 4 fp16 (Coh reinterpreted)
template<int PASSES, int TMH, int OUTMODE, int ROWP>
__global__ __launch_bounds__(256) void k_mm(
    const __bf16* __restrict__ Ah, const __bf16* __restrict__ Al,
    const __bf16* __restrict__ Bh, const __bf16* __restrict__ Bl,
    float* __restrict__ Cf, __bf16* __restrict__ Coh, __bf16* __restrict__ Col,
    int Nn, int K, long sAz, long sBz, long sCz,
    float alpha, const float* __restrict__ alpha_ptr,
    const float* __restrict__ brow, long sBr,
    const float* __restrict__ bcol, long sBc,
    const float* __restrict__ c0p,
    const float* __restrict__ addsrc, long sAddz,
    float* __restrict__ Pm, float* __restrict__ Ps, float* __restrict__ Pq,
    const float* __restrict__ mxp, const float* __restrict__ myp)
{
  constexpr int NB = (PASSES == 3) ? 4 : 2;
  constexpr int SB = (PASSES == 3) ? 2 : 1;
  __shared__ __align__(16) __bf16 sm[NB][128 * 32];
  __shared__ float pmx[2][128], psx[2][128], pqx[2][128];
  const int z = blockIdx.z;
  const int nwx = gridDim.x;
  int lin = blockIdx.y * nwx + blockIdx.x;
  const int nwg = nwx * gridDim.y;
  if ((nwg & 7) == 0){
    const int cpx = nwg >> 3;
    lin = (lin & 7) * cpx + (lin >> 3);
  }
  const int i0 = (lin % nwx) * 128;
  const int j0 = (lin / nwx) * 128;
  const int tid = threadIdx.x;
  const int lane = tid & 63;
  const int w = tid >> 6;
  const int wr = (w >> 1) * 64, wc = (w & 1) * 64;
  const int lr = lane & 15;
  const int g = lane >> 4;

  const __bf16* pAh = Ah + (long)z * sAz + (long)i0 * K;
  const __bf16* pBh = Bh + (long)z * sBz + (long)j0 * K;
  const __bf16* pAl = (PASSES == 3) ? (Al + (long)z * sAz + (long)i0 * K) : nullptr;
  const __bf16* pBl = (PASSES == 3) ? (Bl + (long)z * sBz + (long)j0 * K) : nullptr;

  f32x4 acc[4][4] = {};

  for (int kt = 0; kt < K; kt += 32){
#pragma unroll
    for (int p = 0; p < 2; ++p){
      const int t2 = p * 256 + tid;
      const int row = t2 >> 2;
      const int gs = (t2 & 3) ^ ((row >> 1) & 3);
      const long go = (long)row * K + kt + gs * 8;
      gld16(pAh + go, &sm[0][t2 * 8]);
      gld16(pBh + go, &sm[SB][t2 * 8]);
      if constexpr (PASSES == 3){
        gld16(pAl + go, &sm[1][t2 * 8]);
        gld16(pBl + go, &sm[3][t2 * 8]);
      }
    }
    __syncthreads();
    bf16x8 fa[4], fal[4], fb[4], fbl[4];
#pragma unroll
    for (int mi = 0; mi < 4; ++mi){
      const int row = wr + mi * 16 + lr;
      const int off = row * 32 + ((g ^ ((row >> 1) & 3)) * 8);
      fa[mi] = *(const bf16x8*)(&sm[0][off]);
      if constexpr (PASSES == 3) fal[mi] = *(const bf16x8*)(&sm[1][off]);
    }
#pragma unroll
    for (int ni = 0; ni < 4; ++ni){
      const int row = wc + ni * 16 + lr;
      const int off = row * 32 + ((g ^ ((row >> 1) & 3)) * 8);
      fb[ni] = *(const bf16x8*)(&sm[SB][off]);
      if constexpr (PASSES == 3) fbl[ni] = *(const bf16x8*)(&sm[3][off]);
    }
#pragma unroll
    for (int mi = 0; mi < 4; ++mi)
#pragma unroll
      for (int ni = 0; ni < 4; ++ni){
        acc[mi][ni] = __builtin_amdgcn_mfma_f32_16x16x32_bf16(fa[mi], fb[ni], acc[mi][ni], 0, 0, 0);
        if constexpr (PASSES == 3){
          acc[mi][ni] = __builtin_amdgcn_mfma_f32_16x16x32_bf16(fa[mi],  fbl[ni], acc[mi][ni], 0, 0, 0);
          acc[mi][ni] = __builtin_amdgcn_mfma_f32_16x16x32_bf16(fal[mi], fb[ni],  acc[mi][ni], 0, 0, 0);
        }
      }
    __syncthreads();
  }

  float al2 = alpha;
  if (alpha_ptr) al2 *= alpha_ptr[z];
  const float c0v = c0p ? c0p[z] : 0.f;
#pragma unroll
  for (int mi = 0; mi < 4; ++mi){
    float vv[4][4];
    float mrow[4] = {-3.4e38f, -3.4e38f, -3.4e38f, -3.4e38f};
#pragma unroll
    for (int ni = 0; ni < 4; ++ni){
      const int col = j0 + wc + ni * 16 + lr;
      const float bc = (bcol ? bcol[z * sBc + col] : 0.f) + c0v;
#pragma unroll
      for (int j = 0; j < 4; ++j){
        const int row = i0 + wr + mi * 16 + g * 4 + j;
        float v = acc[mi][ni][j] * al2;
        if (TMH) v = (((row == col) ? 3.f : 0.f) - v) * 0.5f;
        if (brow) v += brow[z * sBr + row];
        v += bc;
        if (addsrc) v += addsrc[(long)z * sAddz + (long)row * Nn + col];
        const long o = (long)z * sCz + (long)row * Nn + col;
        if (OUTMODE == 0){ Cf[o] = v; }
        else if (OUTMODE == 1){ __bf16 h = (__bf16)v; Coh[o] = h; Col[o] = (__bf16)(v - (float)h); }
        else if (OUTMODE == 2){ __bf16 h = (__bf16)v; Coh[o] = h; if (ROWP == 2) v = (float)h; }
        else { _Float16 hf = (_Float16)v; ((_Float16*)Coh)[o] = hf; if (ROWP >= 1) v = (float)hf; }
        if constexpr (ROWP >= 1){
          vv[ni][j] = v;
          mrow[j] = fmaxf(mrow[j], v);
        }
      }
    }
    if constexpr (ROWP >= 1){
#pragma unroll
      for (int j = 0; j < 4; ++j)
#pragma unroll
        for (int o = 1; o <= 8; o <<= 1)
          mrow[j] = fmaxf(mrow[j], __shfl_xor(mrow[j], o, 64));
      float tgt[4];
      if constexpr (ROWP == 2){
#pragma unroll
        for (int j = 0; j < 4; ++j)
          tgt[j] = mxp[i0 + wr + mi * 16 + g * 4 + j];
      }
      float srow[4] = {0.f, 0.f, 0.f, 0.f};
      float qrow[4] = {0.f, 0.f, 0.f, 0.f};
#pragma unroll
      for (int ni = 0; ni < 4; ++ni){
        const float mycol = (ROWP == 2) ? myp[j0 + wc + ni * 16 + lr] : 0.f;
#pragma unroll
        for (int j = 0; j < 4; ++j){
          const float ev = __expf(vv[ni][j] - mrow[j]);
          srow[j] += ev;
          if constexpr (ROWP == 2){
            if (mycol == tgt[j]) qrow[j] += ev;
          }
        }
      }
#pragma unroll
      for (int j = 0; j < 4; ++j){
#pragma unroll
        for (int o = 1; o <= 8; o <<= 1){
          srow[j] += __shfl_xor(srow[j], o, 64);
          if constexpr (ROWP == 2) qrow[j] += __shfl_xor(qrow[j], o, 64);
        }
        if (lr == 0){
          const int rl = wr + mi * 16 + g * 4 + j;
          pmx[w & 1][rl] = mrow[j];
          psx[w & 1][rl] = srow[j];
          if constexpr (ROWP == 2) pqx[w & 1][rl] = qrow[j];
        }
      }
    }
  }
  if constexpr (ROWP >= 1){
    __syncthreads();
    if (tid < 128){
      const float m0 = pmx[0][tid], s0 = psx[0][tid];
      const float m1 = pmx[1][tid], s1 = psx[1][tid];
      const float nm = fmaxf(m0, m1);
      const float c0_ = __expf(m0 - nm), c1_ = __expf(m1 - nm);
      const float s = s0 * c0_ + s1 * c1_;
      const long po = (long)(z * 32 + (j0 >> 7)) * N + i0 + tid;
      Pm[po] = nm;
      Ps[po] = s;
      if constexpr (ROWP == 2){
        Pq[po] = pqx[0][tid] * c0_ + pqx[1][tid] * c1_;
      }
    }
  }
}

// ======================= split-bf16 MFMA GEMM, 64x64 tile, BK=64 (always 3-pass) =======================
template<int TMH, int OUTMODE, int NSYZ>
__global__ __launch_bounds__(256) void k_mm64(
    const __bf16* __restrict__ Ah, const __bf16* __restrict__ Al,
    const __bf16* __restrict__ Bh, const __bf16* __restrict__ Bl,
    const __bf16* __restrict__ tH, const __bf16* __restrict__ tL,
    float* __restrict__ Cf, __bf16* __restrict__ Coh, __bf16* __restrict__ Col,
    int Nn, int K, long sAz, long sBz, long sCz, float alpha)
{
  __shared__ __align__(16) __bf16 sm[4][64 * 64];
  const int z = blockIdx.z;
  const __bf16 *bAh, *bAl, *bBh, *bBl;
  long oC;
  if constexpr (NSYZ == 1){
    if (z < 4){
      bAh = Ah + (long)z * CC; bAl = Al + (long)z * CC;
      bBh = tH + (long)z * CC; bBl = tL + (long)z * CC;
      oC = (long)z * CC;
    } else {
      const int zz = z - 4;
      bAh = tH + (long)zz * CC; bAl = tL + (long)zz * CC;
      bBh = Ah + (long)(4 + zz) * CC; bBl = Al + (long)(4 + zz) * CC;
      oC = (long)(4 + zz) * CC;
    }
  } else if constexpr (NSYZ == 2){
    bAh = tH + (long)z * CC; bAl = tL + (long)z * CC;
    bBh = Ah + (long)(4 + z) * CC; bBl = Al + (long)(4 + z) * CC;
    oC = (long)(4 + z) * CC;
  } else {
    bAh = Ah + (long)z * sAz; bAl = Al + (long)z * sAz;
    bBh = Bh + (long)z * sBz; bBl = Bl + (long)z * sBz;
    oC = (long)z * sCz;
  }
  const int i0 = blockIdx.x * 64;
  const int j0 = blockIdx.y * 64;
  const int tid = threadIdx.x;
  const int lane = tid & 63;
  const int w = tid >> 6;
  const int wr = (w >> 1) * 32, wc = (w & 1) * 32;
  const int lr = lane & 15;
  const int g = lane >> 4;

  const __bf16* pAh = bAh + (long)i0 * K;
  const __bf16* pAl = bAl + (long)i0 * K;
  const __bf16* pBh = bBh + (long)j0 * K;
  const __bf16* pBl = bBl + (long)j0 * K;

  f32x4 acc[2][2] = {};

  for (int kt = 0; kt < K; kt += 64){
#pragma unroll
    for (int p = 0; p < 2; ++p){
      const int t2 = p * 256 + tid;
      const int row = t2 >> 3;
      const int gs = (t2 & 7) ^ (row & 7);
      const long go = (long)row * K + kt + gs * 8;
      gld16(pAh + go, &sm[0][t2 * 8]);
      gld16(pAl + go, &sm[1][t2 * 8]);
      gld16(pBh + go, &sm[2][t2 * 8]);
      gld16(pBl + go, &sm[3][t2 * 8]);
    }
    __syncthreads();
#pragma unroll
    for (int ks = 0; ks < 2; ++ks){
      bf16x8 fa[2], fal[2], fb[2], fbl[2];
#pragma unroll
      for (int mi = 0; mi < 2; ++mi){
        const int row = wr + mi * 16 + lr;
        const int off = row * 64 + (((ks * 4 + g) ^ (row & 7)) * 8);
        fa[mi]  = *(const bf16x8*)(&sm[0][off]);
        fal[mi] = *(const bf16x8*)(&sm[1][off]);
      }
#pragma unroll
      for (int ni = 0; ni < 2; ++ni){
        const int row = wc + ni * 16 + lr;
        const int off = row * 64 + (((ks * 4 + g) ^ (row & 7)) * 8);
        fb[ni]  = *(const bf16x8*)(&sm[2][off]);
        fbl[ni] = *(const bf16x8*)(&sm[3][off]);
      }
#pragma unroll
      for (int mi = 0; mi < 2; ++mi)
#pragma unroll
        for (int ni = 0; ni < 2; ++ni){
          acc[mi][ni] = __builtin_amdgcn_mfma_f32_16x16x32_bf16(fa[mi],  fb[ni],  acc[mi][ni], 0, 0, 0);
          acc[mi][ni] = __builtin_amdgcn_mfma_f32_16x16x32_bf16(fa[mi],  fbl[ni], acc[mi][ni], 0, 0, 0);
          acc[mi][ni] = __builtin_amdgcn_mfma_f32_16x16x32_bf16(fal[mi], fb[ni],  acc[mi][ni], 0, 0, 0);
        }
    }
    __syncthreads();
  }

#pragma unroll
  for (int mi = 0; mi < 2; ++mi){
#pragma unroll
    for (int ni = 0; ni < 2; ++ni){
      const int col = j0 + wc + ni * 16 + lr;
#pragma unroll
      for (int j = 0; j < 4; ++j){
        const int row = i0 + wr + mi * 16 + g * 4 + j;
        float v = acc[mi][ni][j] * alpha;
        if (TMH) v = (((row == col) ? 3.f : 0.f) - v) * 0.5f;
        const long o = oC + (long)row * Nn + col;
        if (OUTMODE == 0){ Cf[o] = v; }
        else { __bf16 h = (__bf16)v; Coh[o] = h; Col[o] = (__bf16)(v - (float)h); }
      }
    }
  }
}

// ======================= fused corr+PV (bf16 E), K-step 64, row-stat merge fused =======================
__global__ __launch_bounds__(256) void k_pv(
    const __bf16* __restrict__ E, const __bf16* __restrict__ Bh,
    const float* __restrict__ Pm, const float* __restrict__ Ps, const float* __restrict__ Pq,
    const float* __restrict__ mxv, const float* __restrict__ myv,
    __bf16* __restrict__ resH)
{
  __shared__ __align__(16) __bf16 sa[64 * 64];
  __shared__ __align__(16) __bf16 sb[128 * 64];
  __shared__ float srm[64], srs[64];
  const int z = blockIdx.z;
  int lin = blockIdx.y * 64 + blockIdx.x;
  lin = (lin & 7) * 32 + (lin >> 3);
  const int n0 = (lin & 63) * 64;
  const int c0 = (lin >> 6) * 128;
  const int tid = threadIdx.x;
  const int lane = tid & 63;
  const int w = tid >> 6;
  const int wr = (w >> 1) * 32, wc = (w & 1) * 64;
  const int lr = lane & 15, g = lane >> 4;

  {
    const int row = n0 + (tid >> 2);
    const int pp = tid & 3;
    float m = -3.4e38f, s = 0.f, q = 0.f;
#pragma unroll
    for (int p = pp * 8; p < pp * 8 + 8; ++p){
      const long idx = (long)(z * 32 + p) * N + row;
      const float mp = Pm[idx], sp = Ps[idx], qp = Pq[idx];
      const float nm = fmaxf(m, mp);
      const float c0_ = __expf(m - nm), c1_ = __expf(mp - nm);
      s = s * c0_ + sp * c1_;
      q = q * c0_ + qp * c1_;
      m = nm;
    }
#pragma unroll
    for (int o = 1; o <= 2; o <<= 1){
      const float mo = __shfl_xor(m, o, 64);
      const float so = __shfl_xor(s, o, 64);
      const float qo = __shfl_xor(q, o, 64);
      const float nm = fmaxf(m, mo);
      const float c0_ = __expf(m - nm), c1_ = __expf(mo - nm);
      s = s * c0_ + so * c1_;
      q = q * c0_ + qo * c1_;
      m = nm;
    }
    if (pp == 0){
      float l1 = q / s;
      if (l1 < 1e-12f) l1 = 1e-12f;
      srm[tid >> 2] = m;
      srs[tid >> 2] = 1.f / (s * l1);
    }
  }
  __syncthreads();

  const __bf16* pe = E + (long)z * NN + (long)n0 * N;
  const __bf16* pB = Bh + (long)z * CN + (long)c0 * N;

  const int ar = tid >> 2;
  const int slot = tid & 3;
  const float rmv = srm[ar];
  const float rsv = srs[ar];
  const float tgt = mxv[n0 + ar];
  const __bf16* per = pe + (long)ar * N;

  f32x4 acc[2][4] = {};

  for (int kt = 0; kt < N; kt += 64){
#pragma unroll
    for (int d = 0; d < 2; ++d){
      const int gd = slot * 2 + d;
      const bf16x8 ev = *(const bf16x8*)(per + kt + gd * 8);
      const float4 m0 = *(const float4*)(myv + kt + gd * 8);
      const float4 m1 = *(const float4*)(myv + kt + gd * 8 + 4);
      bf16x8 pk;
      pk[0] = (__bf16)((m0.x == tgt) ? __expf((float)ev[0] - rmv) * rsv : 0.f);
      pk[1] = (__bf16)((m0.y == tgt) ? __expf((float)ev[1] - rmv) * rsv : 0.f);
      pk[2] = (__bf16)((m0.z == tgt) ? __expf((float)ev[2] - rmv) * rsv : 0.f);
      pk[3] = (__bf16)((m0.w == tgt) ? __expf((float)ev[3] - rmv) * rsv : 0.f);
      pk[4] = (__bf16)((m1.x == tgt) ? __expf((float)ev[4] - rmv) * rsv : 0.f);
      pk[5] = (__bf16)((m1.y == tgt) ? __expf((float)ev[5] - rmv) * rsv : 0.f);
      pk[6] = (__bf16)((m1.z == tgt) ? __expf((float)ev[6] - rmv) * rsv : 0.f);
      pk[7] = (__bf16)((m1.w == tgt) ? __expf((float)ev[7] - rmv) * rsv : 0.f);
      *(bf16x8*)(&sa[ar * 64 + ((gd ^ (ar & 7)) * 8)]) = pk;
    }
#pragma unroll
    for (int p = 0; p < 4; ++p){
      const int t2 = p * 256 + tid;
      const int row = t2 >> 3;
      const int gs = (t2 & 7) ^ (row & 7);
      gld16(pB + (long)row * N + kt + gs * 8, &sb[t2 * 8]);
    }
    __syncthreads();
#pragma unroll
    for (int ks = 0; ks < 2; ++ks){
      bf16x8 fa[2], fb[4];
#pragma unroll
      for (int mi = 0; mi < 2; ++mi){
        const int row = wr + mi * 16 + lr;
        fa[mi] = *(const bf16x8*)(&sa[row * 64 + (((ks * 4 + g) ^ (row & 7)) * 8)]);
      }
#pragma unroll
      for (int ni = 0; ni < 4; ++ni){
        const int row = wc + ni * 16 + lr;
        fb[ni] = *(const bf16x8*)(&sb[row * 64 + (((ks * 4 + g) ^ (row & 7)) * 8)]);
      }
#pragma unroll
      for (int mi = 0; mi < 2; ++mi)
#pragma unroll
        for (int ni = 0; ni < 4; ++ni)
          acc[mi][ni] = __builtin_amdgcn_mfma_f32_16x16x32_bf16(fa[mi], fb[ni], acc[mi][ni], 0, 0, 0);
    }
    __syncthreads();
  }
#pragma unroll
  for (int mi = 0; mi < 2; ++mi)
#pragma unroll
    for (int ni = 0; ni < 4; ++ni){
      const int c = c0 + wc + ni * 16 + lr;
#pragma unroll
      for (int j = 0; j < 4; ++j){
        const int n = n0 + wr + mi * 16 + g * 4 + j;
        resH[(long)z * NC + (long)n * C + c] = (__bf16)acc[mi][ni][j];
      }
    }
}

// ======================= small helpers =======================
// both weight-product GEMMs in one launch: z=0 -> KsT, z=1 -> K2t
__global__ __launch_bounds__(256) void k_wtw2(
    const float* __restrict__ sag_w, const float* __restrict__ saf_w,
    const float* __restrict__ g_w, const float* __restrict__ f_w,
    float* __restrict__ KsTf, float* __restrict__ K2tf)
{
  __shared__ float sa[16][32], sb[16][32];
  const int zz = blockIdx.z;
  const float* A = (zz == 0) ? sag_w : g_w;
  const float* B = (zz == 0) ? saf_w : f_w;
  float* C2 = (zz == 0) ? KsTf : K2tf;
  const int i0 = blockIdx.x * 32, j0 = blockIdx.y * 32;
  const int t = threadIdx.x;
  const int ti = t & 15, tj = t >> 4;
  const int li = t & 31, lc = t >> 5;
  float acc[2][2] = {};
  for (int cb = 0; cb < C; cb += 16){
    sa[lc][li]     = A[(long)(cb + lc) * C + i0 + li];
    sa[lc + 8][li] = A[(long)(cb + lc + 8) * C + i0 + li];
    sb[lc][li]     = B[(long)(cb + lc) * C + j0 + li];
    sb[lc + 8][li] = B[(long)(cb + lc + 8) * C + j0 + li];
    __syncthreads();
#pragma unroll
    for (int c = 0; c < 16; ++c){
      const float a0 = sa[c][ti * 2], a1 = sa[c][ti * 2 + 1];
      const float b0 = sb[c][tj * 2], b1 = sb[c][tj * 2 + 1];
      acc[0][0] = fmaf(a0, b0, acc[0][0]); acc[0][1] = fmaf(a0, b1, acc[0][1]);
      acc[1][0] = fmaf(a1, b0, acc[1][0]); acc[1][1] = fmaf(a1, b1, acc[1][1]);
    }
    __syncthreads();
  }
#pragma unroll
  for (int r = 0; r < 2; ++r)
#pragma unroll
    for (int s = 0; s < 2; ++s)
      C2[(long)(i0 + ti * 2 + r) * C + j0 + tj * 2 + s] = acc[r][s];
}

__global__ __launch_bounds__(256) void k_wtv4(
    const float* __restrict__ g_w, const float* __restrict__ f_b,
    const float* __restrict__ f_w, const float* __restrict__ g_b,
    const float* __restrict__ sag_w, const float* __restrict__ saf_b,
    const float* __restrict__ saf_w, const float* __restrict__ sag_b,
    float* __restrict__ u1m, float* __restrict__ u2m,
    float* __restrict__ u1s, float* __restrict__ u2s)
{
  const int zz = blockIdx.y;
  const float* W; const float* b; float* u;
  if (zz == 0){ W = g_w; b = f_b; u = u1m; }
  else if (zz == 1){ W = f_w; b = g_b; u = u2m; }
  else if (zz == 2){ W = sag_w; b = saf_b; u = u1s; }
  else { W = saf_w; b = sag_b; u = u2s; }
  __shared__ float sb2[C];
  const int t = threadIdx.x;
  sb2[t] = b[t]; sb2[t + 256] = b[t + 256];
  __syncthreads();
  const int e = blockIdx.x * 256 + t;
  float acc = 0.f;
  for (int c = 0; c < C; ++c) acc = fmaf(W[(long)c * C + e], sb2[c], acc);
  u[e] = acc;
}

__global__ void k_dot2(const float* __restrict__ a1, const float* __restrict__ b1,
                       const float* __restrict__ a2, const float* __restrict__ b2,
                       float* __restrict__ c0m2, float* __restrict__ c0s4){
  const int t = threadIdx.x;
  float s1 = 0.f, s2 = 0.f;
  for (int i = t; i < C; i += 256){ s1 += a1[i] * b1[i]; s2 += a2[i] * b2[i]; }
  __shared__ float sh1[4], sh2[4];
  s1 = wredSum(s1); s2 = wredSum(s2);
  if ((t & 63) == 0){ sh1[t >> 6] = s1; sh2[t >> 6] = s2; }
  __syncthreads();
  if (t == 0){
    float d1 = sh1[0] + sh1[1] + sh1[2] + sh1[3];
    float d2 = sh2[0] + sh2[1] + sh2[2] + sh2[3];
    c0m2[0] = d1; c0m2[1] = d1;
    c0s4[0] = d2; c0s4[1] = d2; c0s4[2] = d2; c0s4[3] = d2;
  }
}

__global__ __launch_bounds__(256) void k_pixvecm(const __bf16* __restrict__ xa, const __bf16* __restrict__ ya,
                                                 const float* __restrict__ u2m_, const float* __restrict__ u1m_,
                                                 float* __restrict__ rvec2, float* __restrict__ cvec2){
  const int zz = blockIdx.y;
  const __bf16* X = (zz < 2) ? xa + (long)zz * NC : ya + (long)(zz - 2) * NC;
  const float* u = (zz < 2) ? u2m_ : u1m_;
  float* out = (zz < 2) ? rvec2 + (long)zz * N : cvec2 + (long)(zz - 2) * N;
  const int wv = threadIdx.x >> 6, lane = threadIdx.x & 63;
  const int n = blockIdx.x * 4 + wv;
  float acc = 0.f;
  for (int d = lane; d < C; d += 64) acc += (float)X[(long)n * C + d] * u[d];
  acc = wredSum(acc);
  if (lane == 0) out[n] = acc;
}

__global__ __launch_bounds__(256) void k_pixvec2(const __bf16* __restrict__ X,
                                                 const float* __restrict__ u1, const float* __restrict__ u2,
                                                 float* __restrict__ out1, float* __restrict__ out2){
  const int z = blockIdx.y;
  const int wv = threadIdx.x >> 6, lane = threadIdx.x & 63;
  const int n = blockIdx.x * 4 + wv;
  float a1 = 0.f, a2 = 0.f;
  for (int d = lane; d < C; d += 64){
    const float xv = (float)X[(long)z * NC + (long)n * C + d];
    a1 = fmaf(xv, u1[d], a1);
    a2 = fmaf(xv, u2[d], a2);
  }
  a1 = wredSum(a1);
  a2 = wredSum(a2);
  if (lane == 0){ out1[(long)z * N + n] = a1; out2[(long)z * N + n] = a2; }
}

// ======================= prep / stats =======================
__global__ __launch_bounds__(256) void k_stats(const float* __restrict__ x, const float* __restrict__ y,
                                               float* __restrict__ meanv, float* __restrict__ invs){
  const int bid = blockIdx.x;
  const int t = bid >> 9, c = bid & 511;
  const float* src = (t < 2 ? x : y) + (long)(t & 1) * CN + (long)c * N;
  const int tid = threadIdx.x;
  float s1 = 0.f, s2 = 0.f;
  for (int i = tid; i < N; i += 256){ float v = src[i]; s1 += v; s2 += v * v; }
  __shared__ float sh1[4], sh2[4];
  s1 = wredSum(s1); s2 = wredSum(s2);
  if ((tid & 63) == 0){ sh1[tid >> 6] = s1; sh2[tid >> 6] = s2; }
  __syncthreads();
  if (tid == 0){
    float m = (sh1[0] + sh1[1] + sh1[2] + sh1[3]) * (1.f / (float)N);
    float ex2 = (sh2[0] + sh2[1] + sh2[2] + sh2[3]) * (1.f / (float)N);
    float var = ex2 - m * m;
    meanv[t * C + c] = m;
    invs[t * C + c] = rsqrtf((var > 0.f ? var : 0.f) + EPSC);
  }
}

__global__ __launch_bounds__(256) void k_prep(const float* __restrict__ src,
                                              const float* __restrict__ meanv, const float* __restrict__ invs, int toff,
                                              __bf16* __restrict__ adH,
                                              __bf16* __restrict__ fcH, __bf16* __restrict__ fcL,
                                              __bf16* __restrict__ ccH, __bf16* __restrict__ ccL,
                                              __bf16* __restrict__ rwH){
  __shared__ float tile[64][65];
  const int z = blockIdx.z;
  const int n0 = blockIdx.x * 64;
  const int c0 = blockIdx.y * 64;
  const int tid = threadIdx.x;
  const int tx = tid & 63, ty = tid >> 6;
  const int tgt = toff + z;
#pragma unroll
  for (int it = 0; it < 16; ++it){
    const int cc = it * 4 + ty;
    const float v = src[(long)z * CN + (long)(c0 + cc) * N + n0 + tx];
    tile[cc][tx] = v;
    const float cen = v - meanv[tgt * C + c0 + cc];
    splitw(cen, ccH, ccL, (long)tgt * CN + (long)(c0 + cc) * N + n0 + tx);
  }
  __syncthreads();
  const float m = meanv[tgt * C + c0 + tx];
  const float r = invs[tgt * C + c0 + tx];
#pragma unroll
  for (int it = 0; it < 16; ++it){
    const int p = it * 4 + ty;
    const float v = tile[tx][p];
    const float cen = v - m;
    const long o = (long)z * NC + (long)(n0 + p) * C + c0 + tx;
    adH[o] = (__bf16)(cen * r);
    splitw(cen, fcH, fcL, (long)tgt * NC + (long)(n0 + p) * C + c0 + tx);
    if (rwH) rwH[o] = (__bf16)v;
  }
}

__global__ __launch_bounds__(256) void k_wcvtall(const float* __restrict__ KsTf, const float* __restrict__ K2tf,
                                                 const float* __restrict__ h_w, const float* __restrict__ ow,
                                                 __bf16* __restrict__ KsTH, __bf16* __restrict__ KsTL,
                                                 __bf16* __restrict__ K2tH, __bf16* __restrict__ hwH,
                                                 __bf16* __restrict__ owH){
  const int zz = blockIdx.y;
  const int i = blockIdx.x * 256 + threadIdx.x;
  if (zz == 0){ splitw(KsTf[i], KsTH, KsTL, i); }
  else if (zz == 1){ K2tH[i] = (__bf16)K2tf[i]; }
  else if (zz == 2){ hwH[i] = (__bf16)h_w[i]; }
  else { owH[i] = (__bf16)ow[i]; }
}

// ======================= power iteration / NS init (2eps*I folded in) =======================
__global__ __launch_bounds__(256) void k_powit(const float* __restrict__ cov,
                                               float* __restrict__ invt, float* __restrict__ invsqt){
  __shared__ float v[C], red[4];
  const int z = blockIdx.x, t = threadIdx.x;
  const float* A = cov + (long)z * CC;
  const int j0 = t, j1 = t + 256;
  v[j0] = 1.f + 0.0003f * (float)j0;
  v[j1] = 1.f + 0.0003f * (float)j1;
  __syncthreads();
  float lam = 1.f;
  for (int it = 0; it < 4; ++it){
    float w0a = 0.f, w0b = 0.f, w1a = 0.f, w1b = 0.f;
#pragma unroll 8
    for (int c = 0; c < C; c += 2){
      const float vc0 = v[c], vc1 = v[c + 1];
      w0a = fmaf(A[(long)c * C + j0], vc0, w0a);
      w1a = fmaf(A[(long)c * C + j1], vc0, w1a);
      w0b = fmaf(A[(long)(c + 1) * C + j0], vc1, w0b);
      w1b = fmaf(A[(long)(c + 1) * C + j1], vc1, w1b);
    }
    const float w0 = w0a + w0b + 2.f * EPSC * v[j0];
    const float w1 = w1a + w1b + 2.f * EPSC * v[j1];
    float s = w0 * w0 + w1 * w1;
    s = wredSum(s);
    if ((t & 63) == 0) red[t >> 6] = s;
    __syncthreads();
    const float nrm = sqrtf(red[0] + red[1] + red[2] + red[3]);
    lam = nrm;
    const float inv = 1.f / nrm;
    v[j0] = w0 * inv;
    v[j1] = w1 * inv;
    __syncthreads();
  }
  if (t == 0){
    const float tt = 1.02f * lam;
    invt[z] = 1.f / tt;
    invsqt[z] = rsqrtf(tt);
  }
}

__global__ __launch_bounds__(256) void k_ns_init(const float* __restrict__ cov, const float* __restrict__ invt,
                                                 __bf16* __restrict__ h, __bf16* __restrict__ l,
                                                 __bf16* __restrict__ cph, __bf16* __restrict__ cpl){
  const int r = blockIdx.x, z = blockIdx.y;
  const long base = (long)z * CC + (long)r * C;
  const float it = invt[z];
  for (int i = threadIdx.x; i < C; i += 256){
    const float cv = cov[base + i] + ((i == r) ? 2.f * EPSC : 0.f);
    const float v = cv * it;
    splitw(v, h, l, base + i);
    splitw(v, cph, cpl, base + i);
    h[4 * CC + base + i] = (__bf16)((i == r) ? 1.f : 0.f);
    l[4 * CC + base + i] = (__bf16)0.f;
  }
}

// ======================= self-path col accumulation (fp16 E, z-paired), row-stat merge fused ==========
// grid (2, 64, 2): 64 rows per block, z = pair member
__global__ __launch_bounds__(256) void k_colaccum(const _Float16* __restrict__ E,
                                                  const float* __restrict__ Pm, const float* __restrict__ Ps,
                                                  float* __restrict__ partials){
  __shared__ float srm[64], srs[64];
  const int z = blockIdx.z;
  const int rb = blockIdx.y;
  const int r0 = rb * 64;
  const int tid = threadIdx.x;
  {
    const int row = r0 + (tid >> 2);
    const int pp = tid & 3;
    float m = -3.4e38f, s = 0.f;
#pragma unroll
    for (int p = pp * 8; p < pp * 8 + 8; ++p){
      const float mp = Pm[(long)(z * 32 + p) * N + row];
      const float sp = Ps[(long)(z * 32 + p) * N + row];
      const float nm = fmaxf(m, mp);
      s = s * __expf(m - nm) + sp * __expf(mp - nm);
      m = nm;
    }
#pragma unroll
    for (int o = 1; o <= 2; o <<= 1){
      const float mo = __shfl_xor(m, o, 64);
      const float so = __shfl_xor(s, o, 64);
      const float nm = fmaxf(m, mo);
      s = s * __expf(m - nm) + so * __expf(mo - nm);
      m = nm;
    }
    if (pp == 0){ srm[tid >> 2] = m; srs[tid >> 2] = 1.f / s; }
  }
  __syncthreads();
  const int j = (blockIdx.x * 256 + tid) * 8;
  float a[8] = {0.f, 0.f, 0.f, 0.f, 0.f, 0.f, 0.f, 0.f};
#pragma unroll 4
  for (int r2 = 0; r2 < 64; ++r2){
    const f16x8 e = *reinterpret_cast<const f16x8*>(E + (long)z * NN + (long)(r0 + r2) * N + j);
    const float rmv = srm[r2], rsv = srs[r2];
#pragma unroll
    for (int k = 0; k < 8; ++k)
      a[k] += __expf((float)e[k] - rmv) * rsv;
  }
  float4 o0 = {a[0], a[1], a[2], a[3]};
  float4 o1 = {a[4], a[5], a[6], a[7]};
  const long pb = (long)z * 64 * N + (long)rb * N + j;
  *reinterpret_cast<float4*>(partials + pb) = o0;
  *reinterpret_cast<float4*>(partials + pb + 4) = o1;
}

// grid (16, 2): final reduce per z
__global__ __launch_bounds__(256) void k_colreduce(const float* __restrict__ partials, float* __restrict__ att){
  const int z = blockIdx.y;
  const int j = blockIdx.x * 256 + threadIdx.x;
  float s = 0.f;
#pragma unroll 8
  for (int p = 0; p < 64; ++p) s += partials[(long)z * 64 * N + (long)p * N + j];
  att[(long)z * N + j] = s * (1.f / (float)N);
}

// ======================= mask (radix select), all 4 selections in one launch =======================
__global__ __launch_bounds__(256) void k_radix(const float* __restrict__ a, float* __restrict__ thr){
  __shared__ unsigned int vals[N];
  __shared__ float shc[4];
  __shared__ unsigned int p_sh;
  __shared__ int k_sh;
  const float* pa = a + (long)blockIdx.x * N;
  const int tid = threadIdx.x;
  for (int i = tid; i < N; i += 256) vals[i] = __float_as_uint(pa[i]);
  if (tid == 0){ p_sh = 0u; k_sh = KSEL; }
  __syncthreads();
  for (int b = 31; b >= 0; --b){
    const unsigned int bit = 1u << b;
    const unsigned int above = (b == 31) ? 0u : ~((bit << 1) - 1u);
    const unsigned int p = p_sh;
    int cnt = 0;
    for (int i = tid; i < N; i += 256){
      unsigned int v = vals[i];
      if ((v & above) == p && (v & bit)) cnt++;
    }
    float cf = wredSum((float)cnt);
    if ((tid & 63) == 0) shc[tid >> 6] = cf;
    __syncthreads();
    if (tid == 0){
      int c1 = (int)(shc[0] + shc[1] + shc[2] + shc[3] + 0.5f);
      if (k_sh <= c1) p_sh = p | bit;
      else k_sh -= c1;
    }
    __syncthreads();
  }
  if (tid == 0) thr[blockIdx.x] = __uint_as_float(p_sh);
}

__global__ __launch_bounds__(256) void k_mask(const float* __restrict__ ax, const float* __restrict__ ay,
                                              const float* __restrict__ thr, float* __restrict__ mx,
                                              float* __restrict__ my){
  int j = blockIdx.x * 256 + threadIdx.x;
  mx[j] = (ax[j] >= thr[0] && ax[N + j] >= thr[1]) ? 1.f : 0.f;
  my[j] = (ay[j] >= thr[2] && ay[N + j] >= thr[3]) ? 1.f : 0.f;
}

// ======================= host =======================
extern "C" void kernel_launch(void* const* d_in, const int* in_sizes, int n_in,
                              void* d_out, int out_size, void* d_ws, size_t ws_size,
                              hipStream_t stream)
{
  const float* x     = (const float*)d_in[0];
  const float* y     = (const float*)d_in[1];
  const float* f_w   = (const float*)d_in[2];
  const float* f_b   = (const float*)d_in[3];
  const float* g_w   = (const float*)d_in[4];
  const float* g_b   = (const float*)d_in[5];
  const float* saf_w = (const float*)d_in[6];
  const float* saf_b = (const float*)d_in[7];
  const float* sag_w = (const float*)d_in[8];
  const float* sag_b = (const float*)d_in[9];
  const float* h_w   = (const float*)d_in[10];
  const float* h_b   = (const float*)d_in[11];
  const float* ow    = (const float*)d_in[12];
  const float* ob    = (const float*)d_in[13];

  const size_t MBy = 1ull << 20;
  const size_t KBy = 1ull << 10;
  char* base = (char*)d_ws;
  if (ws_size < 206 * MBy) return;
  auto F  = [&](size_t off){ return (float*)(base + off); };
  auto Bp = [&](size_t off){ return (__bf16*)(base + off); };

  __bf16 *Ebf = Bp(0);                               // main: [2][N][N] bf16 ; self: [2][N][N] fp16 via cast
  _Float16 *E16 = (_Float16*)base;
  __bf16 *ccH = Bp(0), *ccL = Bp(16*MBy);
  float  *covb = F(32*MBy);
  __bf16 *zpolH = Bp(36*MBy), *zpolL = Bp(38*MBy);
  __bf16 *covPH = Bp(40*MBy), *covPL = Bp(42*MBy);
  float  *KsTf = F(44*MBy), *K2tf = F(45*MBy);
  __bf16 *KsTH = Bp(46*MBy), *KsTL = Bp(46*MBy + 512*KBy);
  __bf16 *K2tH = Bp(47*MBy), *hwH = Bp(47*MBy + 512*KBy);
  __bf16 *tpH = Bp(48*MBy), *tpL = Bp(50*MBy);
  __bf16 *xaH = Bp(64*MBy);
  __bf16 *xzH = Bp(64*MBy), *xzL = Bp(80*MBy);
  __bf16 *ypmH = Bp(96*MBy);
  __bf16 *AsH = Bp(96*MBy), *AsL = Bp(112*MBy);
  __bf16 *fcH = Bp(128*MBy), *fcL = Bp(144*MBy);
  __bf16 *resH = Bp(128*MBy);
  __bf16 *nsAh = Bp(160*MBy), *nsAl = Bp(164*MBy);
  __bf16 *nsBh = Bp(168*MBy), *nsBl = Bp(172*MBy);
  __bf16 *A2H = Bp(176*MBy);
  __bf16 *yaH = Bp(184*MBy);
  __bf16 *hH  = Bp(192*MBy);
  __bf16 *owH = Bp(200*MBy);
  size_t so = 200 * MBy + 512 * KBy;
  auto SF = [&](size_t bytes){ float* p = F(so); so += bytes; return p; };
  float *meanv = SF(8*KBy), *invs = SF(8*KBy);
  float *mxv = SF(16*KBy), *myv = SF(16*KBy);
  float *rvec2 = SF(32*KBy), *cvec2 = SF(32*KBy);
  float *rvS = SF(64*KBy), *cvS = SF(64*KBy);
  float *u1m = SF(2*KBy), *u2m = SF(2*KBy), *u1s = SF(2*KBy), *u2s = SF(2*KBy);
  float *c0m2 = SF(64), *c0s4 = SF(64), *thr = SF(64);
  float *invt = SF(64), *invsqt = SF(64);
  float *partials = F(201*MBy);                      // [2][64][N] = 2MB
  float *Pm = F(203*MBy);                            // [64][N]
  float *Ps = F(204*MBy);                            // [64][N]
  float *Pq = F(205*MBy);                            // [64][N]

  float* outm = (float*)d_out;
  float* attx = outm + B2 * CN;
  float* atty = attx + (long)B2 * N;

  // 1) stats + prep
  k_stats<<<dim3(4 * C), dim3(256), 0, stream>>>(x, y, meanv, invs);
  k_prep<<<dim3(64, 8, 2), dim3(256), 0, stream>>>(x, meanv, invs, 0, xaH, fcH, fcL, ccH, ccL, nullptr);
  k_prep<<<dim3(64, 8, 2), dim3(256), 0, stream>>>(y, meanv, invs, 2, yaH, fcH, fcL, ccH, ccL, ypmH);

  // 2) weight products & conversions (merged launches)
  k_wtw2<<<dim3(16, 16, 2), dim3(256), 0, stream>>>(sag_w, saf_w, g_w, f_w, KsTf, K2tf);
  k_wcvtall<<<dim3((int)(CC / 256), 4), dim3(256), 0, stream>>>(KsTf, K2tf, h_w, ow,
      KsTH, KsTL, K2tH, hwH, owH);
  k_wtv4<<<dim3(2, 4), dim3(256), 0, stream>>>(g_w, f_b, f_w, g_b, sag_w, saf_b, saf_w, sag_b,
      u1m, u2m, u1s, u2s);
  k_dot2<<<dim3(1), dim3(256), 0, stream>>>(f_b, g_b, saf_b, sag_b, c0m2, c0s4);
  k_pixvecm<<<dim3(N / 4, 4), dim3(256), 0, stream>>>(xaH, yaH, u2m, u1m, rvec2, cvec2);

  // 3) cov (2eps*I folded downstream) + power-iteration lambda_max
  k_mm64<0,0,0><<<dim3(8, 8, 4), dim3(256), 0, stream>>>(
      ccH, ccL, ccH, ccL, nullptr, nullptr, covb, nullptr, nullptr, C, N, CN, CN, CC, 1.f / (float)(N - 1));
  k_powit<<<dim3(4), dim3(256), 0, stream>>>(covb, invt, invsqt);

  // 4) A2 = xa . K2^T, h conv
  k_mm<1,0,2,0><<<dim3(32, 4, 2), dim3(256), 0, stream>>>(xaH, nullptr, K2tH, nullptr, nullptr, A2H, nullptr,
      C, C, NC, 0, NC, 1.f, nullptr, nullptr, 0, nullptr, 0, nullptr, nullptr, 0,
      nullptr, nullptr, nullptr, nullptr, nullptr);
  k_mm<1,0,2,0><<<dim3(4, 32, 2), dim3(256), 0, stream>>>(hwH, nullptr, ypmH, nullptr, nullptr, hH, nullptr,
      N, C, 0, NC, CN, 1.f, nullptr, h_b, 0, nullptr, 0, nullptr, nullptr, 0,
      nullptr, nullptr, nullptr, nullptr, nullptr);

  // 5) Newton-Schulz (4 iters; last iter Z-only) + split-bf16 polish
  k_ns_init<<<dim3(C, 4), dim3(256), 0, stream>>>(covb, invt, nsAh, nsAl, covPH, covPL);
  __bf16 *cah = nsAh, *cal = nsAl, *cbh = nsBh, *cbl = nsBl;
  for (int it = 0; it < NS_ITERS; ++it){
    k_mm64<1,1,0><<<dim3(8, 8, 4), dim3(256), 0, stream>>>(
        cah + 4*CC, cal + 4*CC, cah, cal, nullptr, nullptr, nullptr, tpH, tpL, C, C, CC, CC, CC, 1.f);
    if (it < NS_ITERS - 1){
      k_mm64<0,1,1><<<dim3(8, 8, 8), dim3(256), 0, stream>>>(
          cah, cal, nullptr, nullptr, tpH, tpL, nullptr, cbh, cbl, C, C, CC, CC, CC, 1.f);
    } else {
      k_mm64<0,1,2><<<dim3(8, 8, 4), dim3(256), 0, stream>>>(
          cah, cal, nullptr, nullptr, tpH, tpL, nullptr, cbh, cbl, C, C, CC, CC, CC, 1.f);
    }
    __bf16* t;
    t = cah; cah = cbh; cbh = t;
    t = cal; cal = cbl; cbl = t;
  }
  k_mm64<0,1,0><<<dim3(8, 8, 4), dim3(256), 0, stream>>>(
      cah + 4*CC, cal + 4*CC, cah + 4*CC, cal + 4*CC, nullptr, nullptr, nullptr, tpH, tpL, C, C, CC, CC, CC, 1.f);
  k_mm64<1,1,0><<<dim3(8, 8, 4), dim3(256), 0, stream>>>(
      covPH, covPL, tpH, tpL, nullptr, nullptr, nullptr, cbh, cbl, C, C, CC, CC, CC, 1.f);
  k_mm64<0,1,0><<<dim3(8, 8, 4), dim3(256), 0, stream>>>(
      cah + 4*CC, cal + 4*CC, cbh, cbl, nullptr, nullptr, nullptr, zpolH, zpolL, C, C, CC, CC, CC, 1.f);

  // 6) zca apply: xz = invsqt * fc . Z
  k_mm<3,0,1,0><<<dim3(32, 4, 4), dim3(256), 0, stream>>>(fcH, fcL, zpolH, zpolL, nullptr, xzH, xzL,
      C, C, NC, CC, NC, 1.f, invsqt, nullptr, 0, nullptr, 0, nullptr, nullptr, 0,
      nullptr, nullptr, nullptr, nullptr, nullptr);

  // 6.5) self bias vecs (one pass) + As = xz . Ks^T
  k_pixvec2<<<dim3(N / 4, 4), dim3(256), 0, stream>>>(xzH, u2s, u1s, rvS, cvS);
  k_mm<3,0,1,0><<<dim3(32, 4, 4), dim3(256), 0, stream>>>(xzH, xzL, KsTH, KsTL, nullptr, AsH, AsL,
      C, C, NC, 0, NC, 1.f, nullptr, nullptr, 0, nullptr, 0, nullptr, nullptr, 0,
      nullptr, nullptr, nullptr, nullptr, nullptr);

  // 7) self-attention energies, z-PAIRED (3-pass, fp16 E [2][N][N], fused row-stats)
  for (int pr = 0; pr < 2; ++pr){
    k_mm<3,0,4,1><<<dim3(32, 32, 2), dim3(256), 0, stream>>>(
        AsH + (long)pr*2*NC, AsL + (long)pr*2*NC,
        xzH + (long)pr*2*NC, xzL + (long)pr*2*NC, nullptr, Ebf, nullptr,
        N, C, NC, NC, NN, 1.f, nullptr,
        rvS + (long)pr*2*N, N, cvS + (long)pr*2*N, N, c0s4 + pr*2, nullptr, 0,
        Pm, Ps, nullptr, nullptr, nullptr);
    k_colaccum<<<dim3(2, 64, 2), dim3(256), 0, stream>>>(E16, Pm, Ps, partials);
    k_colreduce<<<dim3(16, 2), dim3(256), 0, stream>>>(partials, pr == 0 ? attx : atty);
  }

  // 8) masks (single radix launch over the 4 contiguous atten arrays)
  k_radix<<<dim3(4), dim3(256), 0, stream>>>(attx, thr);
  k_mask<<<dim3(16), dim3(256), 0, stream>>>(attx, atty, thr, mxv, myv);

  // 9) main path: energy -> bf16 E with fused masked row-stats; PV (merges stats in-kernel); out conv
  k_mm<1,0,2,2><<<dim3(32, 32, 2), dim3(256), 0, stream>>>(A2H, nullptr, yaH, nullptr, nullptr, Ebf, nullptr,
      N, C, NC, NC, NN, 1.f, nullptr, rvec2, N, cvec2, N, c0m2, nullptr, 0,
      Pm, Ps, Pq, mxv, myv);
  k_pv<<<dim3(64, 4, 2), dim3(256), 0, stream>>>(Ebf, hH, Pm, Ps, Pq, mxv, myv, resH);
  k_mm<1,0,0,0><<<dim3(4, 32, 2), dim3(256), 0, stream>>>(owH, nullptr, resH, nullptr, outm, nullptr, nullptr,
      N, C, 0, NC, CN, 1.f, nullptr, ob, 0, nullptr, 0, nullptr, x, CN,
      nullptr, nullptr, nullptr, nullptr, nullptr);
}

// Round 18
// 1075.994 us; speedup vs baseline: 1.3200x; 1.0023x over previous
//
#include <hip/hip_runtime.h>
#include <cstdint>

static constexpr int B2 = 2;
static constexpr int C = 512;
static constexpr int N = 4096;
static constexpr long CN = (long)C * N;
static constexpr long NC = (long)N * C;
static constexpr long CC = (long)C * C;
static constexpr long NN = (long)N * N;
static constexpr float EPSC = 1e-5f;
static constexpr int KSEL = 308;       // N - int(N*0.925)
static constexpr int NS_ITERS = 4;

typedef __attribute__((ext_vector_type(8))) __bf16 bf16x8;
typedef __attribute__((ext_vector_type(8))) _Float16 f16x8;
typedef __attribute__((ext_vector_type(4))) _Float16 f16x4;
typedef __attribute__((ext_vector_type(4))) float f32x4;

__device__ __forceinline__ float wredSum(float v){
#pragma unroll
  for (int o = 32; o >= 1; o >>= 1) v += __shfl_xor(v, o, 64);
  return v;
}

__device__ __forceinline__ void gld16(const __bf16* g, __bf16* l){
  __builtin_amdgcn_global_load_lds(
      (const __attribute__((address_space(1))) void*)g,
      (__attribute__((address_space(3))) void*)l, 16, 0, 0);
}

__device__ __forceinline__ void splitw(float v, __bf16* ph, __bf16* pl, long o){
  __bf16 h = (__bf16)v;
  ph[o] = h;
  pl[o] = (__bf16)(v - (float)h);
}

// ======================= split/plain bf16 MFMA GEMM, 128x128 tile, BK=32 =======================
// XCD swizzle. ROWP: 0 none | 1 row softmax partials | 2 masked (mxp/myp, writes Pq)
// OUTMODE: 0 fp32 | 1 bf16 pair | 2 bf16 high | 4 fp16 (Coh reinterpreted)
template<int PASSES, int TMH, int OUTMODE, int ROWP>
__global__ __launch_bounds__(256) void k_mm(
    const __bf16* __restrict__ Ah, const __bf16* __restrict__ Al,
    const __bf16* __restrict__ Bh, const __bf16* __restrict__ Bl,
    float* __restrict__ Cf, __bf16* __restrict__ Coh, __bf16* __restrict__ Col,
    int Nn, int K, long sAz, long sBz, long sCz,
    float alpha, const float* __restrict__ alpha_ptr,
    const float* __restrict__ brow, long sBr,
    const float* __restrict__ bcol, long sBc,
    const float* __restrict__ c0p,
    const float* __restrict__ addsrc, long sAddz,
    float* __restrict__ Pm, float* __restrict__ Ps, float* __restrict__ Pq,
    const float* __restrict__ mxp, const float* __restrict__ myp)
{
  constexpr int NB = (PASSES == 3) ? 4 : 2;
  constexpr int SB = (PASSES == 3) ? 2 : 1;
  __shared__ __align__(16) __bf16 sm[NB][128 * 32];
  __shared__ float pmx[2][128], psx[2][128], pqx[2][128];
  const int z = blockIdx.z;
  const int nwx = gridDim.x;
  int lin = blockIdx.y * nwx + blockIdx.x;
  const int nwg = nwx * gridDim.y;
  if ((nwg & 7) == 0){
    const int cpx = nwg >> 3;
    lin = (lin & 7) * cpx + (lin >> 3);
  }
  const int i0 = (lin % nwx) * 128;
  const int j0 = (lin / nwx) * 128;
  const int tid = threadIdx.x;
  const int lane = tid & 63;
  const int w = tid >> 6;
  const int wr = (w >> 1) * 64, wc = (w & 1) * 64;
  const int lr = lane & 15;
  const int g = lane >> 4;

  const __bf16* pAh = Ah + (long)z * sAz + (long)i0 * K;
  const __bf16* pBh = Bh + (long)z * sBz + (long)j0 * K;
  const __bf16* pAl = (PASSES == 3) ? (Al + (long)z * sAz + (long)i0 * K) : nullptr;
  const __bf16* pBl = (PASSES == 3) ? (Bl + (long)z * sBz + (long)j0 * K) : nullptr;

  f32x4 acc[4][4] = {};

  for (int kt = 0; kt < K; kt += 32){
#pragma unroll
    for (int p = 0; p < 2; ++p){
      const int t2 = p * 256 + tid;
      const int row = t2 >> 2;
      const int gs = (t2 & 3) ^ ((row >> 1) & 3);
      const long go = (long)row * K + kt + gs * 8;
      gld16(pAh + go, &sm[0][t2 * 8]);
      gld16(pBh + go, &sm[SB][t2 * 8]);
      if constexpr (PASSES == 3){
        gld16(pAl + go, &sm[1][t2 * 8]);
        gld16(pBl + go, &sm[3][t2 * 8]);
      }
    }
    __syncthreads();
    bf16x8 fa[4], fal[4], fb[4], fbl[4];
#pragma unroll
    for (int mi = 0; mi < 4; ++mi){
      const int row = wr + mi * 16 + lr;
      const int off = row * 32 + ((g ^ ((row >> 1) & 3)) * 8);
      fa[mi] = *(const bf16x8*)(&sm[0][off]);
      if constexpr (PASSES == 3) fal[mi] = *(const bf16x8*)(&sm[1][off]);
    }
#pragma unroll
    for (int ni = 0; ni < 4; ++ni){
      const int row = wc + ni * 16 + lr;
      const int off = row * 32 + ((g ^ ((row >> 1) & 3)) * 8);
      fb[ni] = *(const bf16x8*)(&sm[SB][off]);
      if constexpr (PASSES == 3) fbl[ni] = *(const bf16x8*)(&sm[3][off]);
    }
#pragma unroll
    for (int mi = 0; mi < 4; ++mi)
#pragma unroll
      for (int ni = 0; ni < 4; ++ni){
        acc[mi][ni] = __builtin_amdgcn_mfma_f32_16x16x32_bf16(fa[mi], fb[ni], acc[mi][ni], 0, 0, 0);
        if constexpr (PASSES == 3){
          acc[mi][ni] = __builtin_amdgcn_mfma_f32_16x16x32_bf16(fa[mi],  fbl[ni], acc[mi][ni], 0, 0, 0);
          acc[mi][ni] = __builtin_amdgcn_mfma_f32_16x16x32_bf16(fal[mi], fb[ni],  acc[mi][ni], 0, 0, 0);
        }
      }
    __syncthreads();
  }

  float al2 = alpha;
  if (alpha_ptr) al2 *= alpha_ptr[z];
  const float c0v = c0p ? c0p[z] : 0.f;
#pragma unroll
  for (int mi = 0; mi < 4; ++mi){
    float vv[4][4];
    float mrow[4] = {-3.4e38f, -3.4e38f, -3.4e38f, -3.4e38f};
#pragma unroll
    for (int ni = 0; ni < 4; ++ni){
      const int col = j0 + wc + ni * 16 + lr;
      const float bc = (bcol ? bcol[z * sBc + col] : 0.f) + c0v;
#pragma unroll
      for (int j = 0; j < 4; ++j){
        const int row = i0 + wr + mi * 16 + g * 4 + j;
        float v = acc[mi][ni][j] * al2;
        if (TMH) v = (((row == col) ? 3.f : 0.f) - v) * 0.5f;
        if (brow) v += brow[z * sBr + row];
        v += bc;
        if (addsrc) v += addsrc[(long)z * sAddz + (long)row * Nn + col];
        const long o = (long)z * sCz + (long)row * Nn + col;
        if (OUTMODE == 0){ Cf[o] = v; }
        else if (OUTMODE == 1){ __bf16 h = (__bf16)v; Coh[o] = h; Col[o] = (__bf16)(v - (float)h); }
        else if (OUTMODE == 2){ __bf16 h = (__bf16)v; Coh[o] = h; if (ROWP == 2) v = (float)h; }
        else { _Float16 hf = (_Float16)v; ((_Float16*)Coh)[o] = hf; if (ROWP >= 1) v = (float)hf; }
        if constexpr (ROWP >= 1){
          vv[ni][j] = v;
          mrow[j] = fmaxf(mrow[j], v);
        }
      }
    }
    if constexpr (ROWP >= 1){
#pragma unroll
      for (int j = 0; j < 4; ++j)
#pragma unroll
        for (int o = 1; o <= 8; o <<= 1)
          mrow[j] = fmaxf(mrow[j], __shfl_xor(mrow[j], o, 64));
      float tgt[4];
      if constexpr (ROWP == 2){
#pragma unroll
        for (int j = 0; j < 4; ++j)
          tgt[j] = mxp[i0 + wr + mi * 16 + g * 4 + j];
      }
      float srow[4] = {0.f, 0.f, 0.f, 0.f};
      float qrow[4] = {0.f, 0.f, 0.f, 0.f};
#pragma unroll
      for (int ni = 0; ni < 4; ++ni){
        const float mycol = (ROWP == 2) ? myp[j0 + wc + ni * 16 + lr] : 0.f;
#pragma unroll
        for (int j = 0; j < 4; ++j){
          const float ev = __expf(vv[ni][j] - mrow[j]);
          srow[j] += ev;
          if constexpr (ROWP == 2){
            if (mycol == tgt[j]) qrow[j] += ev;
          }
        }
      }
#pragma unroll
      for (int j = 0; j < 4; ++j){
#pragma unroll
        for (int o = 1; o <= 8; o <<= 1){
          srow[j] += __shfl_xor(srow[j], o, 64);
          if constexpr (ROWP == 2) qrow[j] += __shfl_xor(qrow[j], o, 64);
        }
        if (lr == 0){
          const int rl = wr + mi * 16 + g * 4 + j;
          pmx[w & 1][rl] = mrow[j];
          psx[w & 1][rl] = srow[j];
          if constexpr (ROWP == 2) pqx[w & 1][rl] = qrow[j];
        }
      }
    }
  }
  if constexpr (ROWP >= 1){
    __syncthreads();
    if (tid < 128){
      const float m0 = pmx[0][tid], s0 = psx[0][tid];
      const float m1 = pmx[1][tid], s1 = psx[1][tid];
      const float nm = fmaxf(m0, m1);
      const float c0_ = __expf(m0 - nm), c1_ = __expf(m1 - nm);
      const float s = s0 * c0_ + s1 * c1_;
      const long po = (long)(z * 32 + (j0 >> 7)) * N + i0 + tid;
      Pm[po] = nm;
      Ps[po] = s;
      if constexpr (ROWP == 2){
        Pq[po] = pqx[0][tid] * c0_ + pqx[1][tid] * c1_;
      }
    }
  }
}

// ======================= split-bf16 MFMA GEMM, 64x64 tile, BK=64 (always 3-pass) =======================
template<int TMH, int OUTMODE, int NSYZ>
__global__ __launch_bounds__(256) void k_mm64(
    const __bf16* __restrict__ Ah, const __bf16* __restrict__ Al,
    const __bf16* __restrict__ Bh, const __bf16* __restrict__ Bl,
    const __bf16* __restrict__ tH, const __bf16* __restrict__ tL,
    float* __restrict__ Cf, __bf16* __restrict__ Coh, __bf16* __restrict__ Col,
    int Nn, int K, long sAz, long sBz, long sCz, float alpha)
{
  __shared__ __align__(16) __bf16 sm[4][64 * 64];
  const int z = blockIdx.z;
  const __bf16 *bAh, *bAl, *bBh, *bBl;
  long oC;
  if constexpr (NSYZ == 1){
    if (z < 4){
      bAh = Ah + (long)z * CC; bAl = Al + (long)z * CC;
      bBh = tH + (long)z * CC; bBl = tL + (long)z * CC;
      oC = (long)z * CC;
    } else {
      const int zz = z - 4;
      bAh = tH + (long)zz * CC; bAl = tL + (long)zz * CC;
      bBh = Ah + (long)(4 + zz) * CC; bBl = Al + (long)(4 + zz) * CC;
      oC = (long)(4 + zz) * CC;
    }
  } else if constexpr (NSYZ == 2){
    bAh = tH + (long)z * CC; bAl = tL + (long)z * CC;
    bBh = Ah + (long)(4 + z) * CC; bBl = Al + (long)(4 + z) * CC;
    oC = (long)(4 + z) * CC;
  } else {
    bAh = Ah + (long)z * sAz; bAl = Al + (long)z * sAz;
    bBh = Bh + (long)z * sBz; bBl = Bl + (long)z * sBz;
    oC = (long)z * sCz;
  }
  const int i0 = blockIdx.x * 64;
  const int j0 = blockIdx.y * 64;
  const int tid = threadIdx.x;
  const int lane = tid & 63;
  const int w = tid >> 6;
  const int wr = (w >> 1) * 32, wc = (w & 1) * 32;
  const int lr = lane & 15;
  const int g = lane >> 4;

  const __bf16* pAh = bAh + (long)i0 * K;
  const __bf16* pAl = bAl + (long)i0 * K;
  const __bf16* pBh = bBh + (long)j0 * K;
  const __bf16* pBl = bBl + (long)j0 * K;

  f32x4 acc[2][2] = {};

  for (int kt = 0; kt < K; kt += 64){
#pragma unroll
    for (int p = 0; p < 2; ++p){
      const int t2 = p * 256 + tid;
      const int row = t2 >> 3;
      const int gs = (t2 & 7) ^ (row & 7);
      const long go = (long)row * K + kt + gs * 8;
      gld16(pAh + go, &sm[0][t2 * 8]);
      gld16(pAl + go, &sm[1][t2 * 8]);
      gld16(pBh + go, &sm[2][t2 * 8]);
      gld16(pBl + go, &sm[3][t2 * 8]);
    }
    __syncthreads();
#pragma unroll
    for (int ks = 0; ks < 2; ++ks){
      bf16x8 fa[2], fal[2], fb[2], fbl[2];
#pragma unroll
      for (int mi = 0; mi < 2; ++mi){
        const int row = wr + mi * 16 + lr;
        const int off = row * 64 + (((ks * 4 + g) ^ (row & 7)) * 8);
        fa[mi]  = *(const bf16x8*)(&sm[0][off]);
        fal[mi] = *(const bf16x8*)(&sm[1][off]);
      }
#pragma unroll
      for (int ni = 0; ni < 2; ++ni){
        const int row = wc + ni * 16 + lr;
        const int off = row * 64 + (((ks * 4 + g) ^ (row & 7)) * 8);
        fb[ni]  = *(const bf16x8*)(&sm[2][off]);
        fbl[ni] = *(const bf16x8*)(&sm[3][off]);
      }
#pragma unroll
      for (int mi = 0; mi < 2; ++mi)
#pragma unroll
        for (int ni = 0; ni < 2; ++ni){
          acc[mi][ni] = __builtin_amdgcn_mfma_f32_16x16x32_bf16(fa[mi],  fb[ni],  acc[mi][ni], 0, 0, 0);
          acc[mi][ni] = __builtin_amdgcn_mfma_f32_16x16x32_bf16(fa[mi],  fbl[ni], acc[mi][ni], 0, 0, 0);
          acc[mi][ni] = __builtin_amdgcn_mfma_f32_16x16x32_bf16(fal[mi], fb[ni],  acc[mi][ni], 0, 0, 0);
        }
    }
    __syncthreads();
  }

#pragma unroll
  for (int mi = 0; mi < 2; ++mi){
#pragma unroll
    for (int ni = 0; ni < 2; ++ni){
      const int col = j0 + wc + ni * 16 + lr;
#pragma unroll
      for (int j = 0; j < 4; ++j){
        const int row = i0 + wr + mi * 16 + g * 4 + j;
        float v = acc[mi][ni][j] * alpha;
        if (TMH) v = (((row == col) ? 3.f : 0.f) - v) * 0.5f;
        const long o = oC + (long)row * Nn + col;
        if (OUTMODE == 0){ Cf[o] = v; }
        else { __bf16 h = (__bf16)v; Coh[o] = h; Col[o] = (__bf16)(v - (float)h); }
      }
    }
  }
}

// ======================= fused corr+PV (bf16 E), K-step 64, row-stat merge fused =======================
__global__ __launch_bounds__(256) void k_pv(
    const __bf16* __restrict__ E, const __bf16* __restrict__ Bh,
    const float* __restrict__ Pm, const float* __restrict__ Ps, const float* __restrict__ Pq,
    const float* __restrict__ mxv, const float* __restrict__ myv,
    __bf16* __restrict__ resH)
{
  __shared__ __align__(16) __bf16 sa[64 * 64];
  __shared__ __align__(16) __bf16 sb[128 * 64];
  __shared__ float srm[64], srs[64];
  const int z = blockIdx.z;
  int lin = blockIdx.y * 64 + blockIdx.x;
  lin = (lin & 7) * 32 + (lin >> 3);
  const int n0 = (lin & 63) * 64;
  const int c0 = (lin >> 6) * 128;
  const int tid = threadIdx.x;
  const int lane = tid & 63;
  const int w = tid >> 6;
  const int wr = (w >> 1) * 32, wc = (w & 1) * 64;
  const int lr = lane & 15, g = lane >> 4;

  {
    const int row = n0 + (tid >> 2);
    const int pp = tid & 3;
    float m = -3.4e38f, s = 0.f, q = 0.f;
#pragma unroll
    for (int p = pp * 8; p < pp * 8 + 8; ++p){
      const long idx = (long)(z * 32 + p) * N + row;
      const float mp = Pm[idx], sp = Ps[idx], qp = Pq[idx];
      const float nm = fmaxf(m, mp);
      const float c0_ = __expf(m - nm), c1_ = __expf(mp - nm);
      s = s * c0_ + sp * c1_;
      q = q * c0_ + qp * c1_;
      m = nm;
    }
#pragma unroll
    for (int o = 1; o <= 2; o <<= 1){
      const float mo = __shfl_xor(m, o, 64);
      const float so = __shfl_xor(s, o, 64);
      const float qo = __shfl_xor(q, o, 64);
      const float nm = fmaxf(m, mo);
      const float c0_ = __expf(m - nm), c1_ = __expf(mo - nm);
      s = s * c0_ + so * c1_;
      q = q * c0_ + qo * c1_;
      m = nm;
    }
    if (pp == 0){
      float l1 = q / s;
      if (l1 < 1e-12f) l1 = 1e-12f;
      srm[tid >> 2] = m;
      srs[tid >> 2] = 1.f / (s * l1);
    }
  }
  __syncthreads();

  const __bf16* pe = E + (long)z * NN + (long)n0 * N;
  const __bf16* pB = Bh + (long)z * CN + (long)c0 * N;

  const int ar = tid >> 2;
  const int slot = tid & 3;
  const float rmv = srm[ar];
  const float rsv = srs[ar];
  const float tgt = mxv[n0 + ar];
  const __bf16* per = pe + (long)ar * N;

  f32x4 acc[2][4] = {};

  for (int kt = 0; kt < N; kt += 64){
#pragma unroll
    for (int d = 0; d < 2; ++d){
      const int gd = slot * 2 + d;
      const bf16x8 ev = *(const bf16x8*)(per + kt + gd * 8);
      const float4 m0 = *(const float4*)(myv + kt + gd * 8);
      const float4 m1 = *(const float4*)(myv + kt + gd * 8 + 4);
      bf16x8 pk;
      pk[0] = (__bf16)((m0.x == tgt) ? __expf((float)ev[0] - rmv) * rsv : 0.f);
      pk[1] = (__bf16)((m0.y == tgt) ? __expf((float)ev[1] - rmv) * rsv : 0.f);
      pk[2] = (__bf16)((m0.z == tgt) ? __expf((float)ev[2] - rmv) * rsv : 0.f);
      pk[3] = (__bf16)((m0.w == tgt) ? __expf((float)ev[3] - rmv) * rsv : 0.f);
      pk[4] = (__bf16)((m1.x == tgt) ? __expf((float)ev[4] - rmv) * rsv : 0.f);
      pk[5] = (__bf16)((m1.y == tgt) ? __expf((float)ev[5] - rmv) * rsv : 0.f);
      pk[6] = (__bf16)((m1.z == tgt) ? __expf((float)ev[6] - rmv) * rsv : 0.f);
      pk[7] = (__bf16)((m1.w == tgt) ? __expf((float)ev[7] - rmv) * rsv : 0.f);
      *(bf16x8*)(&sa[ar * 64 + ((gd ^ (ar & 7)) * 8)]) = pk;
    }
#pragma unroll
    for (int p = 0; p < 4; ++p){
      const int t2 = p * 256 + tid;
      const int row = t2 >> 3;
      const int gs = (t2 & 7) ^ (row & 7);
      gld16(pB + (long)row * N + kt + gs * 8, &sb[t2 * 8]);
    }
    __syncthreads();
#pragma unroll
    for (int ks = 0; ks < 2; ++ks){
      bf16x8 fa[2], fb[4];
#pragma unroll
      for (int mi = 0; mi < 2; ++mi){
        const int row = wr + mi * 16 + lr;
        fa[mi] = *(const bf16x8*)(&sa[row * 64 + (((ks * 4 + g) ^ (row & 7)) * 8)]);
      }
#pragma unroll
      for (int ni = 0; ni < 4; ++ni){
        const int row = wc + ni * 16 + lr;
        fb[ni] = *(const bf16x8*)(&sb[row * 64 + (((ks * 4 + g) ^ (row & 7)) * 8)]);
      }
#pragma unroll
      for (int mi = 0; mi < 2; ++mi)
#pragma unroll
        for (int ni = 0; ni < 4; ++ni)
          acc[mi][ni] = __builtin_amdgcn_mfma_f32_16x16x32_bf16(fa[mi], fb[ni], acc[mi][ni], 0, 0, 0);
    }
    __syncthreads();
  }
#pragma unroll
  for (int mi = 0; mi < 2; ++mi)
#pragma unroll
    for (int ni = 0; ni < 4; ++ni){
      const int c = c0 + wc + ni * 16 + lr;
#pragma unroll
      for (int j = 0; j < 4; ++j){
        const int n = n0 + wr + mi * 16 + g * 4 + j;
        resH[(long)z * NC + (long)n * C + c] = (__bf16)acc[mi][ni][j];
      }
    }
}

// ======================= small helpers =======================
__global__ __launch_bounds__(256) void k_wtw2(
    const float* __restrict__ sag_w, const float* __restrict__ saf_w,
    const float* __restrict__ g_w, const float* __restrict__ f_w,
    float* __restrict__ KsTf, float* __restrict__ K2tf)
{
  __shared__ float sa[16][32], sb[16][32];
  const int zz = blockIdx.z;
  const float* A = (zz == 0) ? sag_w : g_w;
  const float* B = (zz == 0) ? saf_w : f_w;
  float* C2 = (zz == 0) ? KsTf : K2tf;
  const int i0 = blockIdx.x * 32, j0 = blockIdx.y * 32;
  const int t = threadIdx.x;
  const int ti = t & 15, tj = t >> 4;
  const int li = t & 31, lc = t >> 5;
  float acc[2][2] = {};
  for (int cb = 0; cb < C; cb += 16){
    sa[lc][li]     = A[(long)(cb + lc) * C + i0 + li];
    sa[lc + 8][li] = A[(long)(cb + lc + 8) * C + i0 + li];
    sb[lc][li]     = B[(long)(cb + lc) * C + j0 + li];
    sb[lc + 8][li] = B[(long)(cb + lc + 8) * C + j0 + li];
    __syncthreads();
#pragma unroll
    for (int c = 0; c < 16; ++c){
      const float a0 = sa[c][ti * 2], a1 = sa[c][ti * 2 + 1];
      const float b0 = sb[c][tj * 2], b1 = sb[c][tj * 2 + 1];
      acc[0][0] = fmaf(a0, b0, acc[0][0]); acc[0][1] = fmaf(a0, b1, acc[0][1]);
      acc[1][0] = fmaf(a1, b0, acc[1][0]); acc[1][1] = fmaf(a1, b1, acc[1][1]);
    }
    __syncthreads();
  }
#pragma unroll
  for (int r = 0; r < 2; ++r)
#pragma unroll
    for (int s = 0; s < 2; ++s)
      C2[(long)(i0 + ti * 2 + r) * C + j0 + tj * 2 + s] = acc[r][s];
}

__global__ __launch_bounds__(256) void k_wtv4(
    const float* __restrict__ g_w, const float* __restrict__ f_b,
    const float* __restrict__ f_w, const float* __restrict__ g_b,
    const float* __restrict__ sag_w, const float* __restrict__ saf_b,
    const float* __restrict__ saf_w, const float* __restrict__ sag_b,
    float* __restrict__ u1m, float* __restrict__ u2m,
    float* __restrict__ u1s, float* __restrict__ u2s)
{
  const int zz = blockIdx.y;
  const float* W; const float* b; float* u;
  if (zz == 0){ W = g_w; b = f_b; u = u1m; }
  else if (zz == 1){ W = f_w; b = g_b; u = u2m; }
  else if (zz == 2){ W = sag_w; b = saf_b; u = u1s; }
  else { W = saf_w; b = sag_b; u = u2s; }
  __shared__ float sb2[C];
  const int t = threadIdx.x;
  sb2[t] = b[t]; sb2[t + 256] = b[t + 256];
  __syncthreads();
  const int e = blockIdx.x * 256 + t;
  float acc = 0.f;
  for (int c = 0; c < C; ++c) acc = fmaf(W[(long)c * C + e], sb2[c], acc);
  u[e] = acc;
}

__global__ void k_dot2(const float* __restrict__ a1, const float* __restrict__ b1,
                       const float* __restrict__ a2, const float* __restrict__ b2,
                       float* __restrict__ c0m2, float* __restrict__ c0s4){
  const int t = threadIdx.x;
  float s1 = 0.f, s2 = 0.f;
  for (int i = t; i < C; i += 256){ s1 += a1[i] * b1[i]; s2 += a2[i] * b2[i]; }
  __shared__ float sh1[4], sh2[4];
  s1 = wredSum(s1); s2 = wredSum(s2);
  if ((t & 63) == 0){ sh1[t >> 6] = s1; sh2[t >> 6] = s2; }
  __syncthreads();
  if (t == 0){
    float d1 = sh1[0] + sh1[1] + sh1[2] + sh1[3];
    float d2 = sh2[0] + sh2[1] + sh2[2] + sh2[3];
    c0m2[0] = d1; c0m2[1] = d1;
    c0s4[0] = d2; c0s4[1] = d2; c0s4[2] = d2; c0s4[3] = d2;
  }
}

__global__ __launch_bounds__(256) void k_pixvecm(const __bf16* __restrict__ xa, const __bf16* __restrict__ ya,
                                                 const float* __restrict__ u2m_, const float* __restrict__ u1m_,
                                                 float* __restrict__ rvec2, float* __restrict__ cvec2){
  const int zz = blockIdx.y;
  const __bf16* X = (zz < 2) ? xa + (long)zz * NC : ya + (long)(zz - 2) * NC;
  const float* u = (zz < 2) ? u2m_ : u1m_;
  float* out = (zz < 2) ? rvec2 + (long)zz * N : cvec2 + (long)(zz - 2) * N;
  const int wv = threadIdx.x >> 6, lane = threadIdx.x & 63;
  const int n = blockIdx.x * 4 + wv;
  float acc = 0.f;
  for (int d = lane; d < C; d += 64) acc += (float)X[(long)n * C + d] * u[d];
  acc = wredSum(acc);
  if (lane == 0) out[n] = acc;
}

__global__ __launch_bounds__(256) void k_pixvec2(const __bf16* __restrict__ X,
                                                 const float* __restrict__ u1, const float* __restrict__ u2,
                                                 float* __restrict__ out1, float* __restrict__ out2){
  const int z = blockIdx.y;
  const int wv = threadIdx.x >> 6, lane = threadIdx.x & 63;
  const int n = blockIdx.x * 4 + wv;
  float a1 = 0.f, a2 = 0.f;
  for (int d = lane; d < C; d += 64){
    const float xv = (float)X[(long)z * NC + (long)n * C + d];
    a1 = fmaf(xv, u1[d], a1);
    a2 = fmaf(xv, u2[d], a2);
  }
  a1 = wredSum(a1);
  a2 = wredSum(a2);
  if (lane == 0){ out1[(long)z * N + n] = a1; out2[(long)z * N + n] = a2; }
}

// ======================= prep / stats (float4 loads) =======================
__global__ __launch_bounds__(256) void k_stats(const float* __restrict__ x, const float* __restrict__ y,
                                               float* __restrict__ meanv, float* __restrict__ invs){
  const int bid = blockIdx.x;
  const int t = bid >> 9, c = bid & 511;
  const float* src = (t < 2 ? x : y) + (long)(t & 1) * CN + (long)c * N;
  const int tid = threadIdx.x;
  float s1 = 0.f, s2 = 0.f;
  for (int i = tid * 4; i < N; i += 1024){
    const float4 v = *reinterpret_cast<const float4*>(src + i);
    s1 += (v.x + v.y) + (v.z + v.w);
    s2 += (v.x * v.x + v.y * v.y) + (v.z * v.z + v.w * v.w);
  }
  __shared__ float sh1[4], sh2[4];
  s1 = wredSum(s1); s2 = wredSum(s2);
  if ((tid & 63) == 0){ sh1[tid >> 6] = s1; sh2[tid >> 6] = s2; }
  __syncthreads();
  if (tid == 0){
    float m = (sh1[0] + sh1[1] + sh1[2] + sh1[3]) * (1.f / (float)N);
    float ex2 = (sh2[0] + sh2[1] + sh2[2] + sh2[3]) * (1.f / (float)N);
    float var = ex2 - m * m;
    meanv[t * C + c] = m;
    invs[t * C + c] = rsqrtf((var > 0.f ? var : 0.f) + EPSC);
  }
}

__global__ __launch_bounds__(256) void k_prep(const float* __restrict__ src,
                                              const float* __restrict__ meanv, const float* __restrict__ invs, int toff,
                                              __bf16* __restrict__ adH,
                                              __bf16* __restrict__ fcH, __bf16* __restrict__ fcL,
                                              __bf16* __restrict__ ccH, __bf16* __restrict__ ccL,
                                              __bf16* __restrict__ rwH){
  __shared__ float tile[64][65];
  const int z = blockIdx.z;
  const int n0 = blockIdx.x * 64;
  const int c0 = blockIdx.y * 64;
  const int tid = threadIdx.x;
  const int tx = tid & 63, ty = tid >> 6;
  const int tgt = toff + z;
#pragma unroll
  for (int it = 0; it < 16; ++it){
    const int cc = it * 4 + ty;
    const float v = src[(long)z * CN + (long)(c0 + cc) * N + n0 + tx];
    tile[cc][tx] = v;
    const float cen = v - meanv[tgt * C + c0 + cc];
    splitw(cen, ccH, ccL, (long)tgt * CN + (long)(c0 + cc) * N + n0 + tx);
  }
  __syncthreads();
  const float m = meanv[tgt * C + c0 + tx];
  const float r = invs[tgt * C + c0 + tx];
#pragma unroll
  for (int it = 0; it < 16; ++it){
    const int p = it * 4 + ty;
    const float v = tile[tx][p];
    const float cen = v - m;
    const long o = (long)z * NC + (long)(n0 + p) * C + c0 + tx;
    adH[o] = (__bf16)(cen * r);
    splitw(cen, fcH, fcL, (long)tgt * NC + (long)(n0 + p) * C + c0 + tx);
    if (rwH) rwH[o] = (__bf16)v;
  }
}

__global__ __launch_bounds__(256) void k_wcvtall(const float* __restrict__ KsTf, const float* __restrict__ K2tf,
                                                 const float* __restrict__ h_w, const float* __restrict__ ow,
                                                 __bf16* __restrict__ KsTH, __bf16* __restrict__ KsTL,
                                                 __bf16* __restrict__ K2tH, __bf16* __restrict__ hwH,
                                                 __bf16* __restrict__ owH){
  const int zz = blockIdx.y;
  const int i = blockIdx.x * 256 + threadIdx.x;
  if (zz == 0){ splitw(KsTf[i], KsTH, KsTL, i); }
  else if (zz == 1){ K2tH[i] = (__bf16)K2tf[i]; }
  else if (zz == 2){ hwH[i] = (__bf16)h_w[i]; }
  else { owH[i] = (__bf16)ow[i]; }
}

// ======================= power iteration / NS init (2eps*I folded in) =======================
__global__ __launch_bounds__(256) void k_powit(const float* __restrict__ cov,
                                               float* __restrict__ invt, float* __restrict__ invsqt){
  __shared__ float v[C], red[4];
  const int z = blockIdx.x, t = threadIdx.x;
  const float* A = cov + (long)z * CC;
  const int j0 = t, j1 = t + 256;
  v[j0] = 1.f + 0.0003f * (float)j0;
  v[j1] = 1.f + 0.0003f * (float)j1;
  __syncthreads();
  float lam = 1.f;
  for (int it = 0; it < 4; ++it){
    float w0a = 0.f, w0b = 0.f, w1a = 0.f, w1b = 0.f;
#pragma unroll 8
    for (int c = 0; c < C; c += 2){
      const float vc0 = v[c], vc1 = v[c + 1];
      w0a = fmaf(A[(long)c * C + j0], vc0, w0a);
      w1a = fmaf(A[(long)c * C + j1], vc0, w1a);
      w0b = fmaf(A[(long)(c + 1) * C + j0], vc1, w0b);
      w1b = fmaf(A[(long)(c + 1) * C + j1], vc1, w1b);
    }
    const float w0 = w0a + w0b + 2.f * EPSC * v[j0];
    const float w1 = w1a + w1b + 2.f * EPSC * v[j1];
    float s = w0 * w0 + w1 * w1;
    s = wredSum(s);
    if ((t & 63) == 0) red[t >> 6] = s;
    __syncthreads();
    const float nrm = sqrtf(red[0] + red[1] + red[2] + red[3]);
    lam = nrm;
    const float inv = 1.f / nrm;
    v[j0] = w0 * inv;
    v[j1] = w1 * inv;
    __syncthreads();
  }
  if (t == 0){
    const float tt = 1.02f * lam;
    invt[z] = 1.f / tt;
    invsqt[z] = rsqrtf(tt);
  }
}

__global__ __launch_bounds__(256) void k_ns_init(const float* __restrict__ cov, const float* __restrict__ invt,
                                                 __bf16* __restrict__ h, __bf16* __restrict__ l,
                                                 __bf16* __restrict__ cph, __bf16* __restrict__ cpl){
  const int r = blockIdx.x, z = blockIdx.y;
  const long base = (long)z * CC + (long)r * C;
  const float it = invt[z];
  for (int i = threadIdx.x; i < C; i += 256){
    const float cv = cov[base + i] + ((i == r) ? 2.f * EPSC : 0.f);
    const float v = cv * it;
    splitw(v, h, l, base + i);
    splitw(v, cph, cpl, base + i);
    h[4 * CC + base + i] = (__bf16)((i == r) ? 1.f : 0.f);
    l[4 * CC + base + i] = (__bf16)0.f;
  }
}

// ======================= self-path col accumulation (fp16 E, z-paired), 4 elems/thread ==========
// grid (4, 64, 2): 64 rows per block, j-split 4 (512 blocks -> 2/CU)
__global__ __launch_bounds__(256) void k_colaccum(const _Float16* __restrict__ E,
                                                  const float* __restrict__ Pm, const float* __restrict__ Ps,
                                                  float* __restrict__ partials){
  __shared__ float srm[64], srs[64];
  const int z = blockIdx.z;
  const int rb = blockIdx.y;
  const int r0 = rb * 64;
  const int tid = threadIdx.x;
  {
    const int row = r0 + (tid >> 2);
    const int pp = tid & 3;
    float m = -3.4e38f, s = 0.f;
#pragma unroll
    for (int p = pp * 8; p < pp * 8 + 8; ++p){
      const float mp = Pm[(long)(z * 32 + p) * N + row];
      const float sp = Ps[(long)(z * 32 + p) * N + row];
      const float nm = fmaxf(m, mp);
      s = s * __expf(m - nm) + sp * __expf(mp - nm);
      m = nm;
    }
#pragma unroll
    for (int o = 1; o <= 2; o <<= 1){
      const float mo = __shfl_xor(m, o, 64);
      const float so = __shfl_xor(s, o, 64);
      const float nm = fmaxf(m, mo);
      s = s * __expf(m - nm) + so * __expf(mo - nm);
      m = nm;
    }
    if (pp == 0){ srm[tid >> 2] = m; srs[tid >> 2] = 1.f / s; }
  }
  __syncthreads();
  const int j = (blockIdx.x * 256 + tid) * 4;
  float a[4] = {0.f, 0.f, 0.f, 0.f};
#pragma unroll 4
  for (int r2 = 0; r2 < 64; ++r2){
    const f16x4 e = *reinterpret_cast<const f16x4*>(E + (long)z * NN + (long)(r0 + r2) * N + j);
    const float rmv = srm[r2], rsv = srs[r2];
#pragma unroll
    for (int k = 0; k < 4; ++k)
      a[k] += __expf((float)e[k] - rmv) * rsv;
  }
  float4 o0 = {a[0], a[1], a[2], a[3]};
  *reinterpret_cast<float4*>(partials + (long)z * 64 * N + (long)rb * N + j) = o0;
}

// grid (16, 2): final reduce per z
__global__ __launch_bounds__(256) void k_colreduce(const float* __restrict__ partials, float* __restrict__ att){
  const int z = blockIdx.y;
  const int j = blockIdx.x * 256 + threadIdx.x;
  float s = 0.f;
#pragma unroll 8
  for (int p = 0; p < 64; ++p) s += partials[(long)z * 64 * N + (long)p * N + j];
  att[(long)z * N + j] = s * (1.f / (float)N);
}

// ======================= mask (radix select), all 4 selections in one launch =======================
__global__ __launch_bounds__(256) void k_radix(const float* __restrict__ a, float* __restrict__ thr){
  __shared__ unsigned int vals[N];
  __shared__ float shc[4];
  __shared__ unsigned int p_sh;
  __shared__ int k_sh;
  const float* pa = a + (long)blockIdx.x * N;
  const int tid = threadIdx.x;
  for (int i = tid; i < N; i += 256) vals[i] = __float_as_uint(pa[i]);
  if (tid == 0){ p_sh = 0u; k_sh = KSEL; }
  __syncthreads();
  for (int b = 31; b >= 0; --b){
    const unsigned int bit = 1u << b;
    const unsigned int above = (b == 31) ? 0u : ~((bit << 1) - 1u);
    const unsigned int p = p_sh;
    int cnt = 0;
    for (int i = tid; i < N; i += 256){
      unsigned int v = vals[i];
      if ((v & above) == p && (v & bit)) cnt++;
    }
    float cf = wredSum((float)cnt);
    if ((tid & 63) == 0) shc[tid >> 6] = cf;
    __syncthreads();
    if (tid == 0){
      int c1 = (int)(shc[0] + shc[1] + shc[2] + shc[3] + 0.5f);
      if (k_sh <= c1) p_sh = p | bit;
      else k_sh -= c1;
    }
    __syncthreads();
  }
  if (tid == 0) thr[blockIdx.x] = __uint_as_float(p_sh);
}

__global__ __launch_bounds__(256) void k_mask(const float* __restrict__ ax, const float* __restrict__ ay,
                                              const float* __restrict__ thr, float* __restrict__ mx,
                                              float* __restrict__ my){
  int j = blockIdx.x * 256 + threadIdx.x;
  mx[j] = (ax[j] >= thr[0] && ax[N + j] >= thr[1]) ? 1.f : 0.f;
  my[j] = (ay[j] >= thr[2] && ay[N + j] >= thr[3]) ? 1.f : 0.f;
}

// ======================= host =======================
extern "C" void kernel_launch(void* const* d_in, const int* in_sizes, int n_in,
                              void* d_out, int out_size, void* d_ws, size_t ws_size,
                              hipStream_t stream)
{
  const float* x     = (const float*)d_in[0];
  const float* y     = (const float*)d_in[1];
  const float* f_w   = (const float*)d_in[2];
  const float* f_b   = (const float*)d_in[3];
  const float* g_w   = (const float*)d_in[4];
  const float* g_b   = (const float*)d_in[5];
  const float* saf_w = (const float*)d_in[6];
  const float* saf_b = (const float*)d_in[7];
  const float* sag_w = (const float*)d_in[8];
  const float* sag_b = (const float*)d_in[9];
  const float* h_w   = (const float*)d_in[10];
  const float* h_b   = (const float*)d_in[11];
  const float* ow    = (const float*)d_in[12];
  const float* ob    = (const float*)d_in[13];

  const size_t MBy = 1ull << 20;
  const size_t KBy = 1ull << 10;
  char* base = (char*)d_ws;
  if (ws_size < 206 * MBy) return;
  auto F  = [&](size_t off){ return (float*)(base + off); };
  auto Bp = [&](size_t off){ return (__bf16*)(base + off); };

  __bf16 *Ebf = Bp(0);                               // main: [2][N][N] bf16 ; self: [2][N][N] fp16 via cast
  _Float16 *E16 = (_Float16*)base;
  __bf16 *ccH = Bp(0), *ccL = Bp(16*MBy);
  float  *covb = F(32*MBy);
  __bf16 *zpolH = Bp(36*MBy), *zpolL = Bp(38*MBy);
  __bf16 *covPH = Bp(40*MBy), *covPL = Bp(42*MBy);
  float  *KsTf = F(44*MBy), *K2tf = F(45*MBy);
  __bf16 *KsTH = Bp(46*MBy), *KsTL = Bp(46*MBy + 512*KBy);
  __bf16 *K2tH = Bp(47*MBy), *hwH = Bp(47*MBy + 512*KBy);
  __bf16 *tpH = Bp(48*MBy), *tpL = Bp(50*MBy);
  __bf16 *xaH = Bp(64*MBy);
  __bf16 *xzH = Bp(64*MBy), *xzL = Bp(80*MBy);
  __bf16 *ypmH = Bp(96*MBy);
  __bf16 *AsH = Bp(96*MBy), *AsL = Bp(112*MBy);
  __bf16 *fcH = Bp(128*MBy), *fcL = Bp(144*MBy);
  __bf16 *resH = Bp(128*MBy);
  __bf16 *nsAh = Bp(160*MBy), *nsAl = Bp(164*MBy);
  __bf16 *nsBh = Bp(168*MBy), *nsBl = Bp(172*MBy);
  __bf16 *A2H = Bp(176*MBy);
  __bf16 *yaH = Bp(184*MBy);
  __bf16 *hH  = Bp(192*MBy);
  __bf16 *owH = Bp(200*MBy);
  size_t so = 200 * MBy + 512 * KBy;
  auto SF = [&](size_t bytes){ float* p = F(so); so += bytes; return p; };
  float *meanv = SF(8*KBy), *invs = SF(8*KBy);
  float *mxv = SF(16*KBy), *myv = SF(16*KBy);
  float *rvec2 = SF(32*KBy), *cvec2 = SF(32*KBy);
  float *rvS = SF(64*KBy), *cvS = SF(64*KBy);
  float *u1m = SF(2*KBy), *u2m = SF(2*KBy), *u1s = SF(2*KBy), *u2s = SF(2*KBy);
  float *c0m2 = SF(64), *c0s4 = SF(64), *thr = SF(64);
  float *invt = SF(64), *invsqt = SF(64);
  float *partials = F(201*MBy);                      // [2][64][N] = 2MB
  float *Pm = F(203*MBy);                            // [64][N]
  float *Ps = F(204*MBy);                            // [64][N]
  float *Pq = F(205*MBy);                            // [64][N]

  float* outm = (float*)d_out;
  float* attx = outm + B2 * CN;
  float* atty = attx + (long)B2 * N;

  // 1) stats + prep
  k_stats<<<dim3(4 * C), dim3(256), 0, stream>>>(x, y, meanv, invs);
  k_prep<<<dim3(64, 8, 2), dim3(256), 0, stream>>>(x, meanv, invs, 0, xaH, fcH, fcL, ccH, ccL, nullptr);
  k_prep<<<dim3(64, 8, 2), dim3(256), 0, stream>>>(y, meanv, invs, 2, yaH, fcH, fcL, ccH, ccL, ypmH);

  // 2) weight products & conversions (merged launches)
  k_wtw2<<<dim3(16, 16, 2), dim3(256), 0, stream>>>(sag_w, saf_w, g_w, f_w, KsTf, K2tf);
  k_wcvtall<<<dim3((int)(CC / 256), 4), dim3(256), 0, stream>>>(KsTf, K2tf, h_w, ow,
      KsTH, KsTL, K2tH, hwH, owH);
  k_wtv4<<<dim3(2, 4), dim3(256), 0, stream>>>(g_w, f_b, f_w, g_b, sag_w, saf_b, saf_w, sag_b,
      u1m, u2m, u1s, u2s);
  k_dot2<<<dim3(1), dim3(256), 0, stream>>>(f_b, g_b, saf_b, sag_b, c0m2, c0s4);
  k_pixvecm<<<dim3(N / 4, 4), dim3(256), 0, stream>>>(xaH, yaH, u2m, u1m, rvec2, cvec2);

  // 3) cov (2eps*I folded downstream) + power-iteration lambda_max
  k_mm64<0,0,0><<<dim3(8, 8, 4), dim3(256), 0, stream>>>(
      ccH, ccL, ccH, ccL, nullptr, nullptr, covb, nullptr, nullptr, C, N, CN, CN, CC, 1.f / (float)(N - 1));
  k_powit<<<dim3(4), dim3(256), 0, stream>>>(covb, invt, invsqt);

  // 4) A2 = xa . K2^T, h conv
  k_mm<1,0,2,0><<<dim3(32, 4, 2), dim3(256), 0, stream>>>(xaH, nullptr, K2tH, nullptr, nullptr, A2H, nullptr,
      C, C, NC, 0, NC, 1.f, nullptr, nullptr, 0, nullptr, 0, nullptr, nullptr, 0,
      nullptr, nullptr, nullptr, nullptr, nullptr);
  k_mm<1,0,2,0><<<dim3(4, 32, 2), dim3(256), 0, stream>>>(hwH, nullptr, ypmH, nullptr, nullptr, hH, nullptr,
      N, C, 0, NC, CN, 1.f, nullptr, h_b, 0, nullptr, 0, nullptr, nullptr, 0,
      nullptr, nullptr, nullptr, nullptr, nullptr);

  // 5) Newton-Schulz (4 iters; last iter Z-only) + split-bf16 polish
  k_ns_init<<<dim3(C, 4), dim3(256), 0, stream>>>(covb, invt, nsAh, nsAl, covPH, covPL);
  __bf16 *cah = nsAh, *cal = nsAl, *cbh = nsBh, *cbl = nsBl;
  for (int it = 0; it < NS_ITERS; ++it){
    k_mm64<1,1,0><<<dim3(8, 8, 4), dim3(256), 0, stream>>>(
        cah + 4*CC, cal + 4*CC, cah, cal, nullptr, nullptr, nullptr, tpH, tpL, C, C, CC, CC, CC, 1.f);
    if (it < NS_ITERS - 1){
      k_mm64<0,1,1><<<dim3(8, 8, 8), dim3(256), 0, stream>>>(
          cah, cal, nullptr, nullptr, tpH, tpL, nullptr, cbh, cbl, C, C, CC, CC, CC, 1.f);
    } else {
      k_mm64<0,1,2><<<dim3(8, 8, 4), dim3(256), 0, stream>>>(
          cah, cal, nullptr, nullptr, tpH, tpL, nullptr, cbh, cbl, C, C, CC, CC, CC, 1.f);
    }
    __bf16* t;
    t = cah; cah = cbh; cbh = t;
    t = cal; cal = cbl; cbl = t;
  }
  k_mm64<0,1,0><<<dim3(8, 8, 4), dim3(256), 0, stream>>>(
      cah + 4*CC, cal + 4*CC, cah + 4*CC, cal + 4*CC, nullptr, nullptr, nullptr, tpH, tpL, C, C, CC, CC, CC, 1.f);
  k_mm64<1,1,0><<<dim3(8, 8, 4), dim3(256), 0, stream>>>(
      covPH, covPL, tpH, tpL, nullptr, nullptr, nullptr, cbh, cbl, C, C, CC, CC, CC, 1.f);
  k_mm64<0,1,0><<<dim3(8, 8, 4), dim3(256), 0, stream>>>(
      cah + 4*CC, cal + 4*CC, cbh, cbl, nullptr, nullptr, nullptr, zpolH, zpolL, C, C, CC, CC, CC, 1.f);

  // 6) zca apply: xz = invsqt * fc . Z
  k_mm<3,0,1,0><<<dim3(32, 4, 4), dim3(256), 0, stream>>>(fcH, fcL, zpolH, zpolL, nullptr, xzH, xzL,
      C, C, NC, CC, NC, 1.f, invsqt, nullptr, 0, nullptr, 0, nullptr, nullptr, 0,
      nullptr, nullptr, nullptr, nullptr, nullptr);

  // 6.5) self bias vecs (one pass) + As = xz . Ks^T
  k_pixvec2<<<dim3(N / 4, 4), dim3(256), 0, stream>>>(xzH, u2s, u1s, rvS, cvS);
  k_mm<3,0,1,0><<<dim3(32, 4, 4), dim3(256), 0, stream>>>(xzH, xzL, KsTH, KsTL, nullptr, AsH, AsL,
      C, C, NC, 0, NC, 1.f, nullptr, nullptr, 0, nullptr, 0, nullptr, nullptr, 0,
      nullptr, nullptr, nullptr, nullptr, nullptr);

  // 7) self-attention energies, z-PAIRED (3-pass, fp16 E [2][N][N], fused row-stats)
  for (int pr = 0; pr < 2; ++pr){
    k_mm<3,0,4,1><<<dim3(32, 32, 2), dim3(256), 0, stream>>>(
        AsH + (long)pr*2*NC, AsL + (long)pr*2*NC,
        xzH + (long)pr*2*NC, xzL + (long)pr*2*NC, nullptr, Ebf, nullptr,
        N, C, NC, NC, NN, 1.f, nullptr,
        rvS + (long)pr*2*N, N, cvS + (long)pr*2*N, N, c0s4 + pr*2, nullptr, 0,
        Pm, Ps, nullptr, nullptr, nullptr);
    k_colaccum<<<dim3(4, 64, 2), dim3(256), 0, stream>>>(E16, Pm, Ps, partials);
    k_colreduce<<<dim3(16, 2), dim3(256), 0, stream>>>(partials, pr == 0 ? attx : atty);
  }

  // 8) masks (single radix launch over the 4 contiguous atten arrays)
  k_radix<<<dim3(4), dim3(256), 0, stream>>>(attx, thr);
  k_mask<<<dim3(16), dim3(256), 0, stream>>>(attx, atty, thr, mxv, myv);

  // 9) main path: energy -> bf16 E with fused masked row-stats; PV (merges stats in-kernel); out conv
  k_mm<1,0,2,2><<<dim3(32, 32, 2), dim3(256), 0, stream>>>(A2H, nullptr, yaH, nullptr, nullptr, Ebf, nullptr,
      N, C, NC, NC, NN, 1.f, nullptr, rvec2, N, cvec2, N, c0m2, nullptr, 0,
      Pm, Ps, Pq, mxv, myv);
  k_pv<<<dim3(64, 4, 2), dim3(256), 0, stream>>>(Ebf, hH, Pm, Ps, Pq, mxv, myv, resH);
  k_mm<1,0,0,0><<<dim3(4, 32, 2), dim3(256), 0, stream>>>(owH, nullptr, resH, nullptr, outm, nullptr, nullptr,
      N, C, 0, NC, CN, 1.f, nullptr, ob, 0, nullptr, 0, nullptr, x, CN,
      nullptr, nullptr, nullptr, nullptr, nullptr);
}